// Round 5
// baseline (1152.565 us; speedup 1.0000x reference)
//
#include <hip/hip_runtime.h>
#include <hip/hip_bf16.h>
#include <math.h>
#include <float.h>
#include <limits.h>

#define T_ROWS 131072   // 32 * 4096 patches

typedef __attribute__((ext_vector_type(8))) short short8;
typedef __attribute__((ext_vector_type(4))) float f32x4;

__device__ __forceinline__ float gelu_f(float x){
    return 0.5f * x * (1.0f + erff(x * 0.7071067811865475f));
}
__device__ __forceinline__ float bf2f(ushort u){
    union { unsigned int i; float f; } v; v.i = ((unsigned int)u) << 16; return v.f;
}
__device__ __forceinline__ ushort f2bf(float f){
    union { float f; unsigned int i; } v; v.f = f;
    unsigned int i = v.i;
    unsigned int r = (i + 0x7fffu + ((i >> 16) & 1u)) >> 16;
    return (ushort)r;
}
// exact 3-way truncation split: x ~= b0+b1+b2 (each bf16), >=24 mantissa bits
__device__ __forceinline__ void split3(float x, ushort &u0, ushort &u1, ushort &u2){
    union { float f; unsigned int i; } v; v.f = x;
    u0 = (ushort)(v.i >> 16);
    union { unsigned int i; float f; } h0; h0.i = ((unsigned int)u0) << 16;
    float r = x - h0.f;                       // exact (Sterbenz)
    union { float f; unsigned int i; } vr; vr.f = r;
    u1 = (ushort)(vr.i >> 16);
    union { unsigned int i; float f; } h1; h1.i = ((unsigned int)u1) << 16;
    float r2 = r - h1.f;                      // exact
    union { float f; unsigned int i; } v2; v2.f = r2;
    u2 = (ushort)(v2.i >> 16);
}

// ---------------------------------------------------------------------------
// f32 tiled GEMM (enc1 only): C[M,256] = gelu(patchify(frames) @ W^T + b)
// ---------------------------------------------------------------------------
template<int K, bool GELU, int LOADER>
__global__ __launch_bounds__(256) void gemm_kernel(
    const float* __restrict__ Ain,
    const float* __restrict__ frames,
    const float* __restrict__ W,
    const float* __restrict__ bias,
    float* __restrict__ Cout)
{
    constexpr int BM=128, BN=128, BK=16;
    __shared__ __align__(16) float As[BK][BM+4];
    __shared__ __align__(16) float Ws[BK][BN+4];

    const int tid = threadIdx.x;
    const int tx = tid & 15, ty = tid >> 4;
    const int m0 = blockIdx.x * BM;
    const int c0 = blockIdx.y * BN;

    const int q  = tid & 3;
    const int r0 = tid >> 2;

    const float* aptr0 = nullptr;
    const float* aptr1 = nullptr;
    int base0 = 0, base1 = 0;
    if constexpr (LOADER == 0){
        aptr0 = Ain + (size_t)(m0 + r0) * K;
        aptr1 = aptr0 + (size_t)64 * K;
    } else {
        int p0 = m0 + r0;
        int b = p0 >> 12, nl = p0 & 4095, hh = nl >> 6, ww = nl & 63;
        base0 = ((b*256 + hh*4)*256 + ww*4)*3;
        int p1 = p0 + 64;
        b = p1 >> 12; nl = p1 & 4095; hh = nl >> 6; ww = nl & 63;
        base1 = ((b*256 + hh*4)*256 + ww*4)*3;
    }
    const float* wptr0 = W + (size_t)(c0 + r0) * K;
    const float* wptr1 = wptr0 + (size_t)64 * K;

    float acc[8][8];
    #pragma unroll
    for (int i=0;i<8;++i)
        #pragma unroll
        for (int j=0;j<8;++j) acc[i][j] = 0.0f;

    for (int k0 = 0; k0 < K; k0 += BK){
        const int k = k0 + q*4;
        float4 va, vb;
        if constexpr (LOADER == 1){
            const int ph = k / 12, rem = k - ph*12;
            va = *(const float4*)(frames + base0 + ph*768 + rem);
            vb = *(const float4*)(frames + base1 + ph*768 + rem);
            const float sc = 2.0f/255.0f;
            va.x = va.x*sc - 1.0f; va.y = va.y*sc - 1.0f;
            va.z = va.z*sc - 1.0f; va.w = va.w*sc - 1.0f;
            vb.x = vb.x*sc - 1.0f; vb.y = vb.y*sc - 1.0f;
            vb.z = vb.z*sc - 1.0f; vb.w = vb.w*sc - 1.0f;
        } else {
            va = *(const float4*)(aptr0 + k);
            vb = *(const float4*)(aptr1 + k);
        }
        As[q*4+0][r0]    = va.x; As[q*4+1][r0]    = va.y;
        As[q*4+2][r0]    = va.z; As[q*4+3][r0]    = va.w;
        As[q*4+0][r0+64] = vb.x; As[q*4+1][r0+64] = vb.y;
        As[q*4+2][r0+64] = vb.z; As[q*4+3][r0+64] = vb.w;

        float4 wa = *(const float4*)(wptr0 + k);
        float4 wb = *(const float4*)(wptr1 + k);
        Ws[q*4+0][r0]    = wa.x; Ws[q*4+1][r0]    = wa.y;
        Ws[q*4+2][r0]    = wa.z; Ws[q*4+3][r0]    = wa.w;
        Ws[q*4+0][r0+64] = wb.x; Ws[q*4+1][r0+64] = wb.y;
        Ws[q*4+2][r0+64] = wb.z; Ws[q*4+3][r0+64] = wb.w;

        __syncthreads();
        #pragma unroll
        for (int kk=0; kk<BK; ++kk){
            float a[8], b[8];
            *(float4*)&a[0] = *(const float4*)&As[kk][ty*4];
            *(float4*)&a[4] = *(const float4*)&As[kk][64+ty*4];
            *(float4*)&b[0] = *(const float4*)&Ws[kk][tx*4];
            *(float4*)&b[4] = *(const float4*)&Ws[kk][64+tx*4];
            #pragma unroll
            for (int i=0;i<8;++i)
                #pragma unroll
                for (int j=0;j<8;++j)
                    acc[i][j] = fmaf(a[i], b[j], acc[i][j]);
        }
        __syncthreads();
    }

    float bj[8];
    *(float4*)&bj[0] = *(const float4*)(bias + c0 + tx*4);
    *(float4*)&bj[4] = *(const float4*)(bias + c0 + 64 + tx*4);
    #pragma unroll
    for (int i=0;i<8;++i){
        const int row = m0 + ((i<4) ? (ty*4+i) : (64+ty*4+i-4));
        float o[8];
        #pragma unroll
        for (int j=0;j<8;++j){
            float x = acc[i][j] + bj[j];
            o[j] = GELU ? gelu_f(x) : x;
        }
        float* dst = Cout + (size_t)row*256 + c0 + tx*4;
        *(float4*)dst      = *(const float4*)&o[0];
        *(float4*)(dst+64) = *(const float4*)&o[4];
    }
}

// ---------------------------------------------------------------------------
// weight prep: 3-way split enc_w2/enc_w3; bf16 round dec_w1/dec_w2
// ---------------------------------------------------------------------------
__global__ __launch_bounds__(256) void wsplit_kernel(
    const float* __restrict__ w2, const float* __restrict__ w3,
    const float* __restrict__ d1, const float* __restrict__ d2,
    ushort* __restrict__ w2s0, ushort* __restrict__ w2s1, ushort* __restrict__ w2s2,
    ushort* __restrict__ w3s0, ushort* __restrict__ w3s1, ushort* __restrict__ w3s2,
    ushort* __restrict__ w1b, ushort* __restrict__ w2b)
{
    const int i = (blockIdx.x*256 + threadIdx.x)*4;
    float4 a = *(const float4*)(w2 + i);
    ushort4 s0, s1, s2;
    split3(a.x, s0.x, s1.x, s2.x); split3(a.y, s0.y, s1.y, s2.y);
    split3(a.z, s0.z, s1.z, s2.z); split3(a.w, s0.w, s1.w, s2.w);
    *(ushort4*)(w2s0+i)=s0; *(ushort4*)(w2s1+i)=s1; *(ushort4*)(w2s2+i)=s2;
    float4 b = *(const float4*)(w3 + i);
    split3(b.x, s0.x, s1.x, s2.x); split3(b.y, s0.y, s1.y, s2.y);
    split3(b.z, s0.z, s1.z, s2.z); split3(b.w, s0.w, s1.w, s2.w);
    *(ushort4*)(w3s0+i)=s0; *(ushort4*)(w3s1+i)=s1; *(ushort4*)(w3s2+i)=s2;
    float4 c = *(const float4*)(d1 + i);
    ushort4 u; u.x=f2bf(c.x); u.y=f2bf(c.y); u.z=f2bf(c.z); u.w=f2bf(c.w);
    *(ushort4*)(w1b+i) = u;
    float4 d = *(const float4*)(d2 + i);
    u.x=f2bf(d.x); u.y=f2bf(d.y); u.z=f2bf(d.z); u.w=f2bf(d.w);
    *(ushort4*)(w2b+i) = u;
}

// ---------------------------------------------------------------------------
// ||c||^2 per code (f32 exact) + bf16 codebook copy
// ---------------------------------------------------------------------------
__global__ __launch_bounds__(256) void cnorm_kernel(
    const float* __restrict__ cb, float* __restrict__ cn,
    ushort* __restrict__ cbb)
{
    const int lane = threadIdx.x & 63;
    const int code = blockIdx.x*4 + (threadIdx.x >> 6);
    float4 v = ((const float4*)(cb + (size_t)code*256))[lane];
    ushort4 u; u.x=f2bf(v.x); u.y=f2bf(v.y); u.z=f2bf(v.z); u.w=f2bf(v.w);
    *(ushort4*)(cbb + (size_t)code*256 + lane*4) = u;
    float s = v.x*v.x + v.y*v.y + v.z*v.z + v.w*v.w;
    #pragma unroll
    for (int m=1; m<64; m<<=1) s += __shfl_xor(s, m);
    if (lane == 0) cn[code] = s;
}

// ---------------------------------------------------------------------------
// f32-faithful MFMA GEMM via 6-term split-bf16:
// C[M,256] = act(A[M,256] @ W[256,256]^T + b), A split in-kernel, W pre-split.
// ---------------------------------------------------------------------------
template<bool GELU>
__global__ __launch_bounds__(256) void split6_gemm(
    const float* __restrict__ Ain,
    const ushort* __restrict__ W0, const ushort* __restrict__ W1,
    const ushort* __restrict__ W2,
    const float* __restrict__ bias,
    float* __restrict__ Cout)
{
    __shared__ __align__(16) ushort Al[3][128][40];
    __shared__ __align__(16) ushort Wl[3][128][40];

    const int tid = threadIdx.x;
    const int m0 = blockIdx.x * 128;
    const int n0 = blockIdx.y * 128;
    const int srow = tid >> 1, shalf = (tid & 1) * 16;
    const int lane = tid & 63;
    const int w = tid >> 6;
    const int wm = (w >> 1) * 64, wn = (w & 1) * 64;
    const int lr = lane & 15, lg = lane >> 4;

    const float*  asrc = Ain + (size_t)(m0 + srow)*256 + shalf;
    const ushort* ws0  = W0  + (size_t)(n0 + srow)*256 + shalf;
    const ushort* ws1  = W1  + (size_t)(n0 + srow)*256 + shalf;
    const ushort* ws2  = W2  + (size_t)(n0 + srow)*256 + shalf;

    f32x4 acc[4][4];
    #pragma unroll
    for (int mi=0;mi<4;++mi)
        #pragma unroll
        for (int ni=0;ni<4;++ni)
            acc[mi][ni] = (f32x4){0.f,0.f,0.f,0.f};

    for (int k0=0; k0<256; k0+=32){
        float x[16];
        *(float4*)&x[0]  = *(const float4*)(asrc + k0);
        *(float4*)&x[4]  = *(const float4*)(asrc + k0 + 4);
        *(float4*)&x[8]  = *(const float4*)(asrc + k0 + 8);
        *(float4*)&x[12] = *(const float4*)(asrc + k0 + 12);
        ushort t0[16], t1[16], t2[16];
        #pragma unroll
        for (int e=0;e<16;++e) split3(x[e], t0[e], t1[e], t2[e]);
        *(uint4*)&Al[0][srow][shalf]   = *(const uint4*)&t0[0];
        *(uint4*)&Al[0][srow][shalf+8] = *(const uint4*)&t0[8];
        *(uint4*)&Al[1][srow][shalf]   = *(const uint4*)&t1[0];
        *(uint4*)&Al[1][srow][shalf+8] = *(const uint4*)&t1[8];
        *(uint4*)&Al[2][srow][shalf]   = *(const uint4*)&t2[0];
        *(uint4*)&Al[2][srow][shalf+8] = *(const uint4*)&t2[8];
        *(uint4*)&Wl[0][srow][shalf]   = *(const uint4*)(ws0 + k0);
        *(uint4*)&Wl[0][srow][shalf+8] = *(const uint4*)(ws0 + k0 + 8);
        *(uint4*)&Wl[1][srow][shalf]   = *(const uint4*)(ws1 + k0);
        *(uint4*)&Wl[1][srow][shalf+8] = *(const uint4*)(ws1 + k0 + 8);
        *(uint4*)&Wl[2][srow][shalf]   = *(const uint4*)(ws2 + k0);
        *(uint4*)&Wl[2][srow][shalf+8] = *(const uint4*)(ws2 + k0 + 8);
        __syncthreads();

        short8 b0[4], b1[4], b2[4];
        #pragma unroll
        for (int ni=0;ni<4;++ni){
            b0[ni] = *(const short8*)&Wl[0][wn + ni*16 + lr][lg*8];
            b1[ni] = *(const short8*)&Wl[1][wn + ni*16 + lr][lg*8];
            b2[ni] = *(const short8*)&Wl[2][wn + ni*16 + lr][lg*8];
        }
        #pragma unroll
        for (int mi=0;mi<4;++mi){
            short8 a0 = *(const short8*)&Al[0][wm + mi*16 + lr][lg*8];
            short8 a1 = *(const short8*)&Al[1][wm + mi*16 + lr][lg*8];
            short8 a2 = *(const short8*)&Al[2][wm + mi*16 + lr][lg*8];
            #pragma unroll
            for (int ni=0;ni<4;++ni)
                acc[mi][ni] = __builtin_amdgcn_mfma_f32_16x16x32_bf16(a0, b0[ni], acc[mi][ni], 0,0,0);
            #pragma unroll
            for (int ni=0;ni<4;++ni)
                acc[mi][ni] = __builtin_amdgcn_mfma_f32_16x16x32_bf16(a0, b1[ni], acc[mi][ni], 0,0,0);
            #pragma unroll
            for (int ni=0;ni<4;++ni)
                acc[mi][ni] = __builtin_amdgcn_mfma_f32_16x16x32_bf16(a1, b0[ni], acc[mi][ni], 0,0,0);
            #pragma unroll
            for (int ni=0;ni<4;++ni)
                acc[mi][ni] = __builtin_amdgcn_mfma_f32_16x16x32_bf16(a0, b2[ni], acc[mi][ni], 0,0,0);
            #pragma unroll
            for (int ni=0;ni<4;++ni)
                acc[mi][ni] = __builtin_amdgcn_mfma_f32_16x16x32_bf16(a1, b1[ni], acc[mi][ni], 0,0,0);
            #pragma unroll
            for (int ni=0;ni<4;++ni)
                acc[mi][ni] = __builtin_amdgcn_mfma_f32_16x16x32_bf16(a2, b0[ni], acc[mi][ni], 0,0,0);
        }
        __syncthreads();
    }

    float bn[4];
    #pragma unroll
    for (int ni=0;ni<4;++ni) bn[ni] = bias[n0 + wn + ni*16 + lr];
    #pragma unroll
    for (int mi=0;mi<4;++mi)
        #pragma unroll
        for (int ni=0;ni<4;++ni)
            #pragma unroll
            for (int r=0;r<4;++r){
                int row = m0 + wm + mi*16 + lg*4 + r;
                float v = acc[mi][ni][r] + bn[ni];
                if (GELU) v = gelu_f(v);
                Cout[(size_t)row*256 + n0 + wn + ni*16 + lr] = v;
            }
}

#define INSERT2(dv, iv) do { \
    float _d = (dv); int _i = (iv); \
    if (_d < b1 || (_d == b1 && _i < i1)){ b2=b1; i2=i1; b1=_d; i1=_i; } \
    else if (_d < b2 || (_d == b2 && _i < i2)){ b2=_d; i2=_i; } \
} while(0)

// ---------------------------------------------------------------------------
// Approximate distance pass (bf16 MFMA), f32 z_e converted in-kernel.
// Per block: 128 rows x 256 codes (2 chunks of 128, dual accumulators).
// ---------------------------------------------------------------------------
__global__ __launch_bounds__(256) void tokens_mfma(
    const float* __restrict__ Zf, const ushort* __restrict__ CBb,
    const float* __restrict__ cn, float4* __restrict__ partials)
{
    __shared__ __align__(16) ushort Al[128][40];
    __shared__ __align__(16) ushort Wl[2][128][40];
    __shared__ float2 ptop[128][2];

    const int tid = threadIdx.x;
    const int m0 = blockIdx.x * 128;
    const int cb2 = blockIdx.y;          // 0,1
    const int n0 = cb2 * 256;
    const int srow = tid >> 1, shalf = (tid & 1) * 16;
    const int lane = tid & 63;
    const int w = tid >> 6;
    const int wm = (w >> 1) * 64, wn = (w & 1) * 64;
    const int lr = lane & 15, lg = lane >> 4;

    const float*  asrc  = Zf  + (size_t)(m0 + srow)*256 + shalf;
    const ushort* wsrc0 = CBb + (size_t)(n0 + srow)*256 + shalf;
    const ushort* wsrc1 = CBb + (size_t)(n0 + 128 + srow)*256 + shalf;

    f32x4 acc[2][4][4];
    #pragma unroll
    for (int u=0;u<2;++u)
        #pragma unroll
        for (int mi=0;mi<4;++mi)
            #pragma unroll
            for (int ni=0;ni<4;++ni)
                acc[u][mi][ni] = (f32x4){0.f,0.f,0.f,0.f};

    for (int k0=0; k0<256; k0+=32){
        float4 f0 = *(const float4*)(asrc + k0);
        float4 f1 = *(const float4*)(asrc + k0 + 4);
        float4 f2 = *(const float4*)(asrc + k0 + 8);
        float4 f3 = *(const float4*)(asrc + k0 + 12);
        ushort t[16];
        t[0]=f2bf(f0.x); t[1]=f2bf(f0.y); t[2]=f2bf(f0.z); t[3]=f2bf(f0.w);
        t[4]=f2bf(f1.x); t[5]=f2bf(f1.y); t[6]=f2bf(f1.z); t[7]=f2bf(f1.w);
        t[8]=f2bf(f2.x); t[9]=f2bf(f2.y); t[10]=f2bf(f2.z); t[11]=f2bf(f2.w);
        t[12]=f2bf(f3.x); t[13]=f2bf(f3.y); t[14]=f2bf(f3.z); t[15]=f2bf(f3.w);
        *(uint4*)&Al[srow][shalf]      = *(const uint4*)&t[0];
        *(uint4*)&Al[srow][shalf+8]    = *(const uint4*)&t[8];
        *(uint4*)&Wl[0][srow][shalf]   = *(const uint4*)(wsrc0 + k0);
        *(uint4*)&Wl[0][srow][shalf+8] = *(const uint4*)(wsrc0 + k0 + 8);
        *(uint4*)&Wl[1][srow][shalf]   = *(const uint4*)(wsrc1 + k0);
        *(uint4*)&Wl[1][srow][shalf+8] = *(const uint4*)(wsrc1 + k0 + 8);
        __syncthreads();

        short8 af[4], b0[4], b1[4];
        #pragma unroll
        for (int mi=0;mi<4;++mi)
            af[mi] = *(const short8*)&Al[wm + mi*16 + lr][lg*8];
        #pragma unroll
        for (int ni=0;ni<4;++ni){
            b0[ni] = *(const short8*)&Wl[0][wn + ni*16 + lr][lg*8];
            b1[ni] = *(const short8*)&Wl[1][wn + ni*16 + lr][lg*8];
        }
        #pragma unroll
        for (int mi=0;mi<4;++mi){
            #pragma unroll
            for (int ni=0;ni<4;++ni)
                acc[0][mi][ni] = __builtin_amdgcn_mfma_f32_16x16x32_bf16(
                    af[mi], b0[ni], acc[0][mi][ni], 0, 0, 0);
            #pragma unroll
            for (int ni=0;ni<4;++ni)
                acc[1][mi][ni] = __builtin_amdgcn_mfma_f32_16x16x32_bf16(
                    af[mi], b1[ni], acc[1][mi][ni], 0, 0, 0);
        }
        __syncthreads();
    }

    #pragma unroll
    for (int u=0;u<2;++u){
        const int c0 = n0 + u*128;
        float cnl[4];
        #pragma unroll
        for (int ni=0;ni<4;++ni) cnl[ni] = cn[c0 + wn + ni*16 + lr];

        #pragma unroll
        for (int mi=0;mi<4;++mi)
            #pragma unroll
            for (int r=0;r<4;++r){
                float b1 = FLT_MAX, b2 = FLT_MAX;
                int   i1 = INT_MAX, i2 = INT_MAX;
                #pragma unroll
                for (int ni=0;ni<4;++ni){
                    float d = cnl[ni] - 2.0f*acc[u][mi][ni][r];
                    int col = c0 + wn + ni*16 + lr;
                    INSERT2(d, col);
                }
                #pragma unroll
                for (int m=1; m<16; m<<=1){
                    float o1 = __shfl_xor(b1, m), o2 = __shfl_xor(b2, m);
                    int   j1 = __shfl_xor(i1, m), j2 = __shfl_xor(i2, m);
                    INSERT2(o1, j1);
                    INSERT2(o2, j2);
                }
                if (lr == 0)
                    ptop[wm + mi*16 + lg*4 + r][w & 1] = make_float2((float)i1, (float)i2);
            }
        __syncthreads();
        if (tid < 128){
            float2 h0 = ptop[tid][0], h1 = ptop[tid][1];
            partials[(size_t)(m0 + tid)*4 + cb2*2 + u] =
                make_float4(h0.x, h0.y, h1.x, h1.y);
        }
        __syncthreads();
    }
}

// ---------------------------------------------------------------------------
// Exact f32 rescore: 16 candidates/row, 4 lanes per candidate (16 in parallel).
// lane = (ci = lane&15 candidate, ch = lane>>4 chunk of 64 elems).
// dot + z2 reduced with 2 shfl; argmin with 4 shfl; commitment = z2 + dmin.
// ---------------------------------------------------------------------------
__global__ __launch_bounds__(256) void rescore_kernel(
    const float* __restrict__ Z, const float* __restrict__ CB,
    const float* __restrict__ cn, const float4* __restrict__ partials,
    float* __restrict__ tokf, float* __restrict__ loss)
{
    const int lane = threadIdx.x & 63;
    const int wv   = threadIdx.x >> 6;
    const int wgid = blockIdx.x*4 + wv;
    const int ci = lane & 15;
    const int ch = lane >> 4;
    float csum = 0.0f;

    for (int rr=0; rr<16; ++rr){
        const int row = wgid*16 + rr;
        float4 p = partials[(size_t)row*4 + (ci >> 2)];
        const int sel = ci & 3;
        int g = (int)(sel==0 ? p.x : sel==1 ? p.y : sel==2 ? p.z : p.w);

        const float4* zp = (const float4*)(Z  + (size_t)row*256 + ch*64);
        const float4* cp = (const float4*)(CB + (size_t)g  *256 + ch*64);
        float4 za[16], ca[16];
        #pragma unroll
        for (int e=0;e<16;++e) za[e] = zp[e];
        #pragma unroll
        for (int e=0;e<16;++e) ca[e] = cp[e];

        float dot = 0.0f, zz = 0.0f;
        #pragma unroll
        for (int e=0;e<16;++e){
            dot = fmaf(za[e].x, ca[e].x, dot);
            dot = fmaf(za[e].y, ca[e].y, dot);
            dot = fmaf(za[e].z, ca[e].z, dot);
            dot = fmaf(za[e].w, ca[e].w, dot);
            zz  = fmaf(za[e].x, za[e].x, zz);
            zz  = fmaf(za[e].y, za[e].y, zz);
            zz  = fmaf(za[e].z, za[e].z, zz);
            zz  = fmaf(za[e].w, za[e].w, zz);
        }
        dot += __shfl_xor(dot, 16); dot += __shfl_xor(dot, 32);
        zz  += __shfl_xor(zz, 16);  zz  += __shfl_xor(zz, 32);

        float d = cn[g] - 2.0f*dot;
        #pragma unroll
        for (int m=1; m<16; m<<=1){
            float od = __shfl_xor(d, m);
            int   og = __shfl_xor(g, m);
            if (od < d || (od == d && og < g)){ d = od; g = og; }
        }
        if (lane == 0){
            tokf[row] = (float)g;
            csum += zz + d;
        }
    }
    __shared__ float wsum[4];
    if (lane == 0) wsum[wv] = csum;
    __syncthreads();
    if (threadIdx.x == 0)
        atomicAdd(loss + 1, wsum[0]+wsum[1]+wsum[2]+wsum[3]);
}

// ---------------------------------------------------------------------------
// bf16 MFMA GEMM (decoder 1/2): Y[M,256] = gelu(A @ W^T + b)
// LOADER: 0 = plain bf16 A, 1 = gather bf16 codebook rows via tokens.
// ---------------------------------------------------------------------------
template<int LOADER>
__global__ __launch_bounds__(256) void mfma_gemm(
    const ushort* __restrict__ Abf,
    const ushort* __restrict__ cbb,
    const float* __restrict__ tokf,
    const ushort* __restrict__ Wbf,
    const float* __restrict__ bias,
    ushort* __restrict__ Ybf)
{
    __shared__ __align__(16) ushort Al[128][40];
    __shared__ __align__(16) ushort Wl[128][40];

    const int tid = threadIdx.x;
    const int m0 = blockIdx.x * 128;
    const int n0 = blockIdx.y * 128;
    const int srow = tid >> 1, shalf = (tid & 1) * 16;
    const int lane = tid & 63;
    const int w = tid >> 6;
    const int wm = (w >> 1) * 64, wn = (w & 1) * 64;
    const int lr = lane & 15, lg = lane >> 4;

    const ushort* asrc;
    if constexpr (LOADER == 1){
        int g = (int)tokf[m0 + srow];
        asrc = cbb + (size_t)g*256 + shalf;
    } else {
        asrc = Abf + (size_t)(m0 + srow)*256 + shalf;
    }
    const ushort* wsrc = Wbf + (size_t)(n0 + srow)*256 + shalf;

    f32x4 acc[4][4];
    #pragma unroll
    for (int mi=0;mi<4;++mi)
        #pragma unroll
        for (int ni=0;ni<4;++ni)
            acc[mi][ni] = (f32x4){0.f,0.f,0.f,0.f};

    for (int k0=0; k0<256; k0+=32){
        *(uint4*)&Al[srow][shalf]   = *(const uint4*)(asrc + k0);
        *(uint4*)&Al[srow][shalf+8] = *(const uint4*)(asrc + k0 + 8);
        *(uint4*)&Wl[srow][shalf]   = *(const uint4*)(wsrc + k0);
        *(uint4*)&Wl[srow][shalf+8] = *(const uint4*)(wsrc + k0 + 8);
        __syncthreads();

        short8 af[4], bfr[4];
        #pragma unroll
        for (int mi=0;mi<4;++mi)
            af[mi] = *(const short8*)&Al[wm + mi*16 + lr][lg*8];
        #pragma unroll
        for (int ni=0;ni<4;++ni)
            bfr[ni] = *(const short8*)&Wl[wn + ni*16 + lr][lg*8];
        #pragma unroll
        for (int mi=0;mi<4;++mi)
            #pragma unroll
            for (int ni=0;ni<4;++ni)
                acc[mi][ni] = __builtin_amdgcn_mfma_f32_16x16x32_bf16(
                    af[mi], bfr[ni], acc[mi][ni], 0, 0, 0);
        __syncthreads();
    }

    float bn[4];
    #pragma unroll
    for (int ni=0;ni<4;++ni) bn[ni] = bias[n0 + wn + ni*16 + lr];
    #pragma unroll
    for (int mi=0;mi<4;++mi)
        #pragma unroll
        for (int ni=0;ni<4;++ni)
            #pragma unroll
            for (int r=0;r<4;++r){
                int row = m0 + wm + mi*16 + lg*4 + r;
                float v = acc[mi][ni][r] + bn[ni];
                v = gelu_f(v);
                Ybf[(size_t)row*256 + n0 + wn + ni*16 + lr] = f2bf(v);
            }
}

// ---------------------------------------------------------------------------
// dec3 MFMA: Y[T,48] = A_bf16 @ W3^T + b3 (W3 converted in-kernel),
// fused un-patchify + recon loss. 256 rows/block, 4 waves of 64 rows.
// ---------------------------------------------------------------------------
__global__ __launch_bounds__(256) void dec3_mfma(
    const ushort* __restrict__ Ain, const float* __restrict__ W,
    const float* __restrict__ bias, const float* __restrict__ frames,
    float* __restrict__ recon, float* __restrict__ loss)
{
    __shared__ __align__(16) ushort Al[256][40];
    __shared__ __align__(16) ushort Wl[48][40];

    const int tid = threadIdx.x;
    const int m0 = blockIdx.x * 256;
    const int lane = tid & 63;
    const int w = tid >> 6;
    const int lr = lane & 15, lg = lane >> 4;

    const ushort* asrc = Ain + (size_t)(m0 + tid)*256;

    f32x4 acc[4][3];
    #pragma unroll
    for (int mi=0;mi<4;++mi)
        #pragma unroll
        for (int ni=0;ni<3;++ni)
            acc[mi][ni] = (f32x4){0.f,0.f,0.f,0.f};

    for (int k0=0; k0<256; k0+=32){
        *(uint4*)&Al[tid][0]  = *(const uint4*)(asrc + k0);
        *(uint4*)&Al[tid][8]  = *(const uint4*)(asrc + k0 + 8);
        *(uint4*)&Al[tid][16] = *(const uint4*)(asrc + k0 + 16);
        *(uint4*)&Al[tid][24] = *(const uint4*)(asrc + k0 + 24);
        if (tid < 96){
            const int wrow = tid >> 1, wh = (tid & 1)*16;
            const float* wp = W + (size_t)wrow*256 + k0 + wh;
            float4 f0 = *(const float4*)(wp);
            float4 f1 = *(const float4*)(wp+4);
            float4 f2 = *(const float4*)(wp+8);
            float4 f3 = *(const float4*)(wp+12);
            ushort t[16];
            t[0]=f2bf(f0.x); t[1]=f2bf(f0.y); t[2]=f2bf(f0.z); t[3]=f2bf(f0.w);
            t[4]=f2bf(f1.x); t[5]=f2bf(f1.y); t[6]=f2bf(f1.z); t[7]=f2bf(f1.w);
            t[8]=f2bf(f2.x); t[9]=f2bf(f2.y); t[10]=f2bf(f2.z); t[11]=f2bf(f2.w);
            t[12]=f2bf(f3.x); t[13]=f2bf(f3.y); t[14]=f2bf(f3.z); t[15]=f2bf(f3.w);
            *(uint4*)&Wl[wrow][wh]   = *(const uint4*)&t[0];
            *(uint4*)&Wl[wrow][wh+8] = *(const uint4*)&t[8];
        }
        __syncthreads();

        short8 bfr[3];
        #pragma unroll
        for (int ni=0;ni<3;++ni)
            bfr[ni] = *(const short8*)&Wl[ni*16 + lr][lg*8];
        #pragma unroll
        for (int mi=0;mi<4;++mi){
            short8 af = *(const short8*)&Al[w*64 + mi*16 + lr][lg*8];
            #pragma unroll
            for (int ni=0;ni<3;++ni)
                acc[mi][ni] = __builtin_amdgcn_mfma_f32_16x16x32_bf16(
                    af, bfr[ni], acc[mi][ni], 0, 0, 0);
        }
        __syncthreads();
    }

    float bn[3]; int phv[3], remv[3];
    #pragma unroll
    for (int ni=0;ni<3;++ni){
        int col = ni*16 + lr;
        bn[ni] = bias[col];
        phv[ni] = col / 12;
        remv[ni] = col - phv[ni]*12;
    }
    const float sc = 2.0f/255.0f;
    float ls = 0.0f;
    #pragma unroll
    for (int mi=0;mi<4;++mi)
        #pragma unroll
        for (int ni=0;ni<3;++ni)
            #pragma unroll
            for (int r=0;r<4;++r){
                int p = m0 + w*64 + mi*16 + lg*4 + r;
                int b = p >> 12, nl = p & 4095, hh = nl >> 6, ww = nl & 63;
                size_t addr = (size_t)(((b*256 + hh*4 + phv[ni])*256 + ww*4)*3 + remv[ni]);
                float y = acc[mi][ni][r] + bn[ni];
                float t = frames[addr]*sc - 1.0f;
                float d = y - t;
                ls += d*d;
                recon[addr] = y;
            }

    #pragma unroll
    for (int off=32; off>0; off>>=1) ls += __shfl_down(ls, off);
    __shared__ float wsum[4];
    if (lane == 0) wsum[w] = ls;
    __syncthreads();
    if (tid == 0) atomicAdd(loss + 0, wsum[0]+wsum[1]+wsum[2]+wsum[3]);
}

__global__ void finalize_kernel(float* __restrict__ loss){
    if (threadIdx.x == 0 && blockIdx.x == 0){
        loss[0] = loss[0] * (1.0f/6291456.0f);
        float c = loss[1] * (1.0f/33554432.0f);
        loss[1] = c;
        loss[2] = c;
    }
}

extern "C" void kernel_launch(void* const* d_in, const int* in_sizes, int n_in,
                              void* d_out, int out_size, void* d_ws, size_t ws_size,
                              hipStream_t stream)
{
    (void)in_sizes; (void)n_in; (void)out_size; (void)ws_size;
    const float* frames   = (const float*)d_in[0];
    const float* enc_w1   = (const float*)d_in[1];
    const float* enc_b1   = (const float*)d_in[2];
    const float* enc_w2   = (const float*)d_in[3];
    const float* enc_b2   = (const float*)d_in[4];
    const float* enc_w3   = (const float*)d_in[5];
    const float* enc_b3   = (const float*)d_in[6];
    const float* codebook = (const float*)d_in[7];
    const float* dec_w1   = (const float*)d_in[8];
    const float* dec_b1   = (const float*)d_in[9];
    const float* dec_w2   = (const float*)d_in[10];
    const float* dec_b2   = (const float*)d_in[11];
    const float* dec_w3   = (const float*)d_in[12];
    const float* dec_b3   = (const float*)d_in[13];

    // workspace: two [T,256] f32 regions (268 MB, proven available)
    float* P = (float*)d_ws;                 // h1 -> z_e -> Y1(bf16)
    float* Q = P + (size_t)33554432;         // h2 -> {Y2(bf16) base, partials}
    float4* partials = (float4*)(Q + 18000000);  // 8.4 MB, disjoint from Y2
    ushort* Y1 = (ushort*)P;
    ushort* Y2 = (ushort*)Q;

    // outputs; recon region doubles as scratch for small constants
    float* recon = (float*)d_out;            // 6,291,456 f32 (written last)
    float* tokf  = recon + 6291456;          // 131,072
    float* loss  = tokf + 131072;            // 3
    float*  cn   = recon;                            // 512 f32
    ushort* cbb  = (ushort*)(recon + 512);           // 131072 us
    ushort* w1b  = (ushort*)(recon + 66048);         // 65536 us
    ushort* w2b  = (ushort*)(recon + 98816);         // 65536 us
    ushort* w2s0 = (ushort*)(recon + 131584);        // 65536 us each
    ushort* w2s1 = (ushort*)(recon + 164352);
    ushort* w2s2 = (ushort*)(recon + 197120);
    ushort* w3s0 = (ushort*)(recon + 229888);
    ushort* w3s1 = (ushort*)(recon + 262656);
    ushort* w3s2 = (ushort*)(recon + 295424);        // ends at 328192 < 6.29M

    hipMemsetAsync(loss, 0, 3*sizeof(float), stream);

    dim3 blk(256), grid2(T_ROWS/128, 2);
    // weight prep
    wsplit_kernel<<<dim3(64), blk, 0, stream>>>(enc_w2, enc_w3, dec_w1, dec_w2,
        w2s0, w2s1, w2s2, w3s0, w3s1, w3s2, w1b, w2b);
    cnorm_kernel<<<dim3(128), blk, 0, stream>>>(codebook, cn, cbb);
    // encoder: f32 layer1, then f32-faithful 6-term split-bf16 MFMA
    gemm_kernel<48, true, 1><<<grid2, blk, 0, stream>>>(nullptr, frames, enc_w1, enc_b1, P);
    split6_gemm<true ><<<grid2, blk, 0, stream>>>(P, w2s0, w2s1, w2s2, enc_b2, Q);
    split6_gemm<false><<<grid2, blk, 0, stream>>>(Q, w3s0, w3s1, w3s2, enc_b3, P);
    // vector quantization: bf16 approx (2-chunk blocks) + exact f32 rescore
    tokens_mfma<<<dim3(T_ROWS/128, 2), blk, 0, stream>>>(P, cbb, cn, partials);
    rescore_kernel<<<dim3(2048), blk, 0, stream>>>(P, codebook, cn, partials, tokf, loss);
    // decoder (bf16 MFMA)
    mfma_gemm<1><<<grid2, blk, 0, stream>>>(nullptr, cbb, tokf, w1b, dec_b1, Y1);
    mfma_gemm<0><<<grid2, blk, 0, stream>>>(Y1, nullptr, nullptr, w2b, dec_b2, Y2);
    dec3_mfma<<<dim3(T_ROWS/256), blk, 0, stream>>>(Y2, dec_w3, dec_b3, frames, recon, loss);
    finalize_kernel<<<dim3(1), dim3(64), 0, stream>>>(loss);
}

// Round 6
// 1006.704 us; speedup vs baseline: 1.1449x; 1.1449x over previous
//
#include <hip/hip_runtime.h>
#include <hip/hip_bf16.h>
#include <math.h>
#include <float.h>
#include <limits.h>

#define T_ROWS 131072   // 32 * 4096 patches

typedef __attribute__((ext_vector_type(8))) short short8;
typedef __attribute__((ext_vector_type(4))) float f32x4;

__device__ __forceinline__ float gelu_f(float x){
    return 0.5f * x * (1.0f + erff(x * 0.7071067811865475f));
}
__device__ __forceinline__ float bf2f(ushort u){
    union { unsigned int i; float f; } v; v.i = ((unsigned int)u) << 16; return v.f;
}
__device__ __forceinline__ ushort f2bf(float f){
    union { float f; unsigned int i; } v; v.f = f;
    unsigned int i = v.i;
    unsigned int r = (i + 0x7fffu + ((i >> 16) & 1u)) >> 16;
    return (ushort)r;
}
// exact 3-way truncation split: x ~= b0+b1+b2 (each bf16), >=24 mantissa bits
__device__ __forceinline__ void split3(float x, ushort &u0, ushort &u1, ushort &u2){
    union { float f; unsigned int i; } v; v.f = x;
    u0 = (ushort)(v.i >> 16);
    union { unsigned int i; float f; } h0; h0.i = ((unsigned int)u0) << 16;
    float r = x - h0.f;                       // exact (Sterbenz)
    union { float f; unsigned int i; } vr; vr.f = r;
    u1 = (ushort)(vr.i >> 16);
    union { unsigned int i; float f; } h1; h1.i = ((unsigned int)u1) << 16;
    float r2 = r - h1.f;                      // exact
    union { float f; unsigned int i; } v2; v2.f = r2;
    u2 = (ushort)(v2.i >> 16);
}

// ---------------------------------------------------------------------------
// f32 tiled GEMM (enc1 only): C[M,256] = gelu(patchify(frames) @ W^T + b)
// ---------------------------------------------------------------------------
template<int K, bool GELU, int LOADER>
__global__ __launch_bounds__(256) void gemm_kernel(
    const float* __restrict__ Ain,
    const float* __restrict__ frames,
    const float* __restrict__ W,
    const float* __restrict__ bias,
    float* __restrict__ Cout)
{
    constexpr int BM=128, BN=128, BK=16;
    __shared__ __align__(16) float As[BK][BM+4];
    __shared__ __align__(16) float Ws[BK][BN+4];

    const int tid = threadIdx.x;
    const int tx = tid & 15, ty = tid >> 4;
    const int m0 = blockIdx.x * BM;
    const int c0 = blockIdx.y * BN;

    const int q  = tid & 3;
    const int r0 = tid >> 2;

    const float* aptr0 = nullptr;
    const float* aptr1 = nullptr;
    int base0 = 0, base1 = 0;
    if constexpr (LOADER == 0){
        aptr0 = Ain + (size_t)(m0 + r0) * K;
        aptr1 = aptr0 + (size_t)64 * K;
    } else {
        int p0 = m0 + r0;
        int b = p0 >> 12, nl = p0 & 4095, hh = nl >> 6, ww = nl & 63;
        base0 = ((b*256 + hh*4)*256 + ww*4)*3;
        int p1 = p0 + 64;
        b = p1 >> 12; nl = p1 & 4095; hh = nl >> 6; ww = nl & 63;
        base1 = ((b*256 + hh*4)*256 + ww*4)*3;
    }
    const float* wptr0 = W + (size_t)(c0 + r0) * K;
    const float* wptr1 = wptr0 + (size_t)64 * K;

    float acc[8][8];
    #pragma unroll
    for (int i=0;i<8;++i)
        #pragma unroll
        for (int j=0;j<8;++j) acc[i][j] = 0.0f;

    for (int k0 = 0; k0 < K; k0 += BK){
        const int k = k0 + q*4;
        float4 va, vb;
        if constexpr (LOADER == 1){
            const int ph = k / 12, rem = k - ph*12;
            va = *(const float4*)(frames + base0 + ph*768 + rem);
            vb = *(const float4*)(frames + base1 + ph*768 + rem);
            const float sc = 2.0f/255.0f;
            va.x = va.x*sc - 1.0f; va.y = va.y*sc - 1.0f;
            va.z = va.z*sc - 1.0f; va.w = va.w*sc - 1.0f;
            vb.x = vb.x*sc - 1.0f; vb.y = vb.y*sc - 1.0f;
            vb.z = vb.z*sc - 1.0f; vb.w = vb.w*sc - 1.0f;
        } else {
            va = *(const float4*)(aptr0 + k);
            vb = *(const float4*)(aptr1 + k);
        }
        As[q*4+0][r0]    = va.x; As[q*4+1][r0]    = va.y;
        As[q*4+2][r0]    = va.z; As[q*4+3][r0]    = va.w;
        As[q*4+0][r0+64] = vb.x; As[q*4+1][r0+64] = vb.y;
        As[q*4+2][r0+64] = vb.z; As[q*4+3][r0+64] = vb.w;

        float4 wa = *(const float4*)(wptr0 + k);
        float4 wb = *(const float4*)(wptr1 + k);
        Ws[q*4+0][r0]    = wa.x; Ws[q*4+1][r0]    = wa.y;
        Ws[q*4+2][r0]    = wa.z; Ws[q*4+3][r0]    = wa.w;
        Ws[q*4+0][r0+64] = wb.x; Ws[q*4+1][r0+64] = wb.y;
        Ws[q*4+2][r0+64] = wb.z; Ws[q*4+3][r0+64] = wb.w;

        __syncthreads();
        #pragma unroll
        for (int kk=0; kk<BK; ++kk){
            float a[8], b[8];
            *(float4*)&a[0] = *(const float4*)&As[kk][ty*4];
            *(float4*)&a[4] = *(const float4*)&As[kk][64+ty*4];
            *(float4*)&b[0] = *(const float4*)&Ws[kk][tx*4];
            *(float4*)&b[4] = *(const float4*)&Ws[kk][64+tx*4];
            #pragma unroll
            for (int i=0;i<8;++i)
                #pragma unroll
                for (int j=0;j<8;++j)
                    acc[i][j] = fmaf(a[i], b[j], acc[i][j]);
        }
        __syncthreads();
    }

    float bj[8];
    *(float4*)&bj[0] = *(const float4*)(bias + c0 + tx*4);
    *(float4*)&bj[4] = *(const float4*)(bias + c0 + 64 + tx*4);
    #pragma unroll
    for (int i=0;i<8;++i){
        const int row = m0 + ((i<4) ? (ty*4+i) : (64+ty*4+i-4));
        float o[8];
        #pragma unroll
        for (int j=0;j<8;++j){
            float x = acc[i][j] + bj[j];
            o[j] = GELU ? gelu_f(x) : x;
        }
        float* dst = Cout + (size_t)row*256 + c0 + tx*4;
        *(float4*)dst      = *(const float4*)&o[0];
        *(float4*)(dst+64) = *(const float4*)&o[4];
    }
}

// ---------------------------------------------------------------------------
// weight prep: 3-way split enc_w2/enc_w3; bf16 round dec_w1/dec_w2
// ---------------------------------------------------------------------------
__global__ __launch_bounds__(256) void wsplit_kernel(
    const float* __restrict__ w2, const float* __restrict__ w3,
    const float* __restrict__ d1, const float* __restrict__ d2,
    ushort* __restrict__ w2s0, ushort* __restrict__ w2s1, ushort* __restrict__ w2s2,
    ushort* __restrict__ w3s0, ushort* __restrict__ w3s1, ushort* __restrict__ w3s2,
    ushort* __restrict__ w1b, ushort* __restrict__ w2b)
{
    const int i = (blockIdx.x*256 + threadIdx.x)*4;
    float4 a = *(const float4*)(w2 + i);
    ushort4 s0, s1, s2;
    split3(a.x, s0.x, s1.x, s2.x); split3(a.y, s0.y, s1.y, s2.y);
    split3(a.z, s0.z, s1.z, s2.z); split3(a.w, s0.w, s1.w, s2.w);
    *(ushort4*)(w2s0+i)=s0; *(ushort4*)(w2s1+i)=s1; *(ushort4*)(w2s2+i)=s2;
    float4 b = *(const float4*)(w3 + i);
    split3(b.x, s0.x, s1.x, s2.x); split3(b.y, s0.y, s1.y, s2.y);
    split3(b.z, s0.z, s1.z, s2.z); split3(b.w, s0.w, s1.w, s2.w);
    *(ushort4*)(w3s0+i)=s0; *(ushort4*)(w3s1+i)=s1; *(ushort4*)(w3s2+i)=s2;
    float4 c = *(const float4*)(d1 + i);
    ushort4 u; u.x=f2bf(c.x); u.y=f2bf(c.y); u.z=f2bf(c.z); u.w=f2bf(c.w);
    *(ushort4*)(w1b+i) = u;
    float4 d = *(const float4*)(d2 + i);
    u.x=f2bf(d.x); u.y=f2bf(d.y); u.z=f2bf(d.z); u.w=f2bf(d.w);
    *(ushort4*)(w2b+i) = u;
}

// ---------------------------------------------------------------------------
// ||c||^2 per code (f32 exact) + bf16 codebook copy
// ---------------------------------------------------------------------------
__global__ __launch_bounds__(256) void cnorm_kernel(
    const float* __restrict__ cb, float* __restrict__ cn,
    ushort* __restrict__ cbb)
{
    const int lane = threadIdx.x & 63;
    const int code = blockIdx.x*4 + (threadIdx.x >> 6);
    float4 v = ((const float4*)(cb + (size_t)code*256))[lane];
    ushort4 u; u.x=f2bf(v.x); u.y=f2bf(v.y); u.z=f2bf(v.z); u.w=f2bf(v.w);
    *(ushort4*)(cbb + (size_t)code*256 + lane*4) = u;
    float s = v.x*v.x + v.y*v.y + v.z*v.z + v.w*v.w;
    #pragma unroll
    for (int m=1; m<64; m<<=1) s += __shfl_xor(s, m);
    if (lane == 0) cn[code] = s;
}

// ---------------------------------------------------------------------------
// f32-faithful MFMA GEMM via 6-term split-bf16.
// A split in-kernel -> LDS; W planes pre-split, fragments loaded DIRECTLY
// from global (L2-resident, 768 KB) -> halves LDS, removes W staging.
// ---------------------------------------------------------------------------
template<bool GELU>
__global__ __launch_bounds__(256) void split6_gemm(
    const float* __restrict__ Ain,
    const ushort* __restrict__ W0, const ushort* __restrict__ W1,
    const ushort* __restrict__ W2,
    const float* __restrict__ bias,
    float* __restrict__ Cout)
{
    __shared__ __align__(16) ushort Al[3][128][40];

    const int tid = threadIdx.x;
    const int m0 = blockIdx.x * 128;
    const int n0 = blockIdx.y * 128;
    const int srow = tid >> 1, shalf = (tid & 1) * 16;
    const int lane = tid & 63;
    const int w = tid >> 6;
    const int wm = (w >> 1) * 64, wn = (w & 1) * 64;
    const int lr = lane & 15, lg = lane >> 4;

    const float*  asrc = Ain + (size_t)(m0 + srow)*256 + shalf;
    // per-lane W fragment base: row (n0+wn+ni*16+lr), k offset lg*8
    const size_t wfrag = (size_t)(n0 + wn + lr)*256 + lg*8;

    f32x4 acc[4][4];
    #pragma unroll
    for (int mi=0;mi<4;++mi)
        #pragma unroll
        for (int ni=0;ni<4;++ni)
            acc[mi][ni] = (f32x4){0.f,0.f,0.f,0.f};

    for (int k0=0; k0<256; k0+=32){
        float x[16];
        *(float4*)&x[0]  = *(const float4*)(asrc + k0);
        *(float4*)&x[4]  = *(const float4*)(asrc + k0 + 4);
        *(float4*)&x[8]  = *(const float4*)(asrc + k0 + 8);
        *(float4*)&x[12] = *(const float4*)(asrc + k0 + 12);
        ushort t0[16], t1[16], t2[16];
        #pragma unroll
        for (int e=0;e<16;++e) split3(x[e], t0[e], t1[e], t2[e]);
        *(uint4*)&Al[0][srow][shalf]   = *(const uint4*)&t0[0];
        *(uint4*)&Al[0][srow][shalf+8] = *(const uint4*)&t0[8];
        *(uint4*)&Al[1][srow][shalf]   = *(const uint4*)&t1[0];
        *(uint4*)&Al[1][srow][shalf+8] = *(const uint4*)&t1[8];
        *(uint4*)&Al[2][srow][shalf]   = *(const uint4*)&t2[0];
        *(uint4*)&Al[2][srow][shalf+8] = *(const uint4*)&t2[8];

        short8 b0[4], b1[4], b2[4];
        #pragma unroll
        for (int ni=0;ni<4;++ni){
            b0[ni] = *(const short8*)(W0 + wfrag + (size_t)ni*16*256 + k0);
            b1[ni] = *(const short8*)(W1 + wfrag + (size_t)ni*16*256 + k0);
            b2[ni] = *(const short8*)(W2 + wfrag + (size_t)ni*16*256 + k0);
        }
        __syncthreads();

        #pragma unroll
        for (int mi=0;mi<4;++mi){
            short8 a0 = *(const short8*)&Al[0][wm + mi*16 + lr][lg*8];
            short8 a1 = *(const short8*)&Al[1][wm + mi*16 + lr][lg*8];
            short8 a2 = *(const short8*)&Al[2][wm + mi*16 + lr][lg*8];
            #pragma unroll
            for (int ni=0;ni<4;++ni)
                acc[mi][ni] = __builtin_amdgcn_mfma_f32_16x16x32_bf16(a0, b0[ni], acc[mi][ni], 0,0,0);
            #pragma unroll
            for (int ni=0;ni<4;++ni)
                acc[mi][ni] = __builtin_amdgcn_mfma_f32_16x16x32_bf16(a0, b1[ni], acc[mi][ni], 0,0,0);
            #pragma unroll
            for (int ni=0;ni<4;++ni)
                acc[mi][ni] = __builtin_amdgcn_mfma_f32_16x16x32_bf16(a1, b0[ni], acc[mi][ni], 0,0,0);
            #pragma unroll
            for (int ni=0;ni<4;++ni)
                acc[mi][ni] = __builtin_amdgcn_mfma_f32_16x16x32_bf16(a0, b2[ni], acc[mi][ni], 0,0,0);
            #pragma unroll
            for (int ni=0;ni<4;++ni)
                acc[mi][ni] = __builtin_amdgcn_mfma_f32_16x16x32_bf16(a1, b1[ni], acc[mi][ni], 0,0,0);
            #pragma unroll
            for (int ni=0;ni<4;++ni)
                acc[mi][ni] = __builtin_amdgcn_mfma_f32_16x16x32_bf16(a2, b0[ni], acc[mi][ni], 0,0,0);
        }
        __syncthreads();
    }

    float bn[4];
    #pragma unroll
    for (int ni=0;ni<4;++ni) bn[ni] = bias[n0 + wn + ni*16 + lr];
    #pragma unroll
    for (int mi=0;mi<4;++mi)
        #pragma unroll
        for (int ni=0;ni<4;++ni)
            #pragma unroll
            for (int r=0;r<4;++r){
                int row = m0 + wm + mi*16 + lg*4 + r;
                float v = acc[mi][ni][r] + bn[ni];
                if (GELU) v = gelu_f(v);
                Cout[(size_t)row*256 + n0 + wn + ni*16 + lr] = v;
            }
}

#define INSERT2(dv, iv) do { \
    float _d = (dv); int _i = (iv); \
    if (_d < b1 || (_d == b1 && _i < i1)){ b2=b1; i2=i1; b1=_d; i1=_i; } \
    else if (_d < b2 || (_d == b2 && _i < i2)){ b2=_d; i2=_i; } \
} while(0)

// ---------------------------------------------------------------------------
// Approximate distance pass (bf16 MFMA), f32 z_e converted in-kernel.
// Per block: 128 rows x 128 codes (R4-proven configuration).
// ---------------------------------------------------------------------------
__global__ __launch_bounds__(256) void tokens_mfma(
    const float* __restrict__ Zf, const ushort* __restrict__ CBb,
    const float* __restrict__ cn, float4* __restrict__ partials)
{
    __shared__ __align__(16) ushort Al[128][40];
    __shared__ __align__(16) ushort Wl[128][40];
    __shared__ float2 ptop[128][2];

    const int tid = threadIdx.x;
    const int m0 = blockIdx.x * 128;
    const int n0 = blockIdx.y * 128;
    const int srow = tid >> 1, shalf = (tid & 1) * 16;
    const int lane = tid & 63;
    const int w = tid >> 6;
    const int wm = (w >> 1) * 64, wn = (w & 1) * 64;
    const int lr = lane & 15, lg = lane >> 4;

    const float*  asrc = Zf  + (size_t)(m0 + srow)*256 + shalf;
    const ushort* wsrc = CBb + (size_t)(n0 + srow)*256 + shalf;

    f32x4 acc[4][4];
    #pragma unroll
    for (int mi=0;mi<4;++mi)
        #pragma unroll
        for (int ni=0;ni<4;++ni)
            acc[mi][ni] = (f32x4){0.f,0.f,0.f,0.f};

    for (int k0=0; k0<256; k0+=32){
        float4 f0 = *(const float4*)(asrc + k0);
        float4 f1 = *(const float4*)(asrc + k0 + 4);
        float4 f2 = *(const float4*)(asrc + k0 + 8);
        float4 f3 = *(const float4*)(asrc + k0 + 12);
        ushort t[16];
        t[0]=f2bf(f0.x); t[1]=f2bf(f0.y); t[2]=f2bf(f0.z); t[3]=f2bf(f0.w);
        t[4]=f2bf(f1.x); t[5]=f2bf(f1.y); t[6]=f2bf(f1.z); t[7]=f2bf(f1.w);
        t[8]=f2bf(f2.x); t[9]=f2bf(f2.y); t[10]=f2bf(f2.z); t[11]=f2bf(f2.w);
        t[12]=f2bf(f3.x); t[13]=f2bf(f3.y); t[14]=f2bf(f3.z); t[15]=f2bf(f3.w);
        *(uint4*)&Al[srow][shalf]   = *(const uint4*)&t[0];
        *(uint4*)&Al[srow][shalf+8] = *(const uint4*)&t[8];
        *(uint4*)&Wl[srow][shalf]   = *(const uint4*)(wsrc + k0);
        *(uint4*)&Wl[srow][shalf+8] = *(const uint4*)(wsrc + k0 + 8);
        __syncthreads();

        short8 af[4], bfr[4];
        #pragma unroll
        for (int mi=0;mi<4;++mi)
            af[mi] = *(const short8*)&Al[wm + mi*16 + lr][lg*8];
        #pragma unroll
        for (int ni=0;ni<4;++ni)
            bfr[ni] = *(const short8*)&Wl[wn + ni*16 + lr][lg*8];
        #pragma unroll
        for (int mi=0;mi<4;++mi)
            #pragma unroll
            for (int ni=0;ni<4;++ni)
                acc[mi][ni] = __builtin_amdgcn_mfma_f32_16x16x32_bf16(
                    af[mi], bfr[ni], acc[mi][ni], 0, 0, 0);
        __syncthreads();
    }

    float cnl[4];
    #pragma unroll
    for (int ni=0;ni<4;++ni) cnl[ni] = cn[n0 + wn + ni*16 + lr];

    #pragma unroll
    for (int mi=0;mi<4;++mi)
        #pragma unroll
        for (int r=0;r<4;++r){
            float b1 = FLT_MAX, b2 = FLT_MAX;
            int   i1 = INT_MAX, i2 = INT_MAX;
            #pragma unroll
            for (int ni=0;ni<4;++ni){
                float d = cnl[ni] - 2.0f*acc[mi][ni][r];
                int col = n0 + wn + ni*16 + lr;
                INSERT2(d, col);
            }
            #pragma unroll
            for (int m=1; m<16; m<<=1){
                float o1 = __shfl_xor(b1, m), o2 = __shfl_xor(b2, m);
                int   j1 = __shfl_xor(i1, m), j2 = __shfl_xor(i2, m);
                INSERT2(o1, j1);
                INSERT2(o2, j2);
            }
            if (lr == 0)
                ptop[wm + mi*16 + lg*4 + r][w & 1] = make_float2((float)i1, (float)i2);
        }
    __syncthreads();
    if (tid < 128){
        float2 h0 = ptop[tid][0], h1 = ptop[tid][1];
        partials[(size_t)(m0 + tid)*4 + blockIdx.y] =
            make_float4(h0.x, h0.y, h1.x, h1.y);
    }
}

// ---------------------------------------------------------------------------
// Exact f32 rescore: 16 candidates/row, 4 lanes per candidate (16 in parallel).
// dot + z2 reduced with 2 shfl; argmin with 4 shfl; commitment = z2 + dmin.
// ---------------------------------------------------------------------------
__global__ __launch_bounds__(256) void rescore_kernel(
    const float* __restrict__ Z, const float* __restrict__ CB,
    const float* __restrict__ cn, const float4* __restrict__ partials,
    float* __restrict__ tokf, float* __restrict__ loss)
{
    const int lane = threadIdx.x & 63;
    const int wv   = threadIdx.x >> 6;
    const int wgid = blockIdx.x*4 + wv;
    const int ci = lane & 15;
    const int ch = lane >> 4;
    float csum = 0.0f;

    for (int rr=0; rr<16; ++rr){
        const int row = wgid*16 + rr;
        float4 p = partials[(size_t)row*4 + (ci >> 2)];
        const int sel = ci & 3;
        int g = (int)(sel==0 ? p.x : sel==1 ? p.y : sel==2 ? p.z : p.w);

        const float4* zp = (const float4*)(Z  + (size_t)row*256 + ch*64);
        const float4* cp = (const float4*)(CB + (size_t)g  *256 + ch*64);
        float4 za[16], ca[16];
        #pragma unroll
        for (int e=0;e<16;++e) za[e] = zp[e];
        #pragma unroll
        for (int e=0;e<16;++e) ca[e] = cp[e];

        float dot = 0.0f, zz = 0.0f;
        #pragma unroll
        for (int e=0;e<16;++e){
            dot = fmaf(za[e].x, ca[e].x, dot);
            dot = fmaf(za[e].y, ca[e].y, dot);
            dot = fmaf(za[e].z, ca[e].z, dot);
            dot = fmaf(za[e].w, ca[e].w, dot);
            zz  = fmaf(za[e].x, za[e].x, zz);
            zz  = fmaf(za[e].y, za[e].y, zz);
            zz  = fmaf(za[e].z, za[e].z, zz);
            zz  = fmaf(za[e].w, za[e].w, zz);
        }
        dot += __shfl_xor(dot, 16); dot += __shfl_xor(dot, 32);
        zz  += __shfl_xor(zz, 16);  zz  += __shfl_xor(zz, 32);

        float d = cn[g] - 2.0f*dot;
        #pragma unroll
        for (int m=1; m<16; m<<=1){
            float od = __shfl_xor(d, m);
            int   og = __shfl_xor(g, m);
            if (od < d || (od == d && og < g)){ d = od; g = og; }
        }
        if (lane == 0){
            tokf[row] = (float)g;
            csum += zz + d;
        }
    }
    __shared__ float wsum[4];
    if (lane == 0) wsum[wv] = csum;
    __syncthreads();
    if (threadIdx.x == 0)
        atomicAdd(loss + 1, wsum[0]+wsum[1]+wsum[2]+wsum[3]);
}

// ---------------------------------------------------------------------------
// bf16 MFMA GEMM (decoder 1/2): Y[M,256] = gelu(A @ W^T + b)
// LOADER: 0 = plain bf16 A, 1 = gather bf16 codebook rows via tokens.
// ---------------------------------------------------------------------------
template<int LOADER>
__global__ __launch_bounds__(256) void mfma_gemm(
    const ushort* __restrict__ Abf,
    const ushort* __restrict__ cbb,
    const float* __restrict__ tokf,
    const ushort* __restrict__ Wbf,
    const float* __restrict__ bias,
    ushort* __restrict__ Ybf)
{
    __shared__ __align__(16) ushort Al[128][40];
    __shared__ __align__(16) ushort Wl[128][40];

    const int tid = threadIdx.x;
    const int m0 = blockIdx.x * 128;
    const int n0 = blockIdx.y * 128;
    const int srow = tid >> 1, shalf = (tid & 1) * 16;
    const int lane = tid & 63;
    const int w = tid >> 6;
    const int wm = (w >> 1) * 64, wn = (w & 1) * 64;
    const int lr = lane & 15, lg = lane >> 4;

    const ushort* asrc;
    if constexpr (LOADER == 1){
        int g = (int)tokf[m0 + srow];
        asrc = cbb + (size_t)g*256 + shalf;
    } else {
        asrc = Abf + (size_t)(m0 + srow)*256 + shalf;
    }
    const ushort* wsrc = Wbf + (size_t)(n0 + srow)*256 + shalf;

    f32x4 acc[4][4];
    #pragma unroll
    for (int mi=0;mi<4;++mi)
        #pragma unroll
        for (int ni=0;ni<4;++ni)
            acc[mi][ni] = (f32x4){0.f,0.f,0.f,0.f};

    for (int k0=0; k0<256; k0+=32){
        *(uint4*)&Al[srow][shalf]   = *(const uint4*)(asrc + k0);
        *(uint4*)&Al[srow][shalf+8] = *(const uint4*)(asrc + k0 + 8);
        *(uint4*)&Wl[srow][shalf]   = *(const uint4*)(wsrc + k0);
        *(uint4*)&Wl[srow][shalf+8] = *(const uint4*)(wsrc + k0 + 8);
        __syncthreads();

        short8 af[4], bfr[4];
        #pragma unroll
        for (int mi=0;mi<4;++mi)
            af[mi] = *(const short8*)&Al[wm + mi*16 + lr][lg*8];
        #pragma unroll
        for (int ni=0;ni<4;++ni)
            bfr[ni] = *(const short8*)&Wl[wn + ni*16 + lr][lg*8];
        #pragma unroll
        for (int mi=0;mi<4;++mi)
            #pragma unroll
            for (int ni=0;ni<4;++ni)
                acc[mi][ni] = __builtin_amdgcn_mfma_f32_16x16x32_bf16(
                    af[mi], bfr[ni], acc[mi][ni], 0, 0, 0);
        __syncthreads();
    }

    float bn[4];
    #pragma unroll
    for (int ni=0;ni<4;++ni) bn[ni] = bias[n0 + wn + ni*16 + lr];
    #pragma unroll
    for (int mi=0;mi<4;++mi)
        #pragma unroll
        for (int ni=0;ni<4;++ni)
            #pragma unroll
            for (int r=0;r<4;++r){
                int row = m0 + wm + mi*16 + lg*4 + r;
                float v = acc[mi][ni][r] + bn[ni];
                v = gelu_f(v);
                Ybf[(size_t)row*256 + n0 + wn + ni*16 + lr] = f2bf(v);
            }
}

// ---------------------------------------------------------------------------
// dec3 MFMA: Y[T,48] = A_bf16 @ W3^T + b3 (W3 converted in-kernel),
// fused un-patchify + recon loss. 256 rows/block, 4 waves of 64 rows.
// ---------------------------------------------------------------------------
__global__ __launch_bounds__(256) void dec3_mfma(
    const ushort* __restrict__ Ain, const float* __restrict__ W,
    const float* __restrict__ bias, const float* __restrict__ frames,
    float* __restrict__ recon, float* __restrict__ loss)
{
    __shared__ __align__(16) ushort Al[256][40];
    __shared__ __align__(16) ushort Wl[48][40];

    const int tid = threadIdx.x;
    const int m0 = blockIdx.x * 256;
    const int lane = tid & 63;
    const int w = tid >> 6;
    const int lr = lane & 15, lg = lane >> 4;

    const ushort* asrc = Ain + (size_t)(m0 + tid)*256;

    f32x4 acc[4][3];
    #pragma unroll
    for (int mi=0;mi<4;++mi)
        #pragma unroll
        for (int ni=0;ni<3;++ni)
            acc[mi][ni] = (f32x4){0.f,0.f,0.f,0.f};

    for (int k0=0; k0<256; k0+=32){
        *(uint4*)&Al[tid][0]  = *(const uint4*)(asrc + k0);
        *(uint4*)&Al[tid][8]  = *(const uint4*)(asrc + k0 + 8);
        *(uint4*)&Al[tid][16] = *(const uint4*)(asrc + k0 + 16);
        *(uint4*)&Al[tid][24] = *(const uint4*)(asrc + k0 + 24);
        if (tid < 96){
            const int wrow = tid >> 1, wh = (tid & 1)*16;
            const float* wp = W + (size_t)wrow*256 + k0 + wh;
            float4 f0 = *(const float4*)(wp);
            float4 f1 = *(const float4*)(wp+4);
            float4 f2 = *(const float4*)(wp+8);
            float4 f3 = *(const float4*)(wp+12);
            ushort t[16];
            t[0]=f2bf(f0.x); t[1]=f2bf(f0.y); t[2]=f2bf(f0.z); t[3]=f2bf(f0.w);
            t[4]=f2bf(f1.x); t[5]=f2bf(f1.y); t[6]=f2bf(f1.z); t[7]=f2bf(f1.w);
            t[8]=f2bf(f2.x); t[9]=f2bf(f2.y); t[10]=f2bf(f2.z); t[11]=f2bf(f2.w);
            t[12]=f2bf(f3.x); t[13]=f2bf(f3.y); t[14]=f2bf(f3.z); t[15]=f2bf(f3.w);
            *(uint4*)&Wl[wrow][wh]   = *(const uint4*)&t[0];
            *(uint4*)&Wl[wrow][wh+8] = *(const uint4*)&t[8];
        }
        __syncthreads();

        short8 bfr[3];
        #pragma unroll
        for (int ni=0;ni<3;++ni)
            bfr[ni] = *(const short8*)&Wl[ni*16 + lr][lg*8];
        #pragma unroll
        for (int mi=0;mi<4;++mi){
            short8 af = *(const short8*)&Al[w*64 + mi*16 + lr][lg*8];
            #pragma unroll
            for (int ni=0;ni<3;++ni)
                acc[mi][ni] = __builtin_amdgcn_mfma_f32_16x16x32_bf16(
                    af, bfr[ni], acc[mi][ni], 0, 0, 0);
        }
        __syncthreads();
    }

    float bn[3]; int phv[3], remv[3];
    #pragma unroll
    for (int ni=0;ni<3;++ni){
        int col = ni*16 + lr;
        bn[ni] = bias[col];
        phv[ni] = col / 12;
        remv[ni] = col - phv[ni]*12;
    }
    const float sc = 2.0f/255.0f;
    float ls = 0.0f;
    #pragma unroll
    for (int mi=0;mi<4;++mi)
        #pragma unroll
        for (int ni=0;ni<3;++ni)
            #pragma unroll
            for (int r=0;r<4;++r){
                int p = m0 + w*64 + mi*16 + lg*4 + r;
                int b = p >> 12, nl = p & 4095, hh = nl >> 6, ww = nl & 63;
                size_t addr = (size_t)(((b*256 + hh*4 + phv[ni])*256 + ww*4)*3 + remv[ni]);
                float y = acc[mi][ni][r] + bn[ni];
                float t = frames[addr]*sc - 1.0f;
                float d = y - t;
                ls += d*d;
                recon[addr] = y;
            }

    #pragma unroll
    for (int off=32; off>0; off>>=1) ls += __shfl_down(ls, off);
    __shared__ float wsum[4];
    if (lane == 0) wsum[w] = ls;
    __syncthreads();
    if (tid == 0) atomicAdd(loss + 0, wsum[0]+wsum[1]+wsum[2]+wsum[3]);
}

__global__ void finalize_kernel(float* __restrict__ loss){
    if (threadIdx.x == 0 && blockIdx.x == 0){
        loss[0] = loss[0] * (1.0f/6291456.0f);
        float c = loss[1] * (1.0f/33554432.0f);
        loss[1] = c;
        loss[2] = c;
    }
}

extern "C" void kernel_launch(void* const* d_in, const int* in_sizes, int n_in,
                              void* d_out, int out_size, void* d_ws, size_t ws_size,
                              hipStream_t stream)
{
    (void)in_sizes; (void)n_in; (void)out_size; (void)ws_size;
    const float* frames   = (const float*)d_in[0];
    const float* enc_w1   = (const float*)d_in[1];
    const float* enc_b1   = (const float*)d_in[2];
    const float* enc_w2   = (const float*)d_in[3];
    const float* enc_b2   = (const float*)d_in[4];
    const float* enc_w3   = (const float*)d_in[5];
    const float* enc_b3   = (const float*)d_in[6];
    const float* codebook = (const float*)d_in[7];
    const float* dec_w1   = (const float*)d_in[8];
    const float* dec_b1   = (const float*)d_in[9];
    const float* dec_w2   = (const float*)d_in[10];
    const float* dec_b2   = (const float*)d_in[11];
    const float* dec_w3   = (const float*)d_in[12];
    const float* dec_b3   = (const float*)d_in[13];

    // workspace: two [T,256] f32 regions (268 MB, proven available)
    float* P = (float*)d_ws;                 // h1 -> z_e -> Y1(bf16)
    float* Q = P + (size_t)33554432;         // h2 -> {Y2(bf16) base, partials}
    float4* partials = (float4*)(Q + 18000000);  // 8.4 MB, disjoint from Y2
    ushort* Y1 = (ushort*)P;
    ushort* Y2 = (ushort*)Q;

    // outputs; recon region doubles as scratch for small constants
    float* recon = (float*)d_out;            // 6,291,456 f32 (written last)
    float* tokf  = recon + 6291456;          // 131,072
    float* loss  = tokf + 131072;            // 3
    float*  cn   = recon;                            // 512 f32
    ushort* cbb  = (ushort*)(recon + 512);           // 131072 us
    ushort* w1b  = (ushort*)(recon + 66048);         // 65536 us
    ushort* w2b  = (ushort*)(recon + 98816);         // 65536 us
    ushort* w2s0 = (ushort*)(recon + 131584);        // 65536 us each
    ushort* w2s1 = (ushort*)(recon + 164352);
    ushort* w2s2 = (ushort*)(recon + 197120);
    ushort* w3s0 = (ushort*)(recon + 229888);
    ushort* w3s1 = (ushort*)(recon + 262656);
    ushort* w3s2 = (ushort*)(recon + 295424);        // ends at 328192 < 6.29M

    hipMemsetAsync(loss, 0, 3*sizeof(float), stream);

    dim3 blk(256), grid2(T_ROWS/128, 2);
    // weight prep
    wsplit_kernel<<<dim3(64), blk, 0, stream>>>(enc_w2, enc_w3, dec_w1, dec_w2,
        w2s0, w2s1, w2s2, w3s0, w3s1, w3s2, w1b, w2b);
    cnorm_kernel<<<dim3(128), blk, 0, stream>>>(codebook, cn, cbb);
    // encoder: f32 layer1, then f32-faithful 6-term split-bf16 MFMA
    gemm_kernel<48, true, 1><<<grid2, blk, 0, stream>>>(nullptr, frames, enc_w1, enc_b1, P);
    split6_gemm<true ><<<grid2, blk, 0, stream>>>(P, w2s0, w2s1, w2s2, enc_b2, Q);
    split6_gemm<false><<<grid2, blk, 0, stream>>>(Q, w3s0, w3s1, w3s2, enc_b3, P);
    // vector quantization: bf16 approx (R4 config) + exact f32 rescore
    tokens_mfma<<<dim3(T_ROWS/128, 4), blk, 0, stream>>>(P, cbb, cn, partials);
    rescore_kernel<<<dim3(2048), blk, 0, stream>>>(P, codebook, cn, partials, tokf, loss);
    // decoder (bf16 MFMA)
    mfma_gemm<1><<<grid2, blk, 0, stream>>>(nullptr, cbb, tokf, w1b, dec_b1, Y1);
    mfma_gemm<0><<<grid2, blk, 0, stream>>>(Y1, nullptr, nullptr, w2b, dec_b2, Y2);
    dec3_mfma<<<dim3(T_ROWS/256), blk, 0, stream>>>(Y2, dec_w3, dec_b3, frames, recon, loss);
    finalize_kernel<<<dim3(1), dim3(64), 0, stream>>>(loss);
}

// Round 7
// 971.684 us; speedup vs baseline: 1.1862x; 1.0360x over previous
//
#include <hip/hip_runtime.h>
#include <hip/hip_bf16.h>
#include <math.h>
#include <float.h>
#include <limits.h>

#define T_ROWS 131072   // 32 * 4096 patches

typedef __attribute__((ext_vector_type(8))) short short8;
typedef __attribute__((ext_vector_type(4))) float f32x4;

__device__ __forceinline__ float gelu_f(float x){
    return 0.5f * x * (1.0f + erff(x * 0.7071067811865475f));
}
__device__ __forceinline__ float bf2f(ushort u){
    union { unsigned int i; float f; } v; v.i = ((unsigned int)u) << 16; return v.f;
}
__device__ __forceinline__ ushort f2bf(float f){
    union { float f; unsigned int i; } v; v.f = f;
    unsigned int i = v.i;
    unsigned int r = (i + 0x7fffu + ((i >> 16) & 1u)) >> 16;
    return (ushort)r;
}
// exact 3-way truncation split: x ~= b0+b1+b2 (each bf16), >=24 mantissa bits
__device__ __forceinline__ void split3(float x, ushort &u0, ushort &u1, ushort &u2){
    union { float f; unsigned int i; } v; v.f = x;
    u0 = (ushort)(v.i >> 16);
    union { unsigned int i; float f; } h0; h0.i = ((unsigned int)u0) << 16;
    float r = x - h0.f;                       // exact (Sterbenz)
    union { float f; unsigned int i; } vr; vr.f = r;
    u1 = (ushort)(vr.i >> 16);
    union { unsigned int i; float f; } h1; h1.i = ((unsigned int)u1) << 16;
    float r2 = r - h1.f;                      // exact
    union { float f; unsigned int i; } v2; v2.f = r2;
    u2 = (ushort)(v2.i >> 16);
}

// ---------------------------------------------------------------------------
// f32 tiled GEMM (enc1 only): C[M,256] = gelu(patchify(frames) @ W^T + b)
// ---------------------------------------------------------------------------
template<int K, bool GELU, int LOADER>
__global__ __launch_bounds__(256) void gemm_kernel(
    const float* __restrict__ Ain,
    const float* __restrict__ frames,
    const float* __restrict__ W,
    const float* __restrict__ bias,
    float* __restrict__ Cout)
{
    constexpr int BM=128, BN=128, BK=16;
    __shared__ __align__(16) float As[BK][BM+4];
    __shared__ __align__(16) float Ws[BK][BN+4];

    const int tid = threadIdx.x;
    const int tx = tid & 15, ty = tid >> 4;
    const int m0 = blockIdx.x * BM;
    const int c0 = blockIdx.y * BN;

    const int q  = tid & 3;
    const int r0 = tid >> 2;

    const float* aptr0 = nullptr;
    const float* aptr1 = nullptr;
    int base0 = 0, base1 = 0;
    if constexpr (LOADER == 0){
        aptr0 = Ain + (size_t)(m0 + r0) * K;
        aptr1 = aptr0 + (size_t)64 * K;
    } else {
        int p0 = m0 + r0;
        int b = p0 >> 12, nl = p0 & 4095, hh = nl >> 6, ww = nl & 63;
        base0 = ((b*256 + hh*4)*256 + ww*4)*3;
        int p1 = p0 + 64;
        b = p1 >> 12; nl = p1 & 4095; hh = nl >> 6; ww = nl & 63;
        base1 = ((b*256 + hh*4)*256 + ww*4)*3;
    }
    const float* wptr0 = W + (size_t)(c0 + r0) * K;
    const float* wptr1 = wptr0 + (size_t)64 * K;

    float acc[8][8];
    #pragma unroll
    for (int i=0;i<8;++i)
        #pragma unroll
        for (int j=0;j<8;++j) acc[i][j] = 0.0f;

    for (int k0 = 0; k0 < K; k0 += BK){
        const int k = k0 + q*4;
        float4 va, vb;
        if constexpr (LOADER == 1){
            const int ph = k / 12, rem = k - ph*12;
            va = *(const float4*)(frames + base0 + ph*768 + rem);
            vb = *(const float4*)(frames + base1 + ph*768 + rem);
            const float sc = 2.0f/255.0f;
            va.x = va.x*sc - 1.0f; va.y = va.y*sc - 1.0f;
            va.z = va.z*sc - 1.0f; va.w = va.w*sc - 1.0f;
            vb.x = vb.x*sc - 1.0f; vb.y = vb.y*sc - 1.0f;
            vb.z = vb.z*sc - 1.0f; vb.w = vb.w*sc - 1.0f;
        } else {
            va = *(const float4*)(aptr0 + k);
            vb = *(const float4*)(aptr1 + k);
        }
        As[q*4+0][r0]    = va.x; As[q*4+1][r0]    = va.y;
        As[q*4+2][r0]    = va.z; As[q*4+3][r0]    = va.w;
        As[q*4+0][r0+64] = vb.x; As[q*4+1][r0+64] = vb.y;
        As[q*4+2][r0+64] = vb.z; As[q*4+3][r0+64] = vb.w;

        float4 wa = *(const float4*)(wptr0 + k);
        float4 wb = *(const float4*)(wptr1 + k);
        Ws[q*4+0][r0]    = wa.x; Ws[q*4+1][r0]    = wa.y;
        Ws[q*4+2][r0]    = wa.z; Ws[q*4+3][r0]    = wa.w;
        Ws[q*4+0][r0+64] = wb.x; Ws[q*4+1][r0+64] = wb.y;
        Ws[q*4+2][r0+64] = wb.z; Ws[q*4+3][r0+64] = wb.w;

        __syncthreads();
        #pragma unroll
        for (int kk=0; kk<BK; ++kk){
            float a[8], b[8];
            *(float4*)&a[0] = *(const float4*)&As[kk][ty*4];
            *(float4*)&a[4] = *(const float4*)&As[kk][64+ty*4];
            *(float4*)&b[0] = *(const float4*)&Ws[kk][tx*4];
            *(float4*)&b[4] = *(const float4*)&Ws[kk][64+tx*4];
            #pragma unroll
            for (int i=0;i<8;++i)
                #pragma unroll
                for (int j=0;j<8;++j)
                    acc[i][j] = fmaf(a[i], b[j], acc[i][j]);
        }
        __syncthreads();
    }

    float bj[8];
    *(float4*)&bj[0] = *(const float4*)(bias + c0 + tx*4);
    *(float4*)&bj[4] = *(const float4*)(bias + c0 + 64 + tx*4);
    #pragma unroll
    for (int i=0;i<8;++i){
        const int row = m0 + ((i<4) ? (ty*4+i) : (64+ty*4+i-4));
        float o[8];
        #pragma unroll
        for (int j=0;j<8;++j){
            float x = acc[i][j] + bj[j];
            o[j] = GELU ? gelu_f(x) : x;
        }
        float* dst = Cout + (size_t)row*256 + c0 + tx*4;
        *(float4*)dst      = *(const float4*)&o[0];
        *(float4*)(dst+64) = *(const float4*)&o[4];
    }
}

// ---------------------------------------------------------------------------
// weight prep: 3-way split enc_w2/enc_w3; bf16 round dec_w1/dec_w2
// ---------------------------------------------------------------------------
__global__ __launch_bounds__(256) void wsplit_kernel(
    const float* __restrict__ w2, const float* __restrict__ w3,
    const float* __restrict__ d1, const float* __restrict__ d2,
    ushort* __restrict__ w2s0, ushort* __restrict__ w2s1, ushort* __restrict__ w2s2,
    ushort* __restrict__ w3s0, ushort* __restrict__ w3s1, ushort* __restrict__ w3s2,
    ushort* __restrict__ w1b, ushort* __restrict__ w2b)
{
    const int i = (blockIdx.x*256 + threadIdx.x)*4;
    float4 a = *(const float4*)(w2 + i);
    ushort4 s0, s1, s2;
    split3(a.x, s0.x, s1.x, s2.x); split3(a.y, s0.y, s1.y, s2.y);
    split3(a.z, s0.z, s1.z, s2.z); split3(a.w, s0.w, s1.w, s2.w);
    *(ushort4*)(w2s0+i)=s0; *(ushort4*)(w2s1+i)=s1; *(ushort4*)(w2s2+i)=s2;
    float4 b = *(const float4*)(w3 + i);
    split3(b.x, s0.x, s1.x, s2.x); split3(b.y, s0.y, s1.y, s2.y);
    split3(b.z, s0.z, s1.z, s2.z); split3(b.w, s0.w, s1.w, s2.w);
    *(ushort4*)(w3s0+i)=s0; *(ushort4*)(w3s1+i)=s1; *(ushort4*)(w3s2+i)=s2;
    float4 c = *(const float4*)(d1 + i);
    ushort4 u; u.x=f2bf(c.x); u.y=f2bf(c.y); u.z=f2bf(c.z); u.w=f2bf(c.w);
    *(ushort4*)(w1b+i) = u;
    float4 d = *(const float4*)(d2 + i);
    u.x=f2bf(d.x); u.y=f2bf(d.y); u.z=f2bf(d.z); u.w=f2bf(d.w);
    *(ushort4*)(w2b+i) = u;
}

// ---------------------------------------------------------------------------
// ||c||^2 per code (f32 exact) + bf16 codebook copy
// ---------------------------------------------------------------------------
__global__ __launch_bounds__(256) void cnorm_kernel(
    const float* __restrict__ cb, float* __restrict__ cn,
    ushort* __restrict__ cbb)
{
    const int lane = threadIdx.x & 63;
    const int code = blockIdx.x*4 + (threadIdx.x >> 6);
    float4 v = ((const float4*)(cb + (size_t)code*256))[lane];
    ushort4 u; u.x=f2bf(v.x); u.y=f2bf(v.y); u.z=f2bf(v.z); u.w=f2bf(v.w);
    *(ushort4*)(cbb + (size_t)code*256 + lane*4) = u;
    float s = v.x*v.x + v.y*v.y + v.z*v.z + v.w*v.w;
    #pragma unroll
    for (int m=1; m<64; m<<=1) s += __shfl_xor(s, m);
    if (lane == 0) cn[code] = s;
}

// ---------------------------------------------------------------------------
// f32-faithful MFMA GEMM via 6-term split-bf16 (R4-proven LDS-staged form):
// C[M,256] = act(A[M,256] @ W[256,256]^T + b), A split in-kernel, W pre-split.
// ---------------------------------------------------------------------------
template<bool GELU>
__global__ __launch_bounds__(256) void split6_gemm(
    const float* __restrict__ Ain,
    const ushort* __restrict__ W0, const ushort* __restrict__ W1,
    const ushort* __restrict__ W2,
    const float* __restrict__ bias,
    float* __restrict__ Cout)
{
    __shared__ __align__(16) ushort Al[3][128][40];
    __shared__ __align__(16) ushort Wl[3][128][40];

    const int tid = threadIdx.x;
    const int m0 = blockIdx.x * 128;
    const int n0 = blockIdx.y * 128;
    const int srow = tid >> 1, shalf = (tid & 1) * 16;
    const int lane = tid & 63;
    const int w = tid >> 6;
    const int wm = (w >> 1) * 64, wn = (w & 1) * 64;
    const int lr = lane & 15, lg = lane >> 4;

    const float*  asrc = Ain + (size_t)(m0 + srow)*256 + shalf;
    const ushort* ws0  = W0  + (size_t)(n0 + srow)*256 + shalf;
    const ushort* ws1  = W1  + (size_t)(n0 + srow)*256 + shalf;
    const ushort* ws2  = W2  + (size_t)(n0 + srow)*256 + shalf;

    f32x4 acc[4][4];
    #pragma unroll
    for (int mi=0;mi<4;++mi)
        #pragma unroll
        for (int ni=0;ni<4;++ni)
            acc[mi][ni] = (f32x4){0.f,0.f,0.f,0.f};

    for (int k0=0; k0<256; k0+=32){
        float x[16];
        *(float4*)&x[0]  = *(const float4*)(asrc + k0);
        *(float4*)&x[4]  = *(const float4*)(asrc + k0 + 4);
        *(float4*)&x[8]  = *(const float4*)(asrc + k0 + 8);
        *(float4*)&x[12] = *(const float4*)(asrc + k0 + 12);
        ushort t0[16], t1[16], t2[16];
        #pragma unroll
        for (int e=0;e<16;++e) split3(x[e], t0[e], t1[e], t2[e]);
        *(uint4*)&Al[0][srow][shalf]   = *(const uint4*)&t0[0];
        *(uint4*)&Al[0][srow][shalf+8] = *(const uint4*)&t0[8];
        *(uint4*)&Al[1][srow][shalf]   = *(const uint4*)&t1[0];
        *(uint4*)&Al[1][srow][shalf+8] = *(const uint4*)&t1[8];
        *(uint4*)&Al[2][srow][shalf]   = *(const uint4*)&t2[0];
        *(uint4*)&Al[2][srow][shalf+8] = *(const uint4*)&t2[8];
        *(uint4*)&Wl[0][srow][shalf]   = *(const uint4*)(ws0 + k0);
        *(uint4*)&Wl[0][srow][shalf+8] = *(const uint4*)(ws0 + k0 + 8);
        *(uint4*)&Wl[1][srow][shalf]   = *(const uint4*)(ws1 + k0);
        *(uint4*)&Wl[1][srow][shalf+8] = *(const uint4*)(ws1 + k0 + 8);
        *(uint4*)&Wl[2][srow][shalf]   = *(const uint4*)(ws2 + k0);
        *(uint4*)&Wl[2][srow][shalf+8] = *(const uint4*)(ws2 + k0 + 8);
        __syncthreads();

        short8 b0[4], b1[4], b2[4];
        #pragma unroll
        for (int ni=0;ni<4;++ni){
            b0[ni] = *(const short8*)&Wl[0][wn + ni*16 + lr][lg*8];
            b1[ni] = *(const short8*)&Wl[1][wn + ni*16 + lr][lg*8];
            b2[ni] = *(const short8*)&Wl[2][wn + ni*16 + lr][lg*8];
        }
        #pragma unroll
        for (int mi=0;mi<4;++mi){
            short8 a0 = *(const short8*)&Al[0][wm + mi*16 + lr][lg*8];
            short8 a1 = *(const short8*)&Al[1][wm + mi*16 + lr][lg*8];
            short8 a2 = *(const short8*)&Al[2][wm + mi*16 + lr][lg*8];
            #pragma unroll
            for (int ni=0;ni<4;++ni)
                acc[mi][ni] = __builtin_amdgcn_mfma_f32_16x16x32_bf16(a0, b0[ni], acc[mi][ni], 0,0,0);
            #pragma unroll
            for (int ni=0;ni<4;++ni)
                acc[mi][ni] = __builtin_amdgcn_mfma_f32_16x16x32_bf16(a0, b1[ni], acc[mi][ni], 0,0,0);
            #pragma unroll
            for (int ni=0;ni<4;++ni)
                acc[mi][ni] = __builtin_amdgcn_mfma_f32_16x16x32_bf16(a1, b0[ni], acc[mi][ni], 0,0,0);
            #pragma unroll
            for (int ni=0;ni<4;++ni)
                acc[mi][ni] = __builtin_amdgcn_mfma_f32_16x16x32_bf16(a0, b2[ni], acc[mi][ni], 0,0,0);
            #pragma unroll
            for (int ni=0;ni<4;++ni)
                acc[mi][ni] = __builtin_amdgcn_mfma_f32_16x16x32_bf16(a1, b1[ni], acc[mi][ni], 0,0,0);
            #pragma unroll
            for (int ni=0;ni<4;++ni)
                acc[mi][ni] = __builtin_amdgcn_mfma_f32_16x16x32_bf16(a2, b0[ni], acc[mi][ni], 0,0,0);
        }
        __syncthreads();
    }

    float bn[4];
    #pragma unroll
    for (int ni=0;ni<4;++ni) bn[ni] = bias[n0 + wn + ni*16 + lr];
    #pragma unroll
    for (int mi=0;mi<4;++mi)
        #pragma unroll
        for (int ni=0;ni<4;++ni)
            #pragma unroll
            for (int r=0;r<4;++r){
                int row = m0 + wm + mi*16 + lg*4 + r;
                float v = acc[mi][ni][r] + bn[ni];
                if (GELU) v = gelu_f(v);
                Cout[(size_t)row*256 + n0 + wn + ni*16 + lr] = v;
            }
}

#define INSERT2(dv, iv) do { \
    float _d = (dv); int _i = (iv); \
    if (_d < b1 || (_d == b1 && _i < i1)){ b2=b1; i2=i1; b1=_d; i1=_i; } \
    else if (_d < b2 || (_d == b2 && _i < i2)){ b2=_d; i2=_i; } \
} while(0)

// ---------------------------------------------------------------------------
// Approximate distance pass (bf16 MFMA), f32 z_e converted in-kernel.
// Per block: 128 rows x 128 codes (R4-proven configuration).
// ---------------------------------------------------------------------------
__global__ __launch_bounds__(256) void tokens_mfma(
    const float* __restrict__ Zf, const ushort* __restrict__ CBb,
    const float* __restrict__ cn, float4* __restrict__ partials)
{
    __shared__ __align__(16) ushort Al[128][40];
    __shared__ __align__(16) ushort Wl[128][40];
    __shared__ float2 ptop[128][2];

    const int tid = threadIdx.x;
    const int m0 = blockIdx.x * 128;
    const int n0 = blockIdx.y * 128;
    const int srow = tid >> 1, shalf = (tid & 1) * 16;
    const int lane = tid & 63;
    const int w = tid >> 6;
    const int wm = (w >> 1) * 64, wn = (w & 1) * 64;
    const int lr = lane & 15, lg = lane >> 4;

    const float*  asrc = Zf  + (size_t)(m0 + srow)*256 + shalf;
    const ushort* wsrc = CBb + (size_t)(n0 + srow)*256 + shalf;

    f32x4 acc[4][4];
    #pragma unroll
    for (int mi=0;mi<4;++mi)
        #pragma unroll
        for (int ni=0;ni<4;++ni)
            acc[mi][ni] = (f32x4){0.f,0.f,0.f,0.f};

    for (int k0=0; k0<256; k0+=32){
        float4 f0 = *(const float4*)(asrc + k0);
        float4 f1 = *(const float4*)(asrc + k0 + 4);
        float4 f2 = *(const float4*)(asrc + k0 + 8);
        float4 f3 = *(const float4*)(asrc + k0 + 12);
        ushort t[16];
        t[0]=f2bf(f0.x); t[1]=f2bf(f0.y); t[2]=f2bf(f0.z); t[3]=f2bf(f0.w);
        t[4]=f2bf(f1.x); t[5]=f2bf(f1.y); t[6]=f2bf(f1.z); t[7]=f2bf(f1.w);
        t[8]=f2bf(f2.x); t[9]=f2bf(f2.y); t[10]=f2bf(f2.z); t[11]=f2bf(f2.w);
        t[12]=f2bf(f3.x); t[13]=f2bf(f3.y); t[14]=f2bf(f3.z); t[15]=f2bf(f3.w);
        *(uint4*)&Al[srow][shalf]   = *(const uint4*)&t[0];
        *(uint4*)&Al[srow][shalf+8] = *(const uint4*)&t[8];
        *(uint4*)&Wl[srow][shalf]   = *(const uint4*)(wsrc + k0);
        *(uint4*)&Wl[srow][shalf+8] = *(const uint4*)(wsrc + k0 + 8);
        __syncthreads();

        short8 af[4], bfr[4];
        #pragma unroll
        for (int mi=0;mi<4;++mi)
            af[mi] = *(const short8*)&Al[wm + mi*16 + lr][lg*8];
        #pragma unroll
        for (int ni=0;ni<4;++ni)
            bfr[ni] = *(const short8*)&Wl[wn + ni*16 + lr][lg*8];
        #pragma unroll
        for (int mi=0;mi<4;++mi)
            #pragma unroll
            for (int ni=0;ni<4;++ni)
                acc[mi][ni] = __builtin_amdgcn_mfma_f32_16x16x32_bf16(
                    af[mi], bfr[ni], acc[mi][ni], 0, 0, 0);
        __syncthreads();
    }

    float cnl[4];
    #pragma unroll
    for (int ni=0;ni<4;++ni) cnl[ni] = cn[n0 + wn + ni*16 + lr];

    #pragma unroll
    for (int mi=0;mi<4;++mi)
        #pragma unroll
        for (int r=0;r<4;++r){
            float b1 = FLT_MAX, b2 = FLT_MAX;
            int   i1 = INT_MAX, i2 = INT_MAX;
            #pragma unroll
            for (int ni=0;ni<4;++ni){
                float d = cnl[ni] - 2.0f*acc[mi][ni][r];
                int col = n0 + wn + ni*16 + lr;
                INSERT2(d, col);
            }
            #pragma unroll
            for (int m=1; m<16; m<<=1){
                float o1 = __shfl_xor(b1, m), o2 = __shfl_xor(b2, m);
                int   j1 = __shfl_xor(i1, m), j2 = __shfl_xor(i2, m);
                INSERT2(o1, j1);
                INSERT2(o2, j2);
            }
            if (lr == 0)
                ptop[wm + mi*16 + lg*4 + r][w & 1] = make_float2((float)i1, (float)i2);
        }
    __syncthreads();
    if (tid < 128){
        float2 h0 = ptop[tid][0], h1 = ptop[tid][1];
        partials[(size_t)(m0 + tid)*4 + blockIdx.y] =
            make_float4(h0.x, h0.y, h1.x, h1.y);
    }
}

// ---------------------------------------------------------------------------
// Exact f32 rescore, MLP-optimized: block = 64 rows, 4 waves.
// Wave pair p (=w>>1) handles rows p*32..p*32+31; half h (=w&1) owns
// candidates h*8..h*8+7. lane = (ci=lane&7 candidate, ch=lane>>3 chunk of 32).
// 16 independent float4 loads issued as named vars before any FMA.
// Cross-wave half-merge via LDS after the loop; commitment = zz + d_min.
// ---------------------------------------------------------------------------
__global__ __launch_bounds__(256) void rescore_kernel(
    const float* __restrict__ Z, const float* __restrict__ CB,
    const float* __restrict__ cn, const float4* __restrict__ partials,
    float* __restrict__ tokf, float* __restrict__ loss)
{
    __shared__ float resd[2][64];
    __shared__ float resg[2][64];
    __shared__ float zzs[64];

    const int tid  = threadIdx.x;
    const int w    = tid >> 6;
    const int lane = tid & 63;
    const int p    = w >> 1;         // row stream 0/1
    const int h    = w & 1;          // candidate half 0/1
    const int ci   = h*8 + (lane & 7);
    const int ch   = lane >> 3;      // 0..7, 32-element chunk
    const int base = blockIdx.x * 64;

    for (int it = 0; it < 32; ++it){
        const int rib = p*32 + it;
        const int row = base + rib;
        float4 pp = partials[(size_t)row*4 + (ci >> 2)];
        const int sel = ci & 3;
        int g = (int)(sel==0 ? pp.x : sel==1 ? pp.y : sel==2 ? pp.z : pp.w);

        const float4* zp = (const float4*)(Z  + (size_t)row*256 + ch*32);
        const float4* cp = (const float4*)(CB + (size_t)g*256  + ch*32);
        // all 16 loads issued before use (named vars -> compiler keeps in flight)
        float4 c0=cp[0], c1=cp[1], c2=cp[2], c3=cp[3];
        float4 c4=cp[4], c5=cp[5], c6=cp[6], c7=cp[7];
        float4 z0=zp[0], z1=zp[1], z2=zp[2], z3=zp[3];
        float4 z4=zp[4], z5=zp[5], z6=zp[6], z7=zp[7];

        float dA=0.f, dB=0.f, zA=0.f, zB=0.f;
        dA=fmaf(z0.x,c0.x,dA); dA=fmaf(z0.y,c0.y,dA); dA=fmaf(z0.z,c0.z,dA); dA=fmaf(z0.w,c0.w,dA);
        dA=fmaf(z1.x,c1.x,dA); dA=fmaf(z1.y,c1.y,dA); dA=fmaf(z1.z,c1.z,dA); dA=fmaf(z1.w,c1.w,dA);
        dA=fmaf(z2.x,c2.x,dA); dA=fmaf(z2.y,c2.y,dA); dA=fmaf(z2.z,c2.z,dA); dA=fmaf(z2.w,c2.w,dA);
        dA=fmaf(z3.x,c3.x,dA); dA=fmaf(z3.y,c3.y,dA); dA=fmaf(z3.z,c3.z,dA); dA=fmaf(z3.w,c3.w,dA);
        dB=fmaf(z4.x,c4.x,dB); dB=fmaf(z4.y,c4.y,dB); dB=fmaf(z4.z,c4.z,dB); dB=fmaf(z4.w,c4.w,dB);
        dB=fmaf(z5.x,c5.x,dB); dB=fmaf(z5.y,c5.y,dB); dB=fmaf(z5.z,c5.z,dB); dB=fmaf(z5.w,c5.w,dB);
        dB=fmaf(z6.x,c6.x,dB); dB=fmaf(z6.y,c6.y,dB); dB=fmaf(z6.z,c6.z,dB); dB=fmaf(z6.w,c6.w,dB);
        dB=fmaf(z7.x,c7.x,dB); dB=fmaf(z7.y,c7.y,dB); dB=fmaf(z7.z,c7.z,dB); dB=fmaf(z7.w,c7.w,dB);
        zA=fmaf(z0.x,z0.x,zA); zA=fmaf(z0.y,z0.y,zA); zA=fmaf(z0.z,z0.z,zA); zA=fmaf(z0.w,z0.w,zA);
        zA=fmaf(z1.x,z1.x,zA); zA=fmaf(z1.y,z1.y,zA); zA=fmaf(z1.z,z1.z,zA); zA=fmaf(z1.w,z1.w,zA);
        zA=fmaf(z2.x,z2.x,zA); zA=fmaf(z2.y,z2.y,zA); zA=fmaf(z2.z,z2.z,zA); zA=fmaf(z2.w,z2.w,zA);
        zA=fmaf(z3.x,z3.x,zA); zA=fmaf(z3.y,z3.y,zA); zA=fmaf(z3.z,z3.z,zA); zA=fmaf(z3.w,z3.w,zA);
        zB=fmaf(z4.x,z4.x,zB); zB=fmaf(z4.y,z4.y,zB); zB=fmaf(z4.z,z4.z,zB); zB=fmaf(z4.w,z4.w,zB);
        zB=fmaf(z5.x,z5.x,zB); zB=fmaf(z5.y,z5.y,zB); zB=fmaf(z5.z,z5.z,zB); zB=fmaf(z5.w,z5.w,zB);
        zB=fmaf(z6.x,z6.x,zB); zB=fmaf(z6.y,z6.y,zB); zB=fmaf(z6.z,z6.z,zB); zB=fmaf(z6.w,z6.w,zB);
        zB=fmaf(z7.x,z7.x,zB); zB=fmaf(z7.y,z7.y,zB); zB=fmaf(z7.z,z7.z,zB); zB=fmaf(z7.w,z7.w,zB);
        float dot = dA + dB, zz = zA + zB;

        // sum across the 8 chunk lanes (bits 3,4,5)
        dot += __shfl_xor(dot, 8); dot += __shfl_xor(dot, 16); dot += __shfl_xor(dot, 32);
        zz  += __shfl_xor(zz, 8);  zz  += __shfl_xor(zz, 16);  zz  += __shfl_xor(zz, 32);

        float d = cn[g] - 2.0f*dot;
        // argmin across the 8 candidate lanes (bits 0,1,2)
        #pragma unroll
        for (int m=1; m<8; m<<=1){
            float od = __shfl_xor(d, m);
            int   og = __shfl_xor(g, m);
            if (od < d || (od == d && og < g)){ d = od; g = og; }
        }
        if (lane == 0){
            resd[h][rib] = d;
            resg[h][rib] = (float)g;
            if (h == 0) zzs[rib] = zz;
        }
    }
    __syncthreads();

    if (tid < 64){
        float dA = resd[0][tid], dB = resd[1][tid];
        int   gA = (int)resg[0][tid], gB = (int)resg[1][tid];
        bool takeB = (dB < dA) || (dB == dA && gB < gA);
        int   g = takeB ? gB : gA;
        float d = takeB ? dB : dA;
        tokf[base + tid] = (float)g;
        float cs = zzs[tid] + d;
        #pragma unroll
        for (int m=1; m<64; m<<=1) cs += __shfl_xor(cs, m);
        if (tid == 0) atomicAdd(loss + 1, cs);
    }
}

// ---------------------------------------------------------------------------
// bf16 MFMA GEMM (decoder 1/2): Y[M,256] = gelu(A @ W^T + b)
// LOADER: 0 = plain bf16 A, 1 = gather bf16 codebook rows via tokens.
// ---------------------------------------------------------------------------
template<int LOADER>
__global__ __launch_bounds__(256) void mfma_gemm(
    const ushort* __restrict__ Abf,
    const ushort* __restrict__ cbb,
    const float* __restrict__ tokf,
    const ushort* __restrict__ Wbf,
    const float* __restrict__ bias,
    ushort* __restrict__ Ybf)
{
    __shared__ __align__(16) ushort Al[128][40];
    __shared__ __align__(16) ushort Wl[128][40];

    const int tid = threadIdx.x;
    const int m0 = blockIdx.x * 128;
    const int n0 = blockIdx.y * 128;
    const int srow = tid >> 1, shalf = (tid & 1) * 16;
    const int lane = tid & 63;
    const int w = tid >> 6;
    const int wm = (w >> 1) * 64, wn = (w & 1) * 64;
    const int lr = lane & 15, lg = lane >> 4;

    const ushort* asrc;
    if constexpr (LOADER == 1){
        int g = (int)tokf[m0 + srow];
        asrc = cbb + (size_t)g*256 + shalf;
    } else {
        asrc = Abf + (size_t)(m0 + srow)*256 + shalf;
    }
    const ushort* wsrc = Wbf + (size_t)(n0 + srow)*256 + shalf;

    f32x4 acc[4][4];
    #pragma unroll
    for (int mi=0;mi<4;++mi)
        #pragma unroll
        for (int ni=0;ni<4;++ni)
            acc[mi][ni] = (f32x4){0.f,0.f,0.f,0.f};

    for (int k0=0; k0<256; k0+=32){
        *(uint4*)&Al[srow][shalf]   = *(const uint4*)(asrc + k0);
        *(uint4*)&Al[srow][shalf+8] = *(const uint4*)(asrc + k0 + 8);
        *(uint4*)&Wl[srow][shalf]   = *(const uint4*)(wsrc + k0);
        *(uint4*)&Wl[srow][shalf+8] = *(const uint4*)(wsrc + k0 + 8);
        __syncthreads();

        short8 af[4], bfr[4];
        #pragma unroll
        for (int mi=0;mi<4;++mi)
            af[mi] = *(const short8*)&Al[wm + mi*16 + lr][lg*8];
        #pragma unroll
        for (int ni=0;ni<4;++ni)
            bfr[ni] = *(const short8*)&Wl[wn + ni*16 + lr][lg*8];
        #pragma unroll
        for (int mi=0;mi<4;++mi)
            #pragma unroll
            for (int ni=0;ni<4;++ni)
                acc[mi][ni] = __builtin_amdgcn_mfma_f32_16x16x32_bf16(
                    af[mi], bfr[ni], acc[mi][ni], 0, 0, 0);
        __syncthreads();
    }

    float bn[4];
    #pragma unroll
    for (int ni=0;ni<4;++ni) bn[ni] = bias[n0 + wn + ni*16 + lr];
    #pragma unroll
    for (int mi=0;mi<4;++mi)
        #pragma unroll
        for (int ni=0;ni<4;++ni)
            #pragma unroll
            for (int r=0;r<4;++r){
                int row = m0 + wm + mi*16 + lg*4 + r;
                float v = acc[mi][ni][r] + bn[ni];
                v = gelu_f(v);
                Ybf[(size_t)row*256 + n0 + wn + ni*16 + lr] = f2bf(v);
            }
}

// ---------------------------------------------------------------------------
// dec3 MFMA: Y[T,48] = A_bf16 @ W3^T + b3 (W3 converted in-kernel),
// fused un-patchify + recon loss. 256 rows/block, 4 waves of 64 rows.
// ---------------------------------------------------------------------------
__global__ __launch_bounds__(256) void dec3_mfma(
    const ushort* __restrict__ Ain, const float* __restrict__ W,
    const float* __restrict__ bias, const float* __restrict__ frames,
    float* __restrict__ recon, float* __restrict__ loss)
{
    __shared__ __align__(16) ushort Al[256][40];
    __shared__ __align__(16) ushort Wl[48][40];

    const int tid = threadIdx.x;
    const int m0 = blockIdx.x * 256;
    const int lane = tid & 63;
    const int w = tid >> 6;
    const int lr = lane & 15, lg = lane >> 4;

    const ushort* asrc = Ain + (size_t)(m0 + tid)*256;

    f32x4 acc[4][3];
    #pragma unroll
    for (int mi=0;mi<4;++mi)
        #pragma unroll
        for (int ni=0;ni<3;++ni)
            acc[mi][ni] = (f32x4){0.f,0.f,0.f,0.f};

    for (int k0=0; k0<256; k0+=32){
        *(uint4*)&Al[tid][0]  = *(const uint4*)(asrc + k0);
        *(uint4*)&Al[tid][8]  = *(const uint4*)(asrc + k0 + 8);
        *(uint4*)&Al[tid][16] = *(const uint4*)(asrc + k0 + 16);
        *(uint4*)&Al[tid][24] = *(const uint4*)(asrc + k0 + 24);
        if (tid < 96){
            const int wrow = tid >> 1, wh = (tid & 1)*16;
            const float* wp = W + (size_t)wrow*256 + k0 + wh;
            float4 f0 = *(const float4*)(wp);
            float4 f1 = *(const float4*)(wp+4);
            float4 f2 = *(const float4*)(wp+8);
            float4 f3 = *(const float4*)(wp+12);
            ushort t[16];
            t[0]=f2bf(f0.x); t[1]=f2bf(f0.y); t[2]=f2bf(f0.z); t[3]=f2bf(f0.w);
            t[4]=f2bf(f1.x); t[5]=f2bf(f1.y); t[6]=f2bf(f1.z); t[7]=f2bf(f1.w);
            t[8]=f2bf(f2.x); t[9]=f2bf(f2.y); t[10]=f2bf(f2.z); t[11]=f2bf(f2.w);
            t[12]=f2bf(f3.x); t[13]=f2bf(f3.y); t[14]=f2bf(f3.z); t[15]=f2bf(f3.w);
            *(uint4*)&Wl[wrow][wh]   = *(const uint4*)&t[0];
            *(uint4*)&Wl[wrow][wh+8] = *(const uint4*)&t[8];
        }
        __syncthreads();

        short8 bfr[3];
        #pragma unroll
        for (int ni=0;ni<3;++ni)
            bfr[ni] = *(const short8*)&Wl[ni*16 + lr][lg*8];
        #pragma unroll
        for (int mi=0;mi<4;++mi){
            short8 af = *(const short8*)&Al[w*64 + mi*16 + lr][lg*8];
            #pragma unroll
            for (int ni=0;ni<3;++ni)
                acc[mi][ni] = __builtin_amdgcn_mfma_f32_16x16x32_bf16(
                    af, bfr[ni], acc[mi][ni], 0, 0, 0);
        }
        __syncthreads();
    }

    float bn[3]; int phv[3], remv[3];
    #pragma unroll
    for (int ni=0;ni<3;++ni){
        int col = ni*16 + lr;
        bn[ni] = bias[col];
        phv[ni] = col / 12;
        remv[ni] = col - phv[ni]*12;
    }
    const float sc = 2.0f/255.0f;
    float ls = 0.0f;
    #pragma unroll
    for (int mi=0;mi<4;++mi)
        #pragma unroll
        for (int ni=0;ni<3;++ni)
            #pragma unroll
            for (int r=0;r<4;++r){
                int p = m0 + w*64 + mi*16 + lg*4 + r;
                int b = p >> 12, nl = p & 4095, hh = nl >> 6, ww = nl & 63;
                size_t addr = (size_t)(((b*256 + hh*4 + phv[ni])*256 + ww*4)*3 + remv[ni]);
                float y = acc[mi][ni][r] + bn[ni];
                float t = frames[addr]*sc - 1.0f;
                float d = y - t;
                ls += d*d;
                recon[addr] = y;
            }

    #pragma unroll
    for (int off=32; off>0; off>>=1) ls += __shfl_down(ls, off);
    __shared__ float wsum[4];
    if (lane == 0) wsum[w] = ls;
    __syncthreads();
    if (tid == 0) atomicAdd(loss + 0, wsum[0]+wsum[1]+wsum[2]+wsum[3]);
}

__global__ void finalize_kernel(float* __restrict__ loss){
    if (threadIdx.x == 0 && blockIdx.x == 0){
        loss[0] = loss[0] * (1.0f/6291456.0f);
        float c = loss[1] * (1.0f/33554432.0f);
        loss[1] = c;
        loss[2] = c;
    }
}

extern "C" void kernel_launch(void* const* d_in, const int* in_sizes, int n_in,
                              void* d_out, int out_size, void* d_ws, size_t ws_size,
                              hipStream_t stream)
{
    (void)in_sizes; (void)n_in; (void)out_size; (void)ws_size;
    const float* frames   = (const float*)d_in[0];
    const float* enc_w1   = (const float*)d_in[1];
    const float* enc_b1   = (const float*)d_in[2];
    const float* enc_w2   = (const float*)d_in[3];
    const float* enc_b2   = (const float*)d_in[4];
    const float* enc_w3   = (const float*)d_in[5];
    const float* enc_b3   = (const float*)d_in[6];
    const float* codebook = (const float*)d_in[7];
    const float* dec_w1   = (const float*)d_in[8];
    const float* dec_b1   = (const float*)d_in[9];
    const float* dec_w2   = (const float*)d_in[10];
    const float* dec_b2   = (const float*)d_in[11];
    const float* dec_w3   = (const float*)d_in[12];
    const float* dec_b3   = (const float*)d_in[13];

    // workspace: two [T,256] f32 regions (268 MB, proven available)
    float* P = (float*)d_ws;                 // h1 -> z_e -> Y1(bf16)
    float* Q = P + (size_t)33554432;         // h2 -> {Y2(bf16) base, partials}
    float4* partials = (float4*)(Q + 18000000);  // 8.4 MB, disjoint from Y2
    ushort* Y1 = (ushort*)P;
    ushort* Y2 = (ushort*)Q;

    // outputs; recon region doubles as scratch for small constants
    float* recon = (float*)d_out;            // 6,291,456 f32 (written last)
    float* tokf  = recon + 6291456;          // 131,072
    float* loss  = tokf + 131072;            // 3
    float*  cn   = recon;                            // 512 f32
    ushort* cbb  = (ushort*)(recon + 512);           // 131072 us
    ushort* w1b  = (ushort*)(recon + 66048);         // 65536 us
    ushort* w2b  = (ushort*)(recon + 98816);         // 65536 us
    ushort* w2s0 = (ushort*)(recon + 131584);        // 65536 us each
    ushort* w2s1 = (ushort*)(recon + 164352);
    ushort* w2s2 = (ushort*)(recon + 197120);
    ushort* w3s0 = (ushort*)(recon + 229888);
    ushort* w3s1 = (ushort*)(recon + 262656);
    ushort* w3s2 = (ushort*)(recon + 295424);        // ends at 328192 < 6.29M

    hipMemsetAsync(loss, 0, 3*sizeof(float), stream);

    dim3 blk(256), grid2(T_ROWS/128, 2);
    // weight prep
    wsplit_kernel<<<dim3(64), blk, 0, stream>>>(enc_w2, enc_w3, dec_w1, dec_w2,
        w2s0, w2s1, w2s2, w3s0, w3s1, w3s2, w1b, w2b);
    cnorm_kernel<<<dim3(128), blk, 0, stream>>>(codebook, cn, cbb);
    // encoder: f32 layer1, then f32-faithful 6-term split-bf16 MFMA
    gemm_kernel<48, true, 1><<<grid2, blk, 0, stream>>>(nullptr, frames, enc_w1, enc_b1, P);
    split6_gemm<true ><<<grid2, blk, 0, stream>>>(P, w2s0, w2s1, w2s2, enc_b2, Q);
    split6_gemm<false><<<grid2, blk, 0, stream>>>(Q, w3s0, w3s1, w3s2, enc_b3, P);
    // vector quantization: bf16 approx (R4 config) + exact f32 rescore (MLP)
    tokens_mfma<<<dim3(T_ROWS/128, 4), blk, 0, stream>>>(P, cbb, cn, partials);
    rescore_kernel<<<dim3(T_ROWS/64), blk, 0, stream>>>(P, codebook, cn, partials, tokf, loss);
    // decoder (bf16 MFMA)
    mfma_gemm<1><<<grid2, blk, 0, stream>>>(nullptr, cbb, tokf, w1b, dec_b1, Y1);
    mfma_gemm<0><<<grid2, blk, 0, stream>>>(Y1, nullptr, nullptr, w2b, dec_b2, Y2);
    dec3_mfma<<<dim3(T_ROWS/256), blk, 0, stream>>>(Y2, dec_w3, dec_b3, frames, recon, loss);
    finalize_kernel<<<dim3(1), dim3(64), 0, stream>>>(loss);
}

// Round 8
// 780.126 us; speedup vs baseline: 1.4774x; 1.2455x over previous
//
#include <hip/hip_runtime.h>
#include <hip/hip_bf16.h>
#include <math.h>
#include <float.h>
#include <limits.h>

#define T_ROWS 131072   // 32 * 4096 patches

typedef __attribute__((ext_vector_type(8))) short short8;
typedef __attribute__((ext_vector_type(4))) float f32x4;

__device__ __forceinline__ float gelu_f(float x){
    return 0.5f * x * (1.0f + erff(x * 0.7071067811865475f));
}
__device__ __forceinline__ float bf2f(ushort u){
    union { unsigned int i; float f; } v; v.i = ((unsigned int)u) << 16; return v.f;
}
__device__ __forceinline__ ushort f2bf(float f){
    union { float f; unsigned int i; } v; v.f = f;
    unsigned int i = v.i;
    unsigned int r = (i + 0x7fffu + ((i >> 16) & 1u)) >> 16;
    return (ushort)r;
}
// exact 3-way truncation split: x ~= b0+b1+b2 (each bf16), >=24 mantissa bits
__device__ __forceinline__ void split3(float x, ushort &u0, ushort &u1, ushort &u2){
    union { float f; unsigned int i; } v; v.f = x;
    u0 = (ushort)(v.i >> 16);
    union { unsigned int i; float f; } h0; h0.i = ((unsigned int)u0) << 16;
    float r = x - h0.f;                       // exact (Sterbenz)
    union { float f; unsigned int i; } vr; vr.f = r;
    u1 = (ushort)(vr.i >> 16);
    union { unsigned int i; float f; } h1; h1.i = ((unsigned int)u1) << 16;
    float r2 = r - h1.f;                      // exact
    union { float f; unsigned int i; } v2; v2.f = r2;
    u2 = (ushort)(v2.i >> 16);
}

// ---------------------------------------------------------------------------
// f32 tiled GEMM (enc1 only): C[M,256] = gelu(patchify(frames) @ W^T + b)
// ---------------------------------------------------------------------------
template<int K, bool GELU, int LOADER>
__global__ __launch_bounds__(256) void gemm_kernel(
    const float* __restrict__ Ain,
    const float* __restrict__ frames,
    const float* __restrict__ W,
    const float* __restrict__ bias,
    float* __restrict__ Cout)
{
    constexpr int BM=128, BN=128, BK=16;
    __shared__ __align__(16) float As[BK][BM+4];
    __shared__ __align__(16) float Ws[BK][BN+4];

    const int tid = threadIdx.x;
    const int tx = tid & 15, ty = tid >> 4;
    const int m0 = blockIdx.x * BM;
    const int c0 = blockIdx.y * BN;

    const int q  = tid & 3;
    const int r0 = tid >> 2;

    const float* aptr0 = nullptr;
    const float* aptr1 = nullptr;
    int base0 = 0, base1 = 0;
    if constexpr (LOADER == 0){
        aptr0 = Ain + (size_t)(m0 + r0) * K;
        aptr1 = aptr0 + (size_t)64 * K;
    } else {
        int p0 = m0 + r0;
        int b = p0 >> 12, nl = p0 & 4095, hh = nl >> 6, ww = nl & 63;
        base0 = ((b*256 + hh*4)*256 + ww*4)*3;
        int p1 = p0 + 64;
        b = p1 >> 12; nl = p1 & 4095; hh = nl >> 6; ww = nl & 63;
        base1 = ((b*256 + hh*4)*256 + ww*4)*3;
    }
    const float* wptr0 = W + (size_t)(c0 + r0) * K;
    const float* wptr1 = wptr0 + (size_t)64 * K;

    float acc[8][8];
    #pragma unroll
    for (int i=0;i<8;++i)
        #pragma unroll
        for (int j=0;j<8;++j) acc[i][j] = 0.0f;

    for (int k0 = 0; k0 < K; k0 += BK){
        const int k = k0 + q*4;
        float4 va, vb;
        if constexpr (LOADER == 1){
            const int ph = k / 12, rem = k - ph*12;
            va = *(const float4*)(frames + base0 + ph*768 + rem);
            vb = *(const float4*)(frames + base1 + ph*768 + rem);
            const float sc = 2.0f/255.0f;
            va.x = va.x*sc - 1.0f; va.y = va.y*sc - 1.0f;
            va.z = va.z*sc - 1.0f; va.w = va.w*sc - 1.0f;
            vb.x = vb.x*sc - 1.0f; vb.y = vb.y*sc - 1.0f;
            vb.z = vb.z*sc - 1.0f; vb.w = vb.w*sc - 1.0f;
        } else {
            va = *(const float4*)(aptr0 + k);
            vb = *(const float4*)(aptr1 + k);
        }
        As[q*4+0][r0]    = va.x; As[q*4+1][r0]    = va.y;
        As[q*4+2][r0]    = va.z; As[q*4+3][r0]    = va.w;
        As[q*4+0][r0+64] = vb.x; As[q*4+1][r0+64] = vb.y;
        As[q*4+2][r0+64] = vb.z; As[q*4+3][r0+64] = vb.w;

        float4 wa = *(const float4*)(wptr0 + k);
        float4 wb = *(const float4*)(wptr1 + k);
        Ws[q*4+0][r0]    = wa.x; Ws[q*4+1][r0]    = wa.y;
        Ws[q*4+2][r0]    = wa.z; Ws[q*4+3][r0]    = wa.w;
        Ws[q*4+0][r0+64] = wb.x; Ws[q*4+1][r0+64] = wb.y;
        Ws[q*4+2][r0+64] = wb.z; Ws[q*4+3][r0+64] = wb.w;

        __syncthreads();
        #pragma unroll
        for (int kk=0; kk<BK; ++kk){
            float a[8], b[8];
            *(float4*)&a[0] = *(const float4*)&As[kk][ty*4];
            *(float4*)&a[4] = *(const float4*)&As[kk][64+ty*4];
            *(float4*)&b[0] = *(const float4*)&Ws[kk][tx*4];
            *(float4*)&b[4] = *(const float4*)&Ws[kk][64+tx*4];
            #pragma unroll
            for (int i=0;i<8;++i)
                #pragma unroll
                for (int j=0;j<8;++j)
                    acc[i][j] = fmaf(a[i], b[j], acc[i][j]);
        }
        __syncthreads();
    }

    float bj[8];
    *(float4*)&bj[0] = *(const float4*)(bias + c0 + tx*4);
    *(float4*)&bj[4] = *(const float4*)(bias + c0 + 64 + tx*4);
    #pragma unroll
    for (int i=0;i<8;++i){
        const int row = m0 + ((i<4) ? (ty*4+i) : (64+ty*4+i-4));
        float o[8];
        #pragma unroll
        for (int j=0;j<8;++j){
            float x = acc[i][j] + bj[j];
            o[j] = GELU ? gelu_f(x) : x;
        }
        float* dst = Cout + (size_t)row*256 + c0 + tx*4;
        *(float4*)dst      = *(const float4*)&o[0];
        *(float4*)(dst+64) = *(const float4*)&o[4];
    }
}

// ---------------------------------------------------------------------------
// weight prep: 3-way split enc_w2/enc_w3; bf16 round dec_w1/dec_w2
// ---------------------------------------------------------------------------
__global__ __launch_bounds__(256) void wsplit_kernel(
    const float* __restrict__ w2, const float* __restrict__ w3,
    const float* __restrict__ d1, const float* __restrict__ d2,
    ushort* __restrict__ w2s0, ushort* __restrict__ w2s1, ushort* __restrict__ w2s2,
    ushort* __restrict__ w3s0, ushort* __restrict__ w3s1, ushort* __restrict__ w3s2,
    ushort* __restrict__ w1b, ushort* __restrict__ w2b)
{
    const int i = (blockIdx.x*256 + threadIdx.x)*4;
    float4 a = *(const float4*)(w2 + i);
    ushort4 s0, s1, s2;
    split3(a.x, s0.x, s1.x, s2.x); split3(a.y, s0.y, s1.y, s2.y);
    split3(a.z, s0.z, s1.z, s2.z); split3(a.w, s0.w, s1.w, s2.w);
    *(ushort4*)(w2s0+i)=s0; *(ushort4*)(w2s1+i)=s1; *(ushort4*)(w2s2+i)=s2;
    float4 b = *(const float4*)(w3 + i);
    split3(b.x, s0.x, s1.x, s2.x); split3(b.y, s0.y, s1.y, s2.y);
    split3(b.z, s0.z, s1.z, s2.z); split3(b.w, s0.w, s1.w, s2.w);
    *(ushort4*)(w3s0+i)=s0; *(ushort4*)(w3s1+i)=s1; *(ushort4*)(w3s2+i)=s2;
    float4 c = *(const float4*)(d1 + i);
    ushort4 u; u.x=f2bf(c.x); u.y=f2bf(c.y); u.z=f2bf(c.z); u.w=f2bf(c.w);
    *(ushort4*)(w1b+i) = u;
    float4 d = *(const float4*)(d2 + i);
    u.x=f2bf(d.x); u.y=f2bf(d.y); u.z=f2bf(d.z); u.w=f2bf(d.w);
    *(ushort4*)(w2b+i) = u;
}

// ---------------------------------------------------------------------------
// ||c||^2 per code (f32 exact) + bf16 codebook copy + 3-way split planes
// ---------------------------------------------------------------------------
__global__ __launch_bounds__(256) void cnorm_kernel(
    const float* __restrict__ cb, float* __restrict__ cn,
    ushort* __restrict__ cbb,
    ushort* __restrict__ cbs0, ushort* __restrict__ cbs1, ushort* __restrict__ cbs2)
{
    const int lane = threadIdx.x & 63;
    const int code = blockIdx.x*4 + (threadIdx.x >> 6);
    float4 v = ((const float4*)(cb + (size_t)code*256))[lane];
    size_t off = (size_t)code*256 + lane*4;
    ushort4 u; u.x=f2bf(v.x); u.y=f2bf(v.y); u.z=f2bf(v.z); u.w=f2bf(v.w);
    *(ushort4*)(cbb + off) = u;
    ushort4 s0, s1, s2;
    split3(v.x, s0.x, s1.x, s2.x); split3(v.y, s0.y, s1.y, s2.y);
    split3(v.z, s0.z, s1.z, s2.z); split3(v.w, s0.w, s1.w, s2.w);
    *(ushort4*)(cbs0 + off) = s0;
    *(ushort4*)(cbs1 + off) = s1;
    *(ushort4*)(cbs2 + off) = s2;
    float s = v.x*v.x + v.y*v.y + v.z*v.z + v.w*v.w;
    #pragma unroll
    for (int m=1; m<64; m<<=1) s += __shfl_xor(s, m);
    if (lane == 0) cn[code] = s;
}

// ---------------------------------------------------------------------------
// f32-faithful MFMA GEMM via 6-term split-bf16 (proven LDS-staged form):
// C[M,256] = act(A[M,256] @ W[256,256]^T + b), A split in-kernel, W pre-split.
// ---------------------------------------------------------------------------
template<bool GELU>
__global__ __launch_bounds__(256) void split6_gemm(
    const float* __restrict__ Ain,
    const ushort* __restrict__ W0, const ushort* __restrict__ W1,
    const ushort* __restrict__ W2,
    const float* __restrict__ bias,
    float* __restrict__ Cout)
{
    __shared__ __align__(16) ushort Al[3][128][40];
    __shared__ __align__(16) ushort Wl[3][128][40];

    const int tid = threadIdx.x;
    const int m0 = blockIdx.x * 128;
    const int n0 = blockIdx.y * 128;
    const int srow = tid >> 1, shalf = (tid & 1) * 16;
    const int lane = tid & 63;
    const int w = tid >> 6;
    const int wm = (w >> 1) * 64, wn = (w & 1) * 64;
    const int lr = lane & 15, lg = lane >> 4;

    const float*  asrc = Ain + (size_t)(m0 + srow)*256 + shalf;
    const ushort* ws0  = W0  + (size_t)(n0 + srow)*256 + shalf;
    const ushort* ws1  = W1  + (size_t)(n0 + srow)*256 + shalf;
    const ushort* ws2  = W2  + (size_t)(n0 + srow)*256 + shalf;

    f32x4 acc[4][4];
    #pragma unroll
    for (int mi=0;mi<4;++mi)
        #pragma unroll
        for (int ni=0;ni<4;++ni)
            acc[mi][ni] = (f32x4){0.f,0.f,0.f,0.f};

    for (int k0=0; k0<256; k0+=32){
        float x[16];
        *(float4*)&x[0]  = *(const float4*)(asrc + k0);
        *(float4*)&x[4]  = *(const float4*)(asrc + k0 + 4);
        *(float4*)&x[8]  = *(const float4*)(asrc + k0 + 8);
        *(float4*)&x[12] = *(const float4*)(asrc + k0 + 12);
        ushort t0[16], t1[16], t2[16];
        #pragma unroll
        for (int e=0;e<16;++e) split3(x[e], t0[e], t1[e], t2[e]);
        *(uint4*)&Al[0][srow][shalf]   = *(const uint4*)&t0[0];
        *(uint4*)&Al[0][srow][shalf+8] = *(const uint4*)&t0[8];
        *(uint4*)&Al[1][srow][shalf]   = *(const uint4*)&t1[0];
        *(uint4*)&Al[1][srow][shalf+8] = *(const uint4*)&t1[8];
        *(uint4*)&Al[2][srow][shalf]   = *(const uint4*)&t2[0];
        *(uint4*)&Al[2][srow][shalf+8] = *(const uint4*)&t2[8];
        *(uint4*)&Wl[0][srow][shalf]   = *(const uint4*)(ws0 + k0);
        *(uint4*)&Wl[0][srow][shalf+8] = *(const uint4*)(ws0 + k0 + 8);
        *(uint4*)&Wl[1][srow][shalf]   = *(const uint4*)(ws1 + k0);
        *(uint4*)&Wl[1][srow][shalf+8] = *(const uint4*)(ws1 + k0 + 8);
        *(uint4*)&Wl[2][srow][shalf]   = *(const uint4*)(ws2 + k0);
        *(uint4*)&Wl[2][srow][shalf+8] = *(const uint4*)(ws2 + k0 + 8);
        __syncthreads();

        short8 b0[4], b1[4], b2[4];
        #pragma unroll
        for (int ni=0;ni<4;++ni){
            b0[ni] = *(const short8*)&Wl[0][wn + ni*16 + lr][lg*8];
            b1[ni] = *(const short8*)&Wl[1][wn + ni*16 + lr][lg*8];
            b2[ni] = *(const short8*)&Wl[2][wn + ni*16 + lr][lg*8];
        }
        #pragma unroll
        for (int mi=0;mi<4;++mi){
            short8 a0 = *(const short8*)&Al[0][wm + mi*16 + lr][lg*8];
            short8 a1 = *(const short8*)&Al[1][wm + mi*16 + lr][lg*8];
            short8 a2 = *(const short8*)&Al[2][wm + mi*16 + lr][lg*8];
            #pragma unroll
            for (int ni=0;ni<4;++ni)
                acc[mi][ni] = __builtin_amdgcn_mfma_f32_16x16x32_bf16(a0, b0[ni], acc[mi][ni], 0,0,0);
            #pragma unroll
            for (int ni=0;ni<4;++ni)
                acc[mi][ni] = __builtin_amdgcn_mfma_f32_16x16x32_bf16(a0, b1[ni], acc[mi][ni], 0,0,0);
            #pragma unroll
            for (int ni=0;ni<4;++ni)
                acc[mi][ni] = __builtin_amdgcn_mfma_f32_16x16x32_bf16(a1, b0[ni], acc[mi][ni], 0,0,0);
            #pragma unroll
            for (int ni=0;ni<4;++ni)
                acc[mi][ni] = __builtin_amdgcn_mfma_f32_16x16x32_bf16(a0, b2[ni], acc[mi][ni], 0,0,0);
            #pragma unroll
            for (int ni=0;ni<4;++ni)
                acc[mi][ni] = __builtin_amdgcn_mfma_f32_16x16x32_bf16(a1, b1[ni], acc[mi][ni], 0,0,0);
            #pragma unroll
            for (int ni=0;ni<4;++ni)
                acc[mi][ni] = __builtin_amdgcn_mfma_f32_16x16x32_bf16(a2, b0[ni], acc[mi][ni], 0,0,0);
        }
        __syncthreads();
    }

    float bn[4];
    #pragma unroll
    for (int ni=0;ni<4;++ni) bn[ni] = bias[n0 + wn + ni*16 + lr];
    #pragma unroll
    for (int mi=0;mi<4;++mi)
        #pragma unroll
        for (int ni=0;ni<4;++ni)
            #pragma unroll
            for (int r=0;r<4;++r){
                int row = m0 + wm + mi*16 + lg*4 + r;
                float v = acc[mi][ni][r] + bn[ni];
                if (GELU) v = gelu_f(v);
                Cout[(size_t)row*256 + n0 + wn + ni*16 + lr] = v;
            }
}

#define INSERT1(dv, iv) do { \
    float _d = (dv); int _i = (iv); \
    if (_d < bd || (_d == bd && _i < bi)){ bd = _d; bi = _i; } \
} while(0)

// ---------------------------------------------------------------------------
// EXACT distance pass via 6-term split-bf16 MFMA (no rescore needed):
// per block 128 rows x 128 codes; d = cn[c] - 2*dot_exact(z,c);
// top-1 per row -> partials[row][colblock] = (d, idx).
// ---------------------------------------------------------------------------
__global__ __launch_bounds__(256) void tokens_split6(
    const float* __restrict__ Zf,
    const ushort* __restrict__ C0, const ushort* __restrict__ C1,
    const ushort* __restrict__ C2,
    const float* __restrict__ cn,
    float2* __restrict__ partials)
{
    __shared__ __align__(16) ushort Al[3][128][40];
    __shared__ __align__(16) ushort Wl[3][128][40];
    __shared__ float2 ptop[128][2];

    const int tid = threadIdx.x;
    const int m0 = blockIdx.x * 128;
    const int n0 = blockIdx.y * 128;
    const int srow = tid >> 1, shalf = (tid & 1) * 16;
    const int lane = tid & 63;
    const int w = tid >> 6;
    const int wm = (w >> 1) * 64, wn = (w & 1) * 64;
    const int lr = lane & 15, lg = lane >> 4;

    const float*  asrc = Zf + (size_t)(m0 + srow)*256 + shalf;
    const ushort* ws0  = C0 + (size_t)(n0 + srow)*256 + shalf;
    const ushort* ws1  = C1 + (size_t)(n0 + srow)*256 + shalf;
    const ushort* ws2  = C2 + (size_t)(n0 + srow)*256 + shalf;

    f32x4 acc[4][4];
    #pragma unroll
    for (int mi=0;mi<4;++mi)
        #pragma unroll
        for (int ni=0;ni<4;++ni)
            acc[mi][ni] = (f32x4){0.f,0.f,0.f,0.f};

    for (int k0=0; k0<256; k0+=32){
        float x[16];
        *(float4*)&x[0]  = *(const float4*)(asrc + k0);
        *(float4*)&x[4]  = *(const float4*)(asrc + k0 + 4);
        *(float4*)&x[8]  = *(const float4*)(asrc + k0 + 8);
        *(float4*)&x[12] = *(const float4*)(asrc + k0 + 12);
        ushort t0[16], t1[16], t2[16];
        #pragma unroll
        for (int e=0;e<16;++e) split3(x[e], t0[e], t1[e], t2[e]);
        *(uint4*)&Al[0][srow][shalf]   = *(const uint4*)&t0[0];
        *(uint4*)&Al[0][srow][shalf+8] = *(const uint4*)&t0[8];
        *(uint4*)&Al[1][srow][shalf]   = *(const uint4*)&t1[0];
        *(uint4*)&Al[1][srow][shalf+8] = *(const uint4*)&t1[8];
        *(uint4*)&Al[2][srow][shalf]   = *(const uint4*)&t2[0];
        *(uint4*)&Al[2][srow][shalf+8] = *(const uint4*)&t2[8];
        *(uint4*)&Wl[0][srow][shalf]   = *(const uint4*)(ws0 + k0);
        *(uint4*)&Wl[0][srow][shalf+8] = *(const uint4*)(ws0 + k0 + 8);
        *(uint4*)&Wl[1][srow][shalf]   = *(const uint4*)(ws1 + k0);
        *(uint4*)&Wl[1][srow][shalf+8] = *(const uint4*)(ws1 + k0 + 8);
        *(uint4*)&Wl[2][srow][shalf]   = *(const uint4*)(ws2 + k0);
        *(uint4*)&Wl[2][srow][shalf+8] = *(const uint4*)(ws2 + k0 + 8);
        __syncthreads();

        short8 b0[4], b1[4], b2[4];
        #pragma unroll
        for (int ni=0;ni<4;++ni){
            b0[ni] = *(const short8*)&Wl[0][wn + ni*16 + lr][lg*8];
            b1[ni] = *(const short8*)&Wl[1][wn + ni*16 + lr][lg*8];
            b2[ni] = *(const short8*)&Wl[2][wn + ni*16 + lr][lg*8];
        }
        #pragma unroll
        for (int mi=0;mi<4;++mi){
            short8 a0 = *(const short8*)&Al[0][wm + mi*16 + lr][lg*8];
            short8 a1 = *(const short8*)&Al[1][wm + mi*16 + lr][lg*8];
            short8 a2 = *(const short8*)&Al[2][wm + mi*16 + lr][lg*8];
            #pragma unroll
            for (int ni=0;ni<4;++ni)
                acc[mi][ni] = __builtin_amdgcn_mfma_f32_16x16x32_bf16(a0, b0[ni], acc[mi][ni], 0,0,0);
            #pragma unroll
            for (int ni=0;ni<4;++ni)
                acc[mi][ni] = __builtin_amdgcn_mfma_f32_16x16x32_bf16(a0, b1[ni], acc[mi][ni], 0,0,0);
            #pragma unroll
            for (int ni=0;ni<4;++ni)
                acc[mi][ni] = __builtin_amdgcn_mfma_f32_16x16x32_bf16(a1, b0[ni], acc[mi][ni], 0,0,0);
            #pragma unroll
            for (int ni=0;ni<4;++ni)
                acc[mi][ni] = __builtin_amdgcn_mfma_f32_16x16x32_bf16(a0, b2[ni], acc[mi][ni], 0,0,0);
            #pragma unroll
            for (int ni=0;ni<4;++ni)
                acc[mi][ni] = __builtin_amdgcn_mfma_f32_16x16x32_bf16(a1, b1[ni], acc[mi][ni], 0,0,0);
            #pragma unroll
            for (int ni=0;ni<4;++ni)
                acc[mi][ni] = __builtin_amdgcn_mfma_f32_16x16x32_bf16(a2, b0[ni], acc[mi][ni], 0,0,0);
        }
        __syncthreads();
    }

    float cnl[4];
    #pragma unroll
    for (int ni=0;ni<4;++ni) cnl[ni] = cn[n0 + wn + ni*16 + lr];

    #pragma unroll
    for (int mi=0;mi<4;++mi)
        #pragma unroll
        for (int r=0;r<4;++r){
            float bd = FLT_MAX; int bi = INT_MAX;
            #pragma unroll
            for (int ni=0;ni<4;++ni){
                float d = cnl[ni] - 2.0f*acc[mi][ni][r];
                int col = n0 + wn + ni*16 + lr;
                INSERT1(d, col);
            }
            #pragma unroll
            for (int m=1; m<16; m<<=1){
                float od = __shfl_xor(bd, m);
                int   oi = __shfl_xor(bi, m);
                INSERT1(od, oi);
            }
            if (lr == 0)
                ptop[wm + mi*16 + lg*4 + r][w & 1] = make_float2(bd, (float)bi);
        }
    __syncthreads();
    if (tid < 128){
        float2 hA = ptop[tid][0], hB = ptop[tid][1];
        int   gA = (int)hA.y, gB = (int)hB.y;
        bool takeB = (hB.x < hA.x) || (hB.x == hA.x && gB < gA);
        partials[(size_t)(m0 + tid)*4 + blockIdx.y] = takeB ? hB : hA;
    }
}

// ---------------------------------------------------------------------------
// Token + commitment: min over 4 (d,idx) partials; zz from one z read.
// commitment = zz + d_min. Block = 4 waves x 16 rows.
// ---------------------------------------------------------------------------
__global__ __launch_bounds__(256) void token_reduce(
    const float* __restrict__ Z, const float2* __restrict__ partials,
    float* __restrict__ tokf, float* __restrict__ loss)
{
    const int tid = threadIdx.x;
    const int w = tid >> 6, lane = tid & 63;
    const int base = blockIdx.x*64 + w*16;
    float csum = 0.0f;

    for (int rr=0; rr<16; ++rr){
        const int row = base + rr;
        float4 z4 = *(const float4*)(Z + (size_t)row*256 + lane*4);
        float zz = z4.x*z4.x + z4.y*z4.y + z4.z*z4.z + z4.w*z4.w;
        #pragma unroll
        for (int m=1;m<64;m<<=1) zz += __shfl_xor(zz, m);
        float2 pp = partials[(size_t)row*4 + (lane & 3)];
        float d = pp.x; int g = (int)pp.y;
        #pragma unroll
        for (int m=1;m<4;m<<=1){
            float od = __shfl_xor(d, m);
            int   og = __shfl_xor(g, m);
            if (od < d || (od == d && og < g)){ d = od; g = og; }
        }
        if (lane == 0){
            tokf[row] = (float)g;
            csum += zz + d;
        }
    }
    __shared__ float wsum[4];
    if (lane == 0) wsum[w] = csum;
    __syncthreads();
    if (tid == 0) atomicAdd(loss + 1, wsum[0]+wsum[1]+wsum[2]+wsum[3]);
}

// ---------------------------------------------------------------------------
// bf16 MFMA GEMM (decoder 1/2): Y[M,256] = gelu(A @ W^T + b)
// LOADER: 0 = plain bf16 A, 1 = gather bf16 codebook rows via tokens.
// ---------------------------------------------------------------------------
template<int LOADER>
__global__ __launch_bounds__(256) void mfma_gemm(
    const ushort* __restrict__ Abf,
    const ushort* __restrict__ cbb,
    const float* __restrict__ tokf,
    const ushort* __restrict__ Wbf,
    const float* __restrict__ bias,
    ushort* __restrict__ Ybf)
{
    __shared__ __align__(16) ushort Al[128][40];
    __shared__ __align__(16) ushort Wl[128][40];

    const int tid = threadIdx.x;
    const int m0 = blockIdx.x * 128;
    const int n0 = blockIdx.y * 128;
    const int srow = tid >> 1, shalf = (tid & 1) * 16;
    const int lane = tid & 63;
    const int w = tid >> 6;
    const int wm = (w >> 1) * 64, wn = (w & 1) * 64;
    const int lr = lane & 15, lg = lane >> 4;

    const ushort* asrc;
    if constexpr (LOADER == 1){
        int g = (int)tokf[m0 + srow];
        asrc = cbb + (size_t)g*256 + shalf;
    } else {
        asrc = Abf + (size_t)(m0 + srow)*256 + shalf;
    }
    const ushort* wsrc = Wbf + (size_t)(n0 + srow)*256 + shalf;

    f32x4 acc[4][4];
    #pragma unroll
    for (int mi=0;mi<4;++mi)
        #pragma unroll
        for (int ni=0;ni<4;++ni)
            acc[mi][ni] = (f32x4){0.f,0.f,0.f,0.f};

    for (int k0=0; k0<256; k0+=32){
        *(uint4*)&Al[srow][shalf]   = *(const uint4*)(asrc + k0);
        *(uint4*)&Al[srow][shalf+8] = *(const uint4*)(asrc + k0 + 8);
        *(uint4*)&Wl[srow][shalf]   = *(const uint4*)(wsrc + k0);
        *(uint4*)&Wl[srow][shalf+8] = *(const uint4*)(wsrc + k0 + 8);
        __syncthreads();

        short8 af[4], bfr[4];
        #pragma unroll
        for (int mi=0;mi<4;++mi)
            af[mi] = *(const short8*)&Al[wm + mi*16 + lr][lg*8];
        #pragma unroll
        for (int ni=0;ni<4;++ni)
            bfr[ni] = *(const short8*)&Wl[wn + ni*16 + lr][lg*8];
        #pragma unroll
        for (int mi=0;mi<4;++mi)
            #pragma unroll
            for (int ni=0;ni<4;++ni)
                acc[mi][ni] = __builtin_amdgcn_mfma_f32_16x16x32_bf16(
                    af[mi], bfr[ni], acc[mi][ni], 0, 0, 0);
        __syncthreads();
    }

    float bn[4];
    #pragma unroll
    for (int ni=0;ni<4;++ni) bn[ni] = bias[n0 + wn + ni*16 + lr];
    #pragma unroll
    for (int mi=0;mi<4;++mi)
        #pragma unroll
        for (int ni=0;ni<4;++ni)
            #pragma unroll
            for (int r=0;r<4;++r){
                int row = m0 + wm + mi*16 + lg*4 + r;
                float v = acc[mi][ni][r] + bn[ni];
                v = gelu_f(v);
                Ybf[(size_t)row*256 + n0 + wn + ni*16 + lr] = f2bf(v);
            }
}

// ---------------------------------------------------------------------------
// dec3 MFMA: Y[T,48] = A_bf16 @ W3^T + b3 (W3 converted in-kernel),
// fused un-patchify + recon loss. 256 rows/block, 4 waves of 64 rows.
// ---------------------------------------------------------------------------
__global__ __launch_bounds__(256) void dec3_mfma(
    const ushort* __restrict__ Ain, const float* __restrict__ W,
    const float* __restrict__ bias, const float* __restrict__ frames,
    float* __restrict__ recon, float* __restrict__ loss)
{
    __shared__ __align__(16) ushort Al[256][40];
    __shared__ __align__(16) ushort Wl[48][40];

    const int tid = threadIdx.x;
    const int m0 = blockIdx.x * 256;
    const int lane = tid & 63;
    const int w = tid >> 6;
    const int lr = lane & 15, lg = lane >> 4;

    const ushort* asrc = Ain + (size_t)(m0 + tid)*256;

    f32x4 acc[4][3];
    #pragma unroll
    for (int mi=0;mi<4;++mi)
        #pragma unroll
        for (int ni=0;ni<3;++ni)
            acc[mi][ni] = (f32x4){0.f,0.f,0.f,0.f};

    for (int k0=0; k0<256; k0+=32){
        *(uint4*)&Al[tid][0]  = *(const uint4*)(asrc + k0);
        *(uint4*)&Al[tid][8]  = *(const uint4*)(asrc + k0 + 8);
        *(uint4*)&Al[tid][16] = *(const uint4*)(asrc + k0 + 16);
        *(uint4*)&Al[tid][24] = *(const uint4*)(asrc + k0 + 24);
        if (tid < 96){
            const int wrow = tid >> 1, wh = (tid & 1)*16;
            const float* wp = W + (size_t)wrow*256 + k0 + wh;
            float4 f0 = *(const float4*)(wp);
            float4 f1 = *(const float4*)(wp+4);
            float4 f2 = *(const float4*)(wp+8);
            float4 f3 = *(const float4*)(wp+12);
            ushort t[16];
            t[0]=f2bf(f0.x); t[1]=f2bf(f0.y); t[2]=f2bf(f0.z); t[3]=f2bf(f0.w);
            t[4]=f2bf(f1.x); t[5]=f2bf(f1.y); t[6]=f2bf(f1.z); t[7]=f2bf(f1.w);
            t[8]=f2bf(f2.x); t[9]=f2bf(f2.y); t[10]=f2bf(f2.z); t[11]=f2bf(f2.w);
            t[12]=f2bf(f3.x); t[13]=f2bf(f3.y); t[14]=f2bf(f3.z); t[15]=f2bf(f3.w);
            *(uint4*)&Wl[wrow][wh]   = *(const uint4*)&t[0];
            *(uint4*)&Wl[wrow][wh+8] = *(const uint4*)&t[8];
        }
        __syncthreads();

        short8 bfr[3];
        #pragma unroll
        for (int ni=0;ni<3;++ni)
            bfr[ni] = *(const short8*)&Wl[ni*16 + lr][lg*8];
        #pragma unroll
        for (int mi=0;mi<4;++mi){
            short8 af = *(const short8*)&Al[w*64 + mi*16 + lr][lg*8];
            #pragma unroll
            for (int ni=0;ni<3;++ni)
                acc[mi][ni] = __builtin_amdgcn_mfma_f32_16x16x32_bf16(
                    af, bfr[ni], acc[mi][ni], 0, 0, 0);
        }
        __syncthreads();
    }

    float bn[3]; int phv[3], remv[3];
    #pragma unroll
    for (int ni=0;ni<3;++ni){
        int col = ni*16 + lr;
        bn[ni] = bias[col];
        phv[ni] = col / 12;
        remv[ni] = col - phv[ni]*12;
    }
    const float sc = 2.0f/255.0f;
    float ls = 0.0f;
    #pragma unroll
    for (int mi=0;mi<4;++mi)
        #pragma unroll
        for (int ni=0;ni<3;++ni)
            #pragma unroll
            for (int r=0;r<4;++r){
                int p = m0 + w*64 + mi*16 + lg*4 + r;
                int b = p >> 12, nl = p & 4095, hh = nl >> 6, ww = nl & 63;
                size_t addr = (size_t)(((b*256 + hh*4 + phv[ni])*256 + ww*4)*3 + remv[ni]);
                float y = acc[mi][ni][r] + bn[ni];
                float t = frames[addr]*sc - 1.0f;
                float d = y - t;
                ls += d*d;
                recon[addr] = y;
            }

    #pragma unroll
    for (int off=32; off>0; off>>=1) ls += __shfl_down(ls, off);
    __shared__ float wsum[4];
    if (lane == 0) wsum[w] = ls;
    __syncthreads();
    if (tid == 0) atomicAdd(loss + 0, wsum[0]+wsum[1]+wsum[2]+wsum[3]);
}

__global__ void finalize_kernel(float* __restrict__ loss){
    if (threadIdx.x == 0 && blockIdx.x == 0){
        loss[0] = loss[0] * (1.0f/6291456.0f);
        float c = loss[1] * (1.0f/33554432.0f);
        loss[1] = c;
        loss[2] = c;
    }
}

extern "C" void kernel_launch(void* const* d_in, const int* in_sizes, int n_in,
                              void* d_out, int out_size, void* d_ws, size_t ws_size,
                              hipStream_t stream)
{
    (void)in_sizes; (void)n_in; (void)out_size; (void)ws_size;
    const float* frames   = (const float*)d_in[0];
    const float* enc_w1   = (const float*)d_in[1];
    const float* enc_b1   = (const float*)d_in[2];
    const float* enc_w2   = (const float*)d_in[3];
    const float* enc_b2   = (const float*)d_in[4];
    const float* enc_w3   = (const float*)d_in[5];
    const float* enc_b3   = (const float*)d_in[6];
    const float* codebook = (const float*)d_in[7];
    const float* dec_w1   = (const float*)d_in[8];
    const float* dec_b1   = (const float*)d_in[9];
    const float* dec_w2   = (const float*)d_in[10];
    const float* dec_b2   = (const float*)d_in[11];
    const float* dec_w3   = (const float*)d_in[12];
    const float* dec_b3   = (const float*)d_in[13];

    // workspace: two [T,256] f32 regions (268 MB, proven available)
    float* P = (float*)d_ws;                 // h1 -> z_e -> Y1(bf16)
    float* Q = P + (size_t)33554432;         // h2 -> {Y2(bf16) base, partials}
    float2* partials = (float2*)(Q + 18000000);  // 4 MB, disjoint from Y2
    ushort* Y1 = (ushort*)P;
    ushort* Y2 = (ushort*)Q;

    // outputs; recon region doubles as scratch for small constants
    float* recon = (float*)d_out;            // 6,291,456 f32 (written last)
    float* tokf  = recon + 6291456;          // 131,072
    float* loss  = tokf + 131072;            // 3
    float*  cn   = recon;                            // 512 f32
    ushort* cbb  = (ushort*)(recon + 512);           // 131072 us
    ushort* w1b  = (ushort*)(recon + 66048);         // 65536 us
    ushort* w2b  = (ushort*)(recon + 98816);         // 65536 us
    ushort* w2s0 = (ushort*)(recon + 131584);        // 65536 us each
    ushort* w2s1 = (ushort*)(recon + 164352);
    ushort* w2s2 = (ushort*)(recon + 197120);
    ushort* w3s0 = (ushort*)(recon + 229888);
    ushort* w3s1 = (ushort*)(recon + 262656);
    ushort* w3s2 = (ushort*)(recon + 295424);
    ushort* cbs0 = (ushort*)(recon + 328192);        // 131072 us each
    ushort* cbs1 = (ushort*)(recon + 393728);
    ushort* cbs2 = (ushort*)(recon + 459264);        // ends 524800 < 6.29M

    hipMemsetAsync(loss, 0, 3*sizeof(float), stream);

    dim3 blk(256), grid2(T_ROWS/128, 2);
    // weight prep
    wsplit_kernel<<<dim3(64), blk, 0, stream>>>(enc_w2, enc_w3, dec_w1, dec_w2,
        w2s0, w2s1, w2s2, w3s0, w3s1, w3s2, w1b, w2b);
    cnorm_kernel<<<dim3(128), blk, 0, stream>>>(codebook, cn, cbb, cbs0, cbs1, cbs2);
    // encoder: f32 layer1, then f32-faithful 6-term split-bf16 MFMA
    gemm_kernel<48, true, 1><<<grid2, blk, 0, stream>>>(nullptr, frames, enc_w1, enc_b1, P);
    split6_gemm<true ><<<grid2, blk, 0, stream>>>(P, w2s0, w2s1, w2s2, enc_b2, Q);
    split6_gemm<false><<<grid2, blk, 0, stream>>>(Q, w3s0, w3s1, w3s2, enc_b3, P);
    // vector quantization: EXACT split6 distances + tiny reduce (no rescore)
    tokens_split6<<<dim3(T_ROWS/128, 4), blk, 0, stream>>>(P, cbs0, cbs1, cbs2, cn, partials);
    token_reduce<<<dim3(T_ROWS/64), blk, 0, stream>>>(P, partials, tokf, loss);
    // decoder (bf16 MFMA)
    mfma_gemm<1><<<grid2, blk, 0, stream>>>(nullptr, cbb, tokf, w1b, dec_b1, Y1);
    mfma_gemm<0><<<grid2, blk, 0, stream>>>(Y1, nullptr, nullptr, w2b, dec_b2, Y2);
    dec3_mfma<<<dim3(T_ROWS/256), blk, 0, stream>>>(Y2, dec_w3, dec_b3, frames, recon, loss);
    finalize_kernel<<<dim3(1), dim3(64), 0, stream>>>(loss);
}

// Round 9
// 736.801 us; speedup vs baseline: 1.5643x; 1.0588x over previous
//
#include <hip/hip_runtime.h>
#include <hip/hip_bf16.h>
#include <math.h>
#include <float.h>
#include <limits.h>

#define T_ROWS 131072   // 32 * 4096 patches

typedef __attribute__((ext_vector_type(8))) short short8;
typedef __attribute__((ext_vector_type(4))) float f32x4;

__device__ __forceinline__ float gelu_f(float x){
    return 0.5f * x * (1.0f + erff(x * 0.7071067811865475f));
}
__device__ __forceinline__ float bf2f(ushort u){
    union { unsigned int i; float f; } v; v.i = ((unsigned int)u) << 16; return v.f;
}
__device__ __forceinline__ ushort f2bf(float f){
    union { float f; unsigned int i; } v; v.f = f;
    unsigned int i = v.i;
    unsigned int r = (i + 0x7fffu + ((i >> 16) & 1u)) >> 16;
    return (ushort)r;
}
// exact 3-way truncation split: x ~= b0+b1+b2 (each bf16), >=24 mantissa bits
__device__ __forceinline__ void split3(float x, ushort &u0, ushort &u1, ushort &u2){
    union { float f; unsigned int i; } v; v.f = x;
    u0 = (ushort)(v.i >> 16);
    union { unsigned int i; float f; } h0; h0.i = ((unsigned int)u0) << 16;
    float r = x - h0.f;                       // exact (Sterbenz)
    union { float f; unsigned int i; } vr; vr.f = r;
    u1 = (ushort)(vr.i >> 16);
    union { unsigned int i; float f; } h1; h1.i = ((unsigned int)u1) << 16;
    float r2 = r - h1.f;                      // exact
    union { float f; unsigned int i; } v2; v2.f = r2;
    u2 = (ushort)(v2.i >> 16);
}

// ---------------------------------------------------------------------------
// f32 tiled GEMM (enc1 only): C[M,256] = gelu(patchify(frames) @ W^T + b)
// ---------------------------------------------------------------------------
template<int K, bool GELU, int LOADER>
__global__ __launch_bounds__(256) void gemm_kernel(
    const float* __restrict__ Ain,
    const float* __restrict__ frames,
    const float* __restrict__ W,
    const float* __restrict__ bias,
    float* __restrict__ Cout)
{
    constexpr int BM=128, BN=128, BK=16;
    __shared__ __align__(16) float As[BK][BM+4];
    __shared__ __align__(16) float Ws[BK][BN+4];

    const int tid = threadIdx.x;
    const int tx = tid & 15, ty = tid >> 4;
    const int m0 = blockIdx.x * BM;
    const int c0 = blockIdx.y * BN;

    const int q  = tid & 3;
    const int r0 = tid >> 2;

    const float* aptr0 = nullptr;
    const float* aptr1 = nullptr;
    int base0 = 0, base1 = 0;
    if constexpr (LOADER == 0){
        aptr0 = Ain + (size_t)(m0 + r0) * K;
        aptr1 = aptr0 + (size_t)64 * K;
    } else {
        int p0 = m0 + r0;
        int b = p0 >> 12, nl = p0 & 4095, hh = nl >> 6, ww = nl & 63;
        base0 = ((b*256 + hh*4)*256 + ww*4)*3;
        int p1 = p0 + 64;
        b = p1 >> 12; nl = p1 & 4095; hh = nl >> 6; ww = nl & 63;
        base1 = ((b*256 + hh*4)*256 + ww*4)*3;
    }
    const float* wptr0 = W + (size_t)(c0 + r0) * K;
    const float* wptr1 = wptr0 + (size_t)64 * K;

    float acc[8][8];
    #pragma unroll
    for (int i=0;i<8;++i)
        #pragma unroll
        for (int j=0;j<8;++j) acc[i][j] = 0.0f;

    for (int k0 = 0; k0 < K; k0 += BK){
        const int k = k0 + q*4;
        float4 va, vb;
        if constexpr (LOADER == 1){
            const int ph = k / 12, rem = k - ph*12;
            va = *(const float4*)(frames + base0 + ph*768 + rem);
            vb = *(const float4*)(frames + base1 + ph*768 + rem);
            const float sc = 2.0f/255.0f;
            va.x = va.x*sc - 1.0f; va.y = va.y*sc - 1.0f;
            va.z = va.z*sc - 1.0f; va.w = va.w*sc - 1.0f;
            vb.x = vb.x*sc - 1.0f; vb.y = vb.y*sc - 1.0f;
            vb.z = vb.z*sc - 1.0f; vb.w = vb.w*sc - 1.0f;
        } else {
            va = *(const float4*)(aptr0 + k);
            vb = *(const float4*)(aptr1 + k);
        }
        As[q*4+0][r0]    = va.x; As[q*4+1][r0]    = va.y;
        As[q*4+2][r0]    = va.z; As[q*4+3][r0]    = va.w;
        As[q*4+0][r0+64] = vb.x; As[q*4+1][r0+64] = vb.y;
        As[q*4+2][r0+64] = vb.z; As[q*4+3][r0+64] = vb.w;

        float4 wa = *(const float4*)(wptr0 + k);
        float4 wb = *(const float4*)(wptr1 + k);
        Ws[q*4+0][r0]    = wa.x; Ws[q*4+1][r0]    = wa.y;
        Ws[q*4+2][r0]    = wa.z; Ws[q*4+3][r0]    = wa.w;
        Ws[q*4+0][r0+64] = wb.x; Ws[q*4+1][r0+64] = wb.y;
        Ws[q*4+2][r0+64] = wb.z; Ws[q*4+3][r0+64] = wb.w;

        __syncthreads();
        #pragma unroll
        for (int kk=0; kk<BK; ++kk){
            float a[8], b[8];
            *(float4*)&a[0] = *(const float4*)&As[kk][ty*4];
            *(float4*)&a[4] = *(const float4*)&As[kk][64+ty*4];
            *(float4*)&b[0] = *(const float4*)&Ws[kk][tx*4];
            *(float4*)&b[4] = *(const float4*)&Ws[kk][64+tx*4];
            #pragma unroll
            for (int i=0;i<8;++i)
                #pragma unroll
                for (int j=0;j<8;++j)
                    acc[i][j] = fmaf(a[i], b[j], acc[i][j]);
        }
        __syncthreads();
    }

    float bj[8];
    *(float4*)&bj[0] = *(const float4*)(bias + c0 + tx*4);
    *(float4*)&bj[4] = *(const float4*)(bias + c0 + 64 + tx*4);
    #pragma unroll
    for (int i=0;i<8;++i){
        const int row = m0 + ((i<4) ? (ty*4+i) : (64+ty*4+i-4));
        float o[8];
        #pragma unroll
        for (int j=0;j<8;++j){
            float x = acc[i][j] + bj[j];
            o[j] = GELU ? gelu_f(x) : x;
        }
        float* dst = Cout + (size_t)row*256 + c0 + tx*4;
        *(float4*)dst      = *(const float4*)&o[0];
        *(float4*)(dst+64) = *(const float4*)&o[4];
    }
}

// ---------------------------------------------------------------------------
// weight prep: 3-way split enc_w2/enc_w3; bf16 round dec_w1/dec_w2
// ---------------------------------------------------------------------------
__global__ __launch_bounds__(256) void wsplit_kernel(
    const float* __restrict__ w2, const float* __restrict__ w3,
    const float* __restrict__ d1, const float* __restrict__ d2,
    ushort* __restrict__ w2s0, ushort* __restrict__ w2s1, ushort* __restrict__ w2s2,
    ushort* __restrict__ w3s0, ushort* __restrict__ w3s1, ushort* __restrict__ w3s2,
    ushort* __restrict__ w1b, ushort* __restrict__ w2b)
{
    const int i = (blockIdx.x*256 + threadIdx.x)*4;
    float4 a = *(const float4*)(w2 + i);
    ushort4 s0, s1, s2;
    split3(a.x, s0.x, s1.x, s2.x); split3(a.y, s0.y, s1.y, s2.y);
    split3(a.z, s0.z, s1.z, s2.z); split3(a.w, s0.w, s1.w, s2.w);
    *(ushort4*)(w2s0+i)=s0; *(ushort4*)(w2s1+i)=s1; *(ushort4*)(w2s2+i)=s2;
    float4 b = *(const float4*)(w3 + i);
    split3(b.x, s0.x, s1.x, s2.x); split3(b.y, s0.y, s1.y, s2.y);
    split3(b.z, s0.z, s1.z, s2.z); split3(b.w, s0.w, s1.w, s2.w);
    *(ushort4*)(w3s0+i)=s0; *(ushort4*)(w3s1+i)=s1; *(ushort4*)(w3s2+i)=s2;
    float4 c = *(const float4*)(d1 + i);
    ushort4 u; u.x=f2bf(c.x); u.y=f2bf(c.y); u.z=f2bf(c.z); u.w=f2bf(c.w);
    *(ushort4*)(w1b+i) = u;
    float4 d = *(const float4*)(d2 + i);
    u.x=f2bf(d.x); u.y=f2bf(d.y); u.z=f2bf(d.z); u.w=f2bf(d.w);
    *(ushort4*)(w2b+i) = u;
}

// ---------------------------------------------------------------------------
// ||c||^2 per code (f32 exact) + bf16 codebook copy + 3-way split planes
// ---------------------------------------------------------------------------
__global__ __launch_bounds__(256) void cnorm_kernel(
    const float* __restrict__ cb, float* __restrict__ cn,
    ushort* __restrict__ cbb,
    ushort* __restrict__ cbs0, ushort* __restrict__ cbs1, ushort* __restrict__ cbs2)
{
    const int lane = threadIdx.x & 63;
    const int code = blockIdx.x*4 + (threadIdx.x >> 6);
    float4 v = ((const float4*)(cb + (size_t)code*256))[lane];
    size_t off = (size_t)code*256 + lane*4;
    ushort4 u; u.x=f2bf(v.x); u.y=f2bf(v.y); u.z=f2bf(v.z); u.w=f2bf(v.w);
    *(ushort4*)(cbb + off) = u;
    ushort4 s0, s1, s2;
    split3(v.x, s0.x, s1.x, s2.x); split3(v.y, s0.y, s1.y, s2.y);
    split3(v.z, s0.z, s1.z, s2.z); split3(v.w, s0.w, s1.w, s2.w);
    *(ushort4*)(cbs0 + off) = s0;
    *(ushort4*)(cbs1 + off) = s1;
    *(ushort4*)(cbs2 + off) = s2;
    float s = v.x*v.x + v.y*v.y + v.z*v.z + v.w*v.w;
    #pragma unroll
    for (int m=1; m<64; m<<=1) s += __shfl_xor(s, m);
    if (lane == 0) cn[code] = s;
}

// ---------------------------------------------------------------------------
// f32-faithful MFMA GEMM via 6-term split-bf16.
// A split in-kernel -> LDS (3 planes); W planes 0,1 staged in LDS,
// plane 2 fragments loaded directly from global (L2-resident) ->
// LDS 50 KB -> 3 blocks/CU.
// ---------------------------------------------------------------------------
template<bool GELU>
__global__ __launch_bounds__(256) void split6_gemm(
    const float* __restrict__ Ain,
    const ushort* __restrict__ W0, const ushort* __restrict__ W1,
    const ushort* __restrict__ W2,
    const float* __restrict__ bias,
    float* __restrict__ Cout)
{
    __shared__ __align__(16) ushort Al[3][128][40];
    __shared__ __align__(16) ushort Wl[2][128][40];

    const int tid = threadIdx.x;
    const int m0 = blockIdx.x * 128;
    const int n0 = blockIdx.y * 128;
    const int srow = tid >> 1, shalf = (tid & 1) * 16;
    const int lane = tid & 63;
    const int w = tid >> 6;
    const int wm = (w >> 1) * 64, wn = (w & 1) * 64;
    const int lr = lane & 15, lg = lane >> 4;

    const float*  asrc = Ain + (size_t)(m0 + srow)*256 + shalf;
    const ushort* ws0  = W0  + (size_t)(n0 + srow)*256 + shalf;
    const ushort* ws1  = W1  + (size_t)(n0 + srow)*256 + shalf;
    const ushort* w2frag = W2 + (size_t)(n0 + wn + lr)*256 + lg*8;

    f32x4 acc[4][4];
    #pragma unroll
    for (int mi=0;mi<4;++mi)
        #pragma unroll
        for (int ni=0;ni<4;++ni)
            acc[mi][ni] = (f32x4){0.f,0.f,0.f,0.f};

    for (int k0=0; k0<256; k0+=32){
        float x[16];
        *(float4*)&x[0]  = *(const float4*)(asrc + k0);
        *(float4*)&x[4]  = *(const float4*)(asrc + k0 + 4);
        *(float4*)&x[8]  = *(const float4*)(asrc + k0 + 8);
        *(float4*)&x[12] = *(const float4*)(asrc + k0 + 12);
        ushort t0[16], t1[16], t2[16];
        #pragma unroll
        for (int e=0;e<16;++e) split3(x[e], t0[e], t1[e], t2[e]);
        *(uint4*)&Al[0][srow][shalf]   = *(const uint4*)&t0[0];
        *(uint4*)&Al[0][srow][shalf+8] = *(const uint4*)&t0[8];
        *(uint4*)&Al[1][srow][shalf]   = *(const uint4*)&t1[0];
        *(uint4*)&Al[1][srow][shalf+8] = *(const uint4*)&t1[8];
        *(uint4*)&Al[2][srow][shalf]   = *(const uint4*)&t2[0];
        *(uint4*)&Al[2][srow][shalf+8] = *(const uint4*)&t2[8];
        *(uint4*)&Wl[0][srow][shalf]   = *(const uint4*)(ws0 + k0);
        *(uint4*)&Wl[0][srow][shalf+8] = *(const uint4*)(ws0 + k0 + 8);
        *(uint4*)&Wl[1][srow][shalf]   = *(const uint4*)(ws1 + k0);
        *(uint4*)&Wl[1][srow][shalf+8] = *(const uint4*)(ws1 + k0 + 8);
        // plane-2 fragments direct from global (L2-resident)
        short8 b2[4];
        #pragma unroll
        for (int ni=0;ni<4;++ni)
            b2[ni] = *(const short8*)(w2frag + (size_t)ni*16*256 + k0);
        __syncthreads();

        short8 b0[4], b1[4];
        #pragma unroll
        for (int ni=0;ni<4;++ni){
            b0[ni] = *(const short8*)&Wl[0][wn + ni*16 + lr][lg*8];
            b1[ni] = *(const short8*)&Wl[1][wn + ni*16 + lr][lg*8];
        }
        #pragma unroll
        for (int mi=0;mi<4;++mi){
            short8 a0 = *(const short8*)&Al[0][wm + mi*16 + lr][lg*8];
            short8 a1 = *(const short8*)&Al[1][wm + mi*16 + lr][lg*8];
            short8 a2 = *(const short8*)&Al[2][wm + mi*16 + lr][lg*8];
            #pragma unroll
            for (int ni=0;ni<4;++ni)
                acc[mi][ni] = __builtin_amdgcn_mfma_f32_16x16x32_bf16(a0, b0[ni], acc[mi][ni], 0,0,0);
            #pragma unroll
            for (int ni=0;ni<4;++ni)
                acc[mi][ni] = __builtin_amdgcn_mfma_f32_16x16x32_bf16(a0, b1[ni], acc[mi][ni], 0,0,0);
            #pragma unroll
            for (int ni=0;ni<4;++ni)
                acc[mi][ni] = __builtin_amdgcn_mfma_f32_16x16x32_bf16(a1, b0[ni], acc[mi][ni], 0,0,0);
            #pragma unroll
            for (int ni=0;ni<4;++ni)
                acc[mi][ni] = __builtin_amdgcn_mfma_f32_16x16x32_bf16(a0, b2[ni], acc[mi][ni], 0,0,0);
            #pragma unroll
            for (int ni=0;ni<4;++ni)
                acc[mi][ni] = __builtin_amdgcn_mfma_f32_16x16x32_bf16(a1, b1[ni], acc[mi][ni], 0,0,0);
            #pragma unroll
            for (int ni=0;ni<4;++ni)
                acc[mi][ni] = __builtin_amdgcn_mfma_f32_16x16x32_bf16(a2, b0[ni], acc[mi][ni], 0,0,0);
        }
        __syncthreads();
    }

    float bn[4];
    #pragma unroll
    for (int ni=0;ni<4;++ni) bn[ni] = bias[n0 + wn + ni*16 + lr];
    #pragma unroll
    for (int mi=0;mi<4;++mi)
        #pragma unroll
        for (int ni=0;ni<4;++ni)
            #pragma unroll
            for (int r=0;r<4;++r){
                int row = m0 + wm + mi*16 + lg*4 + r;
                float v = acc[mi][ni][r] + bn[ni];
                if (GELU) v = gelu_f(v);
                Cout[(size_t)row*256 + n0 + wn + ni*16 + lr] = v;
            }
}

#define INSERT1(dv, iv) do { \
    float _d = (dv); int _i = (iv); \
    if (_d < bd || (_d == bd && _i < bi)){ bd = _d; bi = _i; } \
} while(0)

// ---------------------------------------------------------------------------
// EXACT distance pass via 6-term split-bf16 MFMA; plane-2 of codebook from
// global; fused ||z||^2 (written by colblock-0 blocks).
// ---------------------------------------------------------------------------
__global__ __launch_bounds__(256) void tokens_split6(
    const float* __restrict__ Zf,
    const ushort* __restrict__ C0, const ushort* __restrict__ C1,
    const ushort* __restrict__ C2,
    const float* __restrict__ cn,
    float2* __restrict__ partials,
    float* __restrict__ zz_out)
{
    __shared__ __align__(16) ushort Al[3][128][40];
    __shared__ __align__(16) ushort Wl[2][128][40];
    __shared__ float2 ptop[128][2];

    const int tid = threadIdx.x;
    const int m0 = blockIdx.x * 128;
    const int n0 = blockIdx.y * 128;
    const int srow = tid >> 1, shalf = (tid & 1) * 16;
    const int lane = tid & 63;
    const int w = tid >> 6;
    const int wm = (w >> 1) * 64, wn = (w & 1) * 64;
    const int lr = lane & 15, lg = lane >> 4;

    const float*  asrc = Zf + (size_t)(m0 + srow)*256 + shalf;
    const ushort* ws0  = C0 + (size_t)(n0 + srow)*256 + shalf;
    const ushort* ws1  = C1 + (size_t)(n0 + srow)*256 + shalf;
    const ushort* c2frag = C2 + (size_t)(n0 + wn + lr)*256 + lg*8;

    f32x4 acc[4][4];
    #pragma unroll
    for (int mi=0;mi<4;++mi)
        #pragma unroll
        for (int ni=0;ni<4;++ni)
            acc[mi][ni] = (f32x4){0.f,0.f,0.f,0.f};

    float zzp = 0.0f;

    for (int k0=0; k0<256; k0+=32){
        float x[16];
        *(float4*)&x[0]  = *(const float4*)(asrc + k0);
        *(float4*)&x[4]  = *(const float4*)(asrc + k0 + 4);
        *(float4*)&x[8]  = *(const float4*)(asrc + k0 + 8);
        *(float4*)&x[12] = *(const float4*)(asrc + k0 + 12);
        ushort t0[16], t1[16], t2[16];
        #pragma unroll
        for (int e=0;e<16;++e){
            split3(x[e], t0[e], t1[e], t2[e]);
            zzp = fmaf(x[e], x[e], zzp);
        }
        *(uint4*)&Al[0][srow][shalf]   = *(const uint4*)&t0[0];
        *(uint4*)&Al[0][srow][shalf+8] = *(const uint4*)&t0[8];
        *(uint4*)&Al[1][srow][shalf]   = *(const uint4*)&t1[0];
        *(uint4*)&Al[1][srow][shalf+8] = *(const uint4*)&t1[8];
        *(uint4*)&Al[2][srow][shalf]   = *(const uint4*)&t2[0];
        *(uint4*)&Al[2][srow][shalf+8] = *(const uint4*)&t2[8];
        *(uint4*)&Wl[0][srow][shalf]   = *(const uint4*)(ws0 + k0);
        *(uint4*)&Wl[0][srow][shalf+8] = *(const uint4*)(ws0 + k0 + 8);
        *(uint4*)&Wl[1][srow][shalf]   = *(const uint4*)(ws1 + k0);
        *(uint4*)&Wl[1][srow][shalf+8] = *(const uint4*)(ws1 + k0 + 8);
        short8 b2[4];
        #pragma unroll
        for (int ni=0;ni<4;++ni)
            b2[ni] = *(const short8*)(c2frag + (size_t)ni*16*256 + k0);
        __syncthreads();

        short8 b0[4], b1[4];
        #pragma unroll
        for (int ni=0;ni<4;++ni){
            b0[ni] = *(const short8*)&Wl[0][wn + ni*16 + lr][lg*8];
            b1[ni] = *(const short8*)&Wl[1][wn + ni*16 + lr][lg*8];
        }
        #pragma unroll
        for (int mi=0;mi<4;++mi){
            short8 a0 = *(const short8*)&Al[0][wm + mi*16 + lr][lg*8];
            short8 a1 = *(const short8*)&Al[1][wm + mi*16 + lr][lg*8];
            short8 a2 = *(const short8*)&Al[2][wm + mi*16 + lr][lg*8];
            #pragma unroll
            for (int ni=0;ni<4;++ni)
                acc[mi][ni] = __builtin_amdgcn_mfma_f32_16x16x32_bf16(a0, b0[ni], acc[mi][ni], 0,0,0);
            #pragma unroll
            for (int ni=0;ni<4;++ni)
                acc[mi][ni] = __builtin_amdgcn_mfma_f32_16x16x32_bf16(a0, b1[ni], acc[mi][ni], 0,0,0);
            #pragma unroll
            for (int ni=0;ni<4;++ni)
                acc[mi][ni] = __builtin_amdgcn_mfma_f32_16x16x32_bf16(a1, b0[ni], acc[mi][ni], 0,0,0);
            #pragma unroll
            for (int ni=0;ni<4;++ni)
                acc[mi][ni] = __builtin_amdgcn_mfma_f32_16x16x32_bf16(a0, b2[ni], acc[mi][ni], 0,0,0);
            #pragma unroll
            for (int ni=0;ni<4;++ni)
                acc[mi][ni] = __builtin_amdgcn_mfma_f32_16x16x32_bf16(a1, b1[ni], acc[mi][ni], 0,0,0);
            #pragma unroll
            for (int ni=0;ni<4;++ni)
                acc[mi][ni] = __builtin_amdgcn_mfma_f32_16x16x32_bf16(a2, b0[ni], acc[mi][ni], 0,0,0);
        }
        __syncthreads();
    }

    // ||z||^2 per row: pair-combine the two k-halves (tid even/odd same row)
    {
        float other = __shfl_xor(zzp, 1);
        if (blockIdx.y == 0 && (tid & 1) == 0)
            zz_out[m0 + srow] = zzp + other;
    }

    float cnl[4];
    #pragma unroll
    for (int ni=0;ni<4;++ni) cnl[ni] = cn[n0 + wn + ni*16 + lr];

    #pragma unroll
    for (int mi=0;mi<4;++mi)
        #pragma unroll
        for (int r=0;r<4;++r){
            float bd = FLT_MAX; int bi = INT_MAX;
            #pragma unroll
            for (int ni=0;ni<4;++ni){
                float d = cnl[ni] - 2.0f*acc[mi][ni][r];
                int col = n0 + wn + ni*16 + lr;
                INSERT1(d, col);
            }
            #pragma unroll
            for (int m=1; m<16; m<<=1){
                float od = __shfl_xor(bd, m);
                int   oi = __shfl_xor(bi, m);
                INSERT1(od, oi);
            }
            if (lr == 0)
                ptop[wm + mi*16 + lg*4 + r][w & 1] = make_float2(bd, (float)bi);
        }
    __syncthreads();
    if (tid < 128){
        float2 hA = ptop[tid][0], hB = ptop[tid][1];
        int   gA = (int)hA.y, gB = (int)hB.y;
        bool takeB = (hB.x < hA.x) || (hB.x == hA.x && gB < gA);
        partials[(size_t)(m0 + tid)*4 + blockIdx.y] = takeB ? hB : hA;
    }
}

// ---------------------------------------------------------------------------
// Token + commitment: min over 4 (d,idx) partials, zz from zz_out.
// One row per thread; grid 512 x 256.
// ---------------------------------------------------------------------------
__global__ __launch_bounds__(256) void token_reduce(
    const float* __restrict__ zz_out, const float2* __restrict__ partials,
    float* __restrict__ tokf, float* __restrict__ loss)
{
    const int tid = threadIdx.x;
    const int row = blockIdx.x*256 + tid;
    float2 p0 = partials[(size_t)row*4 + 0];
    float2 p1 = partials[(size_t)row*4 + 1];
    float2 p2 = partials[(size_t)row*4 + 2];
    float2 p3 = partials[(size_t)row*4 + 3];
    float d = p0.x; int g = (int)p0.y;
    if (p1.x < d || (p1.x == d && (int)p1.y < g)){ d = p1.x; g = (int)p1.y; }
    if (p2.x < d || (p2.x == d && (int)p2.y < g)){ d = p2.x; g = (int)p2.y; }
    if (p3.x < d || (p3.x == d && (int)p3.y < g)){ d = p3.x; g = (int)p3.y; }
    tokf[row] = (float)g;
    float cs = zz_out[row] + d;
    #pragma unroll
    for (int m=1; m<64; m<<=1) cs += __shfl_xor(cs, m);
    __shared__ float wsum[4];
    const int lane = tid & 63, w = tid >> 6;
    if (lane == 0) wsum[w] = cs;
    __syncthreads();
    if (tid == 0) atomicAdd(loss + 1, wsum[0]+wsum[1]+wsum[2]+wsum[3]);
}

// ---------------------------------------------------------------------------
// bf16 MFMA GEMM (decoder 1/2): Y[M,256] = gelu(A @ W^T + b)
// LOADER: 0 = plain bf16 A, 1 = gather bf16 codebook rows via tokens.
// ---------------------------------------------------------------------------
template<int LOADER>
__global__ __launch_bounds__(256) void mfma_gemm(
    const ushort* __restrict__ Abf,
    const ushort* __restrict__ cbb,
    const float* __restrict__ tokf,
    const ushort* __restrict__ Wbf,
    const float* __restrict__ bias,
    ushort* __restrict__ Ybf)
{
    __shared__ __align__(16) ushort Al[128][40];
    __shared__ __align__(16) ushort Wl[128][40];

    const int tid = threadIdx.x;
    const int m0 = blockIdx.x * 128;
    const int n0 = blockIdx.y * 128;
    const int srow = tid >> 1, shalf = (tid & 1) * 16;
    const int lane = tid & 63;
    const int w = tid >> 6;
    const int wm = (w >> 1) * 64, wn = (w & 1) * 64;
    const int lr = lane & 15, lg = lane >> 4;

    const ushort* asrc;
    if constexpr (LOADER == 1){
        int g = (int)tokf[m0 + srow];
        asrc = cbb + (size_t)g*256 + shalf;
    } else {
        asrc = Abf + (size_t)(m0 + srow)*256 + shalf;
    }
    const ushort* wsrc = Wbf + (size_t)(n0 + srow)*256 + shalf;

    f32x4 acc[4][4];
    #pragma unroll
    for (int mi=0;mi<4;++mi)
        #pragma unroll
        for (int ni=0;ni<4;++ni)
            acc[mi][ni] = (f32x4){0.f,0.f,0.f,0.f};

    for (int k0=0; k0<256; k0+=32){
        *(uint4*)&Al[srow][shalf]   = *(const uint4*)(asrc + k0);
        *(uint4*)&Al[srow][shalf+8] = *(const uint4*)(asrc + k0 + 8);
        *(uint4*)&Wl[srow][shalf]   = *(const uint4*)(wsrc + k0);
        *(uint4*)&Wl[srow][shalf+8] = *(const uint4*)(wsrc + k0 + 8);
        __syncthreads();

        short8 af[4], bfr[4];
        #pragma unroll
        for (int mi=0;mi<4;++mi)
            af[mi] = *(const short8*)&Al[wm + mi*16 + lr][lg*8];
        #pragma unroll
        for (int ni=0;ni<4;++ni)
            bfr[ni] = *(const short8*)&Wl[wn + ni*16 + lr][lg*8];
        #pragma unroll
        for (int mi=0;mi<4;++mi)
            #pragma unroll
            for (int ni=0;ni<4;++ni)
                acc[mi][ni] = __builtin_amdgcn_mfma_f32_16x16x32_bf16(
                    af[mi], bfr[ni], acc[mi][ni], 0, 0, 0);
        __syncthreads();
    }

    float bn[4];
    #pragma unroll
    for (int ni=0;ni<4;++ni) bn[ni] = bias[n0 + wn + ni*16 + lr];
    #pragma unroll
    for (int mi=0;mi<4;++mi)
        #pragma unroll
        for (int ni=0;ni<4;++ni)
            #pragma unroll
            for (int r=0;r<4;++r){
                int row = m0 + wm + mi*16 + lg*4 + r;
                float v = acc[mi][ni][r] + bn[ni];
                v = gelu_f(v);
                Ybf[(size_t)row*256 + n0 + wn + ni*16 + lr] = f2bf(v);
            }
}

// ---------------------------------------------------------------------------
// dec3 MFMA: Y[T,48] = A_bf16 @ W3^T + b3 (W3 converted in-kernel),
// fused un-patchify + recon loss. 256 rows/block, 4 waves of 64 rows.
// ---------------------------------------------------------------------------
__global__ __launch_bounds__(256) void dec3_mfma(
    const ushort* __restrict__ Ain, const float* __restrict__ W,
    const float* __restrict__ bias, const float* __restrict__ frames,
    float* __restrict__ recon, float* __restrict__ loss)
{
    __shared__ __align__(16) ushort Al[256][40];
    __shared__ __align__(16) ushort Wl[48][40];

    const int tid = threadIdx.x;
    const int m0 = blockIdx.x * 256;
    const int lane = tid & 63;
    const int w = tid >> 6;
    const int lr = lane & 15, lg = lane >> 4;

    const ushort* asrc = Ain + (size_t)(m0 + tid)*256;

    f32x4 acc[4][3];
    #pragma unroll
    for (int mi=0;mi<4;++mi)
        #pragma unroll
        for (int ni=0;ni<3;++ni)
            acc[mi][ni] = (f32x4){0.f,0.f,0.f,0.f};

    for (int k0=0; k0<256; k0+=32){
        *(uint4*)&Al[tid][0]  = *(const uint4*)(asrc + k0);
        *(uint4*)&Al[tid][8]  = *(const uint4*)(asrc + k0 + 8);
        *(uint4*)&Al[tid][16] = *(const uint4*)(asrc + k0 + 16);
        *(uint4*)&Al[tid][24] = *(const uint4*)(asrc + k0 + 24);
        if (tid < 96){
            const int wrow = tid >> 1, wh = (tid & 1)*16;
            const float* wp = W + (size_t)wrow*256 + k0 + wh;
            float4 f0 = *(const float4*)(wp);
            float4 f1 = *(const float4*)(wp+4);
            float4 f2 = *(const float4*)(wp+8);
            float4 f3 = *(const float4*)(wp+12);
            ushort t[16];
            t[0]=f2bf(f0.x); t[1]=f2bf(f0.y); t[2]=f2bf(f0.z); t[3]=f2bf(f0.w);
            t[4]=f2bf(f1.x); t[5]=f2bf(f1.y); t[6]=f2bf(f1.z); t[7]=f2bf(f1.w);
            t[8]=f2bf(f2.x); t[9]=f2bf(f2.y); t[10]=f2bf(f2.z); t[11]=f2bf(f2.w);
            t[12]=f2bf(f3.x); t[13]=f2bf(f3.y); t[14]=f2bf(f3.z); t[15]=f2bf(f3.w);
            *(uint4*)&Wl[wrow][wh]   = *(const uint4*)&t[0];
            *(uint4*)&Wl[wrow][wh+8] = *(const uint4*)&t[8];
        }
        __syncthreads();

        short8 bfr[3];
        #pragma unroll
        for (int ni=0;ni<3;++ni)
            bfr[ni] = *(const short8*)&Wl[ni*16 + lr][lg*8];
        #pragma unroll
        for (int mi=0;mi<4;++mi){
            short8 af = *(const short8*)&Al[w*64 + mi*16 + lr][lg*8];
            #pragma unroll
            for (int ni=0;ni<3;++ni)
                acc[mi][ni] = __builtin_amdgcn_mfma_f32_16x16x32_bf16(
                    af, bfr[ni], acc[mi][ni], 0, 0, 0);
        }
        __syncthreads();
    }

    float bn[3]; int phv[3], remv[3];
    #pragma unroll
    for (int ni=0;ni<3;++ni){
        int col = ni*16 + lr;
        bn[ni] = bias[col];
        phv[ni] = col / 12;
        remv[ni] = col - phv[ni]*12;
    }
    const float sc = 2.0f/255.0f;
    float ls = 0.0f;
    #pragma unroll
    for (int mi=0;mi<4;++mi)
        #pragma unroll
        for (int ni=0;ni<3;++ni)
            #pragma unroll
            for (int r=0;r<4;++r){
                int p = m0 + w*64 + mi*16 + lg*4 + r;
                int b = p >> 12, nl = p & 4095, hh = nl >> 6, ww = nl & 63;
                size_t addr = (size_t)(((b*256 + hh*4 + phv[ni])*256 + ww*4)*3 + remv[ni]);
                float y = acc[mi][ni][r] + bn[ni];
                float t = frames[addr]*sc - 1.0f;
                float d = y - t;
                ls += d*d;
                recon[addr] = y;
            }

    #pragma unroll
    for (int off=32; off>0; off>>=1) ls += __shfl_down(ls, off);
    __shared__ float wsum[4];
    if (lane == 0) wsum[w] = ls;
    __syncthreads();
    if (tid == 0) atomicAdd(loss + 0, wsum[0]+wsum[1]+wsum[2]+wsum[3]);
}

__global__ void finalize_kernel(float* __restrict__ loss){
    if (threadIdx.x == 0 && blockIdx.x == 0){
        loss[0] = loss[0] * (1.0f/6291456.0f);
        float c = loss[1] * (1.0f/33554432.0f);
        loss[1] = c;
        loss[2] = c;
    }
}

extern "C" void kernel_launch(void* const* d_in, const int* in_sizes, int n_in,
                              void* d_out, int out_size, void* d_ws, size_t ws_size,
                              hipStream_t stream)
{
    (void)in_sizes; (void)n_in; (void)out_size; (void)ws_size;
    const float* frames   = (const float*)d_in[0];
    const float* enc_w1   = (const float*)d_in[1];
    const float* enc_b1   = (const float*)d_in[2];
    const float* enc_w2   = (const float*)d_in[3];
    const float* enc_b2   = (const float*)d_in[4];
    const float* enc_w3   = (const float*)d_in[5];
    const float* enc_b3   = (const float*)d_in[6];
    const float* codebook = (const float*)d_in[7];
    const float* dec_w1   = (const float*)d_in[8];
    const float* dec_b1   = (const float*)d_in[9];
    const float* dec_w2   = (const float*)d_in[10];
    const float* dec_b2   = (const float*)d_in[11];
    const float* dec_w3   = (const float*)d_in[12];
    const float* dec_b3   = (const float*)d_in[13];

    // workspace: two [T,256] f32 regions (268 MB, proven available)
    float* P = (float*)d_ws;                 // h1 -> z_e -> Y1(bf16)
    float* Q = P + (size_t)33554432;         // h2 -> {Y2(bf16) base, partials}
    float2* partials = (float2*)(Q + 18000000);  // 4 MB, disjoint from Y2
    ushort* Y1 = (ushort*)P;
    ushort* Y2 = (ushort*)Q;

    // outputs; recon region doubles as scratch for small constants
    float* recon = (float*)d_out;            // 6,291,456 f32 (written last)
    float* tokf  = recon + 6291456;          // 131,072
    float* loss  = tokf + 131072;            // 3
    float*  cn   = recon;                            // 512 f32
    ushort* cbb  = (ushort*)(recon + 512);           // 131072 us
    ushort* w1b  = (ushort*)(recon + 66048);         // 65536 us
    ushort* w2b  = (ushort*)(recon + 98816);         // 65536 us
    ushort* w2s0 = (ushort*)(recon + 131584);        // 65536 us each
    ushort* w2s1 = (ushort*)(recon + 164352);
    ushort* w2s2 = (ushort*)(recon + 197120);
    ushort* w3s0 = (ushort*)(recon + 229888);
    ushort* w3s1 = (ushort*)(recon + 262656);
    ushort* w3s2 = (ushort*)(recon + 295424);
    ushort* cbs0 = (ushort*)(recon + 328192);        // 131072 us each
    ushort* cbs1 = (ushort*)(recon + 393728);
    ushort* cbs2 = (ushort*)(recon + 459264);        // ends 524800
    float*  zzb  = recon + 524800;                   // 131072 f32, ends 655872

    hipMemsetAsync(loss, 0, 3*sizeof(float), stream);

    dim3 blk(256), grid2(T_ROWS/128, 2);
    // weight prep
    wsplit_kernel<<<dim3(64), blk, 0, stream>>>(enc_w2, enc_w3, dec_w1, dec_w2,
        w2s0, w2s1, w2s2, w3s0, w3s1, w3s2, w1b, w2b);
    cnorm_kernel<<<dim3(128), blk, 0, stream>>>(codebook, cn, cbb, cbs0, cbs1, cbs2);
    // encoder: f32 layer1, then f32-faithful 6-term split-bf16 MFMA
    gemm_kernel<48, true, 1><<<grid2, blk, 0, stream>>>(nullptr, frames, enc_w1, enc_b1, P);
    split6_gemm<true ><<<grid2, blk, 0, stream>>>(P, w2s0, w2s1, w2s2, enc_b2, Q);
    split6_gemm<false><<<grid2, blk, 0, stream>>>(Q, w3s0, w3s1, w3s2, enc_b3, P);
    // vector quantization: EXACT split6 distances (+fused ||z||^2) + reduce
    tokens_split6<<<dim3(T_ROWS/128, 4), blk, 0, stream>>>(P, cbs0, cbs1, cbs2, cn, partials, zzb);
    token_reduce<<<dim3(T_ROWS/256), blk, 0, stream>>>(zzb, partials, tokf, loss);
    // decoder (bf16 MFMA)
    mfma_gemm<1><<<grid2, blk, 0, stream>>>(nullptr, cbb, tokf, w1b, dec_b1, Y1);
    mfma_gemm<0><<<grid2, blk, 0, stream>>>(Y1, nullptr, nullptr, w2b, dec_b2, Y2);
    dec3_mfma<<<dim3(T_ROWS/256), blk, 0, stream>>>(Y2, dec_w3, dec_b3, frames, recon, loss);
    finalize_kernel<<<dim3(1), dim3(64), 0, stream>>>(loss);
}

// Round 10
// 727.041 us; speedup vs baseline: 1.5853x; 1.0134x over previous
//
#include <hip/hip_runtime.h>
#include <hip/hip_bf16.h>
#include <math.h>
#include <float.h>
#include <limits.h>

#define T_ROWS 131072   // 32 * 4096 patches

typedef __attribute__((ext_vector_type(8))) short short8;
typedef __attribute__((ext_vector_type(4))) float f32x4;

__device__ __forceinline__ float gelu_f(float x){
    return 0.5f * x * (1.0f + erff(x * 0.7071067811865475f));
}
__device__ __forceinline__ float bf2f(ushort u){
    union { unsigned int i; float f; } v; v.i = ((unsigned int)u) << 16; return v.f;
}
__device__ __forceinline__ ushort f2bf(float f){
    union { float f; unsigned int i; } v; v.f = f;
    unsigned int i = v.i;
    unsigned int r = (i + 0x7fffu + ((i >> 16) & 1u)) >> 16;
    return (ushort)r;
}
// exact 3-way truncation split: x ~= b0+b1+b2 (each bf16), >=24 mantissa bits
__device__ __forceinline__ void split3(float x, ushort &u0, ushort &u1, ushort &u2){
    union { float f; unsigned int i; } v; v.f = x;
    u0 = (ushort)(v.i >> 16);
    union { unsigned int i; float f; } h0; h0.i = ((unsigned int)u0) << 16;
    float r = x - h0.f;                       // exact (Sterbenz)
    union { float f; unsigned int i; } vr; vr.f = r;
    u1 = (ushort)(vr.i >> 16);
    union { unsigned int i; float f; } h1; h1.i = ((unsigned int)u1) << 16;
    float r2 = r - h1.f;                      // exact
    union { float f; unsigned int i; } v2; v2.f = r2;
    u2 = (ushort)(v2.i >> 16);
}

// ---------------------------------------------------------------------------
// f32 tiled GEMM (enc1 only): C[M,256] = gelu(patchify(frames) @ W^T + b)
// ---------------------------------------------------------------------------
template<int K, bool GELU, int LOADER>
__global__ __launch_bounds__(256) void gemm_kernel(
    const float* __restrict__ Ain,
    const float* __restrict__ frames,
    const float* __restrict__ W,
    const float* __restrict__ bias,
    float* __restrict__ Cout)
{
    constexpr int BM=128, BN=128, BK=16;
    __shared__ __align__(16) float As[BK][BM+4];
    __shared__ __align__(16) float Ws[BK][BN+4];

    const int tid = threadIdx.x;
    const int tx = tid & 15, ty = tid >> 4;
    const int m0 = blockIdx.x * BM;
    const int c0 = blockIdx.y * BN;

    const int q  = tid & 3;
    const int r0 = tid >> 2;

    const float* aptr0 = nullptr;
    const float* aptr1 = nullptr;
    int base0 = 0, base1 = 0;
    if constexpr (LOADER == 0){
        aptr0 = Ain + (size_t)(m0 + r0) * K;
        aptr1 = aptr0 + (size_t)64 * K;
    } else {
        int p0 = m0 + r0;
        int b = p0 >> 12, nl = p0 & 4095, hh = nl >> 6, ww = nl & 63;
        base0 = ((b*256 + hh*4)*256 + ww*4)*3;
        int p1 = p0 + 64;
        b = p1 >> 12; nl = p1 & 4095; hh = nl >> 6; ww = nl & 63;
        base1 = ((b*256 + hh*4)*256 + ww*4)*3;
    }
    const float* wptr0 = W + (size_t)(c0 + r0) * K;
    const float* wptr1 = wptr0 + (size_t)64 * K;

    float acc[8][8];
    #pragma unroll
    for (int i=0;i<8;++i)
        #pragma unroll
        for (int j=0;j<8;++j) acc[i][j] = 0.0f;

    for (int k0 = 0; k0 < K; k0 += BK){
        const int k = k0 + q*4;
        float4 va, vb;
        if constexpr (LOADER == 1){
            const int ph = k / 12, rem = k - ph*12;
            va = *(const float4*)(frames + base0 + ph*768 + rem);
            vb = *(const float4*)(frames + base1 + ph*768 + rem);
            const float sc = 2.0f/255.0f;
            va.x = va.x*sc - 1.0f; va.y = va.y*sc - 1.0f;
            va.z = va.z*sc - 1.0f; va.w = va.w*sc - 1.0f;
            vb.x = vb.x*sc - 1.0f; vb.y = vb.y*sc - 1.0f;
            vb.z = vb.z*sc - 1.0f; vb.w = vb.w*sc - 1.0f;
        } else {
            va = *(const float4*)(aptr0 + k);
            vb = *(const float4*)(aptr1 + k);
        }
        As[q*4+0][r0]    = va.x; As[q*4+1][r0]    = va.y;
        As[q*4+2][r0]    = va.z; As[q*4+3][r0]    = va.w;
        As[q*4+0][r0+64] = vb.x; As[q*4+1][r0+64] = vb.y;
        As[q*4+2][r0+64] = vb.z; As[q*4+3][r0+64] = vb.w;

        float4 wa = *(const float4*)(wptr0 + k);
        float4 wb = *(const float4*)(wptr1 + k);
        Ws[q*4+0][r0]    = wa.x; Ws[q*4+1][r0]    = wa.y;
        Ws[q*4+2][r0]    = wa.z; Ws[q*4+3][r0]    = wa.w;
        Ws[q*4+0][r0+64] = wb.x; Ws[q*4+1][r0+64] = wb.y;
        Ws[q*4+2][r0+64] = wb.z; Ws[q*4+3][r0+64] = wb.w;

        __syncthreads();
        #pragma unroll
        for (int kk=0; kk<BK; ++kk){
            float a[8], b[8];
            *(float4*)&a[0] = *(const float4*)&As[kk][ty*4];
            *(float4*)&a[4] = *(const float4*)&As[kk][64+ty*4];
            *(float4*)&b[0] = *(const float4*)&Ws[kk][tx*4];
            *(float4*)&b[4] = *(const float4*)&Ws[kk][64+tx*4];
            #pragma unroll
            for (int i=0;i<8;++i)
                #pragma unroll
                for (int j=0;j<8;++j)
                    acc[i][j] = fmaf(a[i], b[j], acc[i][j]);
        }
        __syncthreads();
    }

    float bj[8];
    *(float4*)&bj[0] = *(const float4*)(bias + c0 + tx*4);
    *(float4*)&bj[4] = *(const float4*)(bias + c0 + 64 + tx*4);
    #pragma unroll
    for (int i=0;i<8;++i){
        const int row = m0 + ((i<4) ? (ty*4+i) : (64+ty*4+i-4));
        float o[8];
        #pragma unroll
        for (int j=0;j<8;++j){
            float x = acc[i][j] + bj[j];
            o[j] = GELU ? gelu_f(x) : x;
        }
        float* dst = Cout + (size_t)row*256 + c0 + tx*4;
        *(float4*)dst      = *(const float4*)&o[0];
        *(float4*)(dst+64) = *(const float4*)&o[4];
    }
}

// ---------------------------------------------------------------------------
// weight prep: 3-way split enc_w2/enc_w3; bf16 round dec_w1/dec_w2
// ---------------------------------------------------------------------------
__global__ __launch_bounds__(256) void wsplit_kernel(
    const float* __restrict__ w2, const float* __restrict__ w3,
    const float* __restrict__ d1, const float* __restrict__ d2,
    ushort* __restrict__ w2s0, ushort* __restrict__ w2s1, ushort* __restrict__ w2s2,
    ushort* __restrict__ w3s0, ushort* __restrict__ w3s1, ushort* __restrict__ w3s2,
    ushort* __restrict__ w1b, ushort* __restrict__ w2b)
{
    const int i = (blockIdx.x*256 + threadIdx.x)*4;
    float4 a = *(const float4*)(w2 + i);
    ushort4 s0, s1, s2;
    split3(a.x, s0.x, s1.x, s2.x); split3(a.y, s0.y, s1.y, s2.y);
    split3(a.z, s0.z, s1.z, s2.z); split3(a.w, s0.w, s1.w, s2.w);
    *(ushort4*)(w2s0+i)=s0; *(ushort4*)(w2s1+i)=s1; *(ushort4*)(w2s2+i)=s2;
    float4 b = *(const float4*)(w3 + i);
    split3(b.x, s0.x, s1.x, s2.x); split3(b.y, s0.y, s1.y, s2.y);
    split3(b.z, s0.z, s1.z, s2.z); split3(b.w, s0.w, s1.w, s2.w);
    *(ushort4*)(w3s0+i)=s0; *(ushort4*)(w3s1+i)=s1; *(ushort4*)(w3s2+i)=s2;
    float4 c = *(const float4*)(d1 + i);
    ushort4 u; u.x=f2bf(c.x); u.y=f2bf(c.y); u.z=f2bf(c.z); u.w=f2bf(c.w);
    *(ushort4*)(w1b+i) = u;
    float4 d = *(const float4*)(d2 + i);
    u.x=f2bf(d.x); u.y=f2bf(d.y); u.z=f2bf(d.z); u.w=f2bf(d.w);
    *(ushort4*)(w2b+i) = u;
}

// ---------------------------------------------------------------------------
// ||c||^2 per code (f32 exact) + bf16 codebook copy + 3-way split planes
// ---------------------------------------------------------------------------
__global__ __launch_bounds__(256) void cnorm_kernel(
    const float* __restrict__ cb, float* __restrict__ cn,
    ushort* __restrict__ cbb,
    ushort* __restrict__ cbs0, ushort* __restrict__ cbs1, ushort* __restrict__ cbs2)
{
    const int lane = threadIdx.x & 63;
    const int code = blockIdx.x*4 + (threadIdx.x >> 6);
    float4 v = ((const float4*)(cb + (size_t)code*256))[lane];
    size_t off = (size_t)code*256 + lane*4;
    ushort4 u; u.x=f2bf(v.x); u.y=f2bf(v.y); u.z=f2bf(v.z); u.w=f2bf(v.w);
    *(ushort4*)(cbb + off) = u;
    ushort4 s0, s1, s2;
    split3(v.x, s0.x, s1.x, s2.x); split3(v.y, s0.y, s1.y, s2.y);
    split3(v.z, s0.z, s1.z, s2.z); split3(v.w, s0.w, s1.w, s2.w);
    *(ushort4*)(cbs0 + off) = s0;
    *(ushort4*)(cbs1 + off) = s1;
    *(ushort4*)(cbs2 + off) = s2;
    float s = v.x*v.x + v.y*v.y + v.z*v.z + v.w*v.w;
    #pragma unroll
    for (int m=1; m<64; m<<=1) s += __shfl_xor(s, m);
    if (lane == 0) cn[code] = s;
}

// ---------------------------------------------------------------------------
// f32-faithful MFMA GEMM via 6-term split-bf16.
// A split in-kernel -> LDS (3 planes); W planes 0,1 in LDS, plane 2 direct
// from global (L2-resident). LDS 50 KB; __launch_bounds__(256,3) caps the
// unified VGPR+AGPR budget at 170 -> 3 blocks/CU.
// ---------------------------------------------------------------------------
template<bool GELU>
__global__ __launch_bounds__(256, 3) void split6_gemm(
    const float* __restrict__ Ain,
    const ushort* __restrict__ W0, const ushort* __restrict__ W1,
    const ushort* __restrict__ W2,
    const float* __restrict__ bias,
    float* __restrict__ Cout)
{
    __shared__ __align__(16) ushort Al[3][128][40];
    __shared__ __align__(16) ushort Wl[2][128][40];

    const int tid = threadIdx.x;
    const int m0 = blockIdx.x * 128;
    const int n0 = blockIdx.y * 128;
    const int srow = tid >> 1, shalf = (tid & 1) * 16;
    const int lane = tid & 63;
    const int w = tid >> 6;
    const int wm = (w >> 1) * 64, wn = (w & 1) * 64;
    const int lr = lane & 15, lg = lane >> 4;

    const float*  asrc = Ain + (size_t)(m0 + srow)*256 + shalf;
    const ushort* ws0  = W0  + (size_t)(n0 + srow)*256 + shalf;
    const ushort* ws1  = W1  + (size_t)(n0 + srow)*256 + shalf;
    const ushort* w2frag = W2 + (size_t)(n0 + wn + lr)*256 + lg*8;

    f32x4 acc[4][4];
    #pragma unroll
    for (int mi=0;mi<4;++mi)
        #pragma unroll
        for (int ni=0;ni<4;++ni)
            acc[mi][ni] = (f32x4){0.f,0.f,0.f,0.f};

    for (int k0=0; k0<256; k0+=32){
        float x[16];
        *(float4*)&x[0]  = *(const float4*)(asrc + k0);
        *(float4*)&x[4]  = *(const float4*)(asrc + k0 + 4);
        *(float4*)&x[8]  = *(const float4*)(asrc + k0 + 8);
        *(float4*)&x[12] = *(const float4*)(asrc + k0 + 12);
        ushort t0[16], t1[16], t2[16];
        #pragma unroll
        for (int e=0;e<16;++e) split3(x[e], t0[e], t1[e], t2[e]);
        *(uint4*)&Al[0][srow][shalf]   = *(const uint4*)&t0[0];
        *(uint4*)&Al[0][srow][shalf+8] = *(const uint4*)&t0[8];
        *(uint4*)&Al[1][srow][shalf]   = *(const uint4*)&t1[0];
        *(uint4*)&Al[1][srow][shalf+8] = *(const uint4*)&t1[8];
        *(uint4*)&Al[2][srow][shalf]   = *(const uint4*)&t2[0];
        *(uint4*)&Al[2][srow][shalf+8] = *(const uint4*)&t2[8];
        *(uint4*)&Wl[0][srow][shalf]   = *(const uint4*)(ws0 + k0);
        *(uint4*)&Wl[0][srow][shalf+8] = *(const uint4*)(ws0 + k0 + 8);
        *(uint4*)&Wl[1][srow][shalf]   = *(const uint4*)(ws1 + k0);
        *(uint4*)&Wl[1][srow][shalf+8] = *(const uint4*)(ws1 + k0 + 8);
        // plane-2 fragments direct from global (L2-resident)
        short8 b2[4];
        #pragma unroll
        for (int ni=0;ni<4;++ni)
            b2[ni] = *(const short8*)(w2frag + (size_t)ni*16*256 + k0);
        __syncthreads();

        short8 b0[4], b1[4];
        #pragma unroll
        for (int ni=0;ni<4;++ni){
            b0[ni] = *(const short8*)&Wl[0][wn + ni*16 + lr][lg*8];
            b1[ni] = *(const short8*)&Wl[1][wn + ni*16 + lr][lg*8];
        }
        #pragma unroll
        for (int mi=0;mi<4;++mi){
            short8 a0 = *(const short8*)&Al[0][wm + mi*16 + lr][lg*8];
            short8 a1 = *(const short8*)&Al[1][wm + mi*16 + lr][lg*8];
            short8 a2 = *(const short8*)&Al[2][wm + mi*16 + lr][lg*8];
            #pragma unroll
            for (int ni=0;ni<4;++ni)
                acc[mi][ni] = __builtin_amdgcn_mfma_f32_16x16x32_bf16(a0, b0[ni], acc[mi][ni], 0,0,0);
            #pragma unroll
            for (int ni=0;ni<4;++ni)
                acc[mi][ni] = __builtin_amdgcn_mfma_f32_16x16x32_bf16(a0, b1[ni], acc[mi][ni], 0,0,0);
            #pragma unroll
            for (int ni=0;ni<4;++ni)
                acc[mi][ni] = __builtin_amdgcn_mfma_f32_16x16x32_bf16(a1, b0[ni], acc[mi][ni], 0,0,0);
            #pragma unroll
            for (int ni=0;ni<4;++ni)
                acc[mi][ni] = __builtin_amdgcn_mfma_f32_16x16x32_bf16(a0, b2[ni], acc[mi][ni], 0,0,0);
            #pragma unroll
            for (int ni=0;ni<4;++ni)
                acc[mi][ni] = __builtin_amdgcn_mfma_f32_16x16x32_bf16(a1, b1[ni], acc[mi][ni], 0,0,0);
            #pragma unroll
            for (int ni=0;ni<4;++ni)
                acc[mi][ni] = __builtin_amdgcn_mfma_f32_16x16x32_bf16(a2, b0[ni], acc[mi][ni], 0,0,0);
        }
        __syncthreads();
    }

    float bn[4];
    #pragma unroll
    for (int ni=0;ni<4;++ni) bn[ni] = bias[n0 + wn + ni*16 + lr];
    #pragma unroll
    for (int mi=0;mi<4;++mi)
        #pragma unroll
        for (int ni=0;ni<4;++ni)
            #pragma unroll
            for (int r=0;r<4;++r){
                int row = m0 + wm + mi*16 + lg*4 + r;
                float v = acc[mi][ni][r] + bn[ni];
                if (GELU) v = gelu_f(v);
                Cout[(size_t)row*256 + n0 + wn + ni*16 + lr] = v;
            }
}

#define INSERT1(dv, iv) do { \
    float _d = (dv); int _i = (iv); \
    if (_d < bd || (_d == bd && _i < bi)){ bd = _d; bi = _i; } \
} while(0)

// ---------------------------------------------------------------------------
// EXACT distance pass via 6-term split-bf16 MFMA; plane-2 of codebook from
// global; fused ||z||^2. __launch_bounds__(256,3) -> 3 blocks/CU.
// ---------------------------------------------------------------------------
__global__ __launch_bounds__(256, 3) void tokens_split6(
    const float* __restrict__ Zf,
    const ushort* __restrict__ C0, const ushort* __restrict__ C1,
    const ushort* __restrict__ C2,
    const float* __restrict__ cn,
    float2* __restrict__ partials,
    float* __restrict__ zz_out)
{
    __shared__ __align__(16) ushort Al[3][128][40];
    __shared__ __align__(16) ushort Wl[2][128][40];
    __shared__ float2 ptop[128][2];

    const int tid = threadIdx.x;
    const int m0 = blockIdx.x * 128;
    const int n0 = blockIdx.y * 128;
    const int srow = tid >> 1, shalf = (tid & 1) * 16;
    const int lane = tid & 63;
    const int w = tid >> 6;
    const int wm = (w >> 1) * 64, wn = (w & 1) * 64;
    const int lr = lane & 15, lg = lane >> 4;

    const float*  asrc = Zf + (size_t)(m0 + srow)*256 + shalf;
    const ushort* ws0  = C0 + (size_t)(n0 + srow)*256 + shalf;
    const ushort* ws1  = C1 + (size_t)(n0 + srow)*256 + shalf;
    const ushort* c2frag = C2 + (size_t)(n0 + wn + lr)*256 + lg*8;

    f32x4 acc[4][4];
    #pragma unroll
    for (int mi=0;mi<4;++mi)
        #pragma unroll
        for (int ni=0;ni<4;++ni)
            acc[mi][ni] = (f32x4){0.f,0.f,0.f,0.f};

    float zzp = 0.0f;

    for (int k0=0; k0<256; k0+=32){
        float x[16];
        *(float4*)&x[0]  = *(const float4*)(asrc + k0);
        *(float4*)&x[4]  = *(const float4*)(asrc + k0 + 4);
        *(float4*)&x[8]  = *(const float4*)(asrc + k0 + 8);
        *(float4*)&x[12] = *(const float4*)(asrc + k0 + 12);
        ushort t0[16], t1[16], t2[16];
        #pragma unroll
        for (int e=0;e<16;++e){
            split3(x[e], t0[e], t1[e], t2[e]);
            zzp = fmaf(x[e], x[e], zzp);
        }
        *(uint4*)&Al[0][srow][shalf]   = *(const uint4*)&t0[0];
        *(uint4*)&Al[0][srow][shalf+8] = *(const uint4*)&t0[8];
        *(uint4*)&Al[1][srow][shalf]   = *(const uint4*)&t1[0];
        *(uint4*)&Al[1][srow][shalf+8] = *(const uint4*)&t1[8];
        *(uint4*)&Al[2][srow][shalf]   = *(const uint4*)&t2[0];
        *(uint4*)&Al[2][srow][shalf+8] = *(const uint4*)&t2[8];
        *(uint4*)&Wl[0][srow][shalf]   = *(const uint4*)(ws0 + k0);
        *(uint4*)&Wl[0][srow][shalf+8] = *(const uint4*)(ws0 + k0 + 8);
        *(uint4*)&Wl[1][srow][shalf]   = *(const uint4*)(ws1 + k0);
        *(uint4*)&Wl[1][srow][shalf+8] = *(const uint4*)(ws1 + k0 + 8);
        short8 b2[4];
        #pragma unroll
        for (int ni=0;ni<4;++ni)
            b2[ni] = *(const short8*)(c2frag + (size_t)ni*16*256 + k0);
        __syncthreads();

        short8 b0[4], b1[4];
        #pragma unroll
        for (int ni=0;ni<4;++ni){
            b0[ni] = *(const short8*)&Wl[0][wn + ni*16 + lr][lg*8];
            b1[ni] = *(const short8*)&Wl[1][wn + ni*16 + lr][lg*8];
        }
        #pragma unroll
        for (int mi=0;mi<4;++mi){
            short8 a0 = *(const short8*)&Al[0][wm + mi*16 + lr][lg*8];
            short8 a1 = *(const short8*)&Al[1][wm + mi*16 + lr][lg*8];
            short8 a2 = *(const short8*)&Al[2][wm + mi*16 + lr][lg*8];
            #pragma unroll
            for (int ni=0;ni<4;++ni)
                acc[mi][ni] = __builtin_amdgcn_mfma_f32_16x16x32_bf16(a0, b0[ni], acc[mi][ni], 0,0,0);
            #pragma unroll
            for (int ni=0;ni<4;++ni)
                acc[mi][ni] = __builtin_amdgcn_mfma_f32_16x16x32_bf16(a0, b1[ni], acc[mi][ni], 0,0,0);
            #pragma unroll
            for (int ni=0;ni<4;++ni)
                acc[mi][ni] = __builtin_amdgcn_mfma_f32_16x16x32_bf16(a1, b0[ni], acc[mi][ni], 0,0,0);
            #pragma unroll
            for (int ni=0;ni<4;++ni)
                acc[mi][ni] = __builtin_amdgcn_mfma_f32_16x16x32_bf16(a0, b2[ni], acc[mi][ni], 0,0,0);
            #pragma unroll
            for (int ni=0;ni<4;++ni)
                acc[mi][ni] = __builtin_amdgcn_mfma_f32_16x16x32_bf16(a1, b1[ni], acc[mi][ni], 0,0,0);
            #pragma unroll
            for (int ni=0;ni<4;++ni)
                acc[mi][ni] = __builtin_amdgcn_mfma_f32_16x16x32_bf16(a2, b0[ni], acc[mi][ni], 0,0,0);
        }
        __syncthreads();
    }

    // ||z||^2 per row: pair-combine the two k-halves (tid even/odd same row)
    {
        float other = __shfl_xor(zzp, 1);
        if (blockIdx.y == 0 && (tid & 1) == 0)
            zz_out[m0 + srow] = zzp + other;
    }

    float cnl[4];
    #pragma unroll
    for (int ni=0;ni<4;++ni) cnl[ni] = cn[n0 + wn + ni*16 + lr];

    #pragma unroll
    for (int mi=0;mi<4;++mi)
        #pragma unroll
        for (int r=0;r<4;++r){
            float bd = FLT_MAX; int bi = INT_MAX;
            #pragma unroll
            for (int ni=0;ni<4;++ni){
                float d = cnl[ni] - 2.0f*acc[mi][ni][r];
                int col = n0 + wn + ni*16 + lr;
                INSERT1(d, col);
            }
            #pragma unroll
            for (int m=1; m<16; m<<=1){
                float od = __shfl_xor(bd, m);
                int   oi = __shfl_xor(bi, m);
                INSERT1(od, oi);
            }
            if (lr == 0)
                ptop[wm + mi*16 + lg*4 + r][w & 1] = make_float2(bd, (float)bi);
        }
    __syncthreads();
    if (tid < 128){
        float2 hA = ptop[tid][0], hB = ptop[tid][1];
        int   gA = (int)hA.y, gB = (int)hB.y;
        bool takeB = (hB.x < hA.x) || (hB.x == hA.x && gB < gA);
        partials[(size_t)(m0 + tid)*4 + blockIdx.y] = takeB ? hB : hA;
    }
}

// ---------------------------------------------------------------------------
// Token + commitment: min over 4 (d,idx) partials, zz from zz_out.
// ---------------------------------------------------------------------------
__global__ __launch_bounds__(256) void token_reduce(
    const float* __restrict__ zz_out, const float2* __restrict__ partials,
    float* __restrict__ tokf, float* __restrict__ loss)
{
    const int tid = threadIdx.x;
    const int row = blockIdx.x*256 + tid;
    float2 p0 = partials[(size_t)row*4 + 0];
    float2 p1 = partials[(size_t)row*4 + 1];
    float2 p2 = partials[(size_t)row*4 + 2];
    float2 p3 = partials[(size_t)row*4 + 3];
    float d = p0.x; int g = (int)p0.y;
    if (p1.x < d || (p1.x == d && (int)p1.y < g)){ d = p1.x; g = (int)p1.y; }
    if (p2.x < d || (p2.x == d && (int)p2.y < g)){ d = p2.x; g = (int)p2.y; }
    if (p3.x < d || (p3.x == d && (int)p3.y < g)){ d = p3.x; g = (int)p3.y; }
    tokf[row] = (float)g;
    float cs = zz_out[row] + d;
    #pragma unroll
    for (int m=1; m<64; m<<=1) cs += __shfl_xor(cs, m);
    __shared__ float wsum[4];
    const int lane = tid & 63, w = tid >> 6;
    if (lane == 0) wsum[w] = cs;
    __syncthreads();
    if (tid == 0) atomicAdd(loss + 1, wsum[0]+wsum[1]+wsum[2]+wsum[3]);
}

// ---------------------------------------------------------------------------
// bf16 MFMA GEMM (decoder 1/2): Y[M,256] = gelu(A @ W^T + b)
// LOADER: 0 = plain bf16 A, 1 = gather bf16 codebook rows via tokens.
// ---------------------------------------------------------------------------
template<int LOADER>
__global__ __launch_bounds__(256) void mfma_gemm(
    const ushort* __restrict__ Abf,
    const ushort* __restrict__ cbb,
    const float* __restrict__ tokf,
    const ushort* __restrict__ Wbf,
    const float* __restrict__ bias,
    ushort* __restrict__ Ybf)
{
    __shared__ __align__(16) ushort Al[128][40];
    __shared__ __align__(16) ushort Wl[128][40];

    const int tid = threadIdx.x;
    const int m0 = blockIdx.x * 128;
    const int n0 = blockIdx.y * 128;
    const int srow = tid >> 1, shalf = (tid & 1) * 16;
    const int lane = tid & 63;
    const int w = tid >> 6;
    const int wm = (w >> 1) * 64, wn = (w & 1) * 64;
    const int lr = lane & 15, lg = lane >> 4;

    const ushort* asrc;
    if constexpr (LOADER == 1){
        int g = (int)tokf[m0 + srow];
        asrc = cbb + (size_t)g*256 + shalf;
    } else {
        asrc = Abf + (size_t)(m0 + srow)*256 + shalf;
    }
    const ushort* wsrc = Wbf + (size_t)(n0 + srow)*256 + shalf;

    f32x4 acc[4][4];
    #pragma unroll
    for (int mi=0;mi<4;++mi)
        #pragma unroll
        for (int ni=0;ni<4;++ni)
            acc[mi][ni] = (f32x4){0.f,0.f,0.f,0.f};

    for (int k0=0; k0<256; k0+=32){
        *(uint4*)&Al[srow][shalf]   = *(const uint4*)(asrc + k0);
        *(uint4*)&Al[srow][shalf+8] = *(const uint4*)(asrc + k0 + 8);
        *(uint4*)&Wl[srow][shalf]   = *(const uint4*)(wsrc + k0);
        *(uint4*)&Wl[srow][shalf+8] = *(const uint4*)(wsrc + k0 + 8);
        __syncthreads();

        short8 af[4], bfr[4];
        #pragma unroll
        for (int mi=0;mi<4;++mi)
            af[mi] = *(const short8*)&Al[wm + mi*16 + lr][lg*8];
        #pragma unroll
        for (int ni=0;ni<4;++ni)
            bfr[ni] = *(const short8*)&Wl[wn + ni*16 + lr][lg*8];
        #pragma unroll
        for (int mi=0;mi<4;++mi)
            #pragma unroll
            for (int ni=0;ni<4;++ni)
                acc[mi][ni] = __builtin_amdgcn_mfma_f32_16x16x32_bf16(
                    af[mi], bfr[ni], acc[mi][ni], 0, 0, 0);
        __syncthreads();
    }

    float bn[4];
    #pragma unroll
    for (int ni=0;ni<4;++ni) bn[ni] = bias[n0 + wn + ni*16 + lr];
    #pragma unroll
    for (int mi=0;mi<4;++mi)
        #pragma unroll
        for (int ni=0;ni<4;++ni)
            #pragma unroll
            for (int r=0;r<4;++r){
                int row = m0 + wm + mi*16 + lg*4 + r;
                float v = acc[mi][ni][r] + bn[ni];
                v = gelu_f(v);
                Ybf[(size_t)row*256 + n0 + wn + ni*16 + lr] = f2bf(v);
            }
}

// ---------------------------------------------------------------------------
// dec3 MFMA: Y[T,48] = A_bf16 @ W3^T + b3 (W3 converted in-kernel),
// fused un-patchify + recon loss. 256 rows/block, 4 waves of 64 rows.
// ---------------------------------------------------------------------------
__global__ __launch_bounds__(256) void dec3_mfma(
    const ushort* __restrict__ Ain, const float* __restrict__ W,
    const float* __restrict__ bias, const float* __restrict__ frames,
    float* __restrict__ recon, float* __restrict__ loss)
{
    __shared__ __align__(16) ushort Al[256][40];
    __shared__ __align__(16) ushort Wl[48][40];

    const int tid = threadIdx.x;
    const int m0 = blockIdx.x * 256;
    const int lane = tid & 63;
    const int w = tid >> 6;
    const int lr = lane & 15, lg = lane >> 4;

    const ushort* asrc = Ain + (size_t)(m0 + tid)*256;

    f32x4 acc[4][3];
    #pragma unroll
    for (int mi=0;mi<4;++mi)
        #pragma unroll
        for (int ni=0;ni<3;++ni)
            acc[mi][ni] = (f32x4){0.f,0.f,0.f,0.f};

    for (int k0=0; k0<256; k0+=32){
        *(uint4*)&Al[tid][0]  = *(const uint4*)(asrc + k0);
        *(uint4*)&Al[tid][8]  = *(const uint4*)(asrc + k0 + 8);
        *(uint4*)&Al[tid][16] = *(const uint4*)(asrc + k0 + 16);
        *(uint4*)&Al[tid][24] = *(const uint4*)(asrc + k0 + 24);
        if (tid < 96){
            const int wrow = tid >> 1, wh = (tid & 1)*16;
            const float* wp = W + (size_t)wrow*256 + k0 + wh;
            float4 f0 = *(const float4*)(wp);
            float4 f1 = *(const float4*)(wp+4);
            float4 f2 = *(const float4*)(wp+8);
            float4 f3 = *(const float4*)(wp+12);
            ushort t[16];
            t[0]=f2bf(f0.x); t[1]=f2bf(f0.y); t[2]=f2bf(f0.z); t[3]=f2bf(f0.w);
            t[4]=f2bf(f1.x); t[5]=f2bf(f1.y); t[6]=f2bf(f1.z); t[7]=f2bf(f1.w);
            t[8]=f2bf(f2.x); t[9]=f2bf(f2.y); t[10]=f2bf(f2.z); t[11]=f2bf(f2.w);
            t[12]=f2bf(f3.x); t[13]=f2bf(f3.y); t[14]=f2bf(f3.z); t[15]=f2bf(f3.w);
            *(uint4*)&Wl[wrow][wh]   = *(const uint4*)&t[0];
            *(uint4*)&Wl[wrow][wh+8] = *(const uint4*)&t[8];
        }
        __syncthreads();

        short8 bfr[3];
        #pragma unroll
        for (int ni=0;ni<3;++ni)
            bfr[ni] = *(const short8*)&Wl[ni*16 + lr][lg*8];
        #pragma unroll
        for (int mi=0;mi<4;++mi){
            short8 af = *(const short8*)&Al[w*64 + mi*16 + lr][lg*8];
            #pragma unroll
            for (int ni=0;ni<3;++ni)
                acc[mi][ni] = __builtin_amdgcn_mfma_f32_16x16x32_bf16(
                    af, bfr[ni], acc[mi][ni], 0, 0, 0);
        }
        __syncthreads();
    }

    float bn[3]; int phv[3], remv[3];
    #pragma unroll
    for (int ni=0;ni<3;++ni){
        int col = ni*16 + lr;
        bn[ni] = bias[col];
        phv[ni] = col / 12;
        remv[ni] = col - phv[ni]*12;
    }
    const float sc = 2.0f/255.0f;
    float ls = 0.0f;
    #pragma unroll
    for (int mi=0;mi<4;++mi)
        #pragma unroll
        for (int ni=0;ni<3;++ni)
            #pragma unroll
            for (int r=0;r<4;++r){
                int p = m0 + w*64 + mi*16 + lg*4 + r;
                int b = p >> 12, nl = p & 4095, hh = nl >> 6, ww = nl & 63;
                size_t addr = (size_t)(((b*256 + hh*4 + phv[ni])*256 + ww*4)*3 + remv[ni]);
                float y = acc[mi][ni][r] + bn[ni];
                float t = frames[addr]*sc - 1.0f;
                float d = y - t;
                ls += d*d;
                recon[addr] = y;
            }

    #pragma unroll
    for (int off=32; off>0; off>>=1) ls += __shfl_down(ls, off);
    __shared__ float wsum[4];
    if (lane == 0) wsum[w] = ls;
    __syncthreads();
    if (tid == 0) atomicAdd(loss + 0, wsum[0]+wsum[1]+wsum[2]+wsum[3]);
}

__global__ void finalize_kernel(float* __restrict__ loss){
    if (threadIdx.x == 0 && blockIdx.x == 0){
        loss[0] = loss[0] * (1.0f/6291456.0f);
        float c = loss[1] * (1.0f/33554432.0f);
        loss[1] = c;
        loss[2] = c;
    }
}

extern "C" void kernel_launch(void* const* d_in, const int* in_sizes, int n_in,
                              void* d_out, int out_size, void* d_ws, size_t ws_size,
                              hipStream_t stream)
{
    (void)in_sizes; (void)n_in; (void)out_size; (void)ws_size;
    const float* frames   = (const float*)d_in[0];
    const float* enc_w1   = (const float*)d_in[1];
    const float* enc_b1   = (const float*)d_in[2];
    const float* enc_w2   = (const float*)d_in[3];
    const float* enc_b2   = (const float*)d_in[4];
    const float* enc_w3   = (const float*)d_in[5];
    const float* enc_b3   = (const float*)d_in[6];
    const float* codebook = (const float*)d_in[7];
    const float* dec_w1   = (const float*)d_in[8];
    const float* dec_b1   = (const float*)d_in[9];
    const float* dec_w2   = (const float*)d_in[10];
    const float* dec_b2   = (const float*)d_in[11];
    const float* dec_w3   = (const float*)d_in[12];
    const float* dec_b3   = (const float*)d_in[13];

    // workspace: two [T,256] f32 regions (268 MB, proven available)
    float* P = (float*)d_ws;                 // h1 -> z_e -> Y1(bf16)
    float* Q = P + (size_t)33554432;         // h2 -> {Y2(bf16) base, partials}
    float2* partials = (float2*)(Q + 18000000);  // 4 MB, disjoint from Y2
    ushort* Y1 = (ushort*)P;
    ushort* Y2 = (ushort*)Q;

    // outputs; recon region doubles as scratch for small constants
    float* recon = (float*)d_out;            // 6,291,456 f32 (written last)
    float* tokf  = recon + 6291456;          // 131,072
    float* loss  = tokf + 131072;            // 3
    float*  cn   = recon;                            // 512 f32
    ushort* cbb  = (ushort*)(recon + 512);           // 131072 us
    ushort* w1b  = (ushort*)(recon + 66048);         // 65536 us
    ushort* w2b  = (ushort*)(recon + 98816);         // 65536 us
    ushort* w2s0 = (ushort*)(recon + 131584);        // 65536 us each
    ushort* w2s1 = (ushort*)(recon + 164352);
    ushort* w2s2 = (ushort*)(recon + 197120);
    ushort* w3s0 = (ushort*)(recon + 229888);
    ushort* w3s1 = (ushort*)(recon + 262656);
    ushort* w3s2 = (ushort*)(recon + 295424);
    ushort* cbs0 = (ushort*)(recon + 328192);        // 131072 us each
    ushort* cbs1 = (ushort*)(recon + 393728);
    ushort* cbs2 = (ushort*)(recon + 459264);        // ends 524800
    float*  zzb  = recon + 524800;                   // 131072 f32, ends 655872

    hipMemsetAsync(loss, 0, 3*sizeof(float), stream);

    dim3 blk(256), grid2(T_ROWS/128, 2);
    // weight prep
    wsplit_kernel<<<dim3(64), blk, 0, stream>>>(enc_w2, enc_w3, dec_w1, dec_w2,
        w2s0, w2s1, w2s2, w3s0, w3s1, w3s2, w1b, w2b);
    cnorm_kernel<<<dim3(128), blk, 0, stream>>>(codebook, cn, cbb, cbs0, cbs1, cbs2);
    // encoder: f32 layer1, then f32-faithful 6-term split-bf16 MFMA
    gemm_kernel<48, true, 1><<<grid2, blk, 0, stream>>>(nullptr, frames, enc_w1, enc_b1, P);
    split6_gemm<true ><<<grid2, blk, 0, stream>>>(P, w2s0, w2s1, w2s2, enc_b2, Q);
    split6_gemm<false><<<grid2, blk, 0, stream>>>(Q, w3s0, w3s1, w3s2, enc_b3, P);
    // vector quantization: EXACT split6 distances (+fused ||z||^2) + reduce
    tokens_split6<<<dim3(T_ROWS/128, 4), blk, 0, stream>>>(P, cbs0, cbs1, cbs2, cn, partials, zzb);
    token_reduce<<<dim3(T_ROWS/256), blk, 0, stream>>>(zzb, partials, tokf, loss);
    // decoder (bf16 MFMA)
    mfma_gemm<1><<<grid2, blk, 0, stream>>>(nullptr, cbb, tokf, w1b, dec_b1, Y1);
    mfma_gemm<0><<<grid2, blk, 0, stream>>>(Y1, nullptr, nullptr, w2b, dec_b2, Y2);
    dec3_mfma<<<dim3(T_ROWS/256), blk, 0, stream>>>(Y2, dec_w3, dec_b3, frames, recon, loss);
    finalize_kernel<<<dim3(1), dim3(64), 0, stream>>>(loss);
}

// Round 11
// 708.568 us; speedup vs baseline: 1.6266x; 1.0261x over previous
//
#include <hip/hip_runtime.h>
#include <hip/hip_bf16.h>
#include <math.h>
#include <float.h>
#include <limits.h>

#define T_ROWS 131072   // 32 * 4096 patches

typedef __attribute__((ext_vector_type(8))) short short8;
typedef __attribute__((ext_vector_type(4))) float f32x4;

__device__ __forceinline__ float gelu_f(float x){
    return 0.5f * x * (1.0f + erff(x * 0.7071067811865475f));
}
__device__ __forceinline__ float bf2f(ushort u){
    union { unsigned int i; float f; } v; v.i = ((unsigned int)u) << 16; return v.f;
}
__device__ __forceinline__ ushort f2bf(float f){
    union { float f; unsigned int i; } v; v.f = f;
    unsigned int i = v.i;
    unsigned int r = (i + 0x7fffu + ((i >> 16) & 1u)) >> 16;
    return (ushort)r;
}
// exact 3-way truncation split: x ~= b0+b1+b2 (each bf16), >=24 mantissa bits
__device__ __forceinline__ void split3(float x, ushort &u0, ushort &u1, ushort &u2){
    union { float f; unsigned int i; } v; v.f = x;
    u0 = (ushort)(v.i >> 16);
    union { unsigned int i; float f; } h0; h0.i = ((unsigned int)u0) << 16;
    float r = x - h0.f;                       // exact (Sterbenz)
    union { float f; unsigned int i; } vr; vr.f = r;
    u1 = (ushort)(vr.i >> 16);
    union { unsigned int i; float f; } h1; h1.i = ((unsigned int)u1) << 16;
    float r2 = r - h1.f;                      // exact
    union { float f; unsigned int i; } v2; v2.f = r2;
    u2 = (ushort)(v2.i >> 16);
}

// ---------------------------------------------------------------------------
// Merged prep:
//  blocks   0..63 : 3-way split enc_w2/enc_w3 ; bf16 round dec_w1/dec_w2
//  blocks  64..191: ||c||^2 + bf16 codebook + 3-way split codebook
//  blocks 192..207: 3-way split enc_w1 into K=64 zero-padded planes
//  block   208    : bias2[n] = enc_b1[n] - sum_k enc_w1[n,k]
// ---------------------------------------------------------------------------
__global__ __launch_bounds__(256) void prep_kernel(
    const float* __restrict__ w2, const float* __restrict__ w3,
    const float* __restrict__ d1, const float* __restrict__ d2,
    const float* __restrict__ w1, const float* __restrict__ b1,
    const float* __restrict__ cb,
    ushort* __restrict__ w2s0, ushort* __restrict__ w2s1, ushort* __restrict__ w2s2,
    ushort* __restrict__ w3s0, ushort* __restrict__ w3s1, ushort* __restrict__ w3s2,
    ushort* __restrict__ w1b, ushort* __restrict__ w2b,
    float* __restrict__ cn, ushort* __restrict__ cbb,
    ushort* __restrict__ cbs0, ushort* __restrict__ cbs1, ushort* __restrict__ cbs2,
    ushort* __restrict__ w1p0, ushort* __restrict__ w1p1, ushort* __restrict__ w1p2,
    float* __restrict__ bias2)
{
    const int blk = blockIdx.x, tid = threadIdx.x;
    if (blk < 64){
        const int i = (blk*256 + tid)*4;
        float4 a = *(const float4*)(w2 + i);
        ushort4 s0, s1, s2;
        split3(a.x, s0.x, s1.x, s2.x); split3(a.y, s0.y, s1.y, s2.y);
        split3(a.z, s0.z, s1.z, s2.z); split3(a.w, s0.w, s1.w, s2.w);
        *(ushort4*)(w2s0+i)=s0; *(ushort4*)(w2s1+i)=s1; *(ushort4*)(w2s2+i)=s2;
        float4 b = *(const float4*)(w3 + i);
        split3(b.x, s0.x, s1.x, s2.x); split3(b.y, s0.y, s1.y, s2.y);
        split3(b.z, s0.z, s1.z, s2.z); split3(b.w, s0.w, s1.w, s2.w);
        *(ushort4*)(w3s0+i)=s0; *(ushort4*)(w3s1+i)=s1; *(ushort4*)(w3s2+i)=s2;
        float4 c = *(const float4*)(d1 + i);
        ushort4 u; u.x=f2bf(c.x); u.y=f2bf(c.y); u.z=f2bf(c.z); u.w=f2bf(c.w);
        *(ushort4*)(w1b+i) = u;
        float4 d = *(const float4*)(d2 + i);
        u.x=f2bf(d.x); u.y=f2bf(d.y); u.z=f2bf(d.z); u.w=f2bf(d.w);
        *(ushort4*)(w2b+i) = u;
    } else if (blk < 192){
        const int lane = tid & 63;
        const int code = (blk-64)*4 + (tid >> 6);
        float4 v = ((const float4*)(cb + (size_t)code*256))[lane];
        size_t off = (size_t)code*256 + lane*4;
        ushort4 u; u.x=f2bf(v.x); u.y=f2bf(v.y); u.z=f2bf(v.z); u.w=f2bf(v.w);
        *(ushort4*)(cbb + off) = u;
        ushort4 s0, s1, s2;
        split3(v.x, s0.x, s1.x, s2.x); split3(v.y, s0.y, s1.y, s2.y);
        split3(v.z, s0.z, s1.z, s2.z); split3(v.w, s0.w, s1.w, s2.w);
        *(ushort4*)(cbs0 + off) = s0;
        *(ushort4*)(cbs1 + off) = s1;
        *(ushort4*)(cbs2 + off) = s2;
        float s = v.x*v.x + v.y*v.y + v.z*v.z + v.w*v.w;
        #pragma unroll
        for (int m=1; m<64; m<<=1) s += __shfl_xor(s, m);
        if (lane == 0) cn[code] = s;
    } else if (blk < 208){
        const int idx = (blk-192)*256 + tid;    // 0..4095
        const int n = idx >> 4, k = (idx & 15)*4;
        ushort4 s0 = {0,0,0,0}, s1 = {0,0,0,0}, s2 = {0,0,0,0};
        if (k < 48){
            float4 v = *(const float4*)(w1 + n*48 + k);
            split3(v.x, s0.x, s1.x, s2.x); split3(v.y, s0.y, s1.y, s2.y);
            split3(v.z, s0.z, s1.z, s2.z); split3(v.w, s0.w, s1.w, s2.w);
        }
        *(ushort4*)(w1p0 + n*64 + k) = s0;
        *(ushort4*)(w1p1 + n*64 + k) = s1;
        *(ushort4*)(w1p2 + n*64 + k) = s2;
    } else {
        float s = 0.0f;
        for (int k=0;k<48;++k) s += w1[tid*48 + k];
        bias2[tid] = b1[tid] - s;
    }
}

// ---------------------------------------------------------------------------
// f32-faithful split6 MFMA GEMM, 64 rows x 256 cols per block (A read ONCE).
// A: 3 planes split in-kernel -> LDS. B: plane0 in LDS, planes 1,2 direct
// from global (L2-resident). LDS ~36 KB, 3 blocks/CU.
// LOADER 0: A = Ain f32 [M][KTOT]. LOADER 1: patchify frames (raw f, exact
// split; normalization folded: out = SCALE*acc + bias  with bias=b1-rowsum).
// ---------------------------------------------------------------------------
template<int KTOT, bool GELU, int LOADER, bool SCALE>
__global__ __launch_bounds__(256, 3) void split6_gemm(
    const float* __restrict__ Ain,
    const float* __restrict__ frames,
    const ushort* __restrict__ W0, const ushort* __restrict__ W1,
    const ushort* __restrict__ W2,
    const float* __restrict__ bias,
    float* __restrict__ Cout)
{
    __shared__ __align__(16) ushort Al[3][64][40];
    __shared__ __align__(16) ushort Wl[256][40];

    const int tid = threadIdx.x;
    const int m0 = blockIdx.x * 64;
    const int arow = tid >> 2, q = tid & 3;
    const int lane = tid & 63;
    const int w = tid >> 6;
    const int lr = lane & 15, lg = lane >> 4;

    const float* asrc = nullptr;
    int pbase = 0;
    if constexpr (LOADER == 0){
        asrc = Ain + (size_t)(m0 + arow)*KTOT + q*8;
    } else {
        int p = m0 + arow;
        int b = p >> 12, nl = p & 4095, hh = nl >> 6, ww = nl & 63;
        pbase = ((b*256 + hh*4)*256 + ww*4)*3;
    }
    const ushort* wsrc  = W0 + (size_t)tid*KTOT;
    const ushort* w1frag = W1 + (size_t)(w*64 + lr)*KTOT + lg*8;
    const ushort* w2frag = W2 + (size_t)(w*64 + lr)*KTOT + lg*8;

    f32x4 acc[4][4];
    #pragma unroll
    for (int mi=0;mi<4;++mi)
        #pragma unroll
        for (int ni=0;ni<4;++ni)
            acc[mi][ni] = (f32x4){0.f,0.f,0.f,0.f};

    for (int k0=0; k0<KTOT; k0+=32){
        float x[8];
        if constexpr (LOADER == 0){
            *(float4*)&x[0] = *(const float4*)(asrc + k0);
            *(float4*)&x[4] = *(const float4*)(asrc + k0 + 4);
        } else {
            #pragma unroll
            for (int j=0;j<2;++j){
                int kk = k0 + q*8 + j*4;
                float4 v = {0.f,0.f,0.f,0.f};
                if (kk < 48){
                    int ph = kk/12, rem = kk - ph*12;
                    v = *(const float4*)(frames + pbase + ph*768 + rem);
                }
                x[j*4+0]=v.x; x[j*4+1]=v.y; x[j*4+2]=v.z; x[j*4+3]=v.w;
            }
        }
        ushort t0[8], t1[8], t2[8];
        #pragma unroll
        for (int e=0;e<8;++e) split3(x[e], t0[e], t1[e], t2[e]);
        *(uint4*)&Al[0][arow][q*8] = *(const uint4*)t0;
        *(uint4*)&Al[1][arow][q*8] = *(const uint4*)t1;
        *(uint4*)&Al[2][arow][q*8] = *(const uint4*)t2;
        *(uint4*)&Wl[tid][0]  = *(const uint4*)(wsrc + k0);
        *(uint4*)&Wl[tid][8]  = *(const uint4*)(wsrc + k0 + 8);
        *(uint4*)&Wl[tid][16] = *(const uint4*)(wsrc + k0 + 16);
        *(uint4*)&Wl[tid][24] = *(const uint4*)(wsrc + k0 + 24);
        short8 b1v[4], b2v[4];
        #pragma unroll
        for (int ni=0;ni<4;++ni){
            b1v[ni] = *(const short8*)(w1frag + (size_t)ni*16*KTOT + k0);
            b2v[ni] = *(const short8*)(w2frag + (size_t)ni*16*KTOT + k0);
        }
        __syncthreads();

        short8 b0v[4];
        #pragma unroll
        for (int ni=0;ni<4;++ni)
            b0v[ni] = *(const short8*)&Wl[w*64 + ni*16 + lr][lg*8];
        #pragma unroll
        for (int mi=0;mi<4;++mi){
            short8 a0 = *(const short8*)&Al[0][mi*16 + lr][lg*8];
            short8 a1 = *(const short8*)&Al[1][mi*16 + lr][lg*8];
            short8 a2 = *(const short8*)&Al[2][mi*16 + lr][lg*8];
            #pragma unroll
            for (int ni=0;ni<4;++ni)
                acc[mi][ni] = __builtin_amdgcn_mfma_f32_16x16x32_bf16(a0, b0v[ni], acc[mi][ni], 0,0,0);
            #pragma unroll
            for (int ni=0;ni<4;++ni)
                acc[mi][ni] = __builtin_amdgcn_mfma_f32_16x16x32_bf16(a0, b1v[ni], acc[mi][ni], 0,0,0);
            #pragma unroll
            for (int ni=0;ni<4;++ni)
                acc[mi][ni] = __builtin_amdgcn_mfma_f32_16x16x32_bf16(a1, b0v[ni], acc[mi][ni], 0,0,0);
            #pragma unroll
            for (int ni=0;ni<4;++ni)
                acc[mi][ni] = __builtin_amdgcn_mfma_f32_16x16x32_bf16(a0, b2v[ni], acc[mi][ni], 0,0,0);
            #pragma unroll
            for (int ni=0;ni<4;++ni)
                acc[mi][ni] = __builtin_amdgcn_mfma_f32_16x16x32_bf16(a1, b1v[ni], acc[mi][ni], 0,0,0);
            #pragma unroll
            for (int ni=0;ni<4;++ni)
                acc[mi][ni] = __builtin_amdgcn_mfma_f32_16x16x32_bf16(a2, b0v[ni], acc[mi][ni], 0,0,0);
        }
        __syncthreads();
    }

    const float alpha = 2.0f/255.0f;
    float bn[4];
    #pragma unroll
    for (int ni=0;ni<4;++ni) bn[ni] = bias[w*64 + ni*16 + lr];
    #pragma unroll
    for (int mi=0;mi<4;++mi)
        #pragma unroll
        for (int ni=0;ni<4;++ni)
            #pragma unroll
            for (int r=0;r<4;++r){
                int row = m0 + mi*16 + lg*4 + r;
                float v;
                if (SCALE) v = fmaf(alpha, acc[mi][ni][r], bn[ni]);
                else       v = acc[mi][ni][r] + bn[ni];
                if (GELU) v = gelu_f(v);
                Cout[(size_t)row*256 + w*64 + ni*16 + lr] = v;
            }
}

#define INSERT1(dv, iv) do { \
    float _d = (dv); int _i = (iv); \
    if (_d < bd || (_d == bd && _i < bi)){ bd = _d; bi = _i; } \
} while(0)

// ---------------------------------------------------------------------------
// EXACT distance pass, 64 rows x 256 codes per block (z read 2x, was 4x).
// Codebook plane0 in LDS, planes 1,2 from global; fused ||z||^2.
// ---------------------------------------------------------------------------
__global__ __launch_bounds__(256, 3) void tokens_split6(
    const float* __restrict__ Zf,
    const ushort* __restrict__ C0, const ushort* __restrict__ C1,
    const ushort* __restrict__ C2,
    const float* __restrict__ cn,
    float2* __restrict__ partials,
    float* __restrict__ zz_out)
{
    __shared__ __align__(16) ushort Al[3][64][40];
    __shared__ __align__(16) ushort Wl[256][40];
    __shared__ float2 ptop[64][4];

    const int tid = threadIdx.x;
    const int m0 = blockIdx.x * 64;
    const int cbk = blockIdx.y;
    const int n0 = cbk * 256;
    const int arow = tid >> 2, q = tid & 3;
    const int lane = tid & 63;
    const int w = tid >> 6;
    const int lr = lane & 15, lg = lane >> 4;

    const float*  asrc = Zf + (size_t)(m0 + arow)*256 + q*8;
    const ushort* wsrc = C0 + (size_t)(n0 + tid)*256;
    const ushort* c1frag = C1 + (size_t)(n0 + w*64 + lr)*256 + lg*8;
    const ushort* c2frag = C2 + (size_t)(n0 + w*64 + lr)*256 + lg*8;

    f32x4 acc[4][4];
    #pragma unroll
    for (int mi=0;mi<4;++mi)
        #pragma unroll
        for (int ni=0;ni<4;++ni)
            acc[mi][ni] = (f32x4){0.f,0.f,0.f,0.f};

    float zzp = 0.0f;

    for (int k0=0; k0<256; k0+=32){
        float x[8];
        *(float4*)&x[0] = *(const float4*)(asrc + k0);
        *(float4*)&x[4] = *(const float4*)(asrc + k0 + 4);
        ushort t0[8], t1[8], t2[8];
        #pragma unroll
        for (int e=0;e<8;++e){
            split3(x[e], t0[e], t1[e], t2[e]);
            zzp = fmaf(x[e], x[e], zzp);
        }
        *(uint4*)&Al[0][arow][q*8] = *(const uint4*)t0;
        *(uint4*)&Al[1][arow][q*8] = *(const uint4*)t1;
        *(uint4*)&Al[2][arow][q*8] = *(const uint4*)t2;
        *(uint4*)&Wl[tid][0]  = *(const uint4*)(wsrc + k0);
        *(uint4*)&Wl[tid][8]  = *(const uint4*)(wsrc + k0 + 8);
        *(uint4*)&Wl[tid][16] = *(const uint4*)(wsrc + k0 + 16);
        *(uint4*)&Wl[tid][24] = *(const uint4*)(wsrc + k0 + 24);
        short8 b1v[4], b2v[4];
        #pragma unroll
        for (int ni=0;ni<4;++ni){
            b1v[ni] = *(const short8*)(c1frag + (size_t)ni*16*256 + k0);
            b2v[ni] = *(const short8*)(c2frag + (size_t)ni*16*256 + k0);
        }
        __syncthreads();

        short8 b0v[4];
        #pragma unroll
        for (int ni=0;ni<4;++ni)
            b0v[ni] = *(const short8*)&Wl[w*64 + ni*16 + lr][lg*8];
        #pragma unroll
        for (int mi=0;mi<4;++mi){
            short8 a0 = *(const short8*)&Al[0][mi*16 + lr][lg*8];
            short8 a1 = *(const short8*)&Al[1][mi*16 + lr][lg*8];
            short8 a2 = *(const short8*)&Al[2][mi*16 + lr][lg*8];
            #pragma unroll
            for (int ni=0;ni<4;++ni)
                acc[mi][ni] = __builtin_amdgcn_mfma_f32_16x16x32_bf16(a0, b0v[ni], acc[mi][ni], 0,0,0);
            #pragma unroll
            for (int ni=0;ni<4;++ni)
                acc[mi][ni] = __builtin_amdgcn_mfma_f32_16x16x32_bf16(a0, b1v[ni], acc[mi][ni], 0,0,0);
            #pragma unroll
            for (int ni=0;ni<4;++ni)
                acc[mi][ni] = __builtin_amdgcn_mfma_f32_16x16x32_bf16(a1, b0v[ni], acc[mi][ni], 0,0,0);
            #pragma unroll
            for (int ni=0;ni<4;++ni)
                acc[mi][ni] = __builtin_amdgcn_mfma_f32_16x16x32_bf16(a0, b2v[ni], acc[mi][ni], 0,0,0);
            #pragma unroll
            for (int ni=0;ni<4;++ni)
                acc[mi][ni] = __builtin_amdgcn_mfma_f32_16x16x32_bf16(a1, b1v[ni], acc[mi][ni], 0,0,0);
            #pragma unroll
            for (int ni=0;ni<4;++ni)
                acc[mi][ni] = __builtin_amdgcn_mfma_f32_16x16x32_bf16(a2, b0v[ni], acc[mi][ni], 0,0,0);
        }
        __syncthreads();
    }

    // ||z||^2 per row (4 threads share a row; combine across q)
    {
        float s = zzp + __shfl_xor(zzp, 1);
        s += __shfl_xor(s, 2);
        if (cbk == 0 && q == 0) zz_out[m0 + arow] = s;
    }

    float cnl[4];
    #pragma unroll
    for (int ni=0;ni<4;++ni) cnl[ni] = cn[n0 + w*64 + ni*16 + lr];

    #pragma unroll
    for (int mi=0;mi<4;++mi)
        #pragma unroll
        for (int r=0;r<4;++r){
            float bd = FLT_MAX; int bi = INT_MAX;
            #pragma unroll
            for (int ni=0;ni<4;++ni){
                float d = cnl[ni] - 2.0f*acc[mi][ni][r];
                int col = n0 + w*64 + ni*16 + lr;
                INSERT1(d, col);
            }
            #pragma unroll
            for (int m=1; m<16; m<<=1){
                float od = __shfl_xor(bd, m);
                int   oi = __shfl_xor(bi, m);
                INSERT1(od, oi);
            }
            if (lr == 0)
                ptop[mi*16 + lg*4 + r][w] = make_float2(bd, (float)bi);
        }
    __syncthreads();
    if (tid < 64){
        float2 h = ptop[tid][0];
        #pragma unroll
        for (int ww=1; ww<4; ++ww){
            float2 o = ptop[tid][ww];
            if (o.x < h.x) h = o;   // codes ascend with ww; ties keep lower idx
        }
        partials[(size_t)(m0 + tid)*2 + cbk] = h;
    }
}

// ---------------------------------------------------------------------------
// Token + commitment: min over 2 (d,idx) partials, zz from zz_out.
// ---------------------------------------------------------------------------
__global__ __launch_bounds__(256) void token_reduce(
    const float* __restrict__ zz_out, const float2* __restrict__ partials,
    float* __restrict__ tokf, float* __restrict__ loss)
{
    const int tid = threadIdx.x;
    const int row = blockIdx.x*256 + tid;
    float2 p0 = partials[(size_t)row*2 + 0];
    float2 p1 = partials[(size_t)row*2 + 1];
    float d = p0.x; int g = (int)p0.y;
    if (p1.x < d || (p1.x == d && (int)p1.y < g)){ d = p1.x; g = (int)p1.y; }
    tokf[row] = (float)g;
    float cs = zz_out[row] + d;
    #pragma unroll
    for (int m=1; m<64; m<<=1) cs += __shfl_xor(cs, m);
    __shared__ float wsum[4];
    const int lane = tid & 63, w = tid >> 6;
    if (lane == 0) wsum[w] = cs;
    __syncthreads();
    if (tid == 0) atomicAdd(loss + 1, wsum[0]+wsum[1]+wsum[2]+wsum[3]);
}

// ---------------------------------------------------------------------------
// bf16 MFMA GEMM (decoder 1/2): Y[M,256] = gelu(A @ W^T + b)
// LOADER: 0 = plain bf16 A, 1 = gather bf16 codebook rows via tokens.
// ---------------------------------------------------------------------------
template<int LOADER>
__global__ __launch_bounds__(256) void mfma_gemm(
    const ushort* __restrict__ Abf,
    const ushort* __restrict__ cbb,
    const float* __restrict__ tokf,
    const ushort* __restrict__ Wbf,
    const float* __restrict__ bias,
    ushort* __restrict__ Ybf)
{
    __shared__ __align__(16) ushort Al[128][40];
    __shared__ __align__(16) ushort Wl[128][40];

    const int tid = threadIdx.x;
    const int m0 = blockIdx.x * 128;
    const int n0 = blockIdx.y * 128;
    const int srow = tid >> 1, shalf = (tid & 1) * 16;
    const int lane = tid & 63;
    const int w = tid >> 6;
    const int wm = (w >> 1) * 64, wn = (w & 1) * 64;
    const int lr = lane & 15, lg = lane >> 4;

    const ushort* asrc;
    if constexpr (LOADER == 1){
        int g = (int)tokf[m0 + srow];
        asrc = cbb + (size_t)g*256 + shalf;
    } else {
        asrc = Abf + (size_t)(m0 + srow)*256 + shalf;
    }
    const ushort* wsrc = Wbf + (size_t)(n0 + srow)*256 + shalf;

    f32x4 acc[4][4];
    #pragma unroll
    for (int mi=0;mi<4;++mi)
        #pragma unroll
        for (int ni=0;ni<4;++ni)
            acc[mi][ni] = (f32x4){0.f,0.f,0.f,0.f};

    for (int k0=0; k0<256; k0+=32){
        *(uint4*)&Al[srow][shalf]   = *(const uint4*)(asrc + k0);
        *(uint4*)&Al[srow][shalf+8] = *(const uint4*)(asrc + k0 + 8);
        *(uint4*)&Wl[srow][shalf]   = *(const uint4*)(wsrc + k0);
        *(uint4*)&Wl[srow][shalf+8] = *(const uint4*)(wsrc + k0 + 8);
        __syncthreads();

        short8 af[4], bfr[4];
        #pragma unroll
        for (int mi=0;mi<4;++mi)
            af[mi] = *(const short8*)&Al[wm + mi*16 + lr][lg*8];
        #pragma unroll
        for (int ni=0;ni<4;++ni)
            bfr[ni] = *(const short8*)&Wl[wn + ni*16 + lr][lg*8];
        #pragma unroll
        for (int mi=0;mi<4;++mi)
            #pragma unroll
            for (int ni=0;ni<4;++ni)
                acc[mi][ni] = __builtin_amdgcn_mfma_f32_16x16x32_bf16(
                    af[mi], bfr[ni], acc[mi][ni], 0, 0, 0);
        __syncthreads();
    }

    float bn[4];
    #pragma unroll
    for (int ni=0;ni<4;++ni) bn[ni] = bias[n0 + wn + ni*16 + lr];
    #pragma unroll
    for (int mi=0;mi<4;++mi)
        #pragma unroll
        for (int ni=0;ni<4;++ni)
            #pragma unroll
            for (int r=0;r<4;++r){
                int row = m0 + wm + mi*16 + lg*4 + r;
                float v = acc[mi][ni][r] + bn[ni];
                v = gelu_f(v);
                Ybf[(size_t)row*256 + n0 + wn + ni*16 + lr] = f2bf(v);
            }
}

// ---------------------------------------------------------------------------
// dec3 MFMA: Y[T,48] = A_bf16 @ W3^T + b3 (W3 converted in-kernel),
// fused un-patchify + recon loss. 256 rows/block, 4 waves of 64 rows.
// ---------------------------------------------------------------------------
__global__ __launch_bounds__(256) void dec3_mfma(
    const ushort* __restrict__ Ain, const float* __restrict__ W,
    const float* __restrict__ bias, const float* __restrict__ frames,
    float* __restrict__ recon, float* __restrict__ loss)
{
    __shared__ __align__(16) ushort Al[256][40];
    __shared__ __align__(16) ushort Wl[48][40];

    const int tid = threadIdx.x;
    const int m0 = blockIdx.x * 256;
    const int lane = tid & 63;
    const int w = tid >> 6;
    const int lr = lane & 15, lg = lane >> 4;

    const ushort* asrc = Ain + (size_t)(m0 + tid)*256;

    f32x4 acc[4][3];
    #pragma unroll
    for (int mi=0;mi<4;++mi)
        #pragma unroll
        for (int ni=0;ni<3;++ni)
            acc[mi][ni] = (f32x4){0.f,0.f,0.f,0.f};

    for (int k0=0; k0<256; k0+=32){
        *(uint4*)&Al[tid][0]  = *(const uint4*)(asrc + k0);
        *(uint4*)&Al[tid][8]  = *(const uint4*)(asrc + k0 + 8);
        *(uint4*)&Al[tid][16] = *(const uint4*)(asrc + k0 + 16);
        *(uint4*)&Al[tid][24] = *(const uint4*)(asrc + k0 + 24);
        if (tid < 96){
            const int wrow = tid >> 1, wh = (tid & 1)*16;
            const float* wp = W + (size_t)wrow*256 + k0 + wh;
            float4 f0 = *(const float4*)(wp);
            float4 f1 = *(const float4*)(wp+4);
            float4 f2 = *(const float4*)(wp+8);
            float4 f3 = *(const float4*)(wp+12);
            ushort t[16];
            t[0]=f2bf(f0.x); t[1]=f2bf(f0.y); t[2]=f2bf(f0.z); t[3]=f2bf(f0.w);
            t[4]=f2bf(f1.x); t[5]=f2bf(f1.y); t[6]=f2bf(f1.z); t[7]=f2bf(f1.w);
            t[8]=f2bf(f2.x); t[9]=f2bf(f2.y); t[10]=f2bf(f2.z); t[11]=f2bf(f2.w);
            t[12]=f2bf(f3.x); t[13]=f2bf(f3.y); t[14]=f2bf(f3.z); t[15]=f2bf(f3.w);
            *(uint4*)&Wl[wrow][wh]   = *(const uint4*)&t[0];
            *(uint4*)&Wl[wrow][wh+8] = *(const uint4*)&t[8];
        }
        __syncthreads();

        short8 bfr[3];
        #pragma unroll
        for (int ni=0;ni<3;++ni)
            bfr[ni] = *(const short8*)&Wl[ni*16 + lr][lg*8];
        #pragma unroll
        for (int mi=0;mi<4;++mi){
            short8 af = *(const short8*)&Al[w*64 + mi*16 + lr][lg*8];
            #pragma unroll
            for (int ni=0;ni<3;++ni)
                acc[mi][ni] = __builtin_amdgcn_mfma_f32_16x16x32_bf16(
                    af, bfr[ni], acc[mi][ni], 0, 0, 0);
        }
        __syncthreads();
    }

    float bn[3]; int phv[3], remv[3];
    #pragma unroll
    for (int ni=0;ni<3;++ni){
        int col = ni*16 + lr;
        bn[ni] = bias[col];
        phv[ni] = col / 12;
        remv[ni] = col - phv[ni]*12;
    }
    const float sc = 2.0f/255.0f;
    float ls = 0.0f;
    #pragma unroll
    for (int mi=0;mi<4;++mi)
        #pragma unroll
        for (int ni=0;ni<3;++ni)
            #pragma unroll
            for (int r=0;r<4;++r){
                int p = m0 + w*64 + mi*16 + lg*4 + r;
                int b = p >> 12, nl = p & 4095, hh = nl >> 6, ww = nl & 63;
                size_t addr = (size_t)(((b*256 + hh*4 + phv[ni])*256 + ww*4)*3 + remv[ni]);
                float y = acc[mi][ni][r] + bn[ni];
                float t = frames[addr]*sc - 1.0f;
                float d = y - t;
                ls += d*d;
                recon[addr] = y;
            }

    #pragma unroll
    for (int off=32; off>0; off>>=1) ls += __shfl_down(ls, off);
    __shared__ float wsum[4];
    if (lane == 0) wsum[w] = ls;
    __syncthreads();
    if (tid == 0) atomicAdd(loss + 0, wsum[0]+wsum[1]+wsum[2]+wsum[3]);
}

__global__ void finalize_kernel(float* __restrict__ loss){
    if (threadIdx.x == 0 && blockIdx.x == 0){
        loss[0] = loss[0] * (1.0f/6291456.0f);
        float c = loss[1] * (1.0f/33554432.0f);
        loss[1] = c;
        loss[2] = c;
    }
}

extern "C" void kernel_launch(void* const* d_in, const int* in_sizes, int n_in,
                              void* d_out, int out_size, void* d_ws, size_t ws_size,
                              hipStream_t stream)
{
    (void)in_sizes; (void)n_in; (void)out_size; (void)ws_size;
    const float* frames   = (const float*)d_in[0];
    const float* enc_w1   = (const float*)d_in[1];
    const float* enc_b1   = (const float*)d_in[2];
    const float* enc_w2   = (const float*)d_in[3];
    const float* enc_b2   = (const float*)d_in[4];
    const float* enc_w3   = (const float*)d_in[5];
    const float* enc_b3   = (const float*)d_in[6];
    const float* codebook = (const float*)d_in[7];
    const float* dec_w1   = (const float*)d_in[8];
    const float* dec_b1   = (const float*)d_in[9];
    const float* dec_w2   = (const float*)d_in[10];
    const float* dec_b2   = (const float*)d_in[11];
    const float* dec_w3   = (const float*)d_in[12];
    const float* dec_b3   = (const float*)d_in[13];

    // workspace: two [T,256] f32 regions (268 MB, proven available)
    float* P = (float*)d_ws;                 // h1 -> z_e -> Y1(bf16)
    float* Q = P + (size_t)33554432;         // h2 -> {Y2(bf16) base, partials}
    float2* partials = (float2*)(Q + 18000000);  // 2 MB, disjoint from Y2
    ushort* Y1 = (ushort*)P;
    ushort* Y2 = (ushort*)Q;

    // outputs; recon region doubles as scratch for small constants
    float* recon = (float*)d_out;            // 6,291,456 f32 (written last)
    float* tokf  = recon + 6291456;          // 131,072
    float* loss  = tokf + 131072;            // 3
    float*  cn   = recon;                            // 512 f32
    ushort* cbb  = (ushort*)(recon + 512);           // 131072 us
    ushort* w1b  = (ushort*)(recon + 66048);         // 65536 us
    ushort* w2b  = (ushort*)(recon + 98816);         // 65536 us
    ushort* w2s0 = (ushort*)(recon + 131584);        // 65536 us each
    ushort* w2s1 = (ushort*)(recon + 164352);
    ushort* w2s2 = (ushort*)(recon + 197120);
    ushort* w3s0 = (ushort*)(recon + 229888);
    ushort* w3s1 = (ushort*)(recon + 262656);
    ushort* w3s2 = (ushort*)(recon + 295424);
    ushort* cbs0 = (ushort*)(recon + 328192);        // 131072 us each
    ushort* cbs1 = (ushort*)(recon + 393728);
    ushort* cbs2 = (ushort*)(recon + 459264);        // ends 524800
    float*  zzb  = recon + 524800;                   // 131072 f32, ends 655872
    ushort* w1p0 = (ushort*)(recon + 655872);        // 16384 us each (K=64 pad)
    ushort* w1p1 = (ushort*)(recon + 664064);
    ushort* w1p2 = (ushort*)(recon + 672256);
    float*  bias2 = recon + 680448;                  // 256 f32, ends 680704

    hipMemsetAsync(loss, 0, 3*sizeof(float), stream);

    dim3 blk(256);
    // merged prep
    prep_kernel<<<dim3(209), blk, 0, stream>>>(enc_w2, enc_w3, dec_w1, dec_w2,
        enc_w1, enc_b1, codebook,
        w2s0, w2s1, w2s2, w3s0, w3s1, w3s2, w1b, w2b,
        cn, cbb, cbs0, cbs1, cbs2, w1p0, w1p1, w1p2, bias2);
    // encoder: all three layers f32-faithful split6 MFMA (64x256 blocks)
    split6_gemm<64,  true, 1, true ><<<dim3(T_ROWS/64), blk, 0, stream>>>(nullptr, frames, w1p0, w1p1, w1p2, bias2, P);
    split6_gemm<256, true, 0, false><<<dim3(T_ROWS/64), blk, 0, stream>>>(P, nullptr, w2s0, w2s1, w2s2, enc_b2, Q);
    split6_gemm<256, false,0, false><<<dim3(T_ROWS/64), blk, 0, stream>>>(Q, nullptr, w3s0, w3s1, w3s2, enc_b3, P);
    // vector quantization: EXACT split6 distances (+fused ||z||^2) + reduce
    tokens_split6<<<dim3(T_ROWS/64, 2), blk, 0, stream>>>(P, cbs0, cbs1, cbs2, cn, partials, zzb);
    token_reduce<<<dim3(T_ROWS/256), blk, 0, stream>>>(zzb, partials, tokf, loss);
    // decoder (bf16 MFMA)
    mfma_gemm<1><<<dim3(T_ROWS/128, 2), blk, 0, stream>>>(nullptr, cbb, tokf, w1b, dec_b1, Y1);
    mfma_gemm<0><<<dim3(T_ROWS/128, 2), blk, 0, stream>>>(Y1, nullptr, nullptr, w2b, dec_b2, Y2);
    dec3_mfma<<<dim3(T_ROWS/256), blk, 0, stream>>>(Y2, dec_w3, dec_b3, frames, recon, loss);
    finalize_kernel<<<dim3(1), dim3(64), 0, stream>>>(loss);
}

// Round 12
// 674.300 us; speedup vs baseline: 1.7093x; 1.0508x over previous
//
#include <hip/hip_runtime.h>
#include <hip/hip_bf16.h>
#include <math.h>
#include <float.h>
#include <limits.h>

#define T_ROWS 131072   // 32 * 4096 patches

typedef __attribute__((ext_vector_type(8))) short short8;
typedef __attribute__((ext_vector_type(4))) float f32x4;

__device__ __forceinline__ float gelu_f(float x){
    return 0.5f * x * (1.0f + erff(x * 0.7071067811865475f));
}
__device__ __forceinline__ float bf2f(ushort u){
    union { unsigned int i; float f; } v; v.i = ((unsigned int)u) << 16; return v.f;
}
__device__ __forceinline__ ushort f2bf(float f){
    union { float f; unsigned int i; } v; v.f = f;
    unsigned int i = v.i;
    unsigned int r = (i + 0x7fffu + ((i >> 16) & 1u)) >> 16;
    return (ushort)r;
}
// exact 3-way truncation split: x ~= b0+b1+b2 (each bf16), >=24 mantissa bits
__device__ __forceinline__ void split3(float x, ushort &u0, ushort &u1, ushort &u2){
    union { float f; unsigned int i; } v; v.f = x;
    u0 = (ushort)(v.i >> 16);
    union { unsigned int i; float f; } h0; h0.i = ((unsigned int)u0) << 16;
    float r = x - h0.f;                       // exact (Sterbenz)
    union { float f; unsigned int i; } vr; vr.f = r;
    u1 = (ushort)(vr.i >> 16);
    union { unsigned int i; float f; } h1; h1.i = ((unsigned int)u1) << 16;
    float r2 = r - h1.f;                      // exact
    union { float f; unsigned int i; } v2; v2.f = r2;
    u2 = (ushort)(v2.i >> 16);
}

// ---------------------------------------------------------------------------
// Merged prep:
//  blocks   0..63 : 3-way split enc_w2/enc_w3 ; bf16 round dec_w1/dec_w2
//  blocks  64..191: ||c||^2 + bf16 codebook + 3-way split codebook
//  blocks 192..207: 3-way split enc_w1 into K=64 zero-padded planes
//  block   208    : bias2[n] = enc_b1[n] - sum_k enc_w1[n,k]
// ---------------------------------------------------------------------------
__global__ __launch_bounds__(256) void prep_kernel(
    const float* __restrict__ w2, const float* __restrict__ w3,
    const float* __restrict__ d1, const float* __restrict__ d2,
    const float* __restrict__ w1, const float* __restrict__ b1,
    const float* __restrict__ cb,
    ushort* __restrict__ w2s0, ushort* __restrict__ w2s1, ushort* __restrict__ w2s2,
    ushort* __restrict__ w3s0, ushort* __restrict__ w3s1, ushort* __restrict__ w3s2,
    ushort* __restrict__ w1b, ushort* __restrict__ w2b,
    float* __restrict__ cn, ushort* __restrict__ cbb,
    ushort* __restrict__ cbs0, ushort* __restrict__ cbs1, ushort* __restrict__ cbs2,
    ushort* __restrict__ w1p0, ushort* __restrict__ w1p1, ushort* __restrict__ w1p2,
    float* __restrict__ bias2)
{
    const int blk = blockIdx.x, tid = threadIdx.x;
    if (blk < 64){
        const int i = (blk*256 + tid)*4;
        float4 a = *(const float4*)(w2 + i);
        ushort4 s0, s1, s2;
        split3(a.x, s0.x, s1.x, s2.x); split3(a.y, s0.y, s1.y, s2.y);
        split3(a.z, s0.z, s1.z, s2.z); split3(a.w, s0.w, s1.w, s2.w);
        *(ushort4*)(w2s0+i)=s0; *(ushort4*)(w2s1+i)=s1; *(ushort4*)(w2s2+i)=s2;
        float4 b = *(const float4*)(w3 + i);
        split3(b.x, s0.x, s1.x, s2.x); split3(b.y, s0.y, s1.y, s2.y);
        split3(b.z, s0.z, s1.z, s2.z); split3(b.w, s0.w, s1.w, s2.w);
        *(ushort4*)(w3s0+i)=s0; *(ushort4*)(w3s1+i)=s1; *(ushort4*)(w3s2+i)=s2;
        float4 c = *(const float4*)(d1 + i);
        ushort4 u; u.x=f2bf(c.x); u.y=f2bf(c.y); u.z=f2bf(c.z); u.w=f2bf(c.w);
        *(ushort4*)(w1b+i) = u;
        float4 d = *(const float4*)(d2 + i);
        u.x=f2bf(d.x); u.y=f2bf(d.y); u.z=f2bf(d.z); u.w=f2bf(d.w);
        *(ushort4*)(w2b+i) = u;
    } else if (blk < 192){
        const int lane = tid & 63;
        const int code = (blk-64)*4 + (tid >> 6);
        float4 v = ((const float4*)(cb + (size_t)code*256))[lane];
        size_t off = (size_t)code*256 + lane*4;
        ushort4 u; u.x=f2bf(v.x); u.y=f2bf(v.y); u.z=f2bf(v.z); u.w=f2bf(v.w);
        *(ushort4*)(cbb + off) = u;
        ushort4 s0, s1, s2;
        split3(v.x, s0.x, s1.x, s2.x); split3(v.y, s0.y, s1.y, s2.y);
        split3(v.z, s0.z, s1.z, s2.z); split3(v.w, s0.w, s1.w, s2.w);
        *(ushort4*)(cbs0 + off) = s0;
        *(ushort4*)(cbs1 + off) = s1;
        *(ushort4*)(cbs2 + off) = s2;
        float s = v.x*v.x + v.y*v.y + v.z*v.z + v.w*v.w;
        #pragma unroll
        for (int m=1; m<64; m<<=1) s += __shfl_xor(s, m);
        if (lane == 0) cn[code] = s;
    } else if (blk < 208){
        const int idx = (blk-192)*256 + tid;    // 0..4095
        const int n = idx >> 4, k = (idx & 15)*4;
        ushort4 s0 = {0,0,0,0}, s1 = {0,0,0,0}, s2 = {0,0,0,0};
        if (k < 48){
            float4 v = *(const float4*)(w1 + n*48 + k);
            split3(v.x, s0.x, s1.x, s2.x); split3(v.y, s0.y, s1.y, s2.y);
            split3(v.z, s0.z, s1.z, s2.z); split3(v.w, s0.w, s1.w, s2.w);
        }
        *(ushort4*)(w1p0 + n*64 + k) = s0;
        *(ushort4*)(w1p1 + n*64 + k) = s1;
        *(ushort4*)(w1p2 + n*64 + k) = s2;
    } else {
        float s = 0.0f;
        for (int k=0;k<48;++k) s += w1[tid*48 + k];
        bias2[tid] = b1[tid] - s;
    }
}

// ---------------------------------------------------------------------------
// f32-faithful split6 MFMA GEMM, 64 rows x 256 cols per block (A read ONCE).
// A: 3 planes split in-kernel -> LDS. B: plane0 in LDS, planes 1,2 direct
// from global (L2-resident). LDS ~36 KB, 3 blocks/CU.
// LOADER 0: A = Ain f32 [M][KTOT]. LOADER 1: patchify frames (raw f, exact
// split; normalization folded: out = SCALE*acc + bias  with bias=b1-rowsum).
// ---------------------------------------------------------------------------
template<int KTOT, bool GELU, int LOADER, bool SCALE>
__global__ __launch_bounds__(256, 3) void split6_gemm(
    const float* __restrict__ Ain,
    const float* __restrict__ frames,
    const ushort* __restrict__ W0, const ushort* __restrict__ W1,
    const ushort* __restrict__ W2,
    const float* __restrict__ bias,
    float* __restrict__ Cout)
{
    __shared__ __align__(16) ushort Al[3][64][40];
    __shared__ __align__(16) ushort Wl[256][40];

    const int tid = threadIdx.x;
    const int m0 = blockIdx.x * 64;
    const int arow = tid >> 2, q = tid & 3;
    const int lane = tid & 63;
    const int w = tid >> 6;
    const int lr = lane & 15, lg = lane >> 4;

    const float* asrc = nullptr;
    int pbase = 0;
    if constexpr (LOADER == 0){
        asrc = Ain + (size_t)(m0 + arow)*KTOT + q*8;
    } else {
        int p = m0 + arow;
        int b = p >> 12, nl = p & 4095, hh = nl >> 6, ww = nl & 63;
        pbase = ((b*256 + hh*4)*256 + ww*4)*3;
    }
    const ushort* wsrc  = W0 + (size_t)tid*KTOT;
    const ushort* w1frag = W1 + (size_t)(w*64 + lr)*KTOT + lg*8;
    const ushort* w2frag = W2 + (size_t)(w*64 + lr)*KTOT + lg*8;

    f32x4 acc[4][4];
    #pragma unroll
    for (int mi=0;mi<4;++mi)
        #pragma unroll
        for (int ni=0;ni<4;++ni)
            acc[mi][ni] = (f32x4){0.f,0.f,0.f,0.f};

    for (int k0=0; k0<KTOT; k0+=32){
        float x[8];
        if constexpr (LOADER == 0){
            *(float4*)&x[0] = *(const float4*)(asrc + k0);
            *(float4*)&x[4] = *(const float4*)(asrc + k0 + 4);
        } else {
            #pragma unroll
            for (int j=0;j<2;++j){
                int kk = k0 + q*8 + j*4;
                float4 v = {0.f,0.f,0.f,0.f};
                if (kk < 48){
                    int ph = kk/12, rem = kk - ph*12;
                    v = *(const float4*)(frames + pbase + ph*768 + rem);
                }
                x[j*4+0]=v.x; x[j*4+1]=v.y; x[j*4+2]=v.z; x[j*4+3]=v.w;
            }
        }
        ushort t0[8], t1[8], t2[8];
        #pragma unroll
        for (int e=0;e<8;++e) split3(x[e], t0[e], t1[e], t2[e]);
        *(uint4*)&Al[0][arow][q*8] = *(const uint4*)t0;
        *(uint4*)&Al[1][arow][q*8] = *(const uint4*)t1;
        *(uint4*)&Al[2][arow][q*8] = *(const uint4*)t2;
        *(uint4*)&Wl[tid][0]  = *(const uint4*)(wsrc + k0);
        *(uint4*)&Wl[tid][8]  = *(const uint4*)(wsrc + k0 + 8);
        *(uint4*)&Wl[tid][16] = *(const uint4*)(wsrc + k0 + 16);
        *(uint4*)&Wl[tid][24] = *(const uint4*)(wsrc + k0 + 24);
        short8 b1v[4], b2v[4];
        #pragma unroll
        for (int ni=0;ni<4;++ni){
            b1v[ni] = *(const short8*)(w1frag + (size_t)ni*16*KTOT + k0);
            b2v[ni] = *(const short8*)(w2frag + (size_t)ni*16*KTOT + k0);
        }
        __syncthreads();

        short8 b0v[4];
        #pragma unroll
        for (int ni=0;ni<4;++ni)
            b0v[ni] = *(const short8*)&Wl[w*64 + ni*16 + lr][lg*8];
        #pragma unroll
        for (int mi=0;mi<4;++mi){
            short8 a0 = *(const short8*)&Al[0][mi*16 + lr][lg*8];
            short8 a1 = *(const short8*)&Al[1][mi*16 + lr][lg*8];
            short8 a2 = *(const short8*)&Al[2][mi*16 + lr][lg*8];
            #pragma unroll
            for (int ni=0;ni<4;++ni)
                acc[mi][ni] = __builtin_amdgcn_mfma_f32_16x16x32_bf16(a0, b0v[ni], acc[mi][ni], 0,0,0);
            #pragma unroll
            for (int ni=0;ni<4;++ni)
                acc[mi][ni] = __builtin_amdgcn_mfma_f32_16x16x32_bf16(a0, b1v[ni], acc[mi][ni], 0,0,0);
            #pragma unroll
            for (int ni=0;ni<4;++ni)
                acc[mi][ni] = __builtin_amdgcn_mfma_f32_16x16x32_bf16(a1, b0v[ni], acc[mi][ni], 0,0,0);
            #pragma unroll
            for (int ni=0;ni<4;++ni)
                acc[mi][ni] = __builtin_amdgcn_mfma_f32_16x16x32_bf16(a0, b2v[ni], acc[mi][ni], 0,0,0);
            #pragma unroll
            for (int ni=0;ni<4;++ni)
                acc[mi][ni] = __builtin_amdgcn_mfma_f32_16x16x32_bf16(a1, b1v[ni], acc[mi][ni], 0,0,0);
            #pragma unroll
            for (int ni=0;ni<4;++ni)
                acc[mi][ni] = __builtin_amdgcn_mfma_f32_16x16x32_bf16(a2, b0v[ni], acc[mi][ni], 0,0,0);
        }
        __syncthreads();
    }

    const float alpha = 2.0f/255.0f;
    float bn[4];
    #pragma unroll
    for (int ni=0;ni<4;++ni) bn[ni] = bias[w*64 + ni*16 + lr];
    #pragma unroll
    for (int mi=0;mi<4;++mi)
        #pragma unroll
        for (int ni=0;ni<4;++ni)
            #pragma unroll
            for (int r=0;r<4;++r){
                int row = m0 + mi*16 + lg*4 + r;
                float v;
                if (SCALE) v = fmaf(alpha, acc[mi][ni][r], bn[ni]);
                else       v = acc[mi][ni][r] + bn[ni];
                if (GELU) v = gelu_f(v);
                Cout[(size_t)row*256 + w*64 + ni*16 + lr] = v;
            }
}

#define INSERT1(dv, iv) do { \
    float _d = (dv); int _i = (iv); \
    if (_d < bd || (_d == bd && _i < bi)){ bd = _d; bi = _i; } \
} while(0)

// ---------------------------------------------------------------------------
// EXACT distance pass via 6-term split-bf16 MFMA (R10-proven config):
// 128 rows x 128 codes per block; codebook planes 0,1 in LDS, plane-2 from
// global; fused ||z||^2. __launch_bounds__(256,3) -> 3 blocks/CU.
// ---------------------------------------------------------------------------
__global__ __launch_bounds__(256, 3) void tokens_split6(
    const float* __restrict__ Zf,
    const ushort* __restrict__ C0, const ushort* __restrict__ C1,
    const ushort* __restrict__ C2,
    const float* __restrict__ cn,
    float2* __restrict__ partials,
    float* __restrict__ zz_out)
{
    __shared__ __align__(16) ushort Al[3][128][40];
    __shared__ __align__(16) ushort Wl[2][128][40];
    __shared__ float2 ptop[128][2];

    const int tid = threadIdx.x;
    const int m0 = blockIdx.x * 128;
    const int n0 = blockIdx.y * 128;
    const int srow = tid >> 1, shalf = (tid & 1) * 16;
    const int lane = tid & 63;
    const int w = tid >> 6;
    const int wm = (w >> 1) * 64, wn = (w & 1) * 64;
    const int lr = lane & 15, lg = lane >> 4;

    const float*  asrc = Zf + (size_t)(m0 + srow)*256 + shalf;
    const ushort* ws0  = C0 + (size_t)(n0 + srow)*256 + shalf;
    const ushort* ws1  = C1 + (size_t)(n0 + srow)*256 + shalf;
    const ushort* c2frag = C2 + (size_t)(n0 + wn + lr)*256 + lg*8;

    f32x4 acc[4][4];
    #pragma unroll
    for (int mi=0;mi<4;++mi)
        #pragma unroll
        for (int ni=0;ni<4;++ni)
            acc[mi][ni] = (f32x4){0.f,0.f,0.f,0.f};

    float zzp = 0.0f;

    for (int k0=0; k0<256; k0+=32){
        float x[16];
        *(float4*)&x[0]  = *(const float4*)(asrc + k0);
        *(float4*)&x[4]  = *(const float4*)(asrc + k0 + 4);
        *(float4*)&x[8]  = *(const float4*)(asrc + k0 + 8);
        *(float4*)&x[12] = *(const float4*)(asrc + k0 + 12);
        ushort t0[16], t1[16], t2[16];
        #pragma unroll
        for (int e=0;e<16;++e){
            split3(x[e], t0[e], t1[e], t2[e]);
            zzp = fmaf(x[e], x[e], zzp);
        }
        *(uint4*)&Al[0][srow][shalf]   = *(const uint4*)&t0[0];
        *(uint4*)&Al[0][srow][shalf+8] = *(const uint4*)&t0[8];
        *(uint4*)&Al[1][srow][shalf]   = *(const uint4*)&t1[0];
        *(uint4*)&Al[1][srow][shalf+8] = *(const uint4*)&t1[8];
        *(uint4*)&Al[2][srow][shalf]   = *(const uint4*)&t2[0];
        *(uint4*)&Al[2][srow][shalf+8] = *(const uint4*)&t2[8];
        *(uint4*)&Wl[0][srow][shalf]   = *(const uint4*)(ws0 + k0);
        *(uint4*)&Wl[0][srow][shalf+8] = *(const uint4*)(ws0 + k0 + 8);
        *(uint4*)&Wl[1][srow][shalf]   = *(const uint4*)(ws1 + k0);
        *(uint4*)&Wl[1][srow][shalf+8] = *(const uint4*)(ws1 + k0 + 8);
        short8 b2[4];
        #pragma unroll
        for (int ni=0;ni<4;++ni)
            b2[ni] = *(const short8*)(c2frag + (size_t)ni*16*256 + k0);
        __syncthreads();

        short8 b0[4], b1[4];
        #pragma unroll
        for (int ni=0;ni<4;++ni){
            b0[ni] = *(const short8*)&Wl[0][wn + ni*16 + lr][lg*8];
            b1[ni] = *(const short8*)&Wl[1][wn + ni*16 + lr][lg*8];
        }
        #pragma unroll
        for (int mi=0;mi<4;++mi){
            short8 a0 = *(const short8*)&Al[0][wm + mi*16 + lr][lg*8];
            short8 a1 = *(const short8*)&Al[1][wm + mi*16 + lr][lg*8];
            short8 a2 = *(const short8*)&Al[2][wm + mi*16 + lr][lg*8];
            #pragma unroll
            for (int ni=0;ni<4;++ni)
                acc[mi][ni] = __builtin_amdgcn_mfma_f32_16x16x32_bf16(a0, b0[ni], acc[mi][ni], 0,0,0);
            #pragma unroll
            for (int ni=0;ni<4;++ni)
                acc[mi][ni] = __builtin_amdgcn_mfma_f32_16x16x32_bf16(a0, b1[ni], acc[mi][ni], 0,0,0);
            #pragma unroll
            for (int ni=0;ni<4;++ni)
                acc[mi][ni] = __builtin_amdgcn_mfma_f32_16x16x32_bf16(a1, b0[ni], acc[mi][ni], 0,0,0);
            #pragma unroll
            for (int ni=0;ni<4;++ni)
                acc[mi][ni] = __builtin_amdgcn_mfma_f32_16x16x32_bf16(a0, b2[ni], acc[mi][ni], 0,0,0);
            #pragma unroll
            for (int ni=0;ni<4;++ni)
                acc[mi][ni] = __builtin_amdgcn_mfma_f32_16x16x32_bf16(a1, b1[ni], acc[mi][ni], 0,0,0);
            #pragma unroll
            for (int ni=0;ni<4;++ni)
                acc[mi][ni] = __builtin_amdgcn_mfma_f32_16x16x32_bf16(a2, b0[ni], acc[mi][ni], 0,0,0);
        }
        __syncthreads();
    }

    // ||z||^2 per row: pair-combine the two k-halves (tid even/odd same row)
    {
        float other = __shfl_xor(zzp, 1);
        if (blockIdx.y == 0 && (tid & 1) == 0)
            zz_out[m0 + srow] = zzp + other;
    }

    float cnl[4];
    #pragma unroll
    for (int ni=0;ni<4;++ni) cnl[ni] = cn[n0 + wn + ni*16 + lr];

    #pragma unroll
    for (int mi=0;mi<4;++mi)
        #pragma unroll
        for (int r=0;r<4;++r){
            float bd = FLT_MAX; int bi = INT_MAX;
            #pragma unroll
            for (int ni=0;ni<4;++ni){
                float d = cnl[ni] - 2.0f*acc[mi][ni][r];
                int col = n0 + wn + ni*16 + lr;
                INSERT1(d, col);
            }
            #pragma unroll
            for (int m=1; m<16; m<<=1){
                float od = __shfl_xor(bd, m);
                int   oi = __shfl_xor(bi, m);
                INSERT1(od, oi);
            }
            if (lr == 0)
                ptop[wm + mi*16 + lg*4 + r][w & 1] = make_float2(bd, (float)bi);
        }
    __syncthreads();
    if (tid < 128){
        float2 hA = ptop[tid][0], hB = ptop[tid][1];
        int   gA = (int)hA.y, gB = (int)hB.y;
        bool takeB = (hB.x < hA.x) || (hB.x == hA.x && gB < gA);
        partials[(size_t)(m0 + tid)*4 + blockIdx.y] = takeB ? hB : hA;
    }
}

// ---------------------------------------------------------------------------
// Token + commitment: min over 4 (d,idx) partials, zz from zz_out.
// ---------------------------------------------------------------------------
__global__ __launch_bounds__(256) void token_reduce(
    const float* __restrict__ zz_out, const float2* __restrict__ partials,
    float* __restrict__ tokf, float* __restrict__ loss)
{
    const int tid = threadIdx.x;
    const int row = blockIdx.x*256 + tid;
    float2 p0 = partials[(size_t)row*4 + 0];
    float2 p1 = partials[(size_t)row*4 + 1];
    float2 p2 = partials[(size_t)row*4 + 2];
    float2 p3 = partials[(size_t)row*4 + 3];
    float d = p0.x; int g = (int)p0.y;
    if (p1.x < d || (p1.x == d && (int)p1.y < g)){ d = p1.x; g = (int)p1.y; }
    if (p2.x < d || (p2.x == d && (int)p2.y < g)){ d = p2.x; g = (int)p2.y; }
    if (p3.x < d || (p3.x == d && (int)p3.y < g)){ d = p3.x; g = (int)p3.y; }
    tokf[row] = (float)g;
    float cs = zz_out[row] + d;
    #pragma unroll
    for (int m=1; m<64; m<<=1) cs += __shfl_xor(cs, m);
    __shared__ float wsum[4];
    const int lane = tid & 63, w = tid >> 6;
    if (lane == 0) wsum[w] = cs;
    __syncthreads();
    if (tid == 0) atomicAdd(loss + 1, wsum[0]+wsum[1]+wsum[2]+wsum[3]);
}

// ---------------------------------------------------------------------------
// bf16 MFMA GEMM (decoder 1/2): Y[M,256] = gelu(A @ W^T + b)
// LOADER: 0 = plain bf16 A, 1 = gather bf16 codebook rows via tokens.
// ---------------------------------------------------------------------------
template<int LOADER>
__global__ __launch_bounds__(256) void mfma_gemm(
    const ushort* __restrict__ Abf,
    const ushort* __restrict__ cbb,
    const float* __restrict__ tokf,
    const ushort* __restrict__ Wbf,
    const float* __restrict__ bias,
    ushort* __restrict__ Ybf)
{
    __shared__ __align__(16) ushort Al[128][40];
    __shared__ __align__(16) ushort Wl[128][40];

    const int tid = threadIdx.x;
    const int m0 = blockIdx.x * 128;
    const int n0 = blockIdx.y * 128;
    const int srow = tid >> 1, shalf = (tid & 1) * 16;
    const int lane = tid & 63;
    const int w = tid >> 6;
    const int wm = (w >> 1) * 64, wn = (w & 1) * 64;
    const int lr = lane & 15, lg = lane >> 4;

    const ushort* asrc;
    if constexpr (LOADER == 1){
        int g = (int)tokf[m0 + srow];
        asrc = cbb + (size_t)g*256 + shalf;
    } else {
        asrc = Abf + (size_t)(m0 + srow)*256 + shalf;
    }
    const ushort* wsrc = Wbf + (size_t)(n0 + srow)*256 + shalf;

    f32x4 acc[4][4];
    #pragma unroll
    for (int mi=0;mi<4;++mi)
        #pragma unroll
        for (int ni=0;ni<4;++ni)
            acc[mi][ni] = (f32x4){0.f,0.f,0.f,0.f};

    for (int k0=0; k0<256; k0+=32){
        *(uint4*)&Al[srow][shalf]   = *(const uint4*)(asrc + k0);
        *(uint4*)&Al[srow][shalf+8] = *(const uint4*)(asrc + k0 + 8);
        *(uint4*)&Wl[srow][shalf]   = *(const uint4*)(wsrc + k0);
        *(uint4*)&Wl[srow][shalf+8] = *(const uint4*)(wsrc + k0 + 8);
        __syncthreads();

        short8 af[4], bfr[4];
        #pragma unroll
        for (int mi=0;mi<4;++mi)
            af[mi] = *(const short8*)&Al[wm + mi*16 + lr][lg*8];
        #pragma unroll
        for (int ni=0;ni<4;++ni)
            bfr[ni] = *(const short8*)&Wl[wn + ni*16 + lr][lg*8];
        #pragma unroll
        for (int mi=0;mi<4;++mi)
            #pragma unroll
            for (int ni=0;ni<4;++ni)
                acc[mi][ni] = __builtin_amdgcn_mfma_f32_16x16x32_bf16(
                    af[mi], bfr[ni], acc[mi][ni], 0, 0, 0);
        __syncthreads();
    }

    float bn[4];
    #pragma unroll
    for (int ni=0;ni<4;++ni) bn[ni] = bias[n0 + wn + ni*16 + lr];
    #pragma unroll
    for (int mi=0;mi<4;++mi)
        #pragma unroll
        for (int ni=0;ni<4;++ni)
            #pragma unroll
            for (int r=0;r<4;++r){
                int row = m0 + wm + mi*16 + lg*4 + r;
                float v = acc[mi][ni][r] + bn[ni];
                v = gelu_f(v);
                Ybf[(size_t)row*256 + n0 + wn + ni*16 + lr] = f2bf(v);
            }
}

// ---------------------------------------------------------------------------
// dec3 MFMA: Y[T,48] = A_bf16 @ W3^T + b3 (W3 converted in-kernel),
// fused un-patchify + recon loss. 256 rows/block, 4 waves of 64 rows.
// ---------------------------------------------------------------------------
__global__ __launch_bounds__(256) void dec3_mfma(
    const ushort* __restrict__ Ain, const float* __restrict__ W,
    const float* __restrict__ bias, const float* __restrict__ frames,
    float* __restrict__ recon, float* __restrict__ loss)
{
    __shared__ __align__(16) ushort Al[256][40];
    __shared__ __align__(16) ushort Wl[48][40];

    const int tid = threadIdx.x;
    const int m0 = blockIdx.x * 256;
    const int lane = tid & 63;
    const int w = tid >> 6;
    const int lr = lane & 15, lg = lane >> 4;

    const ushort* asrc = Ain + (size_t)(m0 + tid)*256;

    f32x4 acc[4][3];
    #pragma unroll
    for (int mi=0;mi<4;++mi)
        #pragma unroll
        for (int ni=0;ni<3;++ni)
            acc[mi][ni] = (f32x4){0.f,0.f,0.f,0.f};

    for (int k0=0; k0<256; k0+=32){
        *(uint4*)&Al[tid][0]  = *(const uint4*)(asrc + k0);
        *(uint4*)&Al[tid][8]  = *(const uint4*)(asrc + k0 + 8);
        *(uint4*)&Al[tid][16] = *(const uint4*)(asrc + k0 + 16);
        *(uint4*)&Al[tid][24] = *(const uint4*)(asrc + k0 + 24);
        if (tid < 96){
            const int wrow = tid >> 1, wh = (tid & 1)*16;
            const float* wp = W + (size_t)wrow*256 + k0 + wh;
            float4 f0 = *(const float4*)(wp);
            float4 f1 = *(const float4*)(wp+4);
            float4 f2 = *(const float4*)(wp+8);
            float4 f3 = *(const float4*)(wp+12);
            ushort t[16];
            t[0]=f2bf(f0.x); t[1]=f2bf(f0.y); t[2]=f2bf(f0.z); t[3]=f2bf(f0.w);
            t[4]=f2bf(f1.x); t[5]=f2bf(f1.y); t[6]=f2bf(f1.z); t[7]=f2bf(f1.w);
            t[8]=f2bf(f2.x); t[9]=f2bf(f2.y); t[10]=f2bf(f2.z); t[11]=f2bf(f2.w);
            t[12]=f2bf(f3.x); t[13]=f2bf(f3.y); t[14]=f2bf(f3.z); t[15]=f2bf(f3.w);
            *(uint4*)&Wl[wrow][wh]   = *(const uint4*)&t[0];
            *(uint4*)&Wl[wrow][wh+8] = *(const uint4*)&t[8];
        }
        __syncthreads();

        short8 bfr[3];
        #pragma unroll
        for (int ni=0;ni<3;++ni)
            bfr[ni] = *(const short8*)&Wl[ni*16 + lr][lg*8];
        #pragma unroll
        for (int mi=0;mi<4;++mi){
            short8 af = *(const short8*)&Al[w*64 + mi*16 + lr][lg*8];
            #pragma unroll
            for (int ni=0;ni<3;++ni)
                acc[mi][ni] = __builtin_amdgcn_mfma_f32_16x16x32_bf16(
                    af, bfr[ni], acc[mi][ni], 0, 0, 0);
        }
        __syncthreads();
    }

    float bn[3]; int phv[3], remv[3];
    #pragma unroll
    for (int ni=0;ni<3;++ni){
        int col = ni*16 + lr;
        bn[ni] = bias[col];
        phv[ni] = col / 12;
        remv[ni] = col - phv[ni]*12;
    }
    const float sc = 2.0f/255.0f;
    float ls = 0.0f;
    #pragma unroll
    for (int mi=0;mi<4;++mi)
        #pragma unroll
        for (int ni=0;ni<3;++ni)
            #pragma unroll
            for (int r=0;r<4;++r){
                int p = m0 + w*64 + mi*16 + lg*4 + r;
                int b = p >> 12, nl = p & 4095, hh = nl >> 6, ww = nl & 63;
                size_t addr = (size_t)(((b*256 + hh*4 + phv[ni])*256 + ww*4)*3 + remv[ni]);
                float y = acc[mi][ni][r] + bn[ni];
                float t = frames[addr]*sc - 1.0f;
                float d = y - t;
                ls += d*d;
                recon[addr] = y;
            }

    #pragma unroll
    for (int off=32; off>0; off>>=1) ls += __shfl_down(ls, off);
    __shared__ float wsum[4];
    if (lane == 0) wsum[w] = ls;
    __syncthreads();
    if (tid == 0) atomicAdd(loss + 0, wsum[0]+wsum[1]+wsum[2]+wsum[3]);
}

__global__ void finalize_kernel(float* __restrict__ loss){
    if (threadIdx.x == 0 && blockIdx.x == 0){
        loss[0] = loss[0] * (1.0f/6291456.0f);
        float c = loss[1] * (1.0f/33554432.0f);
        loss[1] = c;
        loss[2] = c;
    }
}

extern "C" void kernel_launch(void* const* d_in, const int* in_sizes, int n_in,
                              void* d_out, int out_size, void* d_ws, size_t ws_size,
                              hipStream_t stream)
{
    (void)in_sizes; (void)n_in; (void)out_size; (void)ws_size;
    const float* frames   = (const float*)d_in[0];
    const float* enc_w1   = (const float*)d_in[1];
    const float* enc_b1   = (const float*)d_in[2];
    const float* enc_w2   = (const float*)d_in[3];
    const float* enc_b2   = (const float*)d_in[4];
    const float* enc_w3   = (const float*)d_in[5];
    const float* enc_b3   = (const float*)d_in[6];
    const float* codebook = (const float*)d_in[7];
    const float* dec_w1   = (const float*)d_in[8];
    const float* dec_b1   = (const float*)d_in[9];
    const float* dec_w2   = (const float*)d_in[10];
    const float* dec_b2   = (const float*)d_in[11];
    const float* dec_w3   = (const float*)d_in[12];
    const float* dec_b3   = (const float*)d_in[13];

    // workspace: two [T,256] f32 regions (268 MB, proven available)
    float* P = (float*)d_ws;                 // h1 -> z_e -> Y1(bf16)
    float* Q = P + (size_t)33554432;         // h2 -> {Y2(bf16) base, partials}
    float2* partials = (float2*)(Q + 18000000);  // 4 MB, disjoint from Y2
    ushort* Y1 = (ushort*)P;
    ushort* Y2 = (ushort*)Q;

    // outputs; recon region doubles as scratch for small constants
    float* recon = (float*)d_out;            // 6,291,456 f32 (written last)
    float* tokf  = recon + 6291456;          // 131,072
    float* loss  = tokf + 131072;            // 3
    float*  cn   = recon;                            // 512 f32
    ushort* cbb  = (ushort*)(recon + 512);           // 131072 us
    ushort* w1b  = (ushort*)(recon + 66048);         // 65536 us
    ushort* w2b  = (ushort*)(recon + 98816);         // 65536 us
    ushort* w2s0 = (ushort*)(recon + 131584);        // 65536 us each
    ushort* w2s1 = (ushort*)(recon + 164352);
    ushort* w2s2 = (ushort*)(recon + 197120);
    ushort* w3s0 = (ushort*)(recon + 229888);
    ushort* w3s1 = (ushort*)(recon + 262656);
    ushort* w3s2 = (ushort*)(recon + 295424);
    ushort* cbs0 = (ushort*)(recon + 328192);        // 131072 us each
    ushort* cbs1 = (ushort*)(recon + 393728);
    ushort* cbs2 = (ushort*)(recon + 459264);        // ends 524800
    float*  zzb  = recon + 524800;                   // 131072 f32, ends 655872
    ushort* w1p0 = (ushort*)(recon + 655872);        // 16384 us each (K=64 pad)
    ushort* w1p1 = (ushort*)(recon + 664064);
    ushort* w1p2 = (ushort*)(recon + 672256);
    float*  bias2 = recon + 680448;                  // 256 f32, ends 680704

    hipMemsetAsync(loss, 0, 3*sizeof(float), stream);

    dim3 blk(256);
    // merged prep
    prep_kernel<<<dim3(209), blk, 0, stream>>>(enc_w2, enc_w3, dec_w1, dec_w2,
        enc_w1, enc_b1, codebook,
        w2s0, w2s1, w2s2, w3s0, w3s1, w3s2, w1b, w2b,
        cn, cbb, cbs0, cbs1, cbs2, w1p0, w1p1, w1p2, bias2);
    // encoder: all three layers f32-faithful split6 MFMA (64x256 blocks)
    split6_gemm<64,  true, 1, true ><<<dim3(T_ROWS/64), blk, 0, stream>>>(nullptr, frames, w1p0, w1p1, w1p2, bias2, P);
    split6_gemm<256, true, 0, false><<<dim3(T_ROWS/64), blk, 0, stream>>>(P, nullptr, w2s0, w2s1, w2s2, enc_b2, Q);
    split6_gemm<256, false,0, false><<<dim3(T_ROWS/64), blk, 0, stream>>>(Q, nullptr, w3s0, w3s1, w3s2, enc_b3, P);
    // vector quantization: EXACT split6 distances (R10 config) + reduce
    tokens_split6<<<dim3(T_ROWS/128, 4), blk, 0, stream>>>(P, cbs0, cbs1, cbs2, cn, partials, zzb);
    token_reduce<<<dim3(T_ROWS/256), blk, 0, stream>>>(zzb, partials, tokf, loss);
    // decoder (bf16 MFMA)
    mfma_gemm<1><<<dim3(T_ROWS/128, 2), blk, 0, stream>>>(nullptr, cbb, tokf, w1b, dec_b1, Y1);
    mfma_gemm<0><<<dim3(T_ROWS/128, 2), blk, 0, stream>>>(Y1, nullptr, nullptr, w2b, dec_b2, Y2);
    dec3_mfma<<<dim3(T_ROWS/256), blk, 0, stream>>>(Y2, dec_w3, dec_b3, frames, recon, loss);
    finalize_kernel<<<dim3(1), dim3(64), 0, stream>>>(loss);
}

// Round 13
// 597.713 us; speedup vs baseline: 1.9283x; 1.1281x over previous
//
#include <hip/hip_runtime.h>
#include <hip/hip_bf16.h>
#include <math.h>
#include <float.h>
#include <limits.h>

#define T_ROWS 131072   // 32 * 4096 patches

typedef __attribute__((ext_vector_type(8))) short short8;
typedef __attribute__((ext_vector_type(4))) float f32x4;

__device__ __forceinline__ float gelu_f(float x){
    return 0.5f * x * (1.0f + erff(x * 0.7071067811865475f));
}
__device__ __forceinline__ float bf2f(ushort u){
    union { unsigned int i; float f; } v; v.i = ((unsigned int)u) << 16; return v.f;
}
__device__ __forceinline__ ushort f2bf(float f){
    union { float f; unsigned int i; } v; v.f = f;
    unsigned int i = v.i;
    unsigned int r = (i + 0x7fffu + ((i >> 16) & 1u)) >> 16;
    return (ushort)r;
}
// exact 3-way truncation split: x ~= b0+b1+b2 (each bf16), >=24 mantissa bits
__device__ __forceinline__ void split3(float x, ushort &u0, ushort &u1, ushort &u2){
    union { float f; unsigned int i; } v; v.f = x;
    u0 = (ushort)(v.i >> 16);
    union { unsigned int i; float f; } h0; h0.i = ((unsigned int)u0) << 16;
    float r = x - h0.f;                       // exact (Sterbenz)
    union { float f; unsigned int i; } vr; vr.f = r;
    u1 = (ushort)(vr.i >> 16);
    union { unsigned int i; float f; } h1; h1.i = ((unsigned int)u1) << 16;
    float r2 = r - h1.f;                      // exact
    union { float f; unsigned int i; } v2; v2.f = r2;
    u2 = (ushort)(v2.i >> 16);
}

// ---------------------------------------------------------------------------
// Merged prep (unchanged from R12)
// ---------------------------------------------------------------------------
__global__ __launch_bounds__(256) void prep_kernel(
    const float* __restrict__ w2, const float* __restrict__ w3,
    const float* __restrict__ d1, const float* __restrict__ d2,
    const float* __restrict__ w1, const float* __restrict__ b1,
    const float* __restrict__ cb,
    ushort* __restrict__ w2s0, ushort* __restrict__ w2s1, ushort* __restrict__ w2s2,
    ushort* __restrict__ w3s0, ushort* __restrict__ w3s1, ushort* __restrict__ w3s2,
    ushort* __restrict__ w1b, ushort* __restrict__ w2b,
    float* __restrict__ cn, ushort* __restrict__ cbb,
    ushort* __restrict__ cbs0, ushort* __restrict__ cbs1, ushort* __restrict__ cbs2,
    ushort* __restrict__ w1p0, ushort* __restrict__ w1p1, ushort* __restrict__ w1p2,
    float* __restrict__ bias2)
{
    const int blk = blockIdx.x, tid = threadIdx.x;
    if (blk < 64){
        const int i = (blk*256 + tid)*4;
        float4 a = *(const float4*)(w2 + i);
        ushort4 s0, s1, s2;
        split3(a.x, s0.x, s1.x, s2.x); split3(a.y, s0.y, s1.y, s2.y);
        split3(a.z, s0.z, s1.z, s2.z); split3(a.w, s0.w, s1.w, s2.w);
        *(ushort4*)(w2s0+i)=s0; *(ushort4*)(w2s1+i)=s1; *(ushort4*)(w2s2+i)=s2;
        float4 b = *(const float4*)(w3 + i);
        split3(b.x, s0.x, s1.x, s2.x); split3(b.y, s0.y, s1.y, s2.y);
        split3(b.z, s0.z, s1.z, s2.z); split3(b.w, s0.w, s1.w, s2.w);
        *(ushort4*)(w3s0+i)=s0; *(ushort4*)(w3s1+i)=s1; *(ushort4*)(w3s2+i)=s2;
        float4 c = *(const float4*)(d1 + i);
        ushort4 u; u.x=f2bf(c.x); u.y=f2bf(c.y); u.z=f2bf(c.z); u.w=f2bf(c.w);
        *(ushort4*)(w1b+i) = u;
        float4 d = *(const float4*)(d2 + i);
        u.x=f2bf(d.x); u.y=f2bf(d.y); u.z=f2bf(d.z); u.w=f2bf(d.w);
        *(ushort4*)(w2b+i) = u;
    } else if (blk < 192){
        const int lane = tid & 63;
        const int code = (blk-64)*4 + (tid >> 6);
        float4 v = ((const float4*)(cb + (size_t)code*256))[lane];
        size_t off = (size_t)code*256 + lane*4;
        ushort4 u; u.x=f2bf(v.x); u.y=f2bf(v.y); u.z=f2bf(v.z); u.w=f2bf(v.w);
        *(ushort4*)(cbb + off) = u;
        ushort4 s0, s1, s2;
        split3(v.x, s0.x, s1.x, s2.x); split3(v.y, s0.y, s1.y, s2.y);
        split3(v.z, s0.z, s1.z, s2.z); split3(v.w, s0.w, s1.w, s2.w);
        *(ushort4*)(cbs0 + off) = s0;
        *(ushort4*)(cbs1 + off) = s1;
        *(ushort4*)(cbs2 + off) = s2;
        float s = v.x*v.x + v.y*v.y + v.z*v.z + v.w*v.w;
        #pragma unroll
        for (int m=1; m<64; m<<=1) s += __shfl_xor(s, m);
        if (lane == 0) cn[code] = s;
    } else if (blk < 208){
        const int idx = (blk-192)*256 + tid;    // 0..4095
        const int n = idx >> 4, k = (idx & 15)*4;
        ushort4 s0 = {0,0,0,0}, s1 = {0,0,0,0}, s2 = {0,0,0,0};
        if (k < 48){
            float4 v = *(const float4*)(w1 + n*48 + k);
            split3(v.x, s0.x, s1.x, s2.x); split3(v.y, s0.y, s1.y, s2.y);
            split3(v.z, s0.z, s1.z, s2.z); split3(v.w, s0.w, s1.w, s2.w);
        }
        *(ushort4*)(w1p0 + n*64 + k) = s0;
        *(ushort4*)(w1p1 + n*64 + k) = s1;
        *(ushort4*)(w1p2 + n*64 + k) = s2;
    } else {
        float s = 0.0f;
        for (int k=0;k<48;++k) s += w1[tid*48 + k];
        bias2[tid] = b1[tid] - s;
    }
}

// ---------------------------------------------------------------------------
// f32-faithful split6 MFMA GEMM, 64 rows x 256 cols per block (A read ONCE).
// ---------------------------------------------------------------------------
template<int KTOT, bool GELU, int LOADER, bool SCALE>
__global__ __launch_bounds__(256, 3) void split6_gemm(
    const float* __restrict__ Ain,
    const float* __restrict__ frames,
    const ushort* __restrict__ W0, const ushort* __restrict__ W1,
    const ushort* __restrict__ W2,
    const float* __restrict__ bias,
    float* __restrict__ Cout)
{
    __shared__ __align__(16) ushort Al[3][64][40];
    __shared__ __align__(16) ushort Wl[256][40];

    const int tid = threadIdx.x;
    const int m0 = blockIdx.x * 64;
    const int arow = tid >> 2, q = tid & 3;
    const int lane = tid & 63;
    const int w = tid >> 6;
    const int lr = lane & 15, lg = lane >> 4;

    const float* asrc = nullptr;
    int pbase = 0;
    if constexpr (LOADER == 0){
        asrc = Ain + (size_t)(m0 + arow)*KTOT + q*8;
    } else {
        int p = m0 + arow;
        int b = p >> 12, nl = p & 4095, hh = nl >> 6, ww = nl & 63;
        pbase = ((b*256 + hh*4)*256 + ww*4)*3;
    }
    const ushort* wsrc  = W0 + (size_t)tid*KTOT;
    const ushort* w1frag = W1 + (size_t)(w*64 + lr)*KTOT + lg*8;
    const ushort* w2frag = W2 + (size_t)(w*64 + lr)*KTOT + lg*8;

    f32x4 acc[4][4];
    #pragma unroll
    for (int mi=0;mi<4;++mi)
        #pragma unroll
        for (int ni=0;ni<4;++ni)
            acc[mi][ni] = (f32x4){0.f,0.f,0.f,0.f};

    for (int k0=0; k0<KTOT; k0+=32){
        float x[8];
        if constexpr (LOADER == 0){
            *(float4*)&x[0] = *(const float4*)(asrc + k0);
            *(float4*)&x[4] = *(const float4*)(asrc + k0 + 4);
        } else {
            #pragma unroll
            for (int j=0;j<2;++j){
                int kk = k0 + q*8 + j*4;
                float4 v = {0.f,0.f,0.f,0.f};
                if (kk < 48){
                    int ph = kk/12, rem = kk - ph*12;
                    v = *(const float4*)(frames + pbase + ph*768 + rem);
                }
                x[j*4+0]=v.x; x[j*4+1]=v.y; x[j*4+2]=v.z; x[j*4+3]=v.w;
            }
        }
        ushort t0[8], t1[8], t2[8];
        #pragma unroll
        for (int e=0;e<8;++e) split3(x[e], t0[e], t1[e], t2[e]);
        *(uint4*)&Al[0][arow][q*8] = *(const uint4*)t0;
        *(uint4*)&Al[1][arow][q*8] = *(const uint4*)t1;
        *(uint4*)&Al[2][arow][q*8] = *(const uint4*)t2;
        *(uint4*)&Wl[tid][0]  = *(const uint4*)(wsrc + k0);
        *(uint4*)&Wl[tid][8]  = *(const uint4*)(wsrc + k0 + 8);
        *(uint4*)&Wl[tid][16] = *(const uint4*)(wsrc + k0 + 16);
        *(uint4*)&Wl[tid][24] = *(const uint4*)(wsrc + k0 + 24);
        short8 b1v[4], b2v[4];
        #pragma unroll
        for (int ni=0;ni<4;++ni){
            b1v[ni] = *(const short8*)(w1frag + (size_t)ni*16*KTOT + k0);
            b2v[ni] = *(const short8*)(w2frag + (size_t)ni*16*KTOT + k0);
        }
        __syncthreads();

        short8 b0v[4];
        #pragma unroll
        for (int ni=0;ni<4;++ni)
            b0v[ni] = *(const short8*)&Wl[w*64 + ni*16 + lr][lg*8];
        #pragma unroll
        for (int mi=0;mi<4;++mi){
            short8 a0 = *(const short8*)&Al[0][mi*16 + lr][lg*8];
            short8 a1 = *(const short8*)&Al[1][mi*16 + lr][lg*8];
            short8 a2 = *(const short8*)&Al[2][mi*16 + lr][lg*8];
            #pragma unroll
            for (int ni=0;ni<4;++ni)
                acc[mi][ni] = __builtin_amdgcn_mfma_f32_16x16x32_bf16(a0, b0v[ni], acc[mi][ni], 0,0,0);
            #pragma unroll
            for (int ni=0;ni<4;++ni)
                acc[mi][ni] = __builtin_amdgcn_mfma_f32_16x16x32_bf16(a0, b1v[ni], acc[mi][ni], 0,0,0);
            #pragma unroll
            for (int ni=0;ni<4;++ni)
                acc[mi][ni] = __builtin_amdgcn_mfma_f32_16x16x32_bf16(a1, b0v[ni], acc[mi][ni], 0,0,0);
            #pragma unroll
            for (int ni=0;ni<4;++ni)
                acc[mi][ni] = __builtin_amdgcn_mfma_f32_16x16x32_bf16(a0, b2v[ni], acc[mi][ni], 0,0,0);
            #pragma unroll
            for (int ni=0;ni<4;++ni)
                acc[mi][ni] = __builtin_amdgcn_mfma_f32_16x16x32_bf16(a1, b1v[ni], acc[mi][ni], 0,0,0);
            #pragma unroll
            for (int ni=0;ni<4;++ni)
                acc[mi][ni] = __builtin_amdgcn_mfma_f32_16x16x32_bf16(a2, b0v[ni], acc[mi][ni], 0,0,0);
        }
        __syncthreads();
    }

    const float alpha = 2.0f/255.0f;
    float bn[4];
    #pragma unroll
    for (int ni=0;ni<4;++ni) bn[ni] = bias[w*64 + ni*16 + lr];
    #pragma unroll
    for (int mi=0;mi<4;++mi)
        #pragma unroll
        for (int ni=0;ni<4;++ni)
            #pragma unroll
            for (int r=0;r<4;++r){
                int row = m0 + mi*16 + lg*4 + r;
                float v;
                if (SCALE) v = fmaf(alpha, acc[mi][ni][r], bn[ni]);
                else       v = acc[mi][ni][r] + bn[ni];
                if (GELU) v = gelu_f(v);
                Cout[(size_t)row*256 + w*64 + ni*16 + lr] = v;
            }
}

#define INSERT1(dv, iv) do { \
    float _d = (dv); int _i = (iv); \
    if (_d < bd || (_d == bd && _i < bi)){ bd = _d; bi = _i; } \
} while(0)

// ---------------------------------------------------------------------------
// EXACT distance pass via 6-term split-bf16 MFMA (R10/R12-proven config).
// ---------------------------------------------------------------------------
__global__ __launch_bounds__(256, 3) void tokens_split6(
    const float* __restrict__ Zf,
    const ushort* __restrict__ C0, const ushort* __restrict__ C1,
    const ushort* __restrict__ C2,
    const float* __restrict__ cn,
    float2* __restrict__ partials,
    float* __restrict__ zz_out)
{
    __shared__ __align__(16) ushort Al[3][128][40];
    __shared__ __align__(16) ushort Wl[2][128][40];
    __shared__ float2 ptop[128][2];

    const int tid = threadIdx.x;
    const int m0 = blockIdx.x * 128;
    const int n0 = blockIdx.y * 128;
    const int srow = tid >> 1, shalf = (tid & 1) * 16;
    const int lane = tid & 63;
    const int w = tid >> 6;
    const int wm = (w >> 1) * 64, wn = (w & 1) * 64;
    const int lr = lane & 15, lg = lane >> 4;

    const float*  asrc = Zf + (size_t)(m0 + srow)*256 + shalf;
    const ushort* ws0  = C0 + (size_t)(n0 + srow)*256 + shalf;
    const ushort* ws1  = C1 + (size_t)(n0 + srow)*256 + shalf;
    const ushort* c2frag = C2 + (size_t)(n0 + wn + lr)*256 + lg*8;

    f32x4 acc[4][4];
    #pragma unroll
    for (int mi=0;mi<4;++mi)
        #pragma unroll
        for (int ni=0;ni<4;++ni)
            acc[mi][ni] = (f32x4){0.f,0.f,0.f,0.f};

    float zzp = 0.0f;

    for (int k0=0; k0<256; k0+=32){
        float x[16];
        *(float4*)&x[0]  = *(const float4*)(asrc + k0);
        *(float4*)&x[4]  = *(const float4*)(asrc + k0 + 4);
        *(float4*)&x[8]  = *(const float4*)(asrc + k0 + 8);
        *(float4*)&x[12] = *(const float4*)(asrc + k0 + 12);
        ushort t0[16], t1[16], t2[16];
        #pragma unroll
        for (int e=0;e<16;++e){
            split3(x[e], t0[e], t1[e], t2[e]);
            zzp = fmaf(x[e], x[e], zzp);
        }
        *(uint4*)&Al[0][srow][shalf]   = *(const uint4*)&t0[0];
        *(uint4*)&Al[0][srow][shalf+8] = *(const uint4*)&t0[8];
        *(uint4*)&Al[1][srow][shalf]   = *(const uint4*)&t1[0];
        *(uint4*)&Al[1][srow][shalf+8] = *(const uint4*)&t1[8];
        *(uint4*)&Al[2][srow][shalf]   = *(const uint4*)&t2[0];
        *(uint4*)&Al[2][srow][shalf+8] = *(const uint4*)&t2[8];
        *(uint4*)&Wl[0][srow][shalf]   = *(const uint4*)(ws0 + k0);
        *(uint4*)&Wl[0][srow][shalf+8] = *(const uint4*)(ws0 + k0 + 8);
        *(uint4*)&Wl[1][srow][shalf]   = *(const uint4*)(ws1 + k0);
        *(uint4*)&Wl[1][srow][shalf+8] = *(const uint4*)(ws1 + k0 + 8);
        short8 b2[4];
        #pragma unroll
        for (int ni=0;ni<4;++ni)
            b2[ni] = *(const short8*)(c2frag + (size_t)ni*16*256 + k0);
        __syncthreads();

        short8 b0[4], b1[4];
        #pragma unroll
        for (int ni=0;ni<4;++ni){
            b0[ni] = *(const short8*)&Wl[0][wn + ni*16 + lr][lg*8];
            b1[ni] = *(const short8*)&Wl[1][wn + ni*16 + lr][lg*8];
        }
        #pragma unroll
        for (int mi=0;mi<4;++mi){
            short8 a0 = *(const short8*)&Al[0][wm + mi*16 + lr][lg*8];
            short8 a1 = *(const short8*)&Al[1][wm + mi*16 + lr][lg*8];
            short8 a2 = *(const short8*)&Al[2][wm + mi*16 + lr][lg*8];
            #pragma unroll
            for (int ni=0;ni<4;++ni)
                acc[mi][ni] = __builtin_amdgcn_mfma_f32_16x16x32_bf16(a0, b0[ni], acc[mi][ni], 0,0,0);
            #pragma unroll
            for (int ni=0;ni<4;++ni)
                acc[mi][ni] = __builtin_amdgcn_mfma_f32_16x16x32_bf16(a0, b1[ni], acc[mi][ni], 0,0,0);
            #pragma unroll
            for (int ni=0;ni<4;++ni)
                acc[mi][ni] = __builtin_amdgcn_mfma_f32_16x16x32_bf16(a1, b0[ni], acc[mi][ni], 0,0,0);
            #pragma unroll
            for (int ni=0;ni<4;++ni)
                acc[mi][ni] = __builtin_amdgcn_mfma_f32_16x16x32_bf16(a0, b2[ni], acc[mi][ni], 0,0,0);
            #pragma unroll
            for (int ni=0;ni<4;++ni)
                acc[mi][ni] = __builtin_amdgcn_mfma_f32_16x16x32_bf16(a1, b1[ni], acc[mi][ni], 0,0,0);
            #pragma unroll
            for (int ni=0;ni<4;++ni)
                acc[mi][ni] = __builtin_amdgcn_mfma_f32_16x16x32_bf16(a2, b0[ni], acc[mi][ni], 0,0,0);
        }
        __syncthreads();
    }

    // ||z||^2 per row: pair-combine the two k-halves (tid even/odd same row)
    {
        float other = __shfl_xor(zzp, 1);
        if (blockIdx.y == 0 && (tid & 1) == 0)
            zz_out[m0 + srow] = zzp + other;
    }

    float cnl[4];
    #pragma unroll
    for (int ni=0;ni<4;++ni) cnl[ni] = cn[n0 + wn + ni*16 + lr];

    #pragma unroll
    for (int mi=0;mi<4;++mi)
        #pragma unroll
        for (int r=0;r<4;++r){
            float bd = FLT_MAX; int bi = INT_MAX;
            #pragma unroll
            for (int ni=0;ni<4;++ni){
                float d = cnl[ni] - 2.0f*acc[mi][ni][r];
                int col = n0 + wn + ni*16 + lr;
                INSERT1(d, col);
            }
            #pragma unroll
            for (int m=1; m<16; m<<=1){
                float od = __shfl_xor(bd, m);
                int   oi = __shfl_xor(bi, m);
                INSERT1(od, oi);
            }
            if (lr == 0)
                ptop[wm + mi*16 + lg*4 + r][w & 1] = make_float2(bd, (float)bi);
        }
    __syncthreads();
    if (tid < 128){
        float2 hA = ptop[tid][0], hB = ptop[tid][1];
        int   gA = (int)hA.y, gB = (int)hB.y;
        bool takeB = (hB.x < hA.x) || (hB.x == hA.x && gB < gA);
        partials[(size_t)(m0 + tid)*4 + blockIdx.y] = takeB ? hB : hA;
    }
}

// ---------------------------------------------------------------------------
// Token + commitment: min over 4 (d,idx) partials, zz from zz_out.
// ---------------------------------------------------------------------------
__global__ __launch_bounds__(256) void token_reduce(
    const float* __restrict__ zz_out, const float2* __restrict__ partials,
    float* __restrict__ tokf, float* __restrict__ loss)
{
    const int tid = threadIdx.x;
    const int row = blockIdx.x*256 + tid;
    float2 p0 = partials[(size_t)row*4 + 0];
    float2 p1 = partials[(size_t)row*4 + 1];
    float2 p2 = partials[(size_t)row*4 + 2];
    float2 p3 = partials[(size_t)row*4 + 3];
    float d = p0.x; int g = (int)p0.y;
    if (p1.x < d || (p1.x == d && (int)p1.y < g)){ d = p1.x; g = (int)p1.y; }
    if (p2.x < d || (p2.x == d && (int)p2.y < g)){ d = p2.x; g = (int)p2.y; }
    if (p3.x < d || (p3.x == d && (int)p3.y < g)){ d = p3.x; g = (int)p3.y; }
    tokf[row] = (float)g;
    float cs = zz_out[row] + d;
    #pragma unroll
    for (int m=1; m<64; m<<=1) cs += __shfl_xor(cs, m);
    __shared__ float wsum[4];
    const int lane = tid & 63, w = tid >> 6;
    if (lane == 0) wsum[w] = cs;
    __syncthreads();
    if (tid == 0) atomicAdd(loss + 1, wsum[0]+wsum[1]+wsum[2]+wsum[3]);
}

// ---------------------------------------------------------------------------
// bf16 MFMA GEMM (decoder tables): Y[M,256] = gelu(A @ W^T + b), M=512.
// ---------------------------------------------------------------------------
__global__ __launch_bounds__(256) void mfma_gemm(
    const ushort* __restrict__ Abf,
    const ushort* __restrict__ Wbf,
    const float* __restrict__ bias,
    ushort* __restrict__ Ybf)
{
    __shared__ __align__(16) ushort Al[128][40];
    __shared__ __align__(16) ushort Wl[128][40];

    const int tid = threadIdx.x;
    const int m0 = blockIdx.x * 128;
    const int n0 = blockIdx.y * 128;
    const int srow = tid >> 1, shalf = (tid & 1) * 16;
    const int lane = tid & 63;
    const int w = tid >> 6;
    const int wm = (w >> 1) * 64, wn = (w & 1) * 64;
    const int lr = lane & 15, lg = lane >> 4;

    const ushort* asrc = Abf + (size_t)(m0 + srow)*256 + shalf;
    const ushort* wsrc = Wbf + (size_t)(n0 + srow)*256 + shalf;

    f32x4 acc[4][4];
    #pragma unroll
    for (int mi=0;mi<4;++mi)
        #pragma unroll
        for (int ni=0;ni<4;++ni)
            acc[mi][ni] = (f32x4){0.f,0.f,0.f,0.f};

    for (int k0=0; k0<256; k0+=32){
        *(uint4*)&Al[srow][shalf]   = *(const uint4*)(asrc + k0);
        *(uint4*)&Al[srow][shalf+8] = *(const uint4*)(asrc + k0 + 8);
        *(uint4*)&Wl[srow][shalf]   = *(const uint4*)(wsrc + k0);
        *(uint4*)&Wl[srow][shalf+8] = *(const uint4*)(wsrc + k0 + 8);
        __syncthreads();

        short8 af[4], bfr[4];
        #pragma unroll
        for (int mi=0;mi<4;++mi)
            af[mi] = *(const short8*)&Al[wm + mi*16 + lr][lg*8];
        #pragma unroll
        for (int ni=0;ni<4;++ni)
            bfr[ni] = *(const short8*)&Wl[wn + ni*16 + lr][lg*8];
        #pragma unroll
        for (int mi=0;mi<4;++mi)
            #pragma unroll
            for (int ni=0;ni<4;++ni)
                acc[mi][ni] = __builtin_amdgcn_mfma_f32_16x16x32_bf16(
                    af[mi], bfr[ni], acc[mi][ni], 0, 0, 0);
        __syncthreads();
    }

    float bn[4];
    #pragma unroll
    for (int ni=0;ni<4;++ni) bn[ni] = bias[n0 + wn + ni*16 + lr];
    #pragma unroll
    for (int mi=0;mi<4;++mi)
        #pragma unroll
        for (int ni=0;ni<4;++ni)
            #pragma unroll
            for (int r=0;r<4;++r){
                int row = m0 + wm + mi*16 + lg*4 + r;
                float v = acc[mi][ni][r] + bn[ni];
                v = gelu_f(v);
                Ybf[(size_t)row*256 + n0 + wn + ni*16 + lr] = f2bf(v);
            }
}

// ---------------------------------------------------------------------------
// dec3 table: R[512][48] = L2 @ W3^T + b3 (W3 converted in-kernel).
// 256 rows/block, 2 blocks.
// ---------------------------------------------------------------------------
__global__ __launch_bounds__(256) void dec3_table(
    const ushort* __restrict__ Ain, const float* __restrict__ W,
    const float* __restrict__ bias, float* __restrict__ Rt)
{
    __shared__ __align__(16) ushort Al[256][40];
    __shared__ __align__(16) ushort Wl[48][40];

    const int tid = threadIdx.x;
    const int m0 = blockIdx.x * 256;
    const int lane = tid & 63;
    const int w = tid >> 6;
    const int lr = lane & 15, lg = lane >> 4;

    const ushort* asrc = Ain + (size_t)(m0 + tid)*256;

    f32x4 acc[4][3];
    #pragma unroll
    for (int mi=0;mi<4;++mi)
        #pragma unroll
        for (int ni=0;ni<3;++ni)
            acc[mi][ni] = (f32x4){0.f,0.f,0.f,0.f};

    for (int k0=0; k0<256; k0+=32){
        *(uint4*)&Al[tid][0]  = *(const uint4*)(asrc + k0);
        *(uint4*)&Al[tid][8]  = *(const uint4*)(asrc + k0 + 8);
        *(uint4*)&Al[tid][16] = *(const uint4*)(asrc + k0 + 16);
        *(uint4*)&Al[tid][24] = *(const uint4*)(asrc + k0 + 24);
        if (tid < 96){
            const int wrow = tid >> 1, wh = (tid & 1)*16;
            const float* wp = W + (size_t)wrow*256 + k0 + wh;
            float4 f0 = *(const float4*)(wp);
            float4 f1 = *(const float4*)(wp+4);
            float4 f2 = *(const float4*)(wp+8);
            float4 f3 = *(const float4*)(wp+12);
            ushort t[16];
            t[0]=f2bf(f0.x); t[1]=f2bf(f0.y); t[2]=f2bf(f0.z); t[3]=f2bf(f0.w);
            t[4]=f2bf(f1.x); t[5]=f2bf(f1.y); t[6]=f2bf(f1.z); t[7]=f2bf(f1.w);
            t[8]=f2bf(f2.x); t[9]=f2bf(f2.y); t[10]=f2bf(f2.z); t[11]=f2bf(f2.w);
            t[12]=f2bf(f3.x); t[13]=f2bf(f3.y); t[14]=f2bf(f3.z); t[15]=f2bf(f3.w);
            *(uint4*)&Wl[wrow][wh]   = *(const uint4*)&t[0];
            *(uint4*)&Wl[wrow][wh+8] = *(const uint4*)&t[8];
        }
        __syncthreads();

        short8 bfr[3];
        #pragma unroll
        for (int ni=0;ni<3;++ni)
            bfr[ni] = *(const short8*)&Wl[ni*16 + lr][lg*8];
        #pragma unroll
        for (int mi=0;mi<4;++mi){
            short8 af = *(const short8*)&Al[w*64 + mi*16 + lr][lg*8];
            #pragma unroll
            for (int ni=0;ni<3;++ni)
                acc[mi][ni] = __builtin_amdgcn_mfma_f32_16x16x32_bf16(
                    af, bfr[ni], acc[mi][ni], 0, 0, 0);
        }
        __syncthreads();
    }

    #pragma unroll
    for (int ni=0;ni<3;++ni){
        const int col = ni*16 + lr;
        const float bn = bias[col];
        #pragma unroll
        for (int mi=0;mi<4;++mi)
            #pragma unroll
            for (int r=0;r<4;++r){
                int row = m0 + w*64 + mi*16 + lg*4 + r;
                Rt[row*48 + col] = acc[mi][ni][r] + bn;
            }
    }
}

// ---------------------------------------------------------------------------
// gather + unpatchify + recon loss: recon = unpatchify(R[tokens]).
// 4 threads per patch (one pixel-row each, 12 floats).
// ---------------------------------------------------------------------------
__global__ __launch_bounds__(256) void gather_recon(
    const float* __restrict__ Rt, const float* __restrict__ tokf,
    const float* __restrict__ frames, float* __restrict__ recon,
    float* __restrict__ loss)
{
    const int tid = threadIdx.x;
    const int idx = blockIdx.x*256 + tid;
    const int p = idx >> 2, ph = idx & 3;
    const int g = (int)tokf[p];
    int b = p >> 12, nl = p & 4095, hh = nl >> 6, ww = nl & 63;
    size_t base = (size_t)(((b*256 + hh*4 + ph)*256 + ww*4)*3);
    const float* rp = Rt + g*48 + ph*12;
    const float sc = 2.0f/255.0f;
    float ls = 0.0f;
    #pragma unroll
    for (int j=0;j<3;++j){
        float4 y = *(const float4*)(rp + j*4);
        float4 f = *(const float4*)(frames + base + j*4);
        float t0=f.x*sc-1.0f, t1=f.y*sc-1.0f, t2=f.z*sc-1.0f, t3=f.w*sc-1.0f;
        float d0=y.x-t0, d1=y.y-t1, d2=y.z-t2, d3=y.w-t3;
        ls += d0*d0 + d1*d1 + d2*d2 + d3*d3;
        *(float4*)(recon + base + j*4) = y;
    }
    #pragma unroll
    for (int off=32; off>0; off>>=1) ls += __shfl_down(ls, off);
    __shared__ float wsum[4];
    int lane = tid & 63, w = tid >> 6;
    if (lane == 0) wsum[w] = ls;
    __syncthreads();
    if (tid == 0) atomicAdd(loss + 0, wsum[0]+wsum[1]+wsum[2]+wsum[3]);
}

__global__ void finalize_kernel(float* __restrict__ loss){
    if (threadIdx.x == 0 && blockIdx.x == 0){
        loss[0] = loss[0] * (1.0f/6291456.0f);
        float c = loss[1] * (1.0f/33554432.0f);
        loss[1] = c;
        loss[2] = c;
    }
}

extern "C" void kernel_launch(void* const* d_in, const int* in_sizes, int n_in,
                              void* d_out, int out_size, void* d_ws, size_t ws_size,
                              hipStream_t stream)
{
    (void)in_sizes; (void)n_in; (void)out_size; (void)ws_size;
    const float* frames   = (const float*)d_in[0];
    const float* enc_w1   = (const float*)d_in[1];
    const float* enc_b1   = (const float*)d_in[2];
    const float* enc_w2   = (const float*)d_in[3];
    const float* enc_b2   = (const float*)d_in[4];
    const float* enc_w3   = (const float*)d_in[5];
    const float* enc_b3   = (const float*)d_in[6];
    const float* codebook = (const float*)d_in[7];
    const float* dec_w1   = (const float*)d_in[8];
    const float* dec_b1   = (const float*)d_in[9];
    const float* dec_w2   = (const float*)d_in[10];
    const float* dec_b2   = (const float*)d_in[11];
    const float* dec_w3   = (const float*)d_in[12];
    const float* dec_b3   = (const float*)d_in[13];

    // workspace: two [T,256] f32 regions (268 MB, proven available)
    float* P = (float*)d_ws;                 // h1 -> z_e -> decoder tables
    float* Q = P + (size_t)33554432;         // h2
    float2* partials = (float2*)(Q + 18000000);  // 4 MB, disjoint
    // decoder tables in P region (z dead after token_reduce):
    ushort* L1 = (ushort*)P;                 // 512x256 bf16
    ushort* L2 = (ushort*)(P + 65536);       // 512x256 bf16
    float*  Rt = P + 131072;                 // 512x48 f32

    // outputs; recon region doubles as scratch for small constants
    float* recon = (float*)d_out;            // 6,291,456 f32 (written last)
    float* tokf  = recon + 6291456;          // 131,072
    float* loss  = tokf + 131072;            // 3
    float*  cn   = recon;                            // 512 f32
    ushort* cbb  = (ushort*)(recon + 512);           // 131072 us
    ushort* w1b  = (ushort*)(recon + 66048);         // 65536 us
    ushort* w2b  = (ushort*)(recon + 98816);         // 65536 us
    ushort* w2s0 = (ushort*)(recon + 131584);        // 65536 us each
    ushort* w2s1 = (ushort*)(recon + 164352);
    ushort* w2s2 = (ushort*)(recon + 197120);
    ushort* w3s0 = (ushort*)(recon + 229888);
    ushort* w3s1 = (ushort*)(recon + 262656);
    ushort* w3s2 = (ushort*)(recon + 295424);
    ushort* cbs0 = (ushort*)(recon + 328192);        // 131072 us each
    ushort* cbs1 = (ushort*)(recon + 393728);
    ushort* cbs2 = (ushort*)(recon + 459264);        // ends 524800
    float*  zzb  = recon + 524800;                   // 131072 f32, ends 655872
    ushort* w1p0 = (ushort*)(recon + 655872);        // 16384 us each (K=64 pad)
    ushort* w1p1 = (ushort*)(recon + 664064);
    ushort* w1p2 = (ushort*)(recon + 672256);
    float*  bias2 = recon + 680448;                  // 256 f32, ends 680704

    hipMemsetAsync(loss, 0, 3*sizeof(float), stream);

    dim3 blk(256);
    // merged prep
    prep_kernel<<<dim3(209), blk, 0, stream>>>(enc_w2, enc_w3, dec_w1, dec_w2,
        enc_w1, enc_b1, codebook,
        w2s0, w2s1, w2s2, w3s0, w3s1, w3s2, w1b, w2b,
        cn, cbb, cbs0, cbs1, cbs2, w1p0, w1p1, w1p2, bias2);
    // encoder: all three layers f32-faithful split6 MFMA (64x256 blocks)
    split6_gemm<64,  true, 1, true ><<<dim3(T_ROWS/64), blk, 0, stream>>>(nullptr, frames, w1p0, w1p1, w1p2, bias2, P);
    split6_gemm<256, true, 0, false><<<dim3(T_ROWS/64), blk, 0, stream>>>(P, nullptr, w2s0, w2s1, w2s2, enc_b2, Q);
    split6_gemm<256, false,0, false><<<dim3(T_ROWS/64), blk, 0, stream>>>(Q, nullptr, w3s0, w3s1, w3s2, enc_b3, P);
    // vector quantization: EXACT split6 distances + reduce
    tokens_split6<<<dim3(T_ROWS/128, 4), blk, 0, stream>>>(P, cbs0, cbs1, cbs2, cn, partials, zzb);
    token_reduce<<<dim3(T_ROWS/256), blk, 0, stream>>>(zzb, partials, tokf, loss);
    // decoder: per-code tables (512 rows), then gather
    mfma_gemm<<<dim3(4, 2), blk, 0, stream>>>(cbb, w1b, dec_b1, L1);
    mfma_gemm<<<dim3(4, 2), blk, 0, stream>>>(L1, w2b, dec_b2, L2);
    dec3_table<<<dim3(2), blk, 0, stream>>>(L2, dec_w3, dec_b3, Rt);
    gather_recon<<<dim3(T_ROWS*4/256), blk, 0, stream>>>(Rt, tokf, frames, recon, loss);
    finalize_kernel<<<dim3(1), dim3(64), 0, stream>>>(loss);
}

// Round 14
// 597.618 us; speedup vs baseline: 1.9286x; 1.0002x over previous
//
#include <hip/hip_runtime.h>
#include <hip/hip_bf16.h>
#include <math.h>
#include <float.h>
#include <limits.h>

#define T_ROWS 131072   // 32 * 4096 patches

typedef __attribute__((ext_vector_type(8))) short short8;
typedef __attribute__((ext_vector_type(4))) float f32x4;

__device__ __forceinline__ float gelu_f(float x){
    return 0.5f * x * (1.0f + erff(x * 0.7071067811865475f));
}
__device__ __forceinline__ float bf2f(ushort u){
    union { unsigned int i; float f; } v; v.i = ((unsigned int)u) << 16; return v.f;
}
__device__ __forceinline__ ushort f2bf(float f){
    union { float f; unsigned int i; } v; v.f = f;
    unsigned int i = v.i;
    unsigned int r = (i + 0x7fffu + ((i >> 16) & 1u)) >> 16;
    return (ushort)r;
}
// exact 3-way truncation split: x ~= b0+b1+b2 (each bf16), >=24 mantissa bits
__device__ __forceinline__ void split3(float x, ushort &u0, ushort &u1, ushort &u2){
    union { float f; unsigned int i; } v; v.f = x;
    u0 = (ushort)(v.i >> 16);
    union { unsigned int i; float f; } h0; h0.i = ((unsigned int)u0) << 16;
    float r = x - h0.f;                       // exact (Sterbenz)
    union { float f; unsigned int i; } vr; vr.f = r;
    u1 = (ushort)(vr.i >> 16);
    union { unsigned int i; float f; } h1; h1.i = ((unsigned int)u1) << 16;
    float r2 = r - h1.f;                      // exact
    union { float f; unsigned int i; } v2; v2.f = r2;
    u2 = (ushort)(v2.i >> 16);
}

// ---------------------------------------------------------------------------
// Merged prep (unchanged)
// ---------------------------------------------------------------------------
__global__ __launch_bounds__(256) void prep_kernel(
    const float* __restrict__ w2, const float* __restrict__ w3,
    const float* __restrict__ d1, const float* __restrict__ d2,
    const float* __restrict__ w1, const float* __restrict__ b1,
    const float* __restrict__ cb,
    ushort* __restrict__ w2s0, ushort* __restrict__ w2s1, ushort* __restrict__ w2s2,
    ushort* __restrict__ w3s0, ushort* __restrict__ w3s1, ushort* __restrict__ w3s2,
    ushort* __restrict__ w1b, ushort* __restrict__ w2b,
    float* __restrict__ cn, ushort* __restrict__ cbb,
    ushort* __restrict__ cbs0, ushort* __restrict__ cbs1, ushort* __restrict__ cbs2,
    ushort* __restrict__ w1p0, ushort* __restrict__ w1p1, ushort* __restrict__ w1p2,
    float* __restrict__ bias2)
{
    const int blk = blockIdx.x, tid = threadIdx.x;
    if (blk < 64){
        const int i = (blk*256 + tid)*4;
        float4 a = *(const float4*)(w2 + i);
        ushort4 s0, s1, s2;
        split3(a.x, s0.x, s1.x, s2.x); split3(a.y, s0.y, s1.y, s2.y);
        split3(a.z, s0.z, s1.z, s2.z); split3(a.w, s0.w, s1.w, s2.w);
        *(ushort4*)(w2s0+i)=s0; *(ushort4*)(w2s1+i)=s1; *(ushort4*)(w2s2+i)=s2;
        float4 b = *(const float4*)(w3 + i);
        split3(b.x, s0.x, s1.x, s2.x); split3(b.y, s0.y, s1.y, s2.y);
        split3(b.z, s0.z, s1.z, s2.z); split3(b.w, s0.w, s1.w, s2.w);
        *(ushort4*)(w3s0+i)=s0; *(ushort4*)(w3s1+i)=s1; *(ushort4*)(w3s2+i)=s2;
        float4 c = *(const float4*)(d1 + i);
        ushort4 u; u.x=f2bf(c.x); u.y=f2bf(c.y); u.z=f2bf(c.z); u.w=f2bf(c.w);
        *(ushort4*)(w1b+i) = u;
        float4 d = *(const float4*)(d2 + i);
        u.x=f2bf(d.x); u.y=f2bf(d.y); u.z=f2bf(d.z); u.w=f2bf(d.w);
        *(ushort4*)(w2b+i) = u;
    } else if (blk < 192){
        const int lane = tid & 63;
        const int code = (blk-64)*4 + (tid >> 6);
        float4 v = ((const float4*)(cb + (size_t)code*256))[lane];
        size_t off = (size_t)code*256 + lane*4;
        ushort4 u; u.x=f2bf(v.x); u.y=f2bf(v.y); u.z=f2bf(v.z); u.w=f2bf(v.w);
        *(ushort4*)(cbb + off) = u;
        ushort4 s0, s1, s2;
        split3(v.x, s0.x, s1.x, s2.x); split3(v.y, s0.y, s1.y, s2.y);
        split3(v.z, s0.z, s1.z, s2.z); split3(v.w, s0.w, s1.w, s2.w);
        *(ushort4*)(cbs0 + off) = s0;
        *(ushort4*)(cbs1 + off) = s1;
        *(ushort4*)(cbs2 + off) = s2;
        float s = v.x*v.x + v.y*v.y + v.z*v.z + v.w*v.w;
        #pragma unroll
        for (int m=1; m<64; m<<=1) s += __shfl_xor(s, m);
        if (lane == 0) cn[code] = s;
    } else if (blk < 208){
        const int idx = (blk-192)*256 + tid;    // 0..4095
        const int n = idx >> 4, k = (idx & 15)*4;
        ushort4 s0 = {0,0,0,0}, s1 = {0,0,0,0}, s2 = {0,0,0,0};
        if (k < 48){
            float4 v = *(const float4*)(w1 + n*48 + k);
            split3(v.x, s0.x, s1.x, s2.x); split3(v.y, s0.y, s1.y, s2.y);
            split3(v.z, s0.z, s1.z, s2.z); split3(v.w, s0.w, s1.w, s2.w);
        }
        *(ushort4*)(w1p0 + n*64 + k) = s0;
        *(ushort4*)(w1p1 + n*64 + k) = s1;
        *(ushort4*)(w1p2 + n*64 + k) = s2;
    } else {
        float s = 0.0f;
        for (int k=0;k<48;++k) s += w1[tid*48 + k];
        bias2[tid] = b1[tid] - s;
    }
}

// ---------------------------------------------------------------------------
// f32-faithful split6 MFMA GEMM, 64 rows x 256 cols per block (unchanged).
// ---------------------------------------------------------------------------
template<int KTOT, bool GELU, int LOADER, bool SCALE>
__global__ __launch_bounds__(256, 3) void split6_gemm(
    const float* __restrict__ Ain,
    const float* __restrict__ frames,
    const ushort* __restrict__ W0, const ushort* __restrict__ W1,
    const ushort* __restrict__ W2,
    const float* __restrict__ bias,
    float* __restrict__ Cout)
{
    __shared__ __align__(16) ushort Al[3][64][40];
    __shared__ __align__(16) ushort Wl[256][40];

    const int tid = threadIdx.x;
    const int m0 = blockIdx.x * 64;
    const int arow = tid >> 2, q = tid & 3;
    const int lane = tid & 63;
    const int w = tid >> 6;
    const int lr = lane & 15, lg = lane >> 4;

    const float* asrc = nullptr;
    int pbase = 0;
    if constexpr (LOADER == 0){
        asrc = Ain + (size_t)(m0 + arow)*KTOT + q*8;
    } else {
        int p = m0 + arow;
        int b = p >> 12, nl = p & 4095, hh = nl >> 6, ww = nl & 63;
        pbase = ((b*256 + hh*4)*256 + ww*4)*3;
    }
    const ushort* wsrc  = W0 + (size_t)tid*KTOT;
    const ushort* w1frag = W1 + (size_t)(w*64 + lr)*KTOT + lg*8;
    const ushort* w2frag = W2 + (size_t)(w*64 + lr)*KTOT + lg*8;

    f32x4 acc[4][4];
    #pragma unroll
    for (int mi=0;mi<4;++mi)
        #pragma unroll
        for (int ni=0;ni<4;++ni)
            acc[mi][ni] = (f32x4){0.f,0.f,0.f,0.f};

    for (int k0=0; k0<KTOT; k0+=32){
        float x[8];
        if constexpr (LOADER == 0){
            *(float4*)&x[0] = *(const float4*)(asrc + k0);
            *(float4*)&x[4] = *(const float4*)(asrc + k0 + 4);
        } else {
            #pragma unroll
            for (int j=0;j<2;++j){
                int kk = k0 + q*8 + j*4;
                float4 v = {0.f,0.f,0.f,0.f};
                if (kk < 48){
                    int ph = kk/12, rem = kk - ph*12;
                    v = *(const float4*)(frames + pbase + ph*768 + rem);
                }
                x[j*4+0]=v.x; x[j*4+1]=v.y; x[j*4+2]=v.z; x[j*4+3]=v.w;
            }
        }
        ushort t0[8], t1[8], t2[8];
        #pragma unroll
        for (int e=0;e<8;++e) split3(x[e], t0[e], t1[e], t2[e]);
        *(uint4*)&Al[0][arow][q*8] = *(const uint4*)t0;
        *(uint4*)&Al[1][arow][q*8] = *(const uint4*)t1;
        *(uint4*)&Al[2][arow][q*8] = *(const uint4*)t2;
        *(uint4*)&Wl[tid][0]  = *(const uint4*)(wsrc + k0);
        *(uint4*)&Wl[tid][8]  = *(const uint4*)(wsrc + k0 + 8);
        *(uint4*)&Wl[tid][16] = *(const uint4*)(wsrc + k0 + 16);
        *(uint4*)&Wl[tid][24] = *(const uint4*)(wsrc + k0 + 24);
        short8 b1v[4], b2v[4];
        #pragma unroll
        for (int ni=0;ni<4;++ni){
            b1v[ni] = *(const short8*)(w1frag + (size_t)ni*16*KTOT + k0);
            b2v[ni] = *(const short8*)(w2frag + (size_t)ni*16*KTOT + k0);
        }
        __syncthreads();

        short8 b0v[4];
        #pragma unroll
        for (int ni=0;ni<4;++ni)
            b0v[ni] = *(const short8*)&Wl[w*64 + ni*16 + lr][lg*8];
        #pragma unroll
        for (int mi=0;mi<4;++mi){
            short8 a0 = *(const short8*)&Al[0][mi*16 + lr][lg*8];
            short8 a1 = *(const short8*)&Al[1][mi*16 + lr][lg*8];
            short8 a2 = *(const short8*)&Al[2][mi*16 + lr][lg*8];
            #pragma unroll
            for (int ni=0;ni<4;++ni)
                acc[mi][ni] = __builtin_amdgcn_mfma_f32_16x16x32_bf16(a0, b0v[ni], acc[mi][ni], 0,0,0);
            #pragma unroll
            for (int ni=0;ni<4;++ni)
                acc[mi][ni] = __builtin_amdgcn_mfma_f32_16x16x32_bf16(a0, b1v[ni], acc[mi][ni], 0,0,0);
            #pragma unroll
            for (int ni=0;ni<4;++ni)
                acc[mi][ni] = __builtin_amdgcn_mfma_f32_16x16x32_bf16(a1, b0v[ni], acc[mi][ni], 0,0,0);
            #pragma unroll
            for (int ni=0;ni<4;++ni)
                acc[mi][ni] = __builtin_amdgcn_mfma_f32_16x16x32_bf16(a0, b2v[ni], acc[mi][ni], 0,0,0);
            #pragma unroll
            for (int ni=0;ni<4;++ni)
                acc[mi][ni] = __builtin_amdgcn_mfma_f32_16x16x32_bf16(a1, b1v[ni], acc[mi][ni], 0,0,0);
            #pragma unroll
            for (int ni=0;ni<4;++ni)
                acc[mi][ni] = __builtin_amdgcn_mfma_f32_16x16x32_bf16(a2, b0v[ni], acc[mi][ni], 0,0,0);
        }
        __syncthreads();
    }

    const float alpha = 2.0f/255.0f;
    float bn[4];
    #pragma unroll
    for (int ni=0;ni<4;++ni) bn[ni] = bias[w*64 + ni*16 + lr];
    #pragma unroll
    for (int mi=0;mi<4;++mi)
        #pragma unroll
        for (int ni=0;ni<4;++ni)
            #pragma unroll
            for (int r=0;r<4;++r){
                int row = m0 + mi*16 + lg*4 + r;
                float v;
                if (SCALE) v = fmaf(alpha, acc[mi][ni][r], bn[ni]);
                else       v = acc[mi][ni][r] + bn[ni];
                if (GELU) v = gelu_f(v);
                Cout[(size_t)row*256 + w*64 + ni*16 + lr] = v;
            }
}

// ---------------------------------------------------------------------------
// split6 GEMM (enc3 variant): identical math, epilogue writes the 3 exact
// bf16 split planes of z plus per-row ||z||^2 (no f32 z output).
// ---------------------------------------------------------------------------
__global__ __launch_bounds__(256, 3) void split6_zout(
    const float* __restrict__ Ain,
    const ushort* __restrict__ W0, const ushort* __restrict__ W1,
    const ushort* __restrict__ W2,
    const float* __restrict__ bias,
    ushort* __restrict__ zb0, ushort* __restrict__ zb1, ushort* __restrict__ zb2,
    float* __restrict__ zz_out)
{
    __shared__ __align__(16) ushort Al[3][64][40];
    __shared__ __align__(16) ushort Wl[256][40];
    __shared__ float zs[64][4];

    const int tid = threadIdx.x;
    const int m0 = blockIdx.x * 64;
    const int arow = tid >> 2, q = tid & 3;
    const int lane = tid & 63;
    const int w = tid >> 6;
    const int lr = lane & 15, lg = lane >> 4;

    const float* asrc = Ain + (size_t)(m0 + arow)*256 + q*8;
    const ushort* wsrc  = W0 + (size_t)tid*256;
    const ushort* w1frag = W1 + (size_t)(w*64 + lr)*256 + lg*8;
    const ushort* w2frag = W2 + (size_t)(w*64 + lr)*256 + lg*8;

    f32x4 acc[4][4];
    #pragma unroll
    for (int mi=0;mi<4;++mi)
        #pragma unroll
        for (int ni=0;ni<4;++ni)
            acc[mi][ni] = (f32x4){0.f,0.f,0.f,0.f};

    for (int k0=0; k0<256; k0+=32){
        float x[8];
        *(float4*)&x[0] = *(const float4*)(asrc + k0);
        *(float4*)&x[4] = *(const float4*)(asrc + k0 + 4);
        ushort t0[8], t1[8], t2[8];
        #pragma unroll
        for (int e=0;e<8;++e) split3(x[e], t0[e], t1[e], t2[e]);
        *(uint4*)&Al[0][arow][q*8] = *(const uint4*)t0;
        *(uint4*)&Al[1][arow][q*8] = *(const uint4*)t1;
        *(uint4*)&Al[2][arow][q*8] = *(const uint4*)t2;
        *(uint4*)&Wl[tid][0]  = *(const uint4*)(wsrc + k0);
        *(uint4*)&Wl[tid][8]  = *(const uint4*)(wsrc + k0 + 8);
        *(uint4*)&Wl[tid][16] = *(const uint4*)(wsrc + k0 + 16);
        *(uint4*)&Wl[tid][24] = *(const uint4*)(wsrc + k0 + 24);
        short8 b1v[4], b2v[4];
        #pragma unroll
        for (int ni=0;ni<4;++ni){
            b1v[ni] = *(const short8*)(w1frag + (size_t)ni*16*256 + k0);
            b2v[ni] = *(const short8*)(w2frag + (size_t)ni*16*256 + k0);
        }
        __syncthreads();

        short8 b0v[4];
        #pragma unroll
        for (int ni=0;ni<4;++ni)
            b0v[ni] = *(const short8*)&Wl[w*64 + ni*16 + lr][lg*8];
        #pragma unroll
        for (int mi=0;mi<4;++mi){
            short8 a0 = *(const short8*)&Al[0][mi*16 + lr][lg*8];
            short8 a1 = *(const short8*)&Al[1][mi*16 + lr][lg*8];
            short8 a2 = *(const short8*)&Al[2][mi*16 + lr][lg*8];
            #pragma unroll
            for (int ni=0;ni<4;++ni)
                acc[mi][ni] = __builtin_amdgcn_mfma_f32_16x16x32_bf16(a0, b0v[ni], acc[mi][ni], 0,0,0);
            #pragma unroll
            for (int ni=0;ni<4;++ni)
                acc[mi][ni] = __builtin_amdgcn_mfma_f32_16x16x32_bf16(a0, b1v[ni], acc[mi][ni], 0,0,0);
            #pragma unroll
            for (int ni=0;ni<4;++ni)
                acc[mi][ni] = __builtin_amdgcn_mfma_f32_16x16x32_bf16(a1, b0v[ni], acc[mi][ni], 0,0,0);
            #pragma unroll
            for (int ni=0;ni<4;++ni)
                acc[mi][ni] = __builtin_amdgcn_mfma_f32_16x16x32_bf16(a0, b2v[ni], acc[mi][ni], 0,0,0);
            #pragma unroll
            for (int ni=0;ni<4;++ni)
                acc[mi][ni] = __builtin_amdgcn_mfma_f32_16x16x32_bf16(a1, b1v[ni], acc[mi][ni], 0,0,0);
            #pragma unroll
            for (int ni=0;ni<4;++ni)
                acc[mi][ni] = __builtin_amdgcn_mfma_f32_16x16x32_bf16(a2, b0v[ni], acc[mi][ni], 0,0,0);
        }
        __syncthreads();
    }

    float bn[4];
    #pragma unroll
    for (int ni=0;ni<4;++ni) bn[ni] = bias[w*64 + ni*16 + lr];
    #pragma unroll
    for (int mi=0;mi<4;++mi)
        #pragma unroll
        for (int r=0;r<4;++r){
            int row = m0 + mi*16 + lg*4 + r;
            float p = 0.0f;
            #pragma unroll
            for (int ni=0;ni<4;++ni){
                float v = acc[mi][ni][r] + bn[ni];
                p = fmaf(v, v, p);
                ushort s0, s1, s2;
                split3(v, s0, s1, s2);
                size_t off = (size_t)row*256 + w*64 + ni*16 + lr;
                zb0[off] = s0; zb1[off] = s1; zb2[off] = s2;
            }
            p += __shfl_xor(p, 1); p += __shfl_xor(p, 2);
            p += __shfl_xor(p, 4); p += __shfl_xor(p, 8);
            if (lr == 0) zs[mi*16 + lg*4 + r][w] = p;
        }
    __syncthreads();
    if (tid < 64)
        zz_out[m0 + tid] = zs[tid][0] + zs[tid][1] + zs[tid][2] + zs[tid][3];
}

#define INSERT1(dv, iv) do { \
    float _d = (dv); int _i = (iv); \
    if (_d < bd || (_d == bd && _i < bi)){ bd = _d; bi = _i; } \
} while(0)

// ---------------------------------------------------------------------------
// EXACT distance pass (R13 version — fallback path when ws is small).
// ---------------------------------------------------------------------------
__global__ __launch_bounds__(256, 3) void tokens_split6(
    const float* __restrict__ Zf,
    const ushort* __restrict__ C0, const ushort* __restrict__ C1,
    const ushort* __restrict__ C2,
    const float* __restrict__ cn,
    float2* __restrict__ partials,
    float* __restrict__ zz_out)
{
    __shared__ __align__(16) ushort Al[3][128][40];
    __shared__ __align__(16) ushort Wl[2][128][40];
    __shared__ float2 ptop[128][2];

    const int tid = threadIdx.x;
    const int m0 = blockIdx.x * 128;
    const int n0 = blockIdx.y * 128;
    const int srow = tid >> 1, shalf = (tid & 1) * 16;
    const int lane = tid & 63;
    const int w = tid >> 6;
    const int wm = (w >> 1) * 64, wn = (w & 1) * 64;
    const int lr = lane & 15, lg = lane >> 4;

    const float*  asrc = Zf + (size_t)(m0 + srow)*256 + shalf;
    const ushort* ws0  = C0 + (size_t)(n0 + srow)*256 + shalf;
    const ushort* ws1  = C1 + (size_t)(n0 + srow)*256 + shalf;
    const ushort* c2frag = C2 + (size_t)(n0 + wn + lr)*256 + lg*8;

    f32x4 acc[4][4];
    #pragma unroll
    for (int mi=0;mi<4;++mi)
        #pragma unroll
        for (int ni=0;ni<4;++ni)
            acc[mi][ni] = (f32x4){0.f,0.f,0.f,0.f};

    float zzp = 0.0f;

    for (int k0=0; k0<256; k0+=32){
        float x[16];
        *(float4*)&x[0]  = *(const float4*)(asrc + k0);
        *(float4*)&x[4]  = *(const float4*)(asrc + k0 + 4);
        *(float4*)&x[8]  = *(const float4*)(asrc + k0 + 8);
        *(float4*)&x[12] = *(const float4*)(asrc + k0 + 12);
        ushort t0[16], t1[16], t2[16];
        #pragma unroll
        for (int e=0;e<16;++e){
            split3(x[e], t0[e], t1[e], t2[e]);
            zzp = fmaf(x[e], x[e], zzp);
        }
        *(uint4*)&Al[0][srow][shalf]   = *(const uint4*)&t0[0];
        *(uint4*)&Al[0][srow][shalf+8] = *(const uint4*)&t0[8];
        *(uint4*)&Al[1][srow][shalf]   = *(const uint4*)&t1[0];
        *(uint4*)&Al[1][srow][shalf+8] = *(const uint4*)&t1[8];
        *(uint4*)&Al[2][srow][shalf]   = *(const uint4*)&t2[0];
        *(uint4*)&Al[2][srow][shalf+8] = *(const uint4*)&t2[8];
        *(uint4*)&Wl[0][srow][shalf]   = *(const uint4*)(ws0 + k0);
        *(uint4*)&Wl[0][srow][shalf+8] = *(const uint4*)(ws0 + k0 + 8);
        *(uint4*)&Wl[1][srow][shalf]   = *(const uint4*)(ws1 + k0);
        *(uint4*)&Wl[1][srow][shalf+8] = *(const uint4*)(ws1 + k0 + 8);
        short8 b2[4];
        #pragma unroll
        for (int ni=0;ni<4;++ni)
            b2[ni] = *(const short8*)(c2frag + (size_t)ni*16*256 + k0);
        __syncthreads();

        short8 b0[4], b1[4];
        #pragma unroll
        for (int ni=0;ni<4;++ni){
            b0[ni] = *(const short8*)&Wl[0][wn + ni*16 + lr][lg*8];
            b1[ni] = *(const short8*)&Wl[1][wn + ni*16 + lr][lg*8];
        }
        #pragma unroll
        for (int mi=0;mi<4;++mi){
            short8 a0 = *(const short8*)&Al[0][wm + mi*16 + lr][lg*8];
            short8 a1 = *(const short8*)&Al[1][wm + mi*16 + lr][lg*8];
            short8 a2 = *(const short8*)&Al[2][wm + mi*16 + lr][lg*8];
            #pragma unroll
            for (int ni=0;ni<4;++ni)
                acc[mi][ni] = __builtin_amdgcn_mfma_f32_16x16x32_bf16(a0, b0[ni], acc[mi][ni], 0,0,0);
            #pragma unroll
            for (int ni=0;ni<4;++ni)
                acc[mi][ni] = __builtin_amdgcn_mfma_f32_16x16x32_bf16(a0, b1[ni], acc[mi][ni], 0,0,0);
            #pragma unroll
            for (int ni=0;ni<4;++ni)
                acc[mi][ni] = __builtin_amdgcn_mfma_f32_16x16x32_bf16(a1, b0[ni], acc[mi][ni], 0,0,0);
            #pragma unroll
            for (int ni=0;ni<4;++ni)
                acc[mi][ni] = __builtin_amdgcn_mfma_f32_16x16x32_bf16(a0, b2[ni], acc[mi][ni], 0,0,0);
            #pragma unroll
            for (int ni=0;ni<4;++ni)
                acc[mi][ni] = __builtin_amdgcn_mfma_f32_16x16x32_bf16(a1, b1[ni], acc[mi][ni], 0,0,0);
            #pragma unroll
            for (int ni=0;ni<4;++ni)
                acc[mi][ni] = __builtin_amdgcn_mfma_f32_16x16x32_bf16(a2, b0[ni], acc[mi][ni], 0,0,0);
        }
        __syncthreads();
    }

    {
        float other = __shfl_xor(zzp, 1);
        if (blockIdx.y == 0 && (tid & 1) == 0)
            zz_out[m0 + srow] = zzp + other;
    }

    float cnl[4];
    #pragma unroll
    for (int ni=0;ni<4;++ni) cnl[ni] = cn[n0 + wn + ni*16 + lr];

    #pragma unroll
    for (int mi=0;mi<4;++mi)
        #pragma unroll
        for (int r=0;r<4;++r){
            float bd = FLT_MAX; int bi = INT_MAX;
            #pragma unroll
            for (int ni=0;ni<4;++ni){
                float d = cnl[ni] - 2.0f*acc[mi][ni][r];
                int col = n0 + wn + ni*16 + lr;
                INSERT1(d, col);
            }
            #pragma unroll
            for (int m=1; m<16; m<<=1){
                float od = __shfl_xor(bd, m);
                int   oi = __shfl_xor(bi, m);
                INSERT1(od, oi);
            }
            if (lr == 0)
                ptop[wm + mi*16 + lg*4 + r][w & 1] = make_float2(bd, (float)bi);
        }
    __syncthreads();
    if (tid < 128){
        float2 hA = ptop[tid][0], hB = ptop[tid][1];
        int   gA = (int)hA.y, gB = (int)hB.y;
        bool takeB = (hB.x < hA.x) || (hB.x == hA.x && gB < gA);
        partials[(size_t)(m0 + tid)*4 + blockIdx.y] = takeB ? hB : hA;
    }
}

// ---------------------------------------------------------------------------
// EXACT distance pass from PRE-SPLIT z planes (no split3, no zz).
// Identical MFMA sequence -> bitwise identical distances.
// ---------------------------------------------------------------------------
__global__ __launch_bounds__(256, 3) void tokens_split6_pp(
    const ushort* __restrict__ Z0, const ushort* __restrict__ Z1,
    const ushort* __restrict__ Z2,
    const ushort* __restrict__ C0, const ushort* __restrict__ C1,
    const ushort* __restrict__ C2,
    const float* __restrict__ cn,
    float2* __restrict__ partials)
{
    __shared__ __align__(16) ushort Al[3][128][40];
    __shared__ __align__(16) ushort Wl[2][128][40];
    __shared__ float2 ptop[128][2];

    const int tid = threadIdx.x;
    const int m0 = blockIdx.x * 128;
    const int n0 = blockIdx.y * 128;
    const int srow = tid >> 1, shalf = (tid & 1) * 16;
    const int lane = tid & 63;
    const int w = tid >> 6;
    const int wm = (w >> 1) * 64, wn = (w & 1) * 64;
    const int lr = lane & 15, lg = lane >> 4;

    const size_t arow_off = (size_t)(m0 + srow)*256 + shalf;
    const ushort* ws0  = C0 + (size_t)(n0 + srow)*256 + shalf;
    const ushort* ws1  = C1 + (size_t)(n0 + srow)*256 + shalf;
    const ushort* c2frag = C2 + (size_t)(n0 + wn + lr)*256 + lg*8;

    f32x4 acc[4][4];
    #pragma unroll
    for (int mi=0;mi<4;++mi)
        #pragma unroll
        for (int ni=0;ni<4;++ni)
            acc[mi][ni] = (f32x4){0.f,0.f,0.f,0.f};

    for (int k0=0; k0<256; k0+=32){
        *(uint4*)&Al[0][srow][shalf]   = *(const uint4*)(Z0 + arow_off + k0);
        *(uint4*)&Al[0][srow][shalf+8] = *(const uint4*)(Z0 + arow_off + k0 + 8);
        *(uint4*)&Al[1][srow][shalf]   = *(const uint4*)(Z1 + arow_off + k0);
        *(uint4*)&Al[1][srow][shalf+8] = *(const uint4*)(Z1 + arow_off + k0 + 8);
        *(uint4*)&Al[2][srow][shalf]   = *(const uint4*)(Z2 + arow_off + k0);
        *(uint4*)&Al[2][srow][shalf+8] = *(const uint4*)(Z2 + arow_off + k0 + 8);
        *(uint4*)&Wl[0][srow][shalf]   = *(const uint4*)(ws0 + k0);
        *(uint4*)&Wl[0][srow][shalf+8] = *(const uint4*)(ws0 + k0 + 8);
        *(uint4*)&Wl[1][srow][shalf]   = *(const uint4*)(ws1 + k0);
        *(uint4*)&Wl[1][srow][shalf+8] = *(const uint4*)(ws1 + k0 + 8);
        short8 b2[4];
        #pragma unroll
        for (int ni=0;ni<4;++ni)
            b2[ni] = *(const short8*)(c2frag + (size_t)ni*16*256 + k0);
        __syncthreads();

        short8 b0[4], b1[4];
        #pragma unroll
        for (int ni=0;ni<4;++ni){
            b0[ni] = *(const short8*)&Wl[0][wn + ni*16 + lr][lg*8];
            b1[ni] = *(const short8*)&Wl[1][wn + ni*16 + lr][lg*8];
        }
        #pragma unroll
        for (int mi=0;mi<4;++mi){
            short8 a0 = *(const short8*)&Al[0][wm + mi*16 + lr][lg*8];
            short8 a1 = *(const short8*)&Al[1][wm + mi*16 + lr][lg*8];
            short8 a2 = *(const short8*)&Al[2][wm + mi*16 + lr][lg*8];
            #pragma unroll
            for (int ni=0;ni<4;++ni)
                acc[mi][ni] = __builtin_amdgcn_mfma_f32_16x16x32_bf16(a0, b0[ni], acc[mi][ni], 0,0,0);
            #pragma unroll
            for (int ni=0;ni<4;++ni)
                acc[mi][ni] = __builtin_amdgcn_mfma_f32_16x16x32_bf16(a0, b1[ni], acc[mi][ni], 0,0,0);
            #pragma unroll
            for (int ni=0;ni<4;++ni)
                acc[mi][ni] = __builtin_amdgcn_mfma_f32_16x16x32_bf16(a1, b0[ni], acc[mi][ni], 0,0,0);
            #pragma unroll
            for (int ni=0;ni<4;++ni)
                acc[mi][ni] = __builtin_amdgcn_mfma_f32_16x16x32_bf16(a0, b2[ni], acc[mi][ni], 0,0,0);
            #pragma unroll
            for (int ni=0;ni<4;++ni)
                acc[mi][ni] = __builtin_amdgcn_mfma_f32_16x16x32_bf16(a1, b1[ni], acc[mi][ni], 0,0,0);
            #pragma unroll
            for (int ni=0;ni<4;++ni)
                acc[mi][ni] = __builtin_amdgcn_mfma_f32_16x16x32_bf16(a2, b0[ni], acc[mi][ni], 0,0,0);
        }
        __syncthreads();
    }

    float cnl[4];
    #pragma unroll
    for (int ni=0;ni<4;++ni) cnl[ni] = cn[n0 + wn + ni*16 + lr];

    #pragma unroll
    for (int mi=0;mi<4;++mi)
        #pragma unroll
        for (int r=0;r<4;++r){
            float bd = FLT_MAX; int bi = INT_MAX;
            #pragma unroll
            for (int ni=0;ni<4;++ni){
                float d = cnl[ni] - 2.0f*acc[mi][ni][r];
                int col = n0 + wn + ni*16 + lr;
                INSERT1(d, col);
            }
            #pragma unroll
            for (int m=1; m<16; m<<=1){
                float od = __shfl_xor(bd, m);
                int   oi = __shfl_xor(bi, m);
                INSERT1(od, oi);
            }
            if (lr == 0)
                ptop[wm + mi*16 + lg*4 + r][w & 1] = make_float2(bd, (float)bi);
        }
    __syncthreads();
    if (tid < 128){
        float2 hA = ptop[tid][0], hB = ptop[tid][1];
        int   gA = (int)hA.y, gB = (int)hB.y;
        bool takeB = (hB.x < hA.x) || (hB.x == hA.x && gB < gA);
        partials[(size_t)(m0 + tid)*4 + blockIdx.y] = takeB ? hB : hA;
    }
}

// ---------------------------------------------------------------------------
// Token + commitment: min over 4 (d,idx) partials, zz from zz_out.
// ---------------------------------------------------------------------------
__global__ __launch_bounds__(256) void token_reduce(
    const float* __restrict__ zz_out, const float2* __restrict__ partials,
    float* __restrict__ tokf, float* __restrict__ loss)
{
    const int tid = threadIdx.x;
    const int row = blockIdx.x*256 + tid;
    float2 p0 = partials[(size_t)row*4 + 0];
    float2 p1 = partials[(size_t)row*4 + 1];
    float2 p2 = partials[(size_t)row*4 + 2];
    float2 p3 = partials[(size_t)row*4 + 3];
    float d = p0.x; int g = (int)p0.y;
    if (p1.x < d || (p1.x == d && (int)p1.y < g)){ d = p1.x; g = (int)p1.y; }
    if (p2.x < d || (p2.x == d && (int)p2.y < g)){ d = p2.x; g = (int)p2.y; }
    if (p3.x < d || (p3.x == d && (int)p3.y < g)){ d = p3.x; g = (int)p3.y; }
    tokf[row] = (float)g;
    float cs = zz_out[row] + d;
    #pragma unroll
    for (int m=1; m<64; m<<=1) cs += __shfl_xor(cs, m);
    __shared__ float wsum[4];
    const int lane = tid & 63, w = tid >> 6;
    if (lane == 0) wsum[w] = cs;
    __syncthreads();
    if (tid == 0) atomicAdd(loss + 1, wsum[0]+wsum[1]+wsum[2]+wsum[3]);
}

// ---------------------------------------------------------------------------
// bf16 MFMA GEMM (decoder tables): Y[M,256] = gelu(A @ W^T + b), M=512.
// ---------------------------------------------------------------------------
__global__ __launch_bounds__(256) void mfma_gemm(
    const ushort* __restrict__ Abf,
    const ushort* __restrict__ Wbf,
    const float* __restrict__ bias,
    ushort* __restrict__ Ybf)
{
    __shared__ __align__(16) ushort Al[128][40];
    __shared__ __align__(16) ushort Wl[128][40];

    const int tid = threadIdx.x;
    const int m0 = blockIdx.x * 128;
    const int n0 = blockIdx.y * 128;
    const int srow = tid >> 1, shalf = (tid & 1) * 16;
    const int lane = tid & 63;
    const int w = tid >> 6;
    const int wm = (w >> 1) * 64, wn = (w & 1) * 64;
    const int lr = lane & 15, lg = lane >> 4;

    const ushort* asrc = Abf + (size_t)(m0 + srow)*256 + shalf;
    const ushort* wsrc = Wbf + (size_t)(n0 + srow)*256 + shalf;

    f32x4 acc[4][4];
    #pragma unroll
    for (int mi=0;mi<4;++mi)
        #pragma unroll
        for (int ni=0;ni<4;++ni)
            acc[mi][ni] = (f32x4){0.f,0.f,0.f,0.f};

    for (int k0=0; k0<256; k0+=32){
        *(uint4*)&Al[srow][shalf]   = *(const uint4*)(asrc + k0);
        *(uint4*)&Al[srow][shalf+8] = *(const uint4*)(asrc + k0 + 8);
        *(uint4*)&Wl[srow][shalf]   = *(const uint4*)(wsrc + k0);
        *(uint4*)&Wl[srow][shalf+8] = *(const uint4*)(wsrc + k0 + 8);
        __syncthreads();

        short8 af[4], bfr[4];
        #pragma unroll
        for (int mi=0;mi<4;++mi)
            af[mi] = *(const short8*)&Al[wm + mi*16 + lr][lg*8];
        #pragma unroll
        for (int ni=0;ni<4;++ni)
            bfr[ni] = *(const short8*)&Wl[wn + ni*16 + lr][lg*8];
        #pragma unroll
        for (int mi=0;mi<4;++mi)
            #pragma unroll
            for (int ni=0;ni<4;++ni)
                acc[mi][ni] = __builtin_amdgcn_mfma_f32_16x16x32_bf16(
                    af[mi], bfr[ni], acc[mi][ni], 0, 0, 0);
        __syncthreads();
    }

    float bn[4];
    #pragma unroll
    for (int ni=0;ni<4;++ni) bn[ni] = bias[n0 + wn + ni*16 + lr];
    #pragma unroll
    for (int mi=0;mi<4;++mi)
        #pragma unroll
        for (int ni=0;ni<4;++ni)
            #pragma unroll
            for (int r=0;r<4;++r){
                int row = m0 + wm + mi*16 + lg*4 + r;
                float v = acc[mi][ni][r] + bn[ni];
                v = gelu_f(v);
                Ybf[(size_t)row*256 + n0 + wn + ni*16 + lr] = f2bf(v);
            }
}

// ---------------------------------------------------------------------------
// dec3 table: R[512][48] = L2 @ W3^T + b3 (W3 converted in-kernel).
// ---------------------------------------------------------------------------
__global__ __launch_bounds__(256) void dec3_table(
    const ushort* __restrict__ Ain, const float* __restrict__ W,
    const float* __restrict__ bias, float* __restrict__ Rt)
{
    __shared__ __align__(16) ushort Al[256][40];
    __shared__ __align__(16) ushort Wl[48][40];

    const int tid = threadIdx.x;
    const int m0 = blockIdx.x * 256;
    const int lane = tid & 63;
    const int w = tid >> 6;
    const int lr = lane & 15, lg = lane >> 4;

    const ushort* asrc = Ain + (size_t)(m0 + tid)*256;

    f32x4 acc[4][3];
    #pragma unroll
    for (int mi=0;mi<4;++mi)
        #pragma unroll
        for (int ni=0;ni<3;++ni)
            acc[mi][ni] = (f32x4){0.f,0.f,0.f,0.f};

    for (int k0=0; k0<256; k0+=32){
        *(uint4*)&Al[tid][0]  = *(const uint4*)(asrc + k0);
        *(uint4*)&Al[tid][8]  = *(const uint4*)(asrc + k0 + 8);
        *(uint4*)&Al[tid][16] = *(const uint4*)(asrc + k0 + 16);
        *(uint4*)&Al[tid][24] = *(const uint4*)(asrc + k0 + 24);
        if (tid < 96){
            const int wrow = tid >> 1, wh = (tid & 1)*16;
            const float* wp = W + (size_t)wrow*256 + k0 + wh;
            float4 f0 = *(const float4*)(wp);
            float4 f1 = *(const float4*)(wp+4);
            float4 f2 = *(const float4*)(wp+8);
            float4 f3 = *(const float4*)(wp+12);
            ushort t[16];
            t[0]=f2bf(f0.x); t[1]=f2bf(f0.y); t[2]=f2bf(f0.z); t[3]=f2bf(f0.w);
            t[4]=f2bf(f1.x); t[5]=f2bf(f1.y); t[6]=f2bf(f1.z); t[7]=f2bf(f1.w);
            t[8]=f2bf(f2.x); t[9]=f2bf(f2.y); t[10]=f2bf(f2.z); t[11]=f2bf(f2.w);
            t[12]=f2bf(f3.x); t[13]=f2bf(f3.y); t[14]=f2bf(f3.z); t[15]=f2bf(f3.w);
            *(uint4*)&Wl[wrow][wh]   = *(const uint4*)&t[0];
            *(uint4*)&Wl[wrow][wh+8] = *(const uint4*)&t[8];
        }
        __syncthreads();

        short8 bfr[3];
        #pragma unroll
        for (int ni=0;ni<3;++ni)
            bfr[ni] = *(const short8*)&Wl[ni*16 + lr][lg*8];
        #pragma unroll
        for (int mi=0;mi<4;++mi){
            short8 af = *(const short8*)&Al[w*64 + mi*16 + lr][lg*8];
            #pragma unroll
            for (int ni=0;ni<3;++ni)
                acc[mi][ni] = __builtin_amdgcn_mfma_f32_16x16x32_bf16(
                    af, bfr[ni], acc[mi][ni], 0, 0, 0);
        }
        __syncthreads();
    }

    #pragma unroll
    for (int ni=0;ni<3;++ni){
        const int col = ni*16 + lr;
        const float bn = bias[col];
        #pragma unroll
        for (int mi=0;mi<4;++mi)
            #pragma unroll
            for (int r=0;r<4;++r){
                int row = m0 + w*64 + mi*16 + lg*4 + r;
                Rt[row*48 + col] = acc[mi][ni][r] + bn;
            }
    }
}

// ---------------------------------------------------------------------------
// gather + unpatchify + recon loss: recon = unpatchify(R[tokens]).
// ---------------------------------------------------------------------------
__global__ __launch_bounds__(256) void gather_recon(
    const float* __restrict__ Rt, const float* __restrict__ tokf,
    const float* __restrict__ frames, float* __restrict__ recon,
    float* __restrict__ loss)
{
    const int tid = threadIdx.x;
    const int idx = blockIdx.x*256 + tid;
    const int p = idx >> 2, ph = idx & 3;
    const int g = (int)tokf[p];
    int b = p >> 12, nl = p & 4095, hh = nl >> 6, ww = nl & 63;
    size_t base = (size_t)(((b*256 + hh*4 + ph)*256 + ww*4)*3);
    const float* rp = Rt + g*48 + ph*12;
    const float sc = 2.0f/255.0f;
    float ls = 0.0f;
    #pragma unroll
    for (int j=0;j<3;++j){
        float4 y = *(const float4*)(rp + j*4);
        float4 f = *(const float4*)(frames + base + j*4);
        float t0=f.x*sc-1.0f, t1=f.y*sc-1.0f, t2=f.z*sc-1.0f, t3=f.w*sc-1.0f;
        float d0=y.x-t0, d1=y.y-t1, d2=y.z-t2, d3=y.w-t3;
        ls += d0*d0 + d1*d1 + d2*d2 + d3*d3;
        *(float4*)(recon + base + j*4) = y;
    }
    #pragma unroll
    for (int off=32; off>0; off>>=1) ls += __shfl_down(ls, off);
    __shared__ float wsum[4];
    int lane = tid & 63, w = tid >> 6;
    if (lane == 0) wsum[w] = ls;
    __syncthreads();
    if (tid == 0) atomicAdd(loss + 0, wsum[0]+wsum[1]+wsum[2]+wsum[3]);
}

__global__ void finalize_kernel(float* __restrict__ loss){
    if (threadIdx.x == 0 && blockIdx.x == 0){
        loss[0] = loss[0] * (1.0f/6291456.0f);
        float c = loss[1] * (1.0f/33554432.0f);
        loss[1] = c;
        loss[2] = c;
    }
}

extern "C" void kernel_launch(void* const* d_in, const int* in_sizes, int n_in,
                              void* d_out, int out_size, void* d_ws, size_t ws_size,
                              hipStream_t stream)
{
    (void)in_sizes; (void)n_in; (void)out_size;
    const float* frames   = (const float*)d_in[0];
    const float* enc_w1   = (const float*)d_in[1];
    const float* enc_b1   = (const float*)d_in[2];
    const float* enc_w2   = (const float*)d_in[3];
    const float* enc_b2   = (const float*)d_in[4];
    const float* enc_w3   = (const float*)d_in[5];
    const float* enc_b3   = (const float*)d_in[6];
    const float* codebook = (const float*)d_in[7];
    const float* dec_w1   = (const float*)d_in[8];
    const float* dec_b1   = (const float*)d_in[9];
    const float* dec_w2   = (const float*)d_in[10];
    const float* dec_b2   = (const float*)d_in[11];
    const float* dec_w3   = (const float*)d_in[12];
    const float* dec_b3   = (const float*)d_in[13];

    float* P = (float*)d_ws;                 // h1 -> (z f32 | tables)
    float* Q = P + (size_t)33554432;         // h2
    float2* partials = (float2*)(Q + 18000000);  // 8 MB, in dead-h2 zone
    ushort* L1 = (ushort*)P;                 // 512x256 bf16 (after tokens)
    ushort* L2 = (ushort*)(P + 65536);
    float*  Rt = P + 131072;
    // optional pre-split z planes beyond the 268 MB proven region:
    const size_t basefloats = (size_t)2*33554432;
    ushort* zb0 = (ushort*)(P + basefloats);                    // 67 MB each
    ushort* zb1 = zb0 + (size_t)T_ROWS*256;
    ushort* zb2 = zb1 + (size_t)T_ROWS*256;
    const size_t need = basefloats*4 + (size_t)3*T_ROWS*256*2;  // 470 MB
    const bool big_ws = (ws_size >= need);

    float* recon = (float*)d_out;
    float* tokf  = recon + 6291456;
    float* loss  = tokf + 131072;
    float*  cn   = recon;
    ushort* cbb  = (ushort*)(recon + 512);
    ushort* w1b  = (ushort*)(recon + 66048);
    ushort* w2b  = (ushort*)(recon + 98816);
    ushort* w2s0 = (ushort*)(recon + 131584);
    ushort* w2s1 = (ushort*)(recon + 164352);
    ushort* w2s2 = (ushort*)(recon + 197120);
    ushort* w3s0 = (ushort*)(recon + 229888);
    ushort* w3s1 = (ushort*)(recon + 262656);
    ushort* w3s2 = (ushort*)(recon + 295424);
    ushort* cbs0 = (ushort*)(recon + 328192);
    ushort* cbs1 = (ushort*)(recon + 393728);
    ushort* cbs2 = (ushort*)(recon + 459264);
    float*  zzb  = recon + 524800;
    ushort* w1p0 = (ushort*)(recon + 655872);
    ushort* w1p1 = (ushort*)(recon + 664064);
    ushort* w1p2 = (ushort*)(recon + 672256);
    float*  bias2 = recon + 680448;

    hipMemsetAsync(loss, 0, 3*sizeof(float), stream);

    dim3 blk(256);
    prep_kernel<<<dim3(209), blk, 0, stream>>>(enc_w2, enc_w3, dec_w1, dec_w2,
        enc_w1, enc_b1, codebook,
        w2s0, w2s1, w2s2, w3s0, w3s1, w3s2, w1b, w2b,
        cn, cbb, cbs0, cbs1, cbs2, w1p0, w1p1, w1p2, bias2);
    // encoder layers 1-2
    split6_gemm<64,  true, 1, true ><<<dim3(T_ROWS/64), blk, 0, stream>>>(nullptr, frames, w1p0, w1p1, w1p2, bias2, P);
    split6_gemm<256, true, 0, false><<<dim3(T_ROWS/64), blk, 0, stream>>>(P, nullptr, w2s0, w2s1, w2s2, enc_b2, Q);
    if (big_ws){
        // enc3 emits exact bf16 split planes + per-row ||z||^2
        split6_zout<<<dim3(T_ROWS/64), blk, 0, stream>>>(Q, w3s0, w3s1, w3s2, enc_b3, zb0, zb1, zb2, zzb);
        tokens_split6_pp<<<dim3(T_ROWS/128, 4), blk, 0, stream>>>(zb0, zb1, zb2, cbs0, cbs1, cbs2, cn, partials);
    } else {
        split6_gemm<256, false,0, false><<<dim3(T_ROWS/64), blk, 0, stream>>>(Q, nullptr, w3s0, w3s1, w3s2, enc_b3, P);
        tokens_split6<<<dim3(T_ROWS/128, 4), blk, 0, stream>>>(P, cbs0, cbs1, cbs2, cn, partials, zzb);
    }
    token_reduce<<<dim3(T_ROWS/256), blk, 0, stream>>>(zzb, partials, tokf, loss);
    // decoder: per-code tables, then gather
    mfma_gemm<<<dim3(4, 2), blk, 0, stream>>>(cbb, w1b, dec_b1, L1);
    mfma_gemm<<<dim3(4, 2), blk, 0, stream>>>(L1, w2b, dec_b2, L2);
    dec3_table<<<dim3(2), blk, 0, stream>>>(L2, dec_w3, dec_b3, Rt);
    gather_recon<<<dim3(T_ROWS*4/256), blk, 0, stream>>>(Rt, tokf, frames, recon, loss);
    finalize_kernel<<<dim3(1), dim3(64), 0, stream>>>(loss);
}

// Round 15
// 597.516 us; speedup vs baseline: 1.9289x; 1.0002x over previous
//
#include <hip/hip_runtime.h>
#include <hip/hip_bf16.h>
#include <math.h>
#include <float.h>
#include <limits.h>

#define T_ROWS 131072   // 32 * 4096 patches

typedef __attribute__((ext_vector_type(8))) short short8;
typedef __attribute__((ext_vector_type(4))) float f32x4;

__device__ __forceinline__ float gelu_f(float x){
    return 0.5f * x * (1.0f + erff(x * 0.7071067811865475f));
}
__device__ __forceinline__ float bf2f(ushort u){
    union { unsigned int i; float f; } v; v.i = ((unsigned int)u) << 16; return v.f;
}
__device__ __forceinline__ ushort f2bf(float f){
    union { float f; unsigned int i; } v; v.f = f;
    unsigned int i = v.i;
    unsigned int r = (i + 0x7fffu + ((i >> 16) & 1u)) >> 16;
    return (ushort)r;
}
// exact 3-way truncation split: x ~= b0+b1+b2 (each bf16), >=24 mantissa bits
__device__ __forceinline__ void split3(float x, ushort &u0, ushort &u1, ushort &u2){
    union { float f; unsigned int i; } v; v.f = x;
    u0 = (ushort)(v.i >> 16);
    union { unsigned int i; float f; } h0; h0.i = ((unsigned int)u0) << 16;
    float r = x - h0.f;                       // exact (Sterbenz)
    union { float f; unsigned int i; } vr; vr.f = r;
    u1 = (ushort)(vr.i >> 16);
    union { unsigned int i; float f; } h1; h1.i = ((unsigned int)u1) << 16;
    float r2 = r - h1.f;                      // exact
    union { float f; unsigned int i; } v2; v2.f = r2;
    u2 = (ushort)(v2.i >> 16);
}

// ---------------------------------------------------------------------------
// Merged prep (unchanged)
// ---------------------------------------------------------------------------
__global__ __launch_bounds__(256) void prep_kernel(
    const float* __restrict__ w2, const float* __restrict__ w3,
    const float* __restrict__ d1, const float* __restrict__ d2,
    const float* __restrict__ w1, const float* __restrict__ b1,
    const float* __restrict__ cb,
    ushort* __restrict__ w2s0, ushort* __restrict__ w2s1, ushort* __restrict__ w2s2,
    ushort* __restrict__ w3s0, ushort* __restrict__ w3s1, ushort* __restrict__ w3s2,
    ushort* __restrict__ w1b, ushort* __restrict__ w2b,
    float* __restrict__ cn, ushort* __restrict__ cbb,
    ushort* __restrict__ cbs0, ushort* __restrict__ cbs1, ushort* __restrict__ cbs2,
    ushort* __restrict__ w1p0, ushort* __restrict__ w1p1, ushort* __restrict__ w1p2,
    float* __restrict__ bias2)
{
    const int blk = blockIdx.x, tid = threadIdx.x;
    if (blk < 64){
        const int i = (blk*256 + tid)*4;
        float4 a = *(const float4*)(w2 + i);
        ushort4 s0, s1, s2;
        split3(a.x, s0.x, s1.x, s2.x); split3(a.y, s0.y, s1.y, s2.y);
        split3(a.z, s0.z, s1.z, s2.z); split3(a.w, s0.w, s1.w, s2.w);
        *(ushort4*)(w2s0+i)=s0; *(ushort4*)(w2s1+i)=s1; *(ushort4*)(w2s2+i)=s2;
        float4 b = *(const float4*)(w3 + i);
        split3(b.x, s0.x, s1.x, s2.x); split3(b.y, s0.y, s1.y, s2.y);
        split3(b.z, s0.z, s1.z, s2.z); split3(b.w, s0.w, s1.w, s2.w);
        *(ushort4*)(w3s0+i)=s0; *(ushort4*)(w3s1+i)=s1; *(ushort4*)(w3s2+i)=s2;
        float4 c = *(const float4*)(d1 + i);
        ushort4 u; u.x=f2bf(c.x); u.y=f2bf(c.y); u.z=f2bf(c.z); u.w=f2bf(c.w);
        *(ushort4*)(w1b+i) = u;
        float4 d = *(const float4*)(d2 + i);
        u.x=f2bf(d.x); u.y=f2bf(d.y); u.z=f2bf(d.z); u.w=f2bf(d.w);
        *(ushort4*)(w2b+i) = u;
    } else if (blk < 192){
        const int lane = tid & 63;
        const int code = (blk-64)*4 + (tid >> 6);
        float4 v = ((const float4*)(cb + (size_t)code*256))[lane];
        size_t off = (size_t)code*256 + lane*4;
        ushort4 u; u.x=f2bf(v.x); u.y=f2bf(v.y); u.z=f2bf(v.z); u.w=f2bf(v.w);
        *(ushort4*)(cbb + off) = u;
        ushort4 s0, s1, s2;
        split3(v.x, s0.x, s1.x, s2.x); split3(v.y, s0.y, s1.y, s2.y);
        split3(v.z, s0.z, s1.z, s2.z); split3(v.w, s0.w, s1.w, s2.w);
        *(ushort4*)(cbs0 + off) = s0;
        *(ushort4*)(cbs1 + off) = s1;
        *(ushort4*)(cbs2 + off) = s2;
        float s = v.x*v.x + v.y*v.y + v.z*v.z + v.w*v.w;
        #pragma unroll
        for (int m=1; m<64; m<<=1) s += __shfl_xor(s, m);
        if (lane == 0) cn[code] = s;
    } else if (blk < 208){
        const int idx = (blk-192)*256 + tid;    // 0..4095
        const int n = idx >> 4, k = (idx & 15)*4;
        ushort4 s0 = {0,0,0,0}, s1 = {0,0,0,0}, s2 = {0,0,0,0};
        if (k < 48){
            float4 v = *(const float4*)(w1 + n*48 + k);
            split3(v.x, s0.x, s1.x, s2.x); split3(v.y, s0.y, s1.y, s2.y);
            split3(v.z, s0.z, s1.z, s2.z); split3(v.w, s0.w, s1.w, s2.w);
        }
        *(ushort4*)(w1p0 + n*64 + k) = s0;
        *(ushort4*)(w1p1 + n*64 + k) = s1;
        *(ushort4*)(w1p2 + n*64 + k) = s2;
    } else {
        float s = 0.0f;
        for (int k=0;k<48;++k) s += w1[tid*48 + k];
        bias2[tid] = b1[tid] - s;
    }
}

// ---------------------------------------------------------------------------
// f32-faithful split6 MFMA GEMM, 64 rows x 256 cols per block (unchanged).
// ---------------------------------------------------------------------------
template<int KTOT, bool GELU, int LOADER, bool SCALE>
__global__ __launch_bounds__(256, 3) void split6_gemm(
    const float* __restrict__ Ain,
    const float* __restrict__ frames,
    const ushort* __restrict__ W0, const ushort* __restrict__ W1,
    const ushort* __restrict__ W2,
    const float* __restrict__ bias,
    float* __restrict__ Cout)
{
    __shared__ __align__(16) ushort Al[3][64][40];
    __shared__ __align__(16) ushort Wl[256][40];

    const int tid = threadIdx.x;
    const int m0 = blockIdx.x * 64;
    const int arow = tid >> 2, q = tid & 3;
    const int lane = tid & 63;
    const int w = tid >> 6;
    const int lr = lane & 15, lg = lane >> 4;

    const float* asrc = nullptr;
    int pbase = 0;
    if constexpr (LOADER == 0){
        asrc = Ain + (size_t)(m0 + arow)*KTOT + q*8;
    } else {
        int p = m0 + arow;
        int b = p >> 12, nl = p & 4095, hh = nl >> 6, ww = nl & 63;
        pbase = ((b*256 + hh*4)*256 + ww*4)*3;
    }
    const ushort* wsrc  = W0 + (size_t)tid*KTOT;
    const ushort* w1frag = W1 + (size_t)(w*64 + lr)*KTOT + lg*8;
    const ushort* w2frag = W2 + (size_t)(w*64 + lr)*KTOT + lg*8;

    f32x4 acc[4][4];
    #pragma unroll
    for (int mi=0;mi<4;++mi)
        #pragma unroll
        for (int ni=0;ni<4;++ni)
            acc[mi][ni] = (f32x4){0.f,0.f,0.f,0.f};

    for (int k0=0; k0<KTOT; k0+=32){
        float x[8];
        if constexpr (LOADER == 0){
            *(float4*)&x[0] = *(const float4*)(asrc + k0);
            *(float4*)&x[4] = *(const float4*)(asrc + k0 + 4);
        } else {
            #pragma unroll
            for (int j=0;j<2;++j){
                int kk = k0 + q*8 + j*4;
                float4 v = {0.f,0.f,0.f,0.f};
                if (kk < 48){
                    int ph = kk/12, rem = kk - ph*12;
                    v = *(const float4*)(frames + pbase + ph*768 + rem);
                }
                x[j*4+0]=v.x; x[j*4+1]=v.y; x[j*4+2]=v.z; x[j*4+3]=v.w;
            }
        }
        ushort t0[8], t1[8], t2[8];
        #pragma unroll
        for (int e=0;e<8;++e) split3(x[e], t0[e], t1[e], t2[e]);
        *(uint4*)&Al[0][arow][q*8] = *(const uint4*)t0;
        *(uint4*)&Al[1][arow][q*8] = *(const uint4*)t1;
        *(uint4*)&Al[2][arow][q*8] = *(const uint4*)t2;
        *(uint4*)&Wl[tid][0]  = *(const uint4*)(wsrc + k0);
        *(uint4*)&Wl[tid][8]  = *(const uint4*)(wsrc + k0 + 8);
        *(uint4*)&Wl[tid][16] = *(const uint4*)(wsrc + k0 + 16);
        *(uint4*)&Wl[tid][24] = *(const uint4*)(wsrc + k0 + 24);
        short8 b1v[4], b2v[4];
        #pragma unroll
        for (int ni=0;ni<4;++ni){
            b1v[ni] = *(const short8*)(w1frag + (size_t)ni*16*KTOT + k0);
            b2v[ni] = *(const short8*)(w2frag + (size_t)ni*16*KTOT + k0);
        }
        __syncthreads();

        short8 b0v[4];
        #pragma unroll
        for (int ni=0;ni<4;++ni)
            b0v[ni] = *(const short8*)&Wl[w*64 + ni*16 + lr][lg*8];
        #pragma unroll
        for (int mi=0;mi<4;++mi){
            short8 a0 = *(const short8*)&Al[0][mi*16 + lr][lg*8];
            short8 a1 = *(const short8*)&Al[1][mi*16 + lr][lg*8];
            short8 a2 = *(const short8*)&Al[2][mi*16 + lr][lg*8];
            #pragma unroll
            for (int ni=0;ni<4;++ni)
                acc[mi][ni] = __builtin_amdgcn_mfma_f32_16x16x32_bf16(a0, b0v[ni], acc[mi][ni], 0,0,0);
            #pragma unroll
            for (int ni=0;ni<4;++ni)
                acc[mi][ni] = __builtin_amdgcn_mfma_f32_16x16x32_bf16(a0, b1v[ni], acc[mi][ni], 0,0,0);
            #pragma unroll
            for (int ni=0;ni<4;++ni)
                acc[mi][ni] = __builtin_amdgcn_mfma_f32_16x16x32_bf16(a1, b0v[ni], acc[mi][ni], 0,0,0);
            #pragma unroll
            for (int ni=0;ni<4;++ni)
                acc[mi][ni] = __builtin_amdgcn_mfma_f32_16x16x32_bf16(a0, b2v[ni], acc[mi][ni], 0,0,0);
            #pragma unroll
            for (int ni=0;ni<4;++ni)
                acc[mi][ni] = __builtin_amdgcn_mfma_f32_16x16x32_bf16(a1, b1v[ni], acc[mi][ni], 0,0,0);
            #pragma unroll
            for (int ni=0;ni<4;++ni)
                acc[mi][ni] = __builtin_amdgcn_mfma_f32_16x16x32_bf16(a2, b0v[ni], acc[mi][ni], 0,0,0);
        }
        __syncthreads();
    }

    const float alpha = 2.0f/255.0f;
    float bn[4];
    #pragma unroll
    for (int ni=0;ni<4;++ni) bn[ni] = bias[w*64 + ni*16 + lr];
    #pragma unroll
    for (int mi=0;mi<4;++mi)
        #pragma unroll
        for (int ni=0;ni<4;++ni)
            #pragma unroll
            for (int r=0;r<4;++r){
                int row = m0 + mi*16 + lg*4 + r;
                float v;
                if (SCALE) v = fmaf(alpha, acc[mi][ni][r], bn[ni]);
                else       v = acc[mi][ni][r] + bn[ni];
                if (GELU) v = gelu_f(v);
                Cout[(size_t)row*256 + w*64 + ni*16 + lr] = v;
            }
}

// ---------------------------------------------------------------------------
// split6 GEMM (enc3 variant): identical math, epilogue writes the 3 exact
// bf16 split planes of z plus per-row ||z||^2 (no f32 z output).
// ---------------------------------------------------------------------------
__global__ __launch_bounds__(256, 3) void split6_zout(
    const float* __restrict__ Ain,
    const ushort* __restrict__ W0, const ushort* __restrict__ W1,
    const ushort* __restrict__ W2,
    const float* __restrict__ bias,
    ushort* __restrict__ zb0, ushort* __restrict__ zb1, ushort* __restrict__ zb2,
    float* __restrict__ zz_out)
{
    __shared__ __align__(16) ushort Al[3][64][40];
    __shared__ __align__(16) ushort Wl[256][40];
    __shared__ float zs[64][4];

    const int tid = threadIdx.x;
    const int m0 = blockIdx.x * 64;
    const int arow = tid >> 2, q = tid & 3;
    const int lane = tid & 63;
    const int w = tid >> 6;
    const int lr = lane & 15, lg = lane >> 4;

    const float* asrc = Ain + (size_t)(m0 + arow)*256 + q*8;
    const ushort* wsrc  = W0 + (size_t)tid*256;
    const ushort* w1frag = W1 + (size_t)(w*64 + lr)*256 + lg*8;
    const ushort* w2frag = W2 + (size_t)(w*64 + lr)*256 + lg*8;

    f32x4 acc[4][4];
    #pragma unroll
    for (int mi=0;mi<4;++mi)
        #pragma unroll
        for (int ni=0;ni<4;++ni)
            acc[mi][ni] = (f32x4){0.f,0.f,0.f,0.f};

    for (int k0=0; k0<256; k0+=32){
        float x[8];
        *(float4*)&x[0] = *(const float4*)(asrc + k0);
        *(float4*)&x[4] = *(const float4*)(asrc + k0 + 4);
        ushort t0[8], t1[8], t2[8];
        #pragma unroll
        for (int e=0;e<8;++e) split3(x[e], t0[e], t1[e], t2[e]);
        *(uint4*)&Al[0][arow][q*8] = *(const uint4*)t0;
        *(uint4*)&Al[1][arow][q*8] = *(const uint4*)t1;
        *(uint4*)&Al[2][arow][q*8] = *(const uint4*)t2;
        *(uint4*)&Wl[tid][0]  = *(const uint4*)(wsrc + k0);
        *(uint4*)&Wl[tid][8]  = *(const uint4*)(wsrc + k0 + 8);
        *(uint4*)&Wl[tid][16] = *(const uint4*)(wsrc + k0 + 16);
        *(uint4*)&Wl[tid][24] = *(const uint4*)(wsrc + k0 + 24);
        short8 b1v[4], b2v[4];
        #pragma unroll
        for (int ni=0;ni<4;++ni){
            b1v[ni] = *(const short8*)(w1frag + (size_t)ni*16*256 + k0);
            b2v[ni] = *(const short8*)(w2frag + (size_t)ni*16*256 + k0);
        }
        __syncthreads();

        short8 b0v[4];
        #pragma unroll
        for (int ni=0;ni<4;++ni)
            b0v[ni] = *(const short8*)&Wl[w*64 + ni*16 + lr][lg*8];
        #pragma unroll
        for (int mi=0;mi<4;++mi){
            short8 a0 = *(const short8*)&Al[0][mi*16 + lr][lg*8];
            short8 a1 = *(const short8*)&Al[1][mi*16 + lr][lg*8];
            short8 a2 = *(const short8*)&Al[2][mi*16 + lr][lg*8];
            #pragma unroll
            for (int ni=0;ni<4;++ni)
                acc[mi][ni] = __builtin_amdgcn_mfma_f32_16x16x32_bf16(a0, b0v[ni], acc[mi][ni], 0,0,0);
            #pragma unroll
            for (int ni=0;ni<4;++ni)
                acc[mi][ni] = __builtin_amdgcn_mfma_f32_16x16x32_bf16(a0, b1v[ni], acc[mi][ni], 0,0,0);
            #pragma unroll
            for (int ni=0;ni<4;++ni)
                acc[mi][ni] = __builtin_amdgcn_mfma_f32_16x16x32_bf16(a1, b0v[ni], acc[mi][ni], 0,0,0);
            #pragma unroll
            for (int ni=0;ni<4;++ni)
                acc[mi][ni] = __builtin_amdgcn_mfma_f32_16x16x32_bf16(a0, b2v[ni], acc[mi][ni], 0,0,0);
            #pragma unroll
            for (int ni=0;ni<4;++ni)
                acc[mi][ni] = __builtin_amdgcn_mfma_f32_16x16x32_bf16(a1, b1v[ni], acc[mi][ni], 0,0,0);
            #pragma unroll
            for (int ni=0;ni<4;++ni)
                acc[mi][ni] = __builtin_amdgcn_mfma_f32_16x16x32_bf16(a2, b0v[ni], acc[mi][ni], 0,0,0);
        }
        __syncthreads();
    }

    float bn[4];
    #pragma unroll
    for (int ni=0;ni<4;++ni) bn[ni] = bias[w*64 + ni*16 + lr];
    #pragma unroll
    for (int mi=0;mi<4;++mi)
        #pragma unroll
        for (int r=0;r<4;++r){
            int row = m0 + mi*16 + lg*4 + r;
            float p = 0.0f;
            #pragma unroll
            for (int ni=0;ni<4;++ni){
                float v = acc[mi][ni][r] + bn[ni];
                p = fmaf(v, v, p);
                ushort s0, s1, s2;
                split3(v, s0, s1, s2);
                size_t off = (size_t)row*256 + w*64 + ni*16 + lr;
                zb0[off] = s0; zb1[off] = s1; zb2[off] = s2;
            }
            p += __shfl_xor(p, 1); p += __shfl_xor(p, 2);
            p += __shfl_xor(p, 4); p += __shfl_xor(p, 8);
            if (lr == 0) zs[mi*16 + lg*4 + r][w] = p;
        }
    __syncthreads();
    if (tid < 64)
        zz_out[m0 + tid] = zs[tid][0] + zs[tid][1] + zs[tid][2] + zs[tid][3];
}

#define INSERT1(dv, iv) do { \
    float _d = (dv); int _i = (iv); \
    if (_d < bd || (_d == bd && _i < bi)){ bd = _d; bi = _i; } \
} while(0)

// ---------------------------------------------------------------------------
// EXACT distance pass (fallback path when ws is small).
// ---------------------------------------------------------------------------
__global__ __launch_bounds__(256, 3) void tokens_split6(
    const float* __restrict__ Zf,
    const ushort* __restrict__ C0, const ushort* __restrict__ C1,
    const ushort* __restrict__ C2,
    const float* __restrict__ cn,
    float2* __restrict__ partials,
    float* __restrict__ zz_out)
{
    __shared__ __align__(16) ushort Al[3][128][40];
    __shared__ __align__(16) ushort Wl[2][128][40];
    __shared__ float2 ptop[128][2];

    const int tid = threadIdx.x;
    const int m0 = blockIdx.x * 128;
    const int n0 = blockIdx.y * 128;
    const int srow = tid >> 1, shalf = (tid & 1) * 16;
    const int lane = tid & 63;
    const int w = tid >> 6;
    const int wm = (w >> 1) * 64, wn = (w & 1) * 64;
    const int lr = lane & 15, lg = lane >> 4;

    const float*  asrc = Zf + (size_t)(m0 + srow)*256 + shalf;
    const ushort* ws0  = C0 + (size_t)(n0 + srow)*256 + shalf;
    const ushort* ws1  = C1 + (size_t)(n0 + srow)*256 + shalf;
    const ushort* c2frag = C2 + (size_t)(n0 + wn + lr)*256 + lg*8;

    f32x4 acc[4][4];
    #pragma unroll
    for (int mi=0;mi<4;++mi)
        #pragma unroll
        for (int ni=0;ni<4;++ni)
            acc[mi][ni] = (f32x4){0.f,0.f,0.f,0.f};

    float zzp = 0.0f;

    for (int k0=0; k0<256; k0+=32){
        float x[16];
        *(float4*)&x[0]  = *(const float4*)(asrc + k0);
        *(float4*)&x[4]  = *(const float4*)(asrc + k0 + 4);
        *(float4*)&x[8]  = *(const float4*)(asrc + k0 + 8);
        *(float4*)&x[12] = *(const float4*)(asrc + k0 + 12);
        ushort t0[16], t1[16], t2[16];
        #pragma unroll
        for (int e=0;e<16;++e){
            split3(x[e], t0[e], t1[e], t2[e]);
            zzp = fmaf(x[e], x[e], zzp);
        }
        *(uint4*)&Al[0][srow][shalf]   = *(const uint4*)&t0[0];
        *(uint4*)&Al[0][srow][shalf+8] = *(const uint4*)&t0[8];
        *(uint4*)&Al[1][srow][shalf]   = *(const uint4*)&t1[0];
        *(uint4*)&Al[1][srow][shalf+8] = *(const uint4*)&t1[8];
        *(uint4*)&Al[2][srow][shalf]   = *(const uint4*)&t2[0];
        *(uint4*)&Al[2][srow][shalf+8] = *(const uint4*)&t2[8];
        *(uint4*)&Wl[0][srow][shalf]   = *(const uint4*)(ws0 + k0);
        *(uint4*)&Wl[0][srow][shalf+8] = *(const uint4*)(ws0 + k0 + 8);
        *(uint4*)&Wl[1][srow][shalf]   = *(const uint4*)(ws1 + k0);
        *(uint4*)&Wl[1][srow][shalf+8] = *(const uint4*)(ws1 + k0 + 8);
        short8 b2[4];
        #pragma unroll
        for (int ni=0;ni<4;++ni)
            b2[ni] = *(const short8*)(c2frag + (size_t)ni*16*256 + k0);
        __syncthreads();

        short8 b0[4], b1[4];
        #pragma unroll
        for (int ni=0;ni<4;++ni){
            b0[ni] = *(const short8*)&Wl[0][wn + ni*16 + lr][lg*8];
            b1[ni] = *(const short8*)&Wl[1][wn + ni*16 + lr][lg*8];
        }
        #pragma unroll
        for (int mi=0;mi<4;++mi){
            short8 a0 = *(const short8*)&Al[0][wm + mi*16 + lr][lg*8];
            short8 a1 = *(const short8*)&Al[1][wm + mi*16 + lr][lg*8];
            short8 a2 = *(const short8*)&Al[2][wm + mi*16 + lr][lg*8];
            #pragma unroll
            for (int ni=0;ni<4;++ni)
                acc[mi][ni] = __builtin_amdgcn_mfma_f32_16x16x32_bf16(a0, b0[ni], acc[mi][ni], 0,0,0);
            #pragma unroll
            for (int ni=0;ni<4;++ni)
                acc[mi][ni] = __builtin_amdgcn_mfma_f32_16x16x32_bf16(a0, b1[ni], acc[mi][ni], 0,0,0);
            #pragma unroll
            for (int ni=0;ni<4;++ni)
                acc[mi][ni] = __builtin_amdgcn_mfma_f32_16x16x32_bf16(a1, b0[ni], acc[mi][ni], 0,0,0);
            #pragma unroll
            for (int ni=0;ni<4;++ni)
                acc[mi][ni] = __builtin_amdgcn_mfma_f32_16x16x32_bf16(a0, b2[ni], acc[mi][ni], 0,0,0);
            #pragma unroll
            for (int ni=0;ni<4;++ni)
                acc[mi][ni] = __builtin_amdgcn_mfma_f32_16x16x32_bf16(a1, b1[ni], acc[mi][ni], 0,0,0);
            #pragma unroll
            for (int ni=0;ni<4;++ni)
                acc[mi][ni] = __builtin_amdgcn_mfma_f32_16x16x32_bf16(a2, b0[ni], acc[mi][ni], 0,0,0);
        }
        __syncthreads();
    }

    {
        float other = __shfl_xor(zzp, 1);
        if (blockIdx.y == 0 && (tid & 1) == 0)
            zz_out[m0 + srow] = zzp + other;
    }

    float cnl[4];
    #pragma unroll
    for (int ni=0;ni<4;++ni) cnl[ni] = cn[n0 + wn + ni*16 + lr];

    #pragma unroll
    for (int mi=0;mi<4;++mi)
        #pragma unroll
        for (int r=0;r<4;++r){
            float bd = FLT_MAX; int bi = INT_MAX;
            #pragma unroll
            for (int ni=0;ni<4;++ni){
                float d = cnl[ni] - 2.0f*acc[mi][ni][r];
                int col = n0 + wn + ni*16 + lr;
                INSERT1(d, col);
            }
            #pragma unroll
            for (int m=1; m<16; m<<=1){
                float od = __shfl_xor(bd, m);
                int   oi = __shfl_xor(bi, m);
                INSERT1(od, oi);
            }
            if (lr == 0)
                ptop[wm + mi*16 + lg*4 + r][w & 1] = make_float2(bd, (float)bi);
        }
    __syncthreads();
    if (tid < 128){
        float2 hA = ptop[tid][0], hB = ptop[tid][1];
        int   gA = (int)hA.y, gB = (int)hB.y;
        bool takeB = (hB.x < hA.x) || (hB.x == hA.x && gB < gA);
        partials[(size_t)(m0 + tid)*4 + blockIdx.y] = takeB ? hB : hA;
    }
}

// ---------------------------------------------------------------------------
// EXACT distance pass from PRE-SPLIT z planes (no split3, no zz).
// Identical MFMA sequence -> bitwise identical distances.
// ---------------------------------------------------------------------------
__global__ __launch_bounds__(256, 3) void tokens_split6_pp(
    const ushort* __restrict__ Z0, const ushort* __restrict__ Z1,
    const ushort* __restrict__ Z2,
    const ushort* __restrict__ C0, const ushort* __restrict__ C1,
    const ushort* __restrict__ C2,
    const float* __restrict__ cn,
    float2* __restrict__ partials)
{
    __shared__ __align__(16) ushort Al[3][128][40];
    __shared__ __align__(16) ushort Wl[2][128][40];
    __shared__ float2 ptop[128][2];

    const int tid = threadIdx.x;
    const int m0 = blockIdx.x * 128;
    const int n0 = blockIdx.y * 128;
    const int srow = tid >> 1, shalf = (tid & 1) * 16;
    const int lane = tid & 63;
    const int w = tid >> 6;
    const int wm = (w >> 1) * 64, wn = (w & 1) * 64;
    const int lr = lane & 15, lg = lane >> 4;

    const size_t arow_off = (size_t)(m0 + srow)*256 + shalf;
    const ushort* ws0  = C0 + (size_t)(n0 + srow)*256 + shalf;
    const ushort* ws1  = C1 + (size_t)(n0 + srow)*256 + shalf;
    const ushort* c2frag = C2 + (size_t)(n0 + wn + lr)*256 + lg*8;

    f32x4 acc[4][4];
    #pragma unroll
    for (int mi=0;mi<4;++mi)
        #pragma unroll
        for (int ni=0;ni<4;++ni)
            acc[mi][ni] = (f32x4){0.f,0.f,0.f,0.f};

    for (int k0=0; k0<256; k0+=32){
        *(uint4*)&Al[0][srow][shalf]   = *(const uint4*)(Z0 + arow_off + k0);
        *(uint4*)&Al[0][srow][shalf+8] = *(const uint4*)(Z0 + arow_off + k0 + 8);
        *(uint4*)&Al[1][srow][shalf]   = *(const uint4*)(Z1 + arow_off + k0);
        *(uint4*)&Al[1][srow][shalf+8] = *(const uint4*)(Z1 + arow_off + k0 + 8);
        *(uint4*)&Al[2][srow][shalf]   = *(const uint4*)(Z2 + arow_off + k0);
        *(uint4*)&Al[2][srow][shalf+8] = *(const uint4*)(Z2 + arow_off + k0 + 8);
        *(uint4*)&Wl[0][srow][shalf]   = *(const uint4*)(ws0 + k0);
        *(uint4*)&Wl[0][srow][shalf+8] = *(const uint4*)(ws0 + k0 + 8);
        *(uint4*)&Wl[1][srow][shalf]   = *(const uint4*)(ws1 + k0);
        *(uint4*)&Wl[1][srow][shalf+8] = *(const uint4*)(ws1 + k0 + 8);
        short8 b2[4];
        #pragma unroll
        for (int ni=0;ni<4;++ni)
            b2[ni] = *(const short8*)(c2frag + (size_t)ni*16*256 + k0);
        __syncthreads();

        short8 b0[4], b1[4];
        #pragma unroll
        for (int ni=0;ni<4;++ni){
            b0[ni] = *(const short8*)&Wl[0][wn + ni*16 + lr][lg*8];
            b1[ni] = *(const short8*)&Wl[1][wn + ni*16 + lr][lg*8];
        }
        #pragma unroll
        for (int mi=0;mi<4;++mi){
            short8 a0 = *(const short8*)&Al[0][wm + mi*16 + lr][lg*8];
            short8 a1 = *(const short8*)&Al[1][wm + mi*16 + lr][lg*8];
            short8 a2 = *(const short8*)&Al[2][wm + mi*16 + lr][lg*8];
            #pragma unroll
            for (int ni=0;ni<4;++ni)
                acc[mi][ni] = __builtin_amdgcn_mfma_f32_16x16x32_bf16(a0, b0[ni], acc[mi][ni], 0,0,0);
            #pragma unroll
            for (int ni=0;ni<4;++ni)
                acc[mi][ni] = __builtin_amdgcn_mfma_f32_16x16x32_bf16(a0, b1[ni], acc[mi][ni], 0,0,0);
            #pragma unroll
            for (int ni=0;ni<4;++ni)
                acc[mi][ni] = __builtin_amdgcn_mfma_f32_16x16x32_bf16(a1, b0[ni], acc[mi][ni], 0,0,0);
            #pragma unroll
            for (int ni=0;ni<4;++ni)
                acc[mi][ni] = __builtin_amdgcn_mfma_f32_16x16x32_bf16(a0, b2[ni], acc[mi][ni], 0,0,0);
            #pragma unroll
            for (int ni=0;ni<4;++ni)
                acc[mi][ni] = __builtin_amdgcn_mfma_f32_16x16x32_bf16(a1, b1[ni], acc[mi][ni], 0,0,0);
            #pragma unroll
            for (int ni=0;ni<4;++ni)
                acc[mi][ni] = __builtin_amdgcn_mfma_f32_16x16x32_bf16(a2, b0[ni], acc[mi][ni], 0,0,0);
        }
        __syncthreads();
    }

    float cnl[4];
    #pragma unroll
    for (int ni=0;ni<4;++ni) cnl[ni] = cn[n0 + wn + ni*16 + lr];

    #pragma unroll
    for (int mi=0;mi<4;++mi)
        #pragma unroll
        for (int r=0;r<4;++r){
            float bd = FLT_MAX; int bi = INT_MAX;
            #pragma unroll
            for (int ni=0;ni<4;++ni){
                float d = cnl[ni] - 2.0f*acc[mi][ni][r];
                int col = n0 + wn + ni*16 + lr;
                INSERT1(d, col);
            }
            #pragma unroll
            for (int m=1; m<16; m<<=1){
                float od = __shfl_xor(bd, m);
                int   oi = __shfl_xor(bi, m);
                INSERT1(od, oi);
            }
            if (lr == 0)
                ptop[wm + mi*16 + lg*4 + r][w & 1] = make_float2(bd, (float)bi);
        }
    __syncthreads();
    if (tid < 128){
        float2 hA = ptop[tid][0], hB = ptop[tid][1];
        int   gA = (int)hA.y, gB = (int)hB.y;
        bool takeB = (hB.x < hA.x) || (hB.x == hA.x && gB < gA);
        partials[(size_t)(m0 + tid)*4 + blockIdx.y] = takeB ? hB : hA;
    }
}

// ---------------------------------------------------------------------------
// Token + commitment: min over 4 (d,idx) partials, zz from zz_out.
// ---------------------------------------------------------------------------
__global__ __launch_bounds__(256) void token_reduce(
    const float* __restrict__ zz_out, const float2* __restrict__ partials,
    float* __restrict__ tokf, float* __restrict__ loss)
{
    const int tid = threadIdx.x;
    const int row = blockIdx.x*256 + tid;
    float2 p0 = partials[(size_t)row*4 + 0];
    float2 p1 = partials[(size_t)row*4 + 1];
    float2 p2 = partials[(size_t)row*4 + 2];
    float2 p3 = partials[(size_t)row*4 + 3];
    float d = p0.x; int g = (int)p0.y;
    if (p1.x < d || (p1.x == d && (int)p1.y < g)){ d = p1.x; g = (int)p1.y; }
    if (p2.x < d || (p2.x == d && (int)p2.y < g)){ d = p2.x; g = (int)p2.y; }
    if (p3.x < d || (p3.x == d && (int)p3.y < g)){ d = p3.x; g = (int)p3.y; }
    tokf[row] = (float)g;
    float cs = zz_out[row] + d;
    #pragma unroll
    for (int m=1; m<64; m<<=1) cs += __shfl_xor(cs, m);
    __shared__ float wsum[4];
    const int lane = tid & 63, w = tid >> 6;
    if (lane == 0) wsum[w] = cs;
    __syncthreads();
    if (tid == 0) atomicAdd(loss + 1, wsum[0]+wsum[1]+wsum[2]+wsum[3]);
}

// ---------------------------------------------------------------------------
// bf16 MFMA GEMM (decoder tables): Y[M,256] = gelu(A @ W^T + b), M=512.
// ---------------------------------------------------------------------------
__global__ __launch_bounds__(256) void mfma_gemm(
    const ushort* __restrict__ Abf,
    const ushort* __restrict__ Wbf,
    const float* __restrict__ bias,
    ushort* __restrict__ Ybf)
{
    __shared__ __align__(16) ushort Al[128][40];
    __shared__ __align__(16) ushort Wl[128][40];

    const int tid = threadIdx.x;
    const int m0 = blockIdx.x * 128;
    const int n0 = blockIdx.y * 128;
    const int srow = tid >> 1, shalf = (tid & 1) * 16;
    const int lane = tid & 63;
    const int w = tid >> 6;
    const int wm = (w >> 1) * 64, wn = (w & 1) * 64;
    const int lr = lane & 15, lg = lane >> 4;

    const ushort* asrc = Abf + (size_t)(m0 + srow)*256 + shalf;
    const ushort* wsrc = Wbf + (size_t)(n0 + srow)*256 + shalf;

    f32x4 acc[4][4];
    #pragma unroll
    for (int mi=0;mi<4;++mi)
        #pragma unroll
        for (int ni=0;ni<4;++ni)
            acc[mi][ni] = (f32x4){0.f,0.f,0.f,0.f};

    for (int k0=0; k0<256; k0+=32){
        *(uint4*)&Al[srow][shalf]   = *(const uint4*)(asrc + k0);
        *(uint4*)&Al[srow][shalf+8] = *(const uint4*)(asrc + k0 + 8);
        *(uint4*)&Wl[srow][shalf]   = *(const uint4*)(wsrc + k0);
        *(uint4*)&Wl[srow][shalf+8] = *(const uint4*)(wsrc + k0 + 8);
        __syncthreads();

        short8 af[4], bfr[4];
        #pragma unroll
        for (int mi=0;mi<4;++mi)
            af[mi] = *(const short8*)&Al[wm + mi*16 + lr][lg*8];
        #pragma unroll
        for (int ni=0;ni<4;++ni)
            bfr[ni] = *(const short8*)&Wl[wn + ni*16 + lr][lg*8];
        #pragma unroll
        for (int mi=0;mi<4;++mi)
            #pragma unroll
            for (int ni=0;ni<4;++ni)
                acc[mi][ni] = __builtin_amdgcn_mfma_f32_16x16x32_bf16(
                    af[mi], bfr[ni], acc[mi][ni], 0, 0, 0);
        __syncthreads();
    }

    float bn[4];
    #pragma unroll
    for (int ni=0;ni<4;++ni) bn[ni] = bias[n0 + wn + ni*16 + lr];
    #pragma unroll
    for (int mi=0;mi<4;++mi)
        #pragma unroll
        for (int ni=0;ni<4;++ni)
            #pragma unroll
            for (int r=0;r<4;++r){
                int row = m0 + wm + mi*16 + lg*4 + r;
                float v = acc[mi][ni][r] + bn[ni];
                v = gelu_f(v);
                Ybf[(size_t)row*256 + n0 + wn + ni*16 + lr] = f2bf(v);
            }
}

// ---------------------------------------------------------------------------
// dec3 table: R[512][48] = L2 @ W3^T + b3 (W3 converted in-kernel).
// ---------------------------------------------------------------------------
__global__ __launch_bounds__(256) void dec3_table(
    const ushort* __restrict__ Ain, const float* __restrict__ W,
    const float* __restrict__ bias, float* __restrict__ Rt)
{
    __shared__ __align__(16) ushort Al[256][40];
    __shared__ __align__(16) ushort Wl[48][40];

    const int tid = threadIdx.x;
    const int m0 = blockIdx.x * 256;
    const int lane = tid & 63;
    const int w = tid >> 6;
    const int lr = lane & 15, lg = lane >> 4;

    const ushort* asrc = Ain + (size_t)(m0 + tid)*256;

    f32x4 acc[4][3];
    #pragma unroll
    for (int mi=0;mi<4;++mi)
        #pragma unroll
        for (int ni=0;ni<3;++ni)
            acc[mi][ni] = (f32x4){0.f,0.f,0.f,0.f};

    for (int k0=0; k0<256; k0+=32){
        *(uint4*)&Al[tid][0]  = *(const uint4*)(asrc + k0);
        *(uint4*)&Al[tid][8]  = *(const uint4*)(asrc + k0 + 8);
        *(uint4*)&Al[tid][16] = *(const uint4*)(asrc + k0 + 16);
        *(uint4*)&Al[tid][24] = *(const uint4*)(asrc + k0 + 24);
        if (tid < 96){
            const int wrow = tid >> 1, wh = (tid & 1)*16;
            const float* wp = W + (size_t)wrow*256 + k0 + wh;
            float4 f0 = *(const float4*)(wp);
            float4 f1 = *(const float4*)(wp+4);
            float4 f2 = *(const float4*)(wp+8);
            float4 f3 = *(const float4*)(wp+12);
            ushort t[16];
            t[0]=f2bf(f0.x); t[1]=f2bf(f0.y); t[2]=f2bf(f0.z); t[3]=f2bf(f0.w);
            t[4]=f2bf(f1.x); t[5]=f2bf(f1.y); t[6]=f2bf(f1.z); t[7]=f2bf(f1.w);
            t[8]=f2bf(f2.x); t[9]=f2bf(f2.y); t[10]=f2bf(f2.z); t[11]=f2bf(f2.w);
            t[12]=f2bf(f3.x); t[13]=f2bf(f3.y); t[14]=f2bf(f3.z); t[15]=f2bf(f3.w);
            *(uint4*)&Wl[wrow][wh]   = *(const uint4*)&t[0];
            *(uint4*)&Wl[wrow][wh+8] = *(const uint4*)&t[8];
        }
        __syncthreads();

        short8 bfr[3];
        #pragma unroll
        for (int ni=0;ni<3;++ni)
            bfr[ni] = *(const short8*)&Wl[ni*16 + lr][lg*8];
        #pragma unroll
        for (int mi=0;mi<4;++mi){
            short8 af = *(const short8*)&Al[w*64 + mi*16 + lr][lg*8];
            #pragma unroll
            for (int ni=0;ni<3;++ni)
                acc[mi][ni] = __builtin_amdgcn_mfma_f32_16x16x32_bf16(
                    af, bfr[ni], acc[mi][ni], 0, 0, 0);
        }
        __syncthreads();
    }

    #pragma unroll
    for (int ni=0;ni<3;++ni){
        const int col = ni*16 + lr;
        const float bn = bias[col];
        #pragma unroll
        for (int mi=0;mi<4;++mi)
            #pragma unroll
            for (int r=0;r<4;++r){
                int row = m0 + w*64 + mi*16 + lg*4 + r;
                Rt[row*48 + col] = acc[mi][ni][r] + bn;
            }
    }
}

// ---------------------------------------------------------------------------
// gather + unpatchify + recon loss: recon = unpatchify(R[tokens]).
// ---------------------------------------------------------------------------
__global__ __launch_bounds__(256) void gather_recon(
    const float* __restrict__ Rt, const float* __restrict__ tokf,
    const float* __restrict__ frames, float* __restrict__ recon,
    float* __restrict__ loss)
{
    const int tid = threadIdx.x;
    const int idx = blockIdx.x*256 + tid;
    const int p = idx >> 2, ph = idx & 3;
    const int g = (int)tokf[p];
    int b = p >> 12, nl = p & 4095, hh = nl >> 6, ww = nl & 63;
    size_t base = (size_t)(((b*256 + hh*4 + ph)*256 + ww*4)*3);
    const float* rp = Rt + g*48 + ph*12;
    const float sc = 2.0f/255.0f;
    float ls = 0.0f;
    #pragma unroll
    for (int j=0;j<3;++j){
        float4 y = *(const float4*)(rp + j*4);
        float4 f = *(const float4*)(frames + base + j*4);
        float t0=f.x*sc-1.0f, t1=f.y*sc-1.0f, t2=f.z*sc-1.0f, t3=f.w*sc-1.0f;
        float d0=y.x-t0, d1=y.y-t1, d2=y.z-t2, d3=y.w-t3;
        ls += d0*d0 + d1*d1 + d2*d2 + d3*d3;
        *(float4*)(recon + base + j*4) = y;
    }
    #pragma unroll
    for (int off=32; off>0; off>>=1) ls += __shfl_down(ls, off);
    __shared__ float wsum[4];
    int lane = tid & 63, w = tid >> 6;
    if (lane == 0) wsum[w] = ls;
    __syncthreads();
    if (tid == 0) atomicAdd(loss + 0, wsum[0]+wsum[1]+wsum[2]+wsum[3]);
}

__global__ void finalize_kernel(float* __restrict__ loss){
    if (threadIdx.x == 0 && blockIdx.x == 0){
        loss[0] = loss[0] * (1.0f/6291456.0f);
        float c = loss[1] * (1.0f/33554432.0f);
        loss[1] = c;
        loss[2] = c;
    }
}

extern "C" void kernel_launch(void* const* d_in, const int* in_sizes, int n_in,
                              void* d_out, int out_size, void* d_ws, size_t ws_size,
                              hipStream_t stream)
{
    (void)in_sizes; (void)n_in; (void)out_size;
    const float* frames   = (const float*)d_in[0];
    const float* enc_w1   = (const float*)d_in[1];
    const float* enc_b1   = (const float*)d_in[2];
    const float* enc_w2   = (const float*)d_in[3];
    const float* enc_b2   = (const float*)d_in[4];
    const float* enc_w3   = (const float*)d_in[5];
    const float* enc_b3   = (const float*)d_in[6];
    const float* codebook = (const float*)d_in[7];
    const float* dec_w1   = (const float*)d_in[8];
    const float* dec_b1   = (const float*)d_in[9];
    const float* dec_w2   = (const float*)d_in[10];
    const float* dec_b2   = (const float*)d_in[11];
    const float* dec_w3   = (const float*)d_in[12];
    const float* dec_b3   = (const float*)d_in[13];

    float* P = (float*)d_ws;                 // h1 -> (z f32 | zb0/zb1 planes | tables)
    float* Q = P + (size_t)33554432;         // h2
    float2* partials = (float2*)(Q + 18000000);  // 8 MB, in dead-h2 zone
    ushort* L1 = (ushort*)P;                 // 512x256 bf16 (after tokens)
    ushort* L2 = (ushort*)(P + 65536);
    float*  Rt = P + 131072;
    // plane layout (pp path): zb0/zb1 reuse P (h1 dead after enc2);
    // zb2 is the ONLY allocation beyond the proven 256 MiB.
    const size_t MiB256 = (size_t)268435456;
    ushort* zb0 = (ushort*)P;                       // 67 MB
    ushort* zb1 = zb0 + (size_t)T_ROWS*256;         // 67 MB (P is exactly 134 MB)
    ushort* zb2 = (ushort*)((char*)d_ws + MiB256);  // 67 MB beyond 256 MiB
    const size_t need = MiB256 + (size_t)T_ROWS*256*2;  // 335.5 MB
    const bool big_ws = (ws_size >= need);

    float* recon = (float*)d_out;
    float* tokf  = recon + 6291456;
    float* loss  = tokf + 131072;
    float*  cn   = recon;
    ushort* cbb  = (ushort*)(recon + 512);
    ushort* w1b  = (ushort*)(recon + 66048);
    ushort* w2b  = (ushort*)(recon + 98816);
    ushort* w2s0 = (ushort*)(recon + 131584);
    ushort* w2s1 = (ushort*)(recon + 164352);
    ushort* w2s2 = (ushort*)(recon + 197120);
    ushort* w3s0 = (ushort*)(recon + 229888);
    ushort* w3s1 = (ushort*)(recon + 262656);
    ushort* w3s2 = (ushort*)(recon + 295424);
    ushort* cbs0 = (ushort*)(recon + 328192);
    ushort* cbs1 = (ushort*)(recon + 393728);
    ushort* cbs2 = (ushort*)(recon + 459264);
    float*  zzb  = recon + 524800;
    ushort* w1p0 = (ushort*)(recon + 655872);
    ushort* w1p1 = (ushort*)(recon + 664064);
    ushort* w1p2 = (ushort*)(recon + 672256);
    float*  bias2 = recon + 680448;

    hipMemsetAsync(loss, 0, 3*sizeof(float), stream);

    dim3 blk(256);
    prep_kernel<<<dim3(209), blk, 0, stream>>>(enc_w2, enc_w3, dec_w1, dec_w2,
        enc_w1, enc_b1, codebook,
        w2s0, w2s1, w2s2, w3s0, w3s1, w3s2, w1b, w2b,
        cn, cbb, cbs0, cbs1, cbs2, w1p0, w1p1, w1p2, bias2);
    // encoder layers 1-2
    split6_gemm<64,  true, 1, true ><<<dim3(T_ROWS/64), blk, 0, stream>>>(nullptr, frames, w1p0, w1p1, w1p2, bias2, P);
    split6_gemm<256, true, 0, false><<<dim3(T_ROWS/64), blk, 0, stream>>>(P, nullptr, w2s0, w2s1, w2s2, enc_b2, Q);
    if (big_ws){
        // enc3 emits exact bf16 split planes (zb0/zb1 into dead P, zb2 extra)
        split6_zout<<<dim3(T_ROWS/64), blk, 0, stream>>>(Q, w3s0, w3s1, w3s2, enc_b3, zb0, zb1, zb2, zzb);
        tokens_split6_pp<<<dim3(T_ROWS/128, 4), blk, 0, stream>>>(zb0, zb1, zb2, cbs0, cbs1, cbs2, cn, partials);
    } else {
        split6_gemm<256, false,0, false><<<dim3(T_ROWS/64), blk, 0, stream>>>(Q, nullptr, w3s0, w3s1, w3s2, enc_b3, P);
        tokens_split6<<<dim3(T_ROWS/128, 4), blk, 0, stream>>>(P, cbs0, cbs1, cbs2, cn, partials, zzb);
    }
    token_reduce<<<dim3(T_ROWS/256), blk, 0, stream>>>(zzb, partials, tokf, loss);
    // decoder: per-code tables, then gather
    mfma_gemm<<<dim3(4, 2), blk, 0, stream>>>(cbb, w1b, dec_b1, L1);
    mfma_gemm<<<dim3(4, 2), blk, 0, stream>>>(L1, w2b, dec_b2, L2);
    dec3_table<<<dim3(2), blk, 0, stream>>>(L2, dec_w3, dec_b3, Rt);
    gather_recon<<<dim3(T_ROWS*4/256), blk, 0, stream>>>(Rt, tokf, frames, recon, loss);
    finalize_kernel<<<dim3(1), dim3(64), 0, stream>>>(loss);
}